// Round 1
// baseline (3288.991 us; speedup 1.0000x reference)
//
#include <hip/hip_runtime.h>
#include <stdint.h>
#include <stddef.h>

#define NTOK 1552
#define DIMM 512
#define IFFC 1365
#define IFF2 2730
#define GSTRIDE 1376   // padded row stride (in bf16 elems) for geglu output, 16B-aligned rows
#define BATCH 2
#define MALL (BATCH*NTOK)   // 3104

typedef unsigned short u16;
typedef __attribute__((ext_vector_type(8))) short bf16x8;
typedef __attribute__((ext_vector_type(4))) float f32x4;

__device__ __forceinline__ u16 f2bf(float f){
  union { float f; uint32_t u; } v; v.f = f;
  uint32_t u = v.u;
  uint32_t r = (u + 0x7FFFu + ((u >> 16) & 1u)) >> 16;
  return (u16)r;
}

// ---------------- LayerNorm: one block per row ----------------
__global__ void ln_kernel(const float* __restrict__ in, const float* __restrict__ g,
                          const float* __restrict__ bta, float* __restrict__ of32,
                          u16* __restrict__ obf, int D)
{
  const int r = blockIdx.x;
  const float* x = in + (size_t)r * D;
  float s = 0.f, ss = 0.f;
  for (int c = threadIdx.x; c < D; c += 256){ float v = x[c]; s += v; ss += v*v; }
  #pragma unroll
  for (int off = 32; off >= 1; off >>= 1){ s += __shfl_xor(s, off); ss += __shfl_xor(ss, off); }
  __shared__ float rs_[4], rss_[4];
  int w = threadIdx.x >> 6;
  if ((threadIdx.x & 63) == 0){ rs_[w] = s; rss_[w] = ss; }
  __syncthreads();
  s = rs_[0] + rs_[1] + rs_[2] + rs_[3];
  ss = rss_[0] + rss_[1] + rss_[2] + rss_[3];
  float mu = s / D;
  float var = ss / D - mu * mu;
  float rstd = rsqrtf(var + 1e-5f);
  for (int c = threadIdx.x; c < D; c += 256){
    float y = (x[c] - mu) * rstd * g[c] + (bta ? bta[c] : 0.f);
    if (of32) of32[(size_t)r*D + c] = y;
    if (obf)  obf[(size_t)r*D + c] = f2bf(y);
  }
}

// ---------------- GEMM: C[M,N] = A[M,K](bf16) @ B[K,N](f32->bf16) (+bias) (+=C) ----------------
__global__ __launch_bounds__(256) void gemm128(
    const u16* __restrict__ A, int lda,
    const float* __restrict__ Bw, int ldb,
    float* __restrict__ C, int ldc,
    const float* __restrict__ bias,
    int M, int Nn, int K, int addC)
{
  __shared__ __align__(16) u16 As[128][40];
  __shared__ __align__(16) u16 Bs[128][40];
  const int t = threadIdx.x;
  const int lane = t & 63;
  const int w = t >> 6;
  const int wr = (w >> 1) * 64, wc = (w & 1) * 64;
  const int row0 = blockIdx.x * 128, col0 = blockIdx.y * 128;
  const int l15 = lane & 15;
  const int l4 = (lane >> 4) * 8;
  f32x4 acc[4][4];
  #pragma unroll
  for (int m = 0; m < 4; ++m)
    #pragma unroll
    for (int n = 0; n < 4; ++n)
      #pragma unroll
      for (int j = 0; j < 4; ++j) acc[m][n][j] = 0.f;

  for (int k0 = 0; k0 < K; k0 += 32) {
    // stage A (128x32 bf16)
    #pragma unroll
    for (int u = 0; u < 2; ++u){
      int id = t + u*256;
      int r = id >> 2, c8 = (id & 3) * 8;
      bf16x8 av;
      #pragma unroll
      for (int j = 0; j < 8; ++j) av[j] = 0;
      int gr = row0 + r;
      if (gr < M){
        if (k0 + c8 + 8 <= K) av = *(const bf16x8*)(A + (size_t)gr*lda + k0 + c8);
        else {
          #pragma unroll
          for (int j = 0; j < 8; ++j){ int k = k0 + c8 + j; if (k < K) av[j] = (short)A[(size_t)gr*lda + k]; }
        }
      }
      *(bf16x8*)(&As[r][c8]) = av;
    }
    // stage B transposed (Bs[col][k]) with f32->bf16 convert
    {
      int col = t & 127, kb = (t >> 7) * 16;
      u16 sh[16];
      #pragma unroll
      for (int i = 0; i < 16; ++i){
        int k = k0 + kb + i;
        float bv = (k < K && (col0 + col) < Nn) ? Bw[(size_t)k*ldb + col0 + col] : 0.f;
        sh[i] = f2bf(bv);
      }
      *(bf16x8*)(&Bs[col][kb])     = *(bf16x8*)(&sh[0]);
      *(bf16x8*)(&Bs[col][kb + 8]) = *(bf16x8*)(&sh[8]);
    }
    __syncthreads();
    bf16x8 af[4], bfr[4];
    #pragma unroll
    for (int m = 0; m < 4; ++m) af[m]  = *(const bf16x8*)(&As[wr + m*16 + l15][l4]);
    #pragma unroll
    for (int n = 0; n < 4; ++n) bfr[n] = *(const bf16x8*)(&Bs[wc + n*16 + l15][l4]);
    #pragma unroll
    for (int m = 0; m < 4; ++m)
      #pragma unroll
      for (int n = 0; n < 4; ++n)
        acc[m][n] = __builtin_amdgcn_mfma_f32_16x16x32_bf16(af[m], bfr[n], acc[m][n], 0, 0, 0);
    __syncthreads();
  }
  const int rb = (lane >> 4) * 4;
  #pragma unroll
  for (int m = 0; m < 4; ++m){
    int gr0 = row0 + wr + m*16 + rb;
    #pragma unroll
    for (int n = 0; n < 4; ++n){
      int gc = col0 + wc + n*16 + l15;
      if (gc >= Nn) continue;
      float bv = bias ? bias[gc] : 0.f;
      #pragma unroll
      for (int j = 0; j < 4; ++j){
        int gr = gr0 + j;
        if (gr < M){
          float vv = acc[m][n][j] + bv;
          if (addC) C[(size_t)gr*ldc + gc] += vv;
          else      C[(size_t)gr*ldc + gc] = vv;
        }
      }
    }
  }
}

// ---------------- copy fusion tokens into tok ----------------
__global__ void fuscopy_kernel(const float* __restrict__ ft, float* __restrict__ tok)
{
  int i = blockIdx.x * 256 + threadIdx.x;
  if (i >= BATCH*16*DIMM) return;
  int c = i & 511; int tt = i >> 9; int b = tt >> 4; int r = tt & 15;
  tok[((size_t)(b*NTOK + 768 + r))*DIMM + c] = ft[r*DIMM + c];
}

// ---------------- column mean of V over all 1552 rows ----------------
__global__ void colmean_kernel(const float* __restrict__ kvv, float* __restrict__ mv)
{
  int c = blockIdx.x * 256 + threadIdx.x;  // 0..511
  int b = blockIdx.y;
  const float* src = kvv + (size_t)b*NTOK*1024 + 512 + c;
  float s = 0.f;
  for (int r = 0; r < NTOK; ++r) s += src[(size_t)r*1024];
  mv[b*DIMM + c] = s * (1.0f/1552.0f);
}

// ---------------- fusion q@k^T (16 queries x 1536 non-fusion keys) ----------------
__global__ void fsim_kernel(const float* __restrict__ kv, const float* __restrict__ qf,
                            float* __restrict__ sim)
{
  int h = blockIdx.x, b = blockIdx.y;
  __shared__ float qs[16][64];
  for (int i = threadIdx.x; i < 16*64; i += 256){
    int q = i >> 6, d = i & 63;
    qs[q][d] = qf[((size_t)(b*16 + q))*DIMM + h*64 + d];
  }
  __syncthreads();
  for (int jj = threadIdx.x; jj < 1536; jj += 256){
    int j = (jj < 768) ? jj : jj + 16;
    const float* kr = kv + ((size_t)(b*NTOK + j))*1024 + h*64;
    float acc[16];
    #pragma unroll
    for (int q = 0; q < 16; ++q) acc[q] = 0.f;
    for (int d4 = 0; d4 < 16; ++d4){
      float4 kd = *(const float4*)(kr + d4*4);
      #pragma unroll
      for (int q = 0; q < 16; ++q)
        acc[q] += qs[q][d4*4+0]*kd.x + qs[q][d4*4+1]*kd.y + qs[q][d4*4+2]*kd.z + qs[q][d4*4+3]*kd.w;
    }
    float* so = sim + ((size_t)(b*8 + h) * 16) * 1536 + jj;
    #pragma unroll
    for (int q = 0; q < 16; ++q) so[(size_t)q*1536] = acc[q] * 0.125f;
  }
}

// ---------------- softmax over 1536 (in place) ----------------
__global__ void softmax_kernel(float* __restrict__ sim)
{
  float* x = sim + (size_t)blockIdx.x * 1536;
  float e[6];
  float m = -3.4e38f;
  #pragma unroll
  for (int i = 0; i < 6; ++i){ e[i] = x[threadIdx.x + i*256]; m = fmaxf(m, e[i]); }
  #pragma unroll
  for (int off = 32; off >= 1; off >>= 1) m = fmaxf(m, __shfl_xor(m, off));
  __shared__ float red[4];
  int w = threadIdx.x >> 6;
  if ((threadIdx.x & 63) == 0) red[w] = m;
  __syncthreads();
  m = fmaxf(fmaxf(red[0], red[1]), fmaxf(red[2], red[3]));
  __syncthreads();
  float s = 0.f;
  #pragma unroll
  for (int i = 0; i < 6; ++i){ e[i] = expf(e[i] - m); s += e[i]; }
  #pragma unroll
  for (int off = 32; off >= 1; off >>= 1) s += __shfl_xor(s, off);
  if ((threadIdx.x & 63) == 0) red[w] = s;
  __syncthreads();
  s = red[0] + red[1] + red[2] + red[3];
  float inv = 1.0f / s;
  #pragma unroll
  for (int i = 0; i < 6; ++i) x[threadIdx.x + i*256] = e[i] * inv;
}

// ---------------- attn @ V for fusion rows ----------------
__global__ void fpv_kernel(const float* __restrict__ kv, const float* __restrict__ sim,
                           float* __restrict__ outf)
{
  int h = blockIdx.x, b = blockIdx.y;
  int d = threadIdx.x & 63, g = threadIdx.x >> 6;  // g: 0..3
  float acc[4] = {0.f, 0.f, 0.f, 0.f};
  const float* sb = sim + ((size_t)(b*8 + h) * 16) * 1536;
  for (int jj = 0; jj < 1536; ++jj){
    int j = (jj < 768) ? jj : jj + 16;
    float vd = kv[((size_t)(b*NTOK + j))*1024 + 512 + h*64 + d];
    #pragma unroll
    for (int q = 0; q < 4; ++q) acc[q] += sb[(size_t)(g*4 + q)*1536 + jj] * vd;
  }
  #pragma unroll
  for (int q = 0; q < 4; ++q)
    outf[((size_t)(b*16 + g*4 + q))*DIMM + h*64 + d] = acc[q];
}

// ---------------- pack [mean_row ; 16 fusion outs] to bf16 for wo-proj ----------------
__global__ void packz_kernel(const float* __restrict__ mv, const float* __restrict__ outf,
                             u16* __restrict__ zb)
{
  int i = blockIdx.x * 256 + threadIdx.x;
  if (i >= BATCH*17*DIMM) return;
  int c = i & 511;
  int tt = i >> 9;         // b*17 + r
  int b = tt / 17, r = tt % 17;
  float v = (r == 0) ? mv[b*DIMM + c] : outf[((size_t)b*16 + (r-1))*DIMM + c];
  zb[i] = f2bf(v);
}

// ---------------- residual scatter-add of attention projection ----------------
__global__ void resadd_kernel(float* __restrict__ tok, const float* __restrict__ proj)
{
  int n = blockIdx.x, b = blockIdx.y;
  int pr = (n >= 768 && n < 784) ? (1 + n - 768) : 0;
  const float* p = proj + ((size_t)b*17 + pr)*DIMM;
  float* tr = tok + ((size_t)(b*NTOK + n))*DIMM;
  for (int c = threadIdx.x; c < DIMM; c += 256) tr[c] += p[c];
}

// ---------------- GEGLU: g = gelu(h[:,1365:]) * h[:,:1365] -> bf16 ----------------
__global__ void geglu_kernel(const float* __restrict__ h, u16* __restrict__ g)
{
  int i = blockIdx.x * 256 + threadIdx.x;
  if (i >= NTOK * IFFC) return;
  int r = i / IFFC, c = i % IFFC;
  float x1 = h[(size_t)r*IFF2 + c];
  float gt = h[(size_t)r*IFF2 + IFFC + c];
  float ge = 0.5f * gt * (1.0f + erff(gt * 0.70710678118654752f));
  g[(size_t)r*GSTRIDE + c] = f2bf(ge * x1);
}

// ---------------- pool: q for return-token 2 (LN + matvec, scaled) ----------------
__global__ void poolq2_kernel(const float* __restrict__ rt, const float* __restrict__ pg,
                              const float* __restrict__ wq, float* __restrict__ q2)
{
  __shared__ float y[DIMM];
  const float* x = rt + 2*DIMM;
  float s = 0.f, ss = 0.f;
  for (int c = threadIdx.x; c < DIMM; c += 256){ float v = x[c]; s += v; ss += v*v; }
  #pragma unroll
  for (int off = 32; off >= 1; off >>= 1){ s += __shfl_xor(s, off); ss += __shfl_xor(ss, off); }
  __shared__ float rs_[4], rss_[4];
  int w = threadIdx.x >> 6;
  if ((threadIdx.x & 63) == 0){ rs_[w] = s; rss_[w] = ss; }
  __syncthreads();
  s = rs_[0] + rs_[1] + rs_[2] + rs_[3];
  ss = rss_[0] + rss_[1] + rss_[2] + rss_[3];
  float mu = s / DIMM;
  float rstd = rsqrtf(ss / DIMM - mu*mu + 1e-5f);
  for (int c = threadIdx.x; c < DIMM; c += 256) y[c] = (x[c] - mu) * rstd * pg[c];
  __syncthreads();
  for (int c = threadIdx.x; c < DIMM; c += 256){
    float a = 0.f;
    for (int k = 0; k < DIMM; ++k) a += y[k] * wq[(size_t)k*DIMM + c];
    q2[c] = a * 0.125f;
  }
}

// ---------------- pool: attention of return-token 2 over the 16 fusion keys ----------------
__global__ void poolattn2_kernel(const float* __restrict__ kv, const float* __restrict__ q2,
                                 float* __restrict__ out2)
{
  int h = blockIdx.x, b = blockIdx.y, d = threadIdx.x;  // block of 64
  __shared__ float sm[16];
  if (d < 16){
    const float* kr = kv + ((size_t)(b*NTOK + 768 + d))*1024 + h*64;
    float a = 0.f;
    for (int k = 0; k < 64; ++k) a += q2[h*64 + k] * kr[k];
    sm[d] = a;
  }
  __syncthreads();
  float m = -3.4e38f;
  #pragma unroll
  for (int j = 0; j < 16; ++j) m = fmaxf(m, sm[j]);
  float wv[16]; float s = 0.f;
  #pragma unroll
  for (int j = 0; j < 16; ++j){ wv[j] = expf(sm[j] - m); s += wv[j]; }
  float inv = 1.0f / s;
  float a = 0.f;
  #pragma unroll
  for (int j = 0; j < 16; ++j)
    a += wv[j] * kv[((size_t)(b*NTOK + 768 + j))*1024 + 512 + h*64 + d];
  out2[(size_t)b*DIMM + h*64 + d] = a * inv;
}

// ---------------- final pooled = po @ pool_wo + return_tokens ----------------
__global__ void pooled_kernel(const float* __restrict__ mvp, const float* __restrict__ out2,
                              const float* __restrict__ wo, const float* __restrict__ rt,
                              float* __restrict__ out)
{
  int br = blockIdx.x;  // b*3 + r, 0..5
  int b = br / 3, r = br % 3;
  __shared__ float po[DIMM];
  const float* src = (r < 2) ? (mvp + (size_t)b*DIMM) : (out2 + (size_t)b*DIMM);
  for (int c = threadIdx.x; c < DIMM; c += 256) po[c] = src[c];
  __syncthreads();
  for (int c = threadIdx.x; c < DIMM; c += 256){
    float a = 0.f;
    for (int k = 0; k < DIMM; ++k) a += po[k] * wo[(size_t)k*DIMM + c];
    out[(size_t)br*DIMM + c] = a + rt[(size_t)r*DIMM + c];
  }
}

// =================================================================
extern "C" void kernel_launch(void* const* d_in, const int* in_sizes, int n_in,
                              void* d_out, int out_size, void* d_ws, size_t ws_size,
                              hipStream_t stream)
{
  const float* rna        = (const float*)d_in[0];
  const float* atac       = (const float*)d_in[1];
  const float* rna_ln1_g  = (const float*)d_in[2];
  const float* rna_ln1_b  = (const float*)d_in[3];
  const float* rna_w      = (const float*)d_in[4];
  const float* rna_b      = (const float*)d_in[5];
  const float* rna_ln2_g  = (const float*)d_in[6];
  const float* rna_ln2_b  = (const float*)d_in[7];
  const float* atac_ln1_g = (const float*)d_in[8];
  const float* atac_ln1_b = (const float*)d_in[9];
  const float* atac_w     = (const float*)d_in[10];
  const float* atac_b     = (const float*)d_in[11];
  const float* atac_ln2_g = (const float*)d_in[12];
  const float* atac_ln2_b = (const float*)d_in[13];
  const float* fusion_tok = (const float*)d_in[14];
  const float* lay_ag     = (const float*)d_in[15];
  const float* lay_wq     = (const float*)d_in[16];
  const float* lay_wkv    = (const float*)d_in[17];
  const float* lay_wo     = (const float*)d_in[18];
  const float* lay_fg     = (const float*)d_in[19];
  const float* lay_w1     = (const float*)d_in[20];
  const float* lay_w2     = (const float*)d_in[21];
  const float* final_g    = (const float*)d_in[22];
  const float* ret_tok    = (const float*)d_in[23];
  const float* pool_g     = (const float*)d_in[24];
  const float* pool_wq    = (const float*)d_in[25];
  const float* pool_wkv   = (const float*)d_in[26];
  const float* pool_wo    = (const float*)d_in[27];

  // workspace carve (all offsets 256B aligned)
  uint8_t* ws = (uint8_t*)d_ws;
  size_t off = 0;
  auto carve = [&](size_t bytes) -> uint8_t* {
    uint8_t* p = ws + off;
    off += (bytes + 255) & ~(size_t)255;
    return p;
  };
  float* tok   = (float*)carve((size_t)MALL * DIMM * 4);        // 6.36 MB
  u16*   xn    = (u16*)  carve((size_t)MALL * DIMM * 2);        // 3.18 MB
  float* kv    = (float*)carve((size_t)MALL * 1024 * 4);        // 12.7 MB
  float* hbuf  = (float*)carve((size_t)NTOK * IFF2 * 4);        // 16.9 MB
  u16*   gbuf  = (u16*)  carve((size_t)NTOK * GSTRIDE * 2);     // 4.27 MB
  u16*   lnbuf = (u16*)  carve((size_t)1536 * 1024 * 2);        // 3.15 MB
  float* sim   = (float*)carve((size_t)BATCH*8*16*1536 * 4);    // 1.57 MB
  float* qfus  = (float*)carve((size_t)BATCH*16*DIMM * 4);
  float* outf  = (float*)carve((size_t)BATCH*16*DIMM * 4);
  u16*   zb    = (u16*)  carve((size_t)BATCH*17*DIMM * 2);
  float* proj  = (float*)carve((size_t)BATCH*17*DIMM * 4);
  float* mv    = (float*)carve((size_t)BATCH*DIMM * 4);
  float* q2    = (float*)carve((size_t)DIMM * 4);
  float* out2  = (float*)carve((size_t)BATCH*DIMM * 4);
  (void)ws_size;

  // ---- embeddings ----
  // RNA: LN1 -> bf16, GEMM(+bias) -> hbuf, LN2 -> tok rows [0,768)
  ln_kernel<<<1536, 256, 0, stream>>>(rna, rna_ln1_g, rna_ln1_b, nullptr, lnbuf, 1024);
  gemm128<<<dim3(12, 4), 256, 0, stream>>>(lnbuf, 1024, rna_w, 512, hbuf, 512, rna_b, 1536, 512, 1024, 0);
  for (int b = 0; b < BATCH; ++b)
    ln_kernel<<<768, 256, 0, stream>>>(hbuf + (size_t)b*768*DIMM, rna_ln2_g, rna_ln2_b,
                                       tok + (size_t)b*NTOK*DIMM, nullptr, 512);
  // ATAC -> tok rows [784,1552)
  ln_kernel<<<1536, 256, 0, stream>>>(atac, atac_ln1_g, atac_ln1_b, nullptr, lnbuf, 1024);
  gemm128<<<dim3(12, 4), 256, 0, stream>>>(lnbuf, 1024, atac_w, 512, hbuf, 512, atac_b, 1536, 512, 1024, 0);
  for (int b = 0; b < BATCH; ++b)
    ln_kernel<<<768, 256, 0, stream>>>(hbuf + (size_t)b*768*DIMM, atac_ln2_g, atac_ln2_b,
                                       tok + ((size_t)b*NTOK + 784)*DIMM, nullptr, 512);
  // fusion tokens -> tok rows [768,784)
  fuscopy_kernel<<<(BATCH*16*DIMM + 255)/256, 256, 0, stream>>>(fusion_tok, tok);

  // ---- transformer layers ----
  for (int l = 0; l < 4; ++l){
    const float* ag  = lay_ag  + (size_t)l*DIMM;
    const float* wq  = lay_wq  + (size_t)l*DIMM*DIMM;
    const float* wkv = lay_wkv + (size_t)l*DIMM*1024;
    const float* wo  = lay_wo  + (size_t)l*DIMM*DIMM;
    const float* fg  = lay_fg  + (size_t)l*DIMM;
    const float* w1  = lay_w1  + (size_t)l*DIMM*IFF2;
    const float* w2  = lay_w2  + (size_t)l*IFFC*DIMM;

    // attention
    ln_kernel<<<MALL, 256, 0, stream>>>(tok, ag, nullptr, nullptr, xn, 512);
    gemm128<<<dim3(25, 8), 256, 0, stream>>>(xn, 512, wkv, 1024, kv, 1024, nullptr, MALL, 1024, 512, 0);
    for (int b = 0; b < BATCH; ++b)
      gemm128<<<dim3(1, 4), 256, 0, stream>>>(xn + ((size_t)b*NTOK + 768)*DIMM, 512, wq, 512,
                                              qfus + (size_t)b*16*DIMM, 512, nullptr, 16, 512, 512, 0);
    colmean_kernel<<<dim3(2, BATCH), 256, 0, stream>>>(kv, mv);
    fsim_kernel<<<dim3(8, BATCH), 256, 0, stream>>>(kv, qfus, sim);
    softmax_kernel<<<BATCH*8*16, 256, 0, stream>>>(sim);
    fpv_kernel<<<dim3(8, BATCH), 256, 0, stream>>>(kv, sim, outf);
    packz_kernel<<<(BATCH*17*DIMM + 255)/256, 256, 0, stream>>>(mv, outf, zb);
    for (int b = 0; b < BATCH; ++b)
      gemm128<<<dim3(1, 4), 256, 0, stream>>>(zb + (size_t)b*17*DIMM, 512, wo, 512,
                                              proj + (size_t)b*17*DIMM, 512, nullptr, 17, 512, 512, 0);
    resadd_kernel<<<dim3(NTOK, BATCH), 256, 0, stream>>>(tok, proj);

    // GEGLU FFN (two row-halves to bound scratch)
    ln_kernel<<<MALL, 256, 0, stream>>>(tok, fg, nullptr, nullptr, xn, 512);
    for (int half = 0; half < 2; ++half){
      gemm128<<<dim3(13, 22), 256, 0, stream>>>(xn + (size_t)half*NTOK*DIMM, 512, w1, IFF2,
                                                hbuf, IFF2, nullptr, NTOK, IFF2, 512, 0);
      geglu_kernel<<<(NTOK*IFFC + 255)/256, 256, 0, stream>>>(hbuf, gbuf);
      gemm128<<<dim3(13, 4), 256, 0, stream>>>(gbuf, GSTRIDE, w2, 512,
                                               tok + (size_t)half*NTOK*DIMM, 512, nullptr, NTOK, 512, IFFC, 1);
    }
  }

  // ---- final LN + pooling ----
  ln_kernel<<<MALL, 256, 0, stream>>>(tok, final_g, nullptr, nullptr, xn, 512);
  gemm128<<<dim3(25, 8), 256, 0, stream>>>(xn, 512, pool_wkv, 1024, kv, 1024, nullptr, MALL, 1024, 512, 0);
  colmean_kernel<<<dim3(2, BATCH), 256, 0, stream>>>(kv, mv);
  poolq2_kernel<<<1, 256, 0, stream>>>(ret_tok, pool_g, pool_wq, q2);
  poolattn2_kernel<<<dim3(8, BATCH), 64, 0, stream>>>(kv, q2, out2);
  pooled_kernel<<<BATCH*3, 256, 0, stream>>>(mv, out2, pool_wo, ret_tok, (float*)d_out);
}

// Round 2
// 2303.046 us; speedup vs baseline: 1.4281x; 1.4281x over previous
//
#include <hip/hip_runtime.h>
#include <stdint.h>
#include <stddef.h>

#define NTOK 1552
#define DIMM 512
#define IFFC 1365
#define IFF2 2730
#define GSTRIDE 1376   // padded row stride (in bf16 elems) for geglu output, 16B-aligned rows
#define BATCH 2
#define MALL (BATCH*NTOK)   // 3104
#define FPV_Z 12           // j-chunks for fpv (128 j each)
#define CM_Z 16            // row-chunks for colmean (97 rows each)

typedef unsigned short u16;
typedef __attribute__((ext_vector_type(8))) short bf16x8;
typedef __attribute__((ext_vector_type(4))) float f32x4;

__device__ __forceinline__ u16 f2bf(float f){
  union { float f; uint32_t u; } v; v.f = f;
  uint32_t u = v.u;
  uint32_t r = (u + 0x7FFFu + ((u >> 16) & 1u)) >> 16;
  return (u16)r;
}

// ---------------- LayerNorm: one block per row ----------------
__global__ void ln_kernel(const float* __restrict__ in, const float* __restrict__ g,
                          const float* __restrict__ bta, float* __restrict__ of32,
                          u16* __restrict__ obf, int D)
{
  const int r = blockIdx.x;
  const float* x = in + (size_t)r * D;
  float s = 0.f, ss = 0.f;
  for (int c = threadIdx.x; c < D; c += 256){ float v = x[c]; s += v; ss += v*v; }
  #pragma unroll
  for (int off = 32; off >= 1; off >>= 1){ s += __shfl_xor(s, off); ss += __shfl_xor(ss, off); }
  __shared__ float rs_[4], rss_[4];
  int w = threadIdx.x >> 6;
  if ((threadIdx.x & 63) == 0){ rs_[w] = s; rss_[w] = ss; }
  __syncthreads();
  s = rs_[0] + rs_[1] + rs_[2] + rs_[3];
  ss = rss_[0] + rss_[1] + rss_[2] + rss_[3];
  float mu = s / D;
  float var = ss / D - mu * mu;
  float rstd = rsqrtf(var + 1e-5f);
  for (int c = threadIdx.x; c < D; c += 256){
    float y = (x[c] - mu) * rstd * g[c] + (bta ? bta[c] : 0.f);
    if (of32) of32[(size_t)r*D + c] = y;
    if (obf)  obf[(size_t)r*D + c] = f2bf(y);
  }
}

// ---------------- GEMM: C[M,N] = A[M,K](bf16) @ B[K,N](f32->bf16) (+bias) (+=C) ----------------
__global__ __launch_bounds__(256) void gemm128(
    const u16* __restrict__ A, int lda,
    const float* __restrict__ Bw, int ldb,
    float* __restrict__ C, int ldc,
    const float* __restrict__ bias,
    int M, int Nn, int K, int addC)
{
  __shared__ __align__(16) u16 As[128][40];
  __shared__ __align__(16) u16 Bs[128][40];
  const int t = threadIdx.x;
  const int lane = t & 63;
  const int w = t >> 6;
  const int wr = (w >> 1) * 64, wc = (w & 1) * 64;
  const int row0 = blockIdx.x * 128, col0 = blockIdx.y * 128;
  const int l15 = lane & 15;
  const int l4 = (lane >> 4) * 8;
  f32x4 acc[4][4];
  #pragma unroll
  for (int m = 0; m < 4; ++m)
    #pragma unroll
    for (int n = 0; n < 4; ++n)
      #pragma unroll
      for (int j = 0; j < 4; ++j) acc[m][n][j] = 0.f;

  for (int k0 = 0; k0 < K; k0 += 32) {
    // stage A (128x32 bf16)
    #pragma unroll
    for (int u = 0; u < 2; ++u){
      int id = t + u*256;
      int r = id >> 2, c8 = (id & 3) * 8;
      bf16x8 av;
      #pragma unroll
      for (int j = 0; j < 8; ++j) av[j] = 0;
      int gr = row0 + r;
      if (gr < M){
        if (k0 + c8 + 8 <= K) av = *(const bf16x8*)(A + (size_t)gr*lda + k0 + c8);
        else {
          #pragma unroll
          for (int j = 0; j < 8; ++j){ int k = k0 + c8 + j; if (k < K) av[j] = (short)A[(size_t)gr*lda + k]; }
        }
      }
      *(bf16x8*)(&As[r][c8]) = av;
    }
    // stage B transposed (Bs[col][k]) with f32->bf16 convert
    {
      int col = t & 127, kb = (t >> 7) * 16;
      u16 sh[16];
      #pragma unroll
      for (int i = 0; i < 16; ++i){
        int k = k0 + kb + i;
        float bv = (k < K && (col0 + col) < Nn) ? Bw[(size_t)k*ldb + col0 + col] : 0.f;
        sh[i] = f2bf(bv);
      }
      *(bf16x8*)(&Bs[col][kb])     = *(bf16x8*)(&sh[0]);
      *(bf16x8*)(&Bs[col][kb + 8]) = *(bf16x8*)(&sh[8]);
    }
    __syncthreads();
    bf16x8 af[4], bfr[4];
    #pragma unroll
    for (int m = 0; m < 4; ++m) af[m]  = *(const bf16x8*)(&As[wr + m*16 + l15][l4]);
    #pragma unroll
    for (int n = 0; n < 4; ++n) bfr[n] = *(const bf16x8*)(&Bs[wc + n*16 + l15][l4]);
    #pragma unroll
    for (int m = 0; m < 4; ++m)
      #pragma unroll
      for (int n = 0; n < 4; ++n)
        acc[m][n] = __builtin_amdgcn_mfma_f32_16x16x32_bf16(af[m], bfr[n], acc[m][n], 0, 0, 0);
    __syncthreads();
  }
  const int rb = (lane >> 4) * 4;
  #pragma unroll
  for (int m = 0; m < 4; ++m){
    int gr0 = row0 + wr + m*16 + rb;
    #pragma unroll
    for (int n = 0; n < 4; ++n){
      int gc = col0 + wc + n*16 + l15;
      if (gc >= Nn) continue;
      float bv = bias ? bias[gc] : 0.f;
      #pragma unroll
      for (int j = 0; j < 4; ++j){
        int gr = gr0 + j;
        if (gr < M){
          float vv = acc[m][n][j] + bv;
          if (addC) C[(size_t)gr*ldc + gc] += vv;
          else      C[(size_t)gr*ldc + gc] = vv;
        }
      }
    }
  }
}

// ---------------- copy fusion tokens into tok ----------------
__global__ void fuscopy_kernel(const float* __restrict__ ft, float* __restrict__ tok)
{
  int i = blockIdx.x * 256 + threadIdx.x;
  if (i >= BATCH*16*DIMM) return;
  int c = i & 511; int tt = i >> 9; int b = tt >> 4; int r = tt & 15;
  tok[((size_t)(b*NTOK + 768 + r))*DIMM + c] = ft[r*DIMM + c];
}

// ---------------- column mean of V: partial over row-chunks ----------------
__global__ void colmean_part(const float* __restrict__ kvv, float* __restrict__ part)
{
  int c = blockIdx.x * 256 + threadIdx.x;  // 0..511 (grid.x = 2)
  int b = blockIdx.y, z = blockIdx.z;
  int r0 = z * 97;
  int r1 = r0 + 97; if (r1 > NTOK) r1 = NTOK;
  const float* src = kvv + (size_t)b*NTOK*1024 + 512 + c;
  float s = 0.f;
  for (int r = r0; r < r1; ++r) s += src[(size_t)r*1024];
  part[(((size_t)z*BATCH + b) << 9) + c] = s;
}

__global__ void colmean_reduce(const float* __restrict__ part, float* __restrict__ mv)
{
  int i = blockIdx.x * 256 + threadIdx.x;   // BATCH*512
  if (i >= BATCH*DIMM) return;
  int b = i >> 9, c = i & 511;
  float s = 0.f;
  #pragma unroll
  for (int z = 0; z < CM_Z; ++z) s += part[(((size_t)z*BATCH + b) << 9) + c];
  mv[b*DIMM + c] = s * (1.0f/1552.0f);
}

// ---------------- fusion q@k^T: one j per thread, j-chunked over grid.z ----------------
__global__ void fsim_kernel(const float* __restrict__ kv, const float* __restrict__ qf,
                            float* __restrict__ sim)
{
  int h = blockIdx.x, b = blockIdx.y, z = blockIdx.z;  // z in 0..5
  __shared__ float qs[16][64];
  for (int i = threadIdx.x; i < 16*64; i += 256){
    int q = i >> 6, d = i & 63;
    qs[q][d] = qf[((size_t)(b*16 + q))*DIMM + h*64 + d];
  }
  __syncthreads();
  int jj = z*256 + threadIdx.x;
  int j = (jj < 768) ? jj : jj + 16;
  const float* kr = kv + ((size_t)(b*NTOK + j))*1024 + h*64;
  float acc[16];
  #pragma unroll
  for (int q = 0; q < 16; ++q) acc[q] = 0.f;
  #pragma unroll
  for (int d4 = 0; d4 < 16; ++d4){
    float4 kd = *(const float4*)(kr + d4*4);
    #pragma unroll
    for (int q = 0; q < 16; ++q)
      acc[q] += qs[q][d4*4+0]*kd.x + qs[q][d4*4+1]*kd.y + qs[q][d4*4+2]*kd.z + qs[q][d4*4+3]*kd.w;
  }
  float* so = sim + ((size_t)(b*8 + h) * 16) * 1536 + jj;
  #pragma unroll
  for (int q = 0; q < 16; ++q) so[(size_t)q*1536] = acc[q] * 0.125f;
}

// ---------------- softmax over 1536 (in place) ----------------
__global__ void softmax_kernel(float* __restrict__ sim)
{
  float* x = sim + (size_t)blockIdx.x * 1536;
  float e[6];
  float m = -3.4e38f;
  #pragma unroll
  for (int i = 0; i < 6; ++i){ e[i] = x[threadIdx.x + i*256]; m = fmaxf(m, e[i]); }
  #pragma unroll
  for (int off = 32; off >= 1; off >>= 1) m = fmaxf(m, __shfl_xor(m, off));
  __shared__ float red[4];
  int w = threadIdx.x >> 6;
  if ((threadIdx.x & 63) == 0) red[w] = m;
  __syncthreads();
  m = fmaxf(fmaxf(red[0], red[1]), fmaxf(red[2], red[3]));
  __syncthreads();
  float s = 0.f;
  #pragma unroll
  for (int i = 0; i < 6; ++i){ e[i] = expf(e[i] - m); s += e[i]; }
  #pragma unroll
  for (int off = 32; off >= 1; off >>= 1) s += __shfl_xor(s, off);
  if ((threadIdx.x & 63) == 0) red[w] = s;
  __syncthreads();
  s = red[0] + red[1] + red[2] + red[3];
  float inv = 1.0f / s;
  #pragma unroll
  for (int i = 0; i < 6; ++i) x[threadIdx.x + i*256] = e[i] * inv;
}

// ---------------- attn @ V for fusion rows: j-chunked partials ----------------
__global__ void fpv_part(const float* __restrict__ kv, const float* __restrict__ sim,
                         float* __restrict__ part)
{
  int h = blockIdx.x, b = blockIdx.y, z = blockIdx.z;  // z in 0..FPV_Z-1
  int d = threadIdx.x & 63, g = threadIdx.x >> 6;      // g: 0..3
  float acc[4] = {0.f, 0.f, 0.f, 0.f};
  const float* sb = sim + ((size_t)(b*8 + h) * 16) * 1536;
  int j0 = z * 128;
  for (int jj = j0; jj < j0 + 128; ++jj){
    int j = (jj < 768) ? jj : jj + 16;
    float vd = kv[((size_t)(b*NTOK + j))*1024 + 512 + h*64 + d];
    #pragma unroll
    for (int q = 0; q < 4; ++q) acc[q] += sb[(size_t)(g*4 + q)*1536 + jj] * vd;
  }
  float* po = part + ((((size_t)z*BATCH + b)*8 + h)*16)*64;
  #pragma unroll
  for (int q = 0; q < 4; ++q) po[(size_t)(g*4 + q)*64 + d] = acc[q];
}

__global__ void fpv_reduce(const float* __restrict__ part, float* __restrict__ outf)
{
  int i = blockIdx.x * 256 + threadIdx.x;  // over BATCH*16*512 = 16384
  if (i >= BATCH*16*DIMM) return;
  int d = i & 63; int rest = i >> 6;
  int h = rest & 7; rest >>= 3;
  int q = rest & 15; int b = rest >> 4;
  float s = 0.f;
  #pragma unroll
  for (int z = 0; z < FPV_Z; ++z)
    s += part[(((((size_t)z*BATCH + b)*8 + h)*16) + q)*64 + d];
  outf[((size_t)(b*16 + q))*DIMM + h*64 + d] = s;
}

// ---------------- pack [mean_row ; 16 fusion outs] to bf16 for wo-proj ----------------
__global__ void packz_kernel(const float* __restrict__ mv, const float* __restrict__ outf,
                             u16* __restrict__ zb)
{
  int i = blockIdx.x * 256 + threadIdx.x;
  if (i >= BATCH*17*DIMM) return;
  int c = i & 511;
  int tt = i >> 9;         // b*17 + r
  int b = tt / 17, r = tt % 17;
  float v = (r == 0) ? mv[b*DIMM + c] : outf[((size_t)b*16 + (r-1))*DIMM + c];
  zb[i] = f2bf(v);
}

// ---------------- residual scatter-add of attention projection ----------------
__global__ void resadd_kernel(float* __restrict__ tok, const float* __restrict__ proj)
{
  int n = blockIdx.x, b = blockIdx.y;
  int pr = (n >= 768 && n < 784) ? (1 + n - 768) : 0;
  const float* p = proj + ((size_t)b*17 + pr)*DIMM;
  float* tr = tok + ((size_t)(b*NTOK + n))*DIMM;
  for (int c = threadIdx.x; c < DIMM; c += 256) tr[c] += p[c];
}

// ---------------- GEGLU: g = gelu(h[:,1365:]) * h[:,:1365] -> bf16 ----------------
__global__ void geglu_kernel(const float* __restrict__ h, u16* __restrict__ g)
{
  int i = blockIdx.x * 256 + threadIdx.x;
  if (i >= NTOK * IFFC) return;
  int r = i / IFFC, c = i % IFFC;
  float x1 = h[(size_t)r*IFF2 + c];
  float gt = h[(size_t)r*IFF2 + IFFC + c];
  float ge = 0.5f * gt * (1.0f + erff(gt * 0.70710678118654752f));
  g[(size_t)r*GSTRIDE + c] = f2bf(ge * x1);
}

// ---------------- pool: q for return-token 2 (LN + matvec, scaled) ----------------
__global__ void poolq2_kernel(const float* __restrict__ rt, const float* __restrict__ pg,
                              const float* __restrict__ wq, float* __restrict__ q2)
{
  __shared__ float y[DIMM];
  const float* x = rt + 2*DIMM;
  float s = 0.f, ss = 0.f;
  for (int c = threadIdx.x; c < DIMM; c += 256){ float v = x[c]; s += v; ss += v*v; }
  #pragma unroll
  for (int off = 32; off >= 1; off >>= 1){ s += __shfl_xor(s, off); ss += __shfl_xor(ss, off); }
  __shared__ float rs_[4], rss_[4];
  int w = threadIdx.x >> 6;
  if ((threadIdx.x & 63) == 0){ rs_[w] = s; rss_[w] = ss; }
  __syncthreads();
  s = rs_[0] + rs_[1] + rs_[2] + rs_[3];
  ss = rss_[0] + rss_[1] + rss_[2] + rss_[3];
  float mu = s / DIMM;
  float rstd = rsqrtf(ss / DIMM - mu*mu + 1e-5f);
  for (int c = threadIdx.x; c < DIMM; c += 256) y[c] = (x[c] - mu) * rstd * pg[c];
  __syncthreads();
  for (int c = threadIdx.x; c < DIMM; c += 256){
    float a = 0.f;
    for (int k = 0; k < DIMM; ++k) a += y[k] * wq[(size_t)k*DIMM + c];
    q2[c] = a * 0.125f;
  }
}

// ---------------- pool: attention of return-token 2 over the 16 fusion keys ----------------
__global__ void poolattn2_kernel(const float* __restrict__ kv, const float* __restrict__ q2,
                                 float* __restrict__ out2)
{
  int h = blockIdx.x, b = blockIdx.y, d = threadIdx.x;  // block of 64
  __shared__ float sm[16];
  if (d < 16){
    const float* kr = kv + ((size_t)(b*NTOK + 768 + d))*1024 + h*64;
    float a = 0.f;
    for (int k = 0; k < 64; ++k) a += q2[h*64 + k] * kr[k];
    sm[d] = a;
  }
  __syncthreads();
  float m = -3.4e38f;
  #pragma unroll
  for (int j = 0; j < 16; ++j) m = fmaxf(m, sm[j]);
  float wv[16]; float s = 0.f;
  #pragma unroll
  for (int j = 0; j < 16; ++j){ wv[j] = expf(sm[j] - m); s += wv[j]; }
  float inv = 1.0f / s;
  float a = 0.f;
  #pragma unroll
  for (int j = 0; j < 16; ++j)
    a += wv[j] * kv[((size_t)(b*NTOK + 768 + j))*1024 + 512 + h*64 + d];
  out2[(size_t)b*DIMM + h*64 + d] = a * inv;
}

// ---------------- final pooled = po @ pool_wo + return_tokens ----------------
__global__ void pooled_kernel(const float* __restrict__ mvp, const float* __restrict__ out2,
                              const float* __restrict__ wo, const float* __restrict__ rt,
                              float* __restrict__ out)
{
  int br = blockIdx.x;  // b*3 + r, 0..5
  int b = br / 3, r = br % 3;
  __shared__ float po[DIMM];
  const float* src = (r < 2) ? (mvp + (size_t)b*DIMM) : (out2 + (size_t)b*DIMM);
  for (int c = threadIdx.x; c < DIMM; c += 256) po[c] = src[c];
  __syncthreads();
  for (int c = threadIdx.x; c < DIMM; c += 256){
    float a = 0.f;
    for (int k = 0; k < DIMM; ++k) a += po[k] * wo[(size_t)k*DIMM + c];
    out[(size_t)br*DIMM + c] = a + rt[(size_t)r*DIMM + c];
  }
}

// =================================================================
extern "C" void kernel_launch(void* const* d_in, const int* in_sizes, int n_in,
                              void* d_out, int out_size, void* d_ws, size_t ws_size,
                              hipStream_t stream)
{
  const float* rna        = (const float*)d_in[0];
  const float* atac       = (const float*)d_in[1];
  const float* rna_ln1_g  = (const float*)d_in[2];
  const float* rna_ln1_b  = (const float*)d_in[3];
  const float* rna_w      = (const float*)d_in[4];
  const float* rna_b      = (const float*)d_in[5];
  const float* rna_ln2_g  = (const float*)d_in[6];
  const float* rna_ln2_b  = (const float*)d_in[7];
  const float* atac_ln1_g = (const float*)d_in[8];
  const float* atac_ln1_b = (const float*)d_in[9];
  const float* atac_w     = (const float*)d_in[10];
  const float* atac_b     = (const float*)d_in[11];
  const float* atac_ln2_g = (const float*)d_in[12];
  const float* atac_ln2_b = (const float*)d_in[13];
  const float* fusion_tok = (const float*)d_in[14];
  const float* lay_ag     = (const float*)d_in[15];
  const float* lay_wq     = (const float*)d_in[16];
  const float* lay_wkv    = (const float*)d_in[17];
  const float* lay_wo     = (const float*)d_in[18];
  const float* lay_fg     = (const float*)d_in[19];
  const float* lay_w1     = (const float*)d_in[20];
  const float* lay_w2     = (const float*)d_in[21];
  const float* final_g    = (const float*)d_in[22];
  const float* ret_tok    = (const float*)d_in[23];
  const float* pool_g     = (const float*)d_in[24];
  const float* pool_wq    = (const float*)d_in[25];
  const float* pool_wkv   = (const float*)d_in[26];
  const float* pool_wo    = (const float*)d_in[27];

  // workspace carve (all offsets 256B aligned)
  uint8_t* ws = (uint8_t*)d_ws;
  size_t off = 0;
  auto carve = [&](size_t bytes) -> uint8_t* {
    uint8_t* p = ws + off;
    off += (bytes + 255) & ~(size_t)255;
    return p;
  };
  float* tok   = (float*)carve((size_t)MALL * DIMM * 4);        // 6.36 MB
  u16*   xn    = (u16*)  carve((size_t)MALL * DIMM * 2);        // 3.18 MB
  float* kv    = (float*)carve((size_t)MALL * 1024 * 4);        // 12.7 MB
  float* hbuf  = (float*)carve((size_t)NTOK * IFF2 * 4);        // 16.9 MB
  u16*   gbuf  = (u16*)  carve((size_t)NTOK * GSTRIDE * 2);     // 4.27 MB
  u16*   lnbuf = (u16*)  carve((size_t)1536 * 1024 * 2);        // 3.15 MB
  float* sim   = (float*)carve((size_t)BATCH*8*16*1536 * 4);    // 1.57 MB
  float* qfus  = (float*)carve((size_t)BATCH*16*DIMM * 4);
  float* outf  = (float*)carve((size_t)BATCH*16*DIMM * 4);
  u16*   zb    = (u16*)  carve((size_t)BATCH*17*DIMM * 2);
  float* proj  = (float*)carve((size_t)BATCH*17*DIMM * 4);
  float* mv    = (float*)carve((size_t)BATCH*DIMM * 4);
  float* q2    = (float*)carve((size_t)DIMM * 4);
  float* out2  = (float*)carve((size_t)BATCH*DIMM * 4);
  float* fpvp  = (float*)carve((size_t)FPV_Z*BATCH*8*16*64 * 4); // 786 KB
  float* cmp_  = (float*)carve((size_t)CM_Z*BATCH*DIMM * 4);     // 64 KB
  (void)ws_size;

  // ---- embeddings ----
  ln_kernel<<<1536, 256, 0, stream>>>(rna, rna_ln1_g, rna_ln1_b, nullptr, lnbuf, 1024);
  gemm128<<<dim3(12, 4), 256, 0, stream>>>(lnbuf, 1024, rna_w, 512, hbuf, 512, rna_b, 1536, 512, 1024, 0);
  for (int b = 0; b < BATCH; ++b)
    ln_kernel<<<768, 256, 0, stream>>>(hbuf + (size_t)b*768*DIMM, rna_ln2_g, rna_ln2_b,
                                       tok + (size_t)b*NTOK*DIMM, nullptr, 512);
  ln_kernel<<<1536, 256, 0, stream>>>(atac, atac_ln1_g, atac_ln1_b, nullptr, lnbuf, 1024);
  gemm128<<<dim3(12, 4), 256, 0, stream>>>(lnbuf, 1024, atac_w, 512, hbuf, 512, atac_b, 1536, 512, 1024, 0);
  for (int b = 0; b < BATCH; ++b)
    ln_kernel<<<768, 256, 0, stream>>>(hbuf + (size_t)b*768*DIMM, atac_ln2_g, atac_ln2_b,
                                       tok + ((size_t)b*NTOK + 784)*DIMM, nullptr, 512);
  fuscopy_kernel<<<(BATCH*16*DIMM + 255)/256, 256, 0, stream>>>(fusion_tok, tok);

  // ---- transformer layers ----
  for (int l = 0; l < 4; ++l){
    const float* ag  = lay_ag  + (size_t)l*DIMM;
    const float* wq  = lay_wq  + (size_t)l*DIMM*DIMM;
    const float* wkv = lay_wkv + (size_t)l*DIMM*1024;
    const float* wo  = lay_wo  + (size_t)l*DIMM*DIMM;
    const float* fg  = lay_fg  + (size_t)l*DIMM;
    const float* w1  = lay_w1  + (size_t)l*DIMM*IFF2;
    const float* w2  = lay_w2  + (size_t)l*IFFC*DIMM;

    // attention
    ln_kernel<<<MALL, 256, 0, stream>>>(tok, ag, nullptr, nullptr, xn, 512);
    gemm128<<<dim3(25, 8), 256, 0, stream>>>(xn, 512, wkv, 1024, kv, 1024, nullptr, MALL, 1024, 512, 0);
    for (int b = 0; b < BATCH; ++b)
      gemm128<<<dim3(1, 4), 256, 0, stream>>>(xn + ((size_t)b*NTOK + 768)*DIMM, 512, wq, 512,
                                              qfus + (size_t)b*16*DIMM, 512, nullptr, 16, 512, 512, 0);
    colmean_part<<<dim3(2, BATCH, CM_Z), 256, 0, stream>>>(kv, cmp_);
    colmean_reduce<<<(BATCH*DIMM + 255)/256, 256, 0, stream>>>(cmp_, mv);
    fsim_kernel<<<dim3(8, BATCH, 6), 256, 0, stream>>>(kv, qfus, sim);
    softmax_kernel<<<BATCH*8*16, 256, 0, stream>>>(sim);
    fpv_part<<<dim3(8, BATCH, FPV_Z), 256, 0, stream>>>(kv, sim, fpvp);
    fpv_reduce<<<(BATCH*16*DIMM + 255)/256, 256, 0, stream>>>(fpvp, outf);
    packz_kernel<<<(BATCH*17*DIMM + 255)/256, 256, 0, stream>>>(mv, outf, zb);
    for (int b = 0; b < BATCH; ++b)
      gemm128<<<dim3(1, 4), 256, 0, stream>>>(zb + (size_t)b*17*DIMM, 512, wo, 512,
                                              proj + (size_t)b*17*DIMM, 512, nullptr, 17, 512, 512, 0);
    resadd_kernel<<<dim3(NTOK, BATCH), 256, 0, stream>>>(tok, proj);

    // GEGLU FFN (two row-halves to bound scratch)
    ln_kernel<<<MALL, 256, 0, stream>>>(tok, fg, nullptr, nullptr, xn, 512);
    for (int half = 0; half < 2; ++half){
      gemm128<<<dim3(13, 22), 256, 0, stream>>>(xn + (size_t)half*NTOK*DIMM, 512, w1, IFF2,
                                                hbuf, IFF2, nullptr, NTOK, IFF2, 512, 0);
      geglu_kernel<<<(NTOK*IFFC + 255)/256, 256, 0, stream>>>(hbuf, gbuf);
      gemm128<<<dim3(13, 4), 256, 0, stream>>>(gbuf, GSTRIDE, w2, 512,
                                               tok + (size_t)half*NTOK*DIMM, 512, nullptr, NTOK, 512, IFFC, 1);
    }
  }

  // ---- final LN + pooling ----
  ln_kernel<<<MALL, 256, 0, stream>>>(tok, final_g, nullptr, nullptr, xn, 512);
  gemm128<<<dim3(25, 8), 256, 0, stream>>>(xn, 512, pool_wkv, 1024, kv, 1024, nullptr, MALL, 1024, 512, 0);
  colmean_part<<<dim3(2, BATCH, CM_Z), 256, 0, stream>>>(kv, cmp_);
  colmean_reduce<<<(BATCH*DIMM + 255)/256, 256, 0, stream>>>(cmp_, mv);
  poolq2_kernel<<<1, 256, 0, stream>>>(ret_tok, pool_g, pool_wq, q2);
  poolattn2_kernel<<<dim3(8, BATCH), 64, 0, stream>>>(kv, q2, out2);
  pooled_kernel<<<BATCH*3, 256, 0, stream>>>(mv, out2, pool_wo, ret_tok, (float*)d_out);
}

// Round 3
// 1119.269 us; speedup vs baseline: 2.9385x; 2.0576x over previous
//
#include <hip/hip_runtime.h>
#include <stdint.h>
#include <stddef.h>

#define NTOK 1552
#define DIMM 512
#define IFFC 1365
#define IFF2 2730
#define GSTRIDE 1376   // padded row stride (bf16 elems) for geglu output
#define BATCH 2
#define MALL (BATCH*NTOK)   // 3104
#define FPV_Z 12
#define CM_Z 16

typedef unsigned short u16;
typedef __attribute__((ext_vector_type(8))) short bf16x8;
typedef __attribute__((ext_vector_type(4))) float f32x4;

__device__ __forceinline__ u16 f2bf(float f){
  union { float f; uint32_t u; } v; v.f = f;
  uint32_t u = v.u;
  uint32_t r = (u + 0x7FFFu + ((u >> 16) & 1u)) >> 16;
  return (u16)r;
}

// ---------------- LayerNorm: one block per row ----------------
__global__ void ln_kernel(const float* __restrict__ in, const float* __restrict__ g,
                          const float* __restrict__ bta, float* __restrict__ of32,
                          u16* __restrict__ obf, int D)
{
  const int r = blockIdx.x;
  const float* x = in + (size_t)r * D;
  float s = 0.f, ss = 0.f;
  for (int c = threadIdx.x; c < D; c += 256){ float v = x[c]; s += v; ss += v*v; }
  #pragma unroll
  for (int off = 32; off >= 1; off >>= 1){ s += __shfl_xor(s, off); ss += __shfl_xor(ss, off); }
  __shared__ float rs_[4], rss_[4];
  int w = threadIdx.x >> 6;
  if ((threadIdx.x & 63) == 0){ rs_[w] = s; rss_[w] = ss; }
  __syncthreads();
  s = rs_[0] + rs_[1] + rs_[2] + rs_[3];
  ss = rss_[0] + rss_[1] + rss_[2] + rss_[3];
  float mu = s / D;
  float var = ss / D - mu * mu;
  float rstd = rsqrtf(var + 1e-5f);
  for (int c = threadIdx.x; c < D; c += 256){
    float y = (x[c] - mu) * rstd * g[c] + (bta ? bta[c] : 0.f);
    if (of32) of32[(size_t)r*D + c] = y;
    if (obf)  obf[(size_t)r*D + c] = f2bf(y);
  }
}

// ------- gemm512: 8-wave 128x128 tile, optional split-K via grid.z -------
// C[M,N] = A[M,K](bf16) @ B[K,N](f32->bf16); partial z writes C + z*Cz.
__global__ __launch_bounds__(512) void gemm512(
    const u16* __restrict__ A, int lda,
    const float* __restrict__ Bw, int ldb,
    float* __restrict__ C, int ldc, size_t Cz,
    int M, int Nn, int K, int kchunk)
{
  __shared__ __align__(16) u16 As[128][40];
  __shared__ __align__(16) u16 Bs[128][40];
  const int t = threadIdx.x;
  const int lane = t & 63;
  const int w = t >> 6;          // 0..7
  const int wr = (w >> 2) * 64;  // 0,64
  const int wc = (w & 3) * 32;   // 0,32,64,96
  const int row0 = blockIdx.x * 128, col0 = blockIdx.y * 128;
  const int z = blockIdx.z;
  const int kbeg = z * kchunk;
  const int kend = (kbeg + kchunk < K) ? (kbeg + kchunk) : K;
  C += (size_t)z * Cz;
  const int l15 = lane & 15;
  const int l4 = (lane >> 4) * 8;
  f32x4 acc[4][2];
  #pragma unroll
  for (int m = 0; m < 4; ++m)
    #pragma unroll
    for (int n = 0; n < 2; ++n)
      #pragma unroll
      for (int j = 0; j < 4; ++j) acc[m][n][j] = 0.f;

  for (int k0 = kbeg; k0 < kend; k0 += 32) {
    // stage A (128x32)
    {
      int r = t >> 2, c8 = (t & 3) * 8;
      bf16x8 av;
      #pragma unroll
      for (int j = 0; j < 8; ++j) av[j] = 0;
      int gr = row0 + r;
      if (gr < M){
        if (k0 + c8 + 8 <= kend) av = *(const bf16x8*)(A + (size_t)gr*lda + k0 + c8);
        else {
          #pragma unroll
          for (int j = 0; j < 8; ++j){ int k = k0 + c8 + j; if (k < kend) av[j] = (short)A[(size_t)gr*lda + k]; }
        }
      }
      *(bf16x8*)(&As[r][c8]) = av;
    }
    // stage B transposed (Bs[col][k]) f32->bf16
    {
      int col = t & 127, kb = (t >> 7) * 8;
      u16 sh[8];
      #pragma unroll
      for (int i = 0; i < 8; ++i){
        int k = k0 + kb + i;
        float bv = (k < kend && (col0 + col) < Nn) ? Bw[(size_t)k*ldb + col0 + col] : 0.f;
        sh[i] = f2bf(bv);
      }
      *(bf16x8*)(&Bs[col][kb]) = *(bf16x8*)(&sh[0]);
    }
    __syncthreads();
    bf16x8 af[4], bfr[2];
    #pragma unroll
    for (int m = 0; m < 4; ++m) af[m]  = *(const bf16x8*)(&As[wr + m*16 + l15][l4]);
    #pragma unroll
    for (int n = 0; n < 2; ++n) bfr[n] = *(const bf16x8*)(&Bs[wc + n*16 + l15][l4]);
    #pragma unroll
    for (int m = 0; m < 4; ++m)
      #pragma unroll
      for (int n = 0; n < 2; ++n)
        acc[m][n] = __builtin_amdgcn_mfma_f32_16x16x32_bf16(af[m], bfr[n], acc[m][n], 0, 0, 0);
    __syncthreads();
  }
  const int rb = (lane >> 4) * 4;
  #pragma unroll
  for (int m = 0; m < 4; ++m){
    int gr0 = row0 + wr + m*16 + rb;
    #pragma unroll
    for (int n = 0; n < 2; ++n){
      int gc = col0 + wc + n*16 + l15;
      if (gc >= Nn) continue;
      #pragma unroll
      for (int j = 0; j < 4; ++j){
        int gr = gr0 + j;
        if (gr < M) C[(size_t)gr*ldc + gc] = acc[m][n][j];
      }
    }
  }
}

// ------- split-K / bias reduce: dst (+)= part[0]+part[1] (+ bias[c&511]) -------
__global__ void skreduce(float* __restrict__ dst, const float* __restrict__ part,
                         int len, const float* __restrict__ bias, int addDst)
{
  int i = blockIdx.x * 256 + threadIdx.x;
  if (i >= len) return;
  float s = part[i] + part[(size_t)len + i];
  if (bias) s += bias[i & 511];
  if (addDst) dst[i] += s; else dst[i] = s;
}

// ------- tiny GEMM (M<=128), batched over grid.z -------
__global__ __launch_bounds__(256) void gemm_tiny(
    const u16* __restrict__ A, int lda, size_t Abat,
    const float* __restrict__ Bw, int ldb,
    float* __restrict__ C, int ldc, size_t Cbat,
    int M, int Nn, int K)
{
  A += (size_t)blockIdx.z * Abat;
  C += (size_t)blockIdx.z * Cbat;
  __shared__ __align__(16) u16 As[128][40];
  __shared__ __align__(16) u16 Bs[128][40];
  const int t = threadIdx.x;
  const int lane = t & 63;
  const int w = t >> 6;
  const int wr = (w >> 1) * 64, wc = (w & 1) * 64;
  const int col0 = blockIdx.y * 128;
  const int l15 = lane & 15;
  const int l4 = (lane >> 4) * 8;
  f32x4 acc[4][4];
  #pragma unroll
  for (int m = 0; m < 4; ++m)
    #pragma unroll
    for (int n = 0; n < 4; ++n)
      #pragma unroll
      for (int j = 0; j < 4; ++j) acc[m][n][j] = 0.f;

  for (int k0 = 0; k0 < K; k0 += 32) {
    #pragma unroll
    for (int u = 0; u < 2; ++u){
      int id = t + u*256;
      int r = id >> 2, c8 = (id & 3) * 8;
      bf16x8 av;
      #pragma unroll
      for (int j = 0; j < 8; ++j) av[j] = 0;
      if (r < M && k0 + c8 < K) av = *(const bf16x8*)(A + (size_t)r*lda + k0 + c8);
      *(bf16x8*)(&As[r][c8]) = av;
    }
    {
      int col = t & 127, kb = (t >> 7) * 16;
      u16 sh[16];
      #pragma unroll
      for (int i = 0; i < 16; ++i){
        int k = k0 + kb + i;
        float bv = (k < K && (col0 + col) < Nn) ? Bw[(size_t)k*ldb + col0 + col] : 0.f;
        sh[i] = f2bf(bv);
      }
      *(bf16x8*)(&Bs[col][kb])     = *(bf16x8*)(&sh[0]);
      *(bf16x8*)(&Bs[col][kb + 8]) = *(bf16x8*)(&sh[8]);
    }
    __syncthreads();
    bf16x8 af[4], bfr[4];
    #pragma unroll
    for (int m = 0; m < 4; ++m) af[m]  = *(const bf16x8*)(&As[wr + m*16 + l15][l4]);
    #pragma unroll
    for (int n = 0; n < 4; ++n) bfr[n] = *(const bf16x8*)(&Bs[wc + n*16 + l15][l4]);
    #pragma unroll
    for (int m = 0; m < 4; ++m)
      #pragma unroll
      for (int n = 0; n < 4; ++n)
        acc[m][n] = __builtin_amdgcn_mfma_f32_16x16x32_bf16(af[m], bfr[n], acc[m][n], 0, 0, 0);
    __syncthreads();
  }
  const int rb = (lane >> 4) * 4;
  #pragma unroll
  for (int m = 0; m < 4; ++m){
    int gr0 = wr + m*16 + rb;
    #pragma unroll
    for (int n = 0; n < 4; ++n){
      int gc = col0 + wc + n*16 + l15;
      if (gc >= Nn) continue;
      #pragma unroll
      for (int j = 0; j < 4; ++j){
        int gr = gr0 + j;
        if (gr < M) C[(size_t)gr*ldc + gc] = acc[m][n][j];
      }
    }
  }
}

// ---------------- copy fusion tokens into tok ----------------
__global__ void fuscopy_kernel(const float* __restrict__ ft, float* __restrict__ tok)
{
  int i = blockIdx.x * 256 + threadIdx.x;
  if (i >= BATCH*16*DIMM) return;
  int c = i & 511; int tt = i >> 9; int b = tt >> 4; int r = tt & 15;
  tok[((size_t)(b*NTOK + 768 + r))*DIMM + c] = ft[r*DIMM + c];
}

// ---------------- column mean of V: partials over row-chunks ----------------
__global__ void colmean_part(const float* __restrict__ kvv, float* __restrict__ part)
{
  int c = blockIdx.x * 256 + threadIdx.x;
  int b = blockIdx.y, z = blockIdx.z;
  int r0 = z * 97;
  int r1 = r0 + 97; if (r1 > NTOK) r1 = NTOK;
  const float* src = kvv + (size_t)b*NTOK*1024 + 512 + c;
  float s = 0.f;
  for (int r = r0; r < r1; ++r) s += src[(size_t)r*1024];
  part[(((size_t)z*BATCH + b) << 9) + c] = s;
}

__global__ void colmean_reduce(const float* __restrict__ part, float* __restrict__ mv)
{
  int i = blockIdx.x * 256 + threadIdx.x;
  if (i >= BATCH*DIMM) return;
  int b = i >> 9, c = i & 511;
  float s = 0.f;
  #pragma unroll
  for (int z = 0; z < CM_Z; ++z) s += part[(((size_t)z*BATCH + b) << 9) + c];
  mv[b*DIMM + c] = s * (1.0f/1552.0f);
}

// ---------------- fusion q@k^T: one j per thread ----------------
__global__ void fsim_kernel(const float* __restrict__ kv, const float* __restrict__ qf,
                            float* __restrict__ sim)
{
  int h = blockIdx.x, b = blockIdx.y, z = blockIdx.z;
  __shared__ float qs[16][64];
  for (int i = threadIdx.x; i < 16*64; i += 256){
    int q = i >> 6, d = i & 63;
    qs[q][d] = qf[((size_t)(b*16 + q))*DIMM + h*64 + d];
  }
  __syncthreads();
  int jj = z*256 + threadIdx.x;
  int j = (jj < 768) ? jj : jj + 16;
  const float* kr = kv + ((size_t)(b*NTOK + j))*1024 + h*64;
  float acc[16];
  #pragma unroll
  for (int q = 0; q < 16; ++q) acc[q] = 0.f;
  #pragma unroll
  for (int d4 = 0; d4 < 16; ++d4){
    float4 kd = *(const float4*)(kr + d4*4);
    #pragma unroll
    for (int q = 0; q < 16; ++q)
      acc[q] += qs[q][d4*4+0]*kd.x + qs[q][d4*4+1]*kd.y + qs[q][d4*4+2]*kd.z + qs[q][d4*4+3]*kd.w;
  }
  float* so = sim + ((size_t)(b*8 + h) * 16) * 1536 + jj;
  #pragma unroll
  for (int q = 0; q < 16; ++q) so[(size_t)q*1536] = acc[q] * 0.125f;
}

// ---------------- softmax over 1536 (in place) ----------------
__global__ void softmax_kernel(float* __restrict__ sim)
{
  float* x = sim + (size_t)blockIdx.x * 1536;
  float e[6];
  float m = -3.4e38f;
  #pragma unroll
  for (int i = 0; i < 6; ++i){ e[i] = x[threadIdx.x + i*256]; m = fmaxf(m, e[i]); }
  #pragma unroll
  for (int off = 32; off >= 1; off >>= 1) m = fmaxf(m, __shfl_xor(m, off));
  __shared__ float red[4];
  int w = threadIdx.x >> 6;
  if ((threadIdx.x & 63) == 0) red[w] = m;
  __syncthreads();
  m = fmaxf(fmaxf(red[0], red[1]), fmaxf(red[2], red[3]));
  __syncthreads();
  float s = 0.f;
  #pragma unroll
  for (int i = 0; i < 6; ++i){ e[i] = expf(e[i] - m); s += e[i]; }
  #pragma unroll
  for (int off = 32; off >= 1; off >>= 1) s += __shfl_xor(s, off);
  if ((threadIdx.x & 63) == 0) red[w] = s;
  __syncthreads();
  s = red[0] + red[1] + red[2] + red[3];
  float inv = 1.0f / s;
  #pragma unroll
  for (int i = 0; i < 6; ++i) x[threadIdx.x + i*256] = e[i] * inv;
}

// ---------------- attn @ V for fusion rows: j-chunked partials ----------------
__global__ void fpv_part(const float* __restrict__ kv, const float* __restrict__ sim,
                         float* __restrict__ part)
{
  int h = blockIdx.x, b = blockIdx.y, z = blockIdx.z;
  int d = threadIdx.x & 63, g = threadIdx.x >> 6;
  float acc[4] = {0.f, 0.f, 0.f, 0.f};
  const float* sb = sim + ((size_t)(b*8 + h) * 16) * 1536;
  int j0 = z * 128;
  for (int jj = j0; jj < j0 + 128; ++jj){
    int j = (jj < 768) ? jj : jj + 16;
    float vd = kv[((size_t)(b*NTOK + j))*1024 + 512 + h*64 + d];
    #pragma unroll
    for (int q = 0; q < 4; ++q) acc[q] += sb[(size_t)(g*4 + q)*1536 + jj] * vd;
  }
  float* po = part + ((((size_t)z*BATCH + b)*8 + h)*16)*64;
  #pragma unroll
  for (int q = 0; q < 4; ++q) po[(size_t)(g*4 + q)*64 + d] = acc[q];
}

__global__ void fpv_reduce(const float* __restrict__ part, float* __restrict__ outf)
{
  int i = blockIdx.x * 256 + threadIdx.x;
  if (i >= BATCH*16*DIMM) return;
  int d = i & 63; int rest = i >> 6;
  int h = rest & 7; rest >>= 3;
  int q = rest & 15; int b = rest >> 4;
  float s = 0.f;
  #pragma unroll
  for (int z = 0; z < FPV_Z; ++z)
    s += part[(((((size_t)z*BATCH + b)*8 + h)*16) + q)*64 + d];
  outf[((size_t)(b*16 + q))*DIMM + h*64 + d] = s;
}

// ---------------- pack [mean ; 16 fusion outs] -> bf16 ----------------
__global__ void packz_kernel(const float* __restrict__ mv, const float* __restrict__ outf,
                             u16* __restrict__ zb)
{
  int i = blockIdx.x * 256 + threadIdx.x;
  if (i >= BATCH*17*DIMM) return;
  int c = i & 511;
  int tt = i >> 9;
  int b = tt / 17, r = tt % 17;
  float v = (r == 0) ? mv[b*DIMM + c] : outf[((size_t)b*16 + (r-1))*DIMM + c];
  zb[i] = f2bf(v);
}

// ---------------- residual scatter-add of attention projection ----------------
__global__ void resadd_kernel(float* __restrict__ tok, const float* __restrict__ proj)
{
  int n = blockIdx.x, b = blockIdx.y;
  int pr = (n >= 768 && n < 784) ? (1 + n - 768) : 0;
  const float* p = proj + ((size_t)b*17 + pr)*DIMM;
  float* tr = tok + ((size_t)(b*NTOK + n))*DIMM;
  for (int c = threadIdx.x; c < DIMM; c += 256) tr[c] += p[c];
}

// ---------------- GEGLU ----------------
__global__ void geglu_kernel(const float* __restrict__ h, u16* __restrict__ g, int n)
{
  int i = blockIdx.x * 256 + threadIdx.x;
  if (i >= n) return;
  int r = i / IFFC, c = i % IFFC;
  float x1 = h[(size_t)r*IFF2 + c];
  float gt = h[(size_t)r*IFF2 + IFFC + c];
  float ge = 0.5f * gt * (1.0f + erff(gt * 0.70710678118654752f));
  g[(size_t)r*GSTRIDE + c] = f2bf(ge * x1);
}

// ---------------- pool helpers ----------------
__global__ void poolq2_kernel(const float* __restrict__ rt, const float* __restrict__ pg,
                              const float* __restrict__ wq, float* __restrict__ q2)
{
  __shared__ float y[DIMM];
  const float* x = rt + 2*DIMM;
  float s = 0.f, ss = 0.f;
  for (int c = threadIdx.x; c < DIMM; c += 256){ float v = x[c]; s += v; ss += v*v; }
  #pragma unroll
  for (int off = 32; off >= 1; off >>= 1){ s += __shfl_xor(s, off); ss += __shfl_xor(ss, off); }
  __shared__ float rs_[4], rss_[4];
  int w = threadIdx.x >> 6;
  if ((threadIdx.x & 63) == 0){ rs_[w] = s; rss_[w] = ss; }
  __syncthreads();
  s = rs_[0] + rs_[1] + rs_[2] + rs_[3];
  ss = rss_[0] + rss_[1] + rss_[2] + rss_[3];
  float mu = s / DIMM;
  float rstd = rsqrtf(ss / DIMM - mu*mu + 1e-5f);
  for (int c = threadIdx.x; c < DIMM; c += 256) y[c] = (x[c] - mu) * rstd * pg[c];
  __syncthreads();
  for (int c = threadIdx.x; c < DIMM; c += 256){
    float a = 0.f;
    for (int k = 0; k < DIMM; ++k) a += y[k] * wq[(size_t)k*DIMM + c];
    q2[c] = a * 0.125f;
  }
}

__global__ void poolattn2_kernel(const float* __restrict__ kv, const float* __restrict__ q2,
                                 float* __restrict__ out2)
{
  int h = blockIdx.x, b = blockIdx.y, d = threadIdx.x;
  __shared__ float sm[16];
  if (d < 16){
    const float* kr = kv + ((size_t)(b*NTOK + 768 + d))*1024 + h*64;
    float a = 0.f;
    for (int k = 0; k < 64; ++k) a += q2[h*64 + k] * kr[k];
    sm[d] = a;
  }
  __syncthreads();
  float m = -3.4e38f;
  #pragma unroll
  for (int j = 0; j < 16; ++j) m = fmaxf(m, sm[j]);
  float wv[16]; float s = 0.f;
  #pragma unroll
  for (int j = 0; j < 16; ++j){ wv[j] = expf(sm[j] - m); s += wv[j]; }
  float inv = 1.0f / s;
  float a = 0.f;
  #pragma unroll
  for (int j = 0; j < 16; ++j)
    a += wv[j] * kv[((size_t)(b*NTOK + 768 + j))*1024 + 512 + h*64 + d];
  out2[(size_t)b*DIMM + h*64 + d] = a * inv;
}

__global__ void pooled_kernel(const float* __restrict__ mvp, const float* __restrict__ out2,
                              const float* __restrict__ wo, const float* __restrict__ rt,
                              float* __restrict__ out)
{
  int br = blockIdx.x;
  int b = br / 3, r = br % 3;
  __shared__ float po[DIMM];
  const float* src = (r < 2) ? (mvp + (size_t)b*DIMM) : (out2 + (size_t)b*DIMM);
  for (int c = threadIdx.x; c < DIMM; c += 256) po[c] = src[c];
  __syncthreads();
  for (int c = threadIdx.x; c < DIMM; c += 256){
    float a = 0.f;
    for (int k = 0; k < DIMM; ++k) a += po[k] * wo[(size_t)k*DIMM + c];
    out[(size_t)br*DIMM + c] = a + rt[(size_t)r*DIMM + c];
  }
}

// =================================================================
extern "C" void kernel_launch(void* const* d_in, const int* in_sizes, int n_in,
                              void* d_out, int out_size, void* d_ws, size_t ws_size,
                              hipStream_t stream)
{
  const float* rna        = (const float*)d_in[0];
  const float* atac       = (const float*)d_in[1];
  const float* rna_ln1_g  = (const float*)d_in[2];
  const float* rna_ln1_b  = (const float*)d_in[3];
  const float* rna_w      = (const float*)d_in[4];
  const float* rna_b      = (const float*)d_in[5];
  const float* rna_ln2_g  = (const float*)d_in[6];
  const float* rna_ln2_b  = (const float*)d_in[7];
  const float* atac_ln1_g = (const float*)d_in[8];
  const float* atac_ln1_b = (const float*)d_in[9];
  const float* atac_w     = (const float*)d_in[10];
  const float* atac_b     = (const float*)d_in[11];
  const float* atac_ln2_g = (const float*)d_in[12];
  const float* atac_ln2_b = (const float*)d_in[13];
  const float* fusion_tok = (const float*)d_in[14];
  const float* lay_ag     = (const float*)d_in[15];
  const float* lay_wq     = (const float*)d_in[16];
  const float* lay_wkv    = (const float*)d_in[17];
  const float* lay_wo     = (const float*)d_in[18];
  const float* lay_fg     = (const float*)d_in[19];
  const float* lay_w1     = (const float*)d_in[20];
  const float* lay_w2     = (const float*)d_in[21];
  const float* final_g    = (const float*)d_in[22];
  const float* ret_tok    = (const float*)d_in[23];
  const float* pool_g     = (const float*)d_in[24];
  const float* pool_wq    = (const float*)d_in[25];
  const float* pool_wkv   = (const float*)d_in[26];
  const float* pool_wo    = (const float*)d_in[27];

  // decide FFN width: full (rows=3104) if workspace allows, else halves
  const size_t FIXED = 28500000ULL;           // fixed carve budget (with slop)
  const size_t VAR_FULL = (size_t)MALL*IFF2*4 + (size_t)MALL*GSTRIDE*2 + (size_t)2*MALL*512*4;
  const int nh = (ws_size >= FIXED + VAR_FULL) ? 1 : 2;
  const int rowsF = MALL / nh;          // 3104 or 1552
  const int mgF = (rowsF + 127) / 128;  // 25 or 13

  uint8_t* ws = (uint8_t*)d_ws;
  size_t off = 0;
  auto carve = [&](size_t bytes) -> uint8_t* {
    uint8_t* p = ws + off;
    off += (bytes + 255) & ~(size_t)255;
    return p;
  };
  float* tok   = (float*)carve((size_t)MALL * DIMM * 4);
  u16*   xn    = (u16*)  carve((size_t)MALL * DIMM * 2);
  float* kv    = (float*)carve((size_t)MALL * 1024 * 4);
  u16*   lnbuf = (u16*)  carve((size_t)1536 * 1024 * 2);
  float* sim   = (float*)carve((size_t)BATCH*8*16*1536 * 4);
  float* qfus  = (float*)carve((size_t)BATCH*16*DIMM * 4);
  float* outf  = (float*)carve((size_t)BATCH*16*DIMM * 4);
  u16*   zb    = (u16*)  carve((size_t)BATCH*17*DIMM * 2);
  float* proj  = (float*)carve((size_t)BATCH*17*DIMM * 4);
  float* mv    = (float*)carve((size_t)BATCH*DIMM * 4);
  float* q2    = (float*)carve((size_t)DIMM * 4);
  float* out2  = (float*)carve((size_t)BATCH*DIMM * 4);
  float* fpvp  = (float*)carve((size_t)FPV_Z*BATCH*8*16*64 * 4);
  float* cmp_  = (float*)carve((size_t)CM_Z*BATCH*DIMM * 4);
  float* hbuf  = (float*)carve((size_t)rowsF * IFF2 * 4);
  u16*   gbuf  = (u16*)  carve((size_t)rowsF * GSTRIDE * 2);
  size_t skmax = (size_t)((rowsF > 1536) ? rowsF : 1536) * 512;
  float* skpart = (float*)carve(2 * skmax * 4);
  (void)ws_size;

  // ---- embeddings (split-K 2 over K=1024) ----
  ln_kernel<<<1536, 256, 0, stream>>>(rna, rna_ln1_g, rna_ln1_b, nullptr, lnbuf, 1024);
  gemm512<<<dim3(12, 4, 2), 512, 0, stream>>>(lnbuf, 1024, rna_w, 512, skpart, 512,
                                              (size_t)1536*512, 1536, 512, 1024, 512);
  skreduce<<<(1536*512 + 255)/256, 256, 0, stream>>>(hbuf, skpart, 1536*512, rna_b, 0);
  for (int b = 0; b < BATCH; ++b)
    ln_kernel<<<768, 256, 0, stream>>>(hbuf + (size_t)b*768*DIMM, rna_ln2_g, rna_ln2_b,
                                       tok + (size_t)b*NTOK*DIMM, nullptr, 512);
  ln_kernel<<<1536, 256, 0, stream>>>(atac, atac_ln1_g, atac_ln1_b, nullptr, lnbuf, 1024);
  gemm512<<<dim3(12, 4, 2), 512, 0, stream>>>(lnbuf, 1024, atac_w, 512, skpart, 512,
                                              (size_t)1536*512, 1536, 512, 1024, 512);
  skreduce<<<(1536*512 + 255)/256, 256, 0, stream>>>(hbuf, skpart, 1536*512, atac_b, 0);
  for (int b = 0; b < BATCH; ++b)
    ln_kernel<<<768, 256, 0, stream>>>(hbuf + (size_t)b*768*DIMM, atac_ln2_g, atac_ln2_b,
                                       tok + ((size_t)b*NTOK + 784)*DIMM, nullptr, 512);
  fuscopy_kernel<<<(BATCH*16*DIMM + 255)/256, 256, 0, stream>>>(fusion_tok, tok);

  // ---- transformer layers ----
  for (int l = 0; l < 4; ++l){
    const float* ag  = lay_ag  + (size_t)l*DIMM;
    const float* wq  = lay_wq  + (size_t)l*DIMM*DIMM;
    const float* wkv = lay_wkv + (size_t)l*DIMM*1024;
    const float* wo  = lay_wo  + (size_t)l*DIMM*DIMM;
    const float* fg  = lay_fg  + (size_t)l*DIMM;
    const float* w1  = lay_w1  + (size_t)l*DIMM*IFF2;
    const float* w2  = lay_w2  + (size_t)l*IFFC*DIMM;

    // attention
    ln_kernel<<<MALL, 256, 0, stream>>>(tok, ag, nullptr, nullptr, xn, 512);
    gemm512<<<dim3(25, 8, 1), 512, 0, stream>>>(xn, 512, wkv, 1024, kv, 1024, 0,
                                                MALL, 1024, 512, 512);
    gemm_tiny<<<dim3(1, 4, 2), 256, 0, stream>>>(xn + (size_t)768*DIMM, 512, (size_t)NTOK*DIMM,
                                                 wq, 512, qfus, 512, (size_t)16*DIMM, 16, 512, 512);
    colmean_part<<<dim3(2, BATCH, CM_Z), 256, 0, stream>>>(kv, cmp_);
    colmean_reduce<<<(BATCH*DIMM + 255)/256, 256, 0, stream>>>(cmp_, mv);
    fsim_kernel<<<dim3(8, BATCH, 6), 256, 0, stream>>>(kv, qfus, sim);
    softmax_kernel<<<BATCH*8*16, 256, 0, stream>>>(sim);
    fpv_part<<<dim3(8, BATCH, FPV_Z), 256, 0, stream>>>(kv, sim, fpvp);
    fpv_reduce<<<(BATCH*16*DIMM + 255)/256, 256, 0, stream>>>(fpvp, outf);
    packz_kernel<<<(BATCH*17*DIMM + 255)/256, 256, 0, stream>>>(mv, outf, zb);
    gemm_tiny<<<dim3(1, 4, 2), 256, 0, stream>>>(zb, 512, (size_t)17*DIMM,
                                                 wo, 512, proj, 512, (size_t)17*DIMM, 17, 512, 512);
    resadd_kernel<<<dim3(NTOK, BATCH), 256, 0, stream>>>(tok, proj);

    // GEGLU FFN
    ln_kernel<<<MALL, 256, 0, stream>>>(tok, fg, nullptr, nullptr, xn, 512);
    for (int hf = 0; hf < nh; ++hf){
      const u16* xh = xn + (size_t)hf*rowsF*DIMM;
      gemm512<<<dim3(mgF, 22, 1), 512, 0, stream>>>(xh, 512, w1, IFF2, hbuf, IFF2, 0,
                                                    rowsF, IFF2, 512, 512);
      geglu_kernel<<<(rowsF*IFFC + 255)/256, 256, 0, stream>>>(hbuf, gbuf, rowsF*IFFC);
      gemm512<<<dim3(mgF, 4, 2), 512, 0, stream>>>(gbuf, GSTRIDE, w2, 512, skpart, 512,
                                                   (size_t)rowsF*512, rowsF, 512, IFFC, 704);
      skreduce<<<(rowsF*512 + 255)/256, 256, 0, stream>>>(tok + (size_t)hf*rowsF*DIMM,
                                                          skpart, rowsF*512, nullptr, 1);
    }
  }

  // ---- final LN + pooling ----
  ln_kernel<<<MALL, 256, 0, stream>>>(tok, final_g, nullptr, nullptr, xn, 512);
  gemm512<<<dim3(25, 8, 1), 512, 0, stream>>>(xn, 512, pool_wkv, 1024, kv, 1024, 0,
                                              MALL, 1024, 512, 512);
  colmean_part<<<dim3(2, BATCH, CM_Z), 256, 0, stream>>>(kv, cmp_);
  colmean_reduce<<<(BATCH*DIMM + 255)/256, 256, 0, stream>>>(cmp_, mv);
  poolq2_kernel<<<1, 256, 0, stream>>>(ret_tok, pool_g, pool_wq, q2);
  poolattn2_kernel<<<dim3(8, BATCH), 64, 0, stream>>>(kv, q2, out2);
  pooled_kernel<<<BATCH*3, 256, 0, stream>>>(mv, out2, pool_wo, ret_tok, (float*)d_out);
}

// Round 4
// 962.352 us; speedup vs baseline: 3.4177x; 1.1631x over previous
//
#include <hip/hip_runtime.h>
#include <stdint.h>
#include <stddef.h>

#define NTOK 1552
#define DIMM 512
#define IFFC 1365
#define IFF2 2730
#define GSTRIDE 1376   // padded row stride (bf16 elems) for geglu output; also padded K of w2t
#define BATCH 2
#define MALL (BATCH*NTOK)   // 3104
#define FPV_Z 12
#define CM_Z 16

typedef unsigned short u16;
typedef __attribute__((ext_vector_type(8))) short bf16x8;
typedef __attribute__((ext_vector_type(4))) float f32x4;

__device__ __forceinline__ u16 f2bf(float f){
  union { float f; uint32_t u; } v; v.f = f;
  uint32_t u = v.u;
  uint32_t r = (u + 0x7FFFu + ((u >> 16) & 1u)) >> 16;
  return (u16)r;
}

// ---------------- weight convert+transpose: f32 [K][N] -> bf16 [N][ldk], zero pad ----------------
__global__ void convT_kernel(const float* __restrict__ w, u16* __restrict__ wt,
                             int K, int N, int ldk, size_t wstride, size_t wtstride)
{
  w  += (size_t)blockIdx.z * wstride;
  wt += (size_t)blockIdx.z * wtstride;
  __shared__ float tile[32][33];
  int kb = blockIdx.x*32, nb = blockIdx.y*32;
  int tx = threadIdx.x & 31, ty = threadIdx.x >> 5;   // 256 thr: ty 0..7
  for (int r = ty; r < 32; r += 8){
    int k = kb + r, n = nb + tx;
    tile[r][tx] = (k < K && n < N) ? w[(size_t)k*N + n] : 0.f;
  }
  __syncthreads();
  for (int r = ty; r < 32; r += 8){
    int n = nb + r, k = kb + tx;
    if (n < N && k < ldk) wt[(size_t)n*ldk + k] = f2bf(tile[tx][r]);
  }
}

// ---------------- LayerNorm: one block per row ----------------
__global__ void ln_kernel(const float* __restrict__ in, const float* __restrict__ g,
                          const float* __restrict__ bta, float* __restrict__ of32,
                          u16* __restrict__ obf, int D)
{
  const int r = blockIdx.x;
  const float* x = in + (size_t)r * D;
  float s = 0.f, ss = 0.f;
  for (int c = threadIdx.x; c < D; c += 256){ float v = x[c]; s += v; ss += v*v; }
  #pragma unroll
  for (int off = 32; off >= 1; off >>= 1){ s += __shfl_xor(s, off); ss += __shfl_xor(ss, off); }
  __shared__ float rs_[4], rss_[4];
  int w = threadIdx.x >> 6;
  if ((threadIdx.x & 63) == 0){ rs_[w] = s; rss_[w] = ss; }
  __syncthreads();
  s = rs_[0] + rs_[1] + rs_[2] + rs_[3];
  ss = rss_[0] + rss_[1] + rss_[2] + rss_[3];
  float mu = s / D;
  float var = ss / D - mu * mu;
  float rstd = rsqrtf(var + 1e-5f);
  for (int c = threadIdx.x; c < D; c += 256){
    float y = (x[c] - mu) * rstd * g[c] + (bta ? bta[c] : 0.f);
    if (of32) of32[(size_t)r*D + c] = y;
    if (obf)  obf[(size_t)r*D + c] = f2bf(y);
  }
}

// ------- gemm512: 8-wave 128x128 tile, B pre-transposed bf16 [N][ldk], split-K via grid.z -------
__global__ __launch_bounds__(512) void gemm512(
    const u16* __restrict__ A, int lda,
    const u16* __restrict__ Bt, int ldk,
    float* __restrict__ C, int ldc, size_t Cz,
    int M, int Nn, int K, int kchunk)
{
  __shared__ __align__(16) u16 As[128][40];
  __shared__ __align__(16) u16 Bs[128][40];
  const int t = threadIdx.x;
  const int lane = t & 63;
  const int w = t >> 6;          // 0..7
  const int wr = (w >> 2) * 64;  // 0,64
  const int wc = (w & 3) * 32;   // 0,32,64,96
  const int row0 = blockIdx.x * 128, col0 = blockIdx.y * 128;
  const int z = blockIdx.z;
  const int kbeg = z * kchunk;
  const int kend = (kbeg + kchunk < K) ? (kbeg + kchunk) : K;
  C += (size_t)z * Cz;
  const int l15 = lane & 15;
  const int l4 = (lane >> 4) * 8;
  f32x4 acc[4][2];
  #pragma unroll
  for (int m = 0; m < 4; ++m)
    #pragma unroll
    for (int n = 0; n < 2; ++n)
      #pragma unroll
      for (int j = 0; j < 4; ++j) acc[m][n][j] = 0.f;

  for (int k0 = kbeg; k0 < kend; k0 += 32) {
    // stage A (128x32) -- all k-tiles are full (K padded to multiple of 32)
    {
      int r = t >> 2, c8 = (t & 3) * 8;
      bf16x8 av;
      #pragma unroll
      for (int j = 0; j < 8; ++j) av[j] = 0;
      int gr = row0 + r;
      if (gr < M) av = *(const bf16x8*)(A + (size_t)gr*lda + k0 + c8);
      *(bf16x8*)(&As[r][c8]) = av;
    }
    // stage B (128 cols x 32 k) from bf16 [N][ldk]
    {
      int col = t & 127, kb = (t >> 7) * 8;
      bf16x8 bv;
      #pragma unroll
      for (int j = 0; j < 8; ++j) bv[j] = 0;
      int gc = col0 + col;
      if (gc < Nn) bv = *(const bf16x8*)(Bt + (size_t)gc*ldk + k0 + kb);
      *(bf16x8*)(&Bs[col][kb]) = bv;
    }
    __syncthreads();
    bf16x8 af[4], bfr[2];
    #pragma unroll
    for (int m = 0; m < 4; ++m) af[m]  = *(const bf16x8*)(&As[wr + m*16 + l15][l4]);
    #pragma unroll
    for (int n = 0; n < 2; ++n) bfr[n] = *(const bf16x8*)(&Bs[wc + n*16 + l15][l4]);
    #pragma unroll
    for (int m = 0; m < 4; ++m)
      #pragma unroll
      for (int n = 0; n < 2; ++n)
        acc[m][n] = __builtin_amdgcn_mfma_f32_16x16x32_bf16(af[m], bfr[n], acc[m][n], 0, 0, 0);
    __syncthreads();
  }
  const int rb = (lane >> 4) * 4;
  #pragma unroll
  for (int m = 0; m < 4; ++m){
    int gr0 = row0 + wr + m*16 + rb;
    #pragma unroll
    for (int n = 0; n < 2; ++n){
      int gc = col0 + wc + n*16 + l15;
      if (gc >= Nn) continue;
      #pragma unroll
      for (int j = 0; j < 4; ++j){
        int gr = gr0 + j;
        if (gr < M) C[(size_t)gr*ldc + gc] = acc[m][n][j];
      }
    }
  }
}

// ------- split-K / bias reduce -------
__global__ void skreduce(float* __restrict__ dst, const float* __restrict__ part,
                         int len, const float* __restrict__ bias, int addDst)
{
  int i = blockIdx.x * 256 + threadIdx.x;
  if (i >= len) return;
  float s = part[i] + part[(size_t)len + i];
  if (bias) s += bias[i & 511];
  if (addDst) dst[i] += s; else dst[i] = s;
}

// ------- tiny GEMM (M<=128), B pre-transposed bf16, batched over grid.z -------
__global__ __launch_bounds__(256) void gemm_tiny(
    const u16* __restrict__ A, int lda, size_t Abat,
    const u16* __restrict__ Bt, int ldk,
    float* __restrict__ C, int ldc, size_t Cbat,
    int M, int Nn, int K)
{
  A += (size_t)blockIdx.z * Abat;
  C += (size_t)blockIdx.z * Cbat;
  __shared__ __align__(16) u16 As[128][40];
  __shared__ __align__(16) u16 Bs[128][40];
  const int t = threadIdx.x;
  const int lane = t & 63;
  const int w = t >> 6;
  const int wr = (w >> 1) * 64, wc = (w & 1) * 64;
  const int col0 = blockIdx.y * 128;
  const int l15 = lane & 15;
  const int l4 = (lane >> 4) * 8;
  f32x4 acc[4][4];
  #pragma unroll
  for (int m = 0; m < 4; ++m)
    #pragma unroll
    for (int n = 0; n < 4; ++n)
      #pragma unroll
      for (int j = 0; j < 4; ++j) acc[m][n][j] = 0.f;

  for (int k0 = 0; k0 < K; k0 += 32) {
    #pragma unroll
    for (int u = 0; u < 2; ++u){
      int id = t + u*256;
      int r = id >> 2, c8 = (id & 3) * 8;
      bf16x8 av;
      #pragma unroll
      for (int j = 0; j < 8; ++j) av[j] = 0;
      if (r < M) av = *(const bf16x8*)(A + (size_t)r*lda + k0 + c8);
      *(bf16x8*)(&As[r][c8]) = av;
    }
    {
      int col = t & 127, kb = (t >> 7) * 16;
      bf16x8 b0, b1;
      #pragma unroll
      for (int j = 0; j < 8; ++j){ b0[j] = 0; b1[j] = 0; }
      int gc = col0 + col;
      if (gc < Nn){
        b0 = *(const bf16x8*)(Bt + (size_t)gc*ldk + k0 + kb);
        b1 = *(const bf16x8*)(Bt + (size_t)gc*ldk + k0 + kb + 8);
      }
      *(bf16x8*)(&Bs[col][kb])     = b0;
      *(bf16x8*)(&Bs[col][kb + 8]) = b1;
    }
    __syncthreads();
    bf16x8 af[4], bfr[4];
    #pragma unroll
    for (int m = 0; m < 4; ++m) af[m]  = *(const bf16x8*)(&As[wr + m*16 + l15][l4]);
    #pragma unroll
    for (int n = 0; n < 4; ++n) bfr[n] = *(const bf16x8*)(&Bs[wc + n*16 + l15][l4]);
    #pragma unroll
    for (int m = 0; m < 4; ++m)
      #pragma unroll
      for (int n = 0; n < 4; ++n)
        acc[m][n] = __builtin_amdgcn_mfma_f32_16x16x32_bf16(af[m], bfr[n], acc[m][n], 0, 0, 0);
    __syncthreads();
  }
  const int rb = (lane >> 4) * 4;
  #pragma unroll
  for (int m = 0; m < 4; ++m){
    int gr0 = wr + m*16 + rb;
    #pragma unroll
    for (int n = 0; n < 4; ++n){
      int gc = col0 + wc + n*16 + l15;
      if (gc >= Nn) continue;
      #pragma unroll
      for (int j = 0; j < 4; ++j){
        int gr = gr0 + j;
        if (gr < M) C[(size_t)gr*ldc + gc] = acc[m][n][j];
      }
    }
  }
}

// ---------------- copy fusion tokens into tok ----------------
__global__ void fuscopy_kernel(const float* __restrict__ ft, float* __restrict__ tok)
{
  int i = blockIdx.x * 256 + threadIdx.x;
  if (i >= BATCH*16*DIMM) return;
  int c = i & 511; int tt = i >> 9; int b = tt >> 4; int r = tt & 15;
  tok[((size_t)(b*NTOK + 768 + r))*DIMM + c] = ft[r*DIMM + c];
}

// ---------------- column mean of V: partials over row-chunks ----------------
__global__ void colmean_part(const float* __restrict__ kvv, float* __restrict__ part)
{
  int c = blockIdx.x * 256 + threadIdx.x;
  int b = blockIdx.y, z = blockIdx.z;
  int r0 = z * 97;
  int r1 = r0 + 97; if (r1 > NTOK) r1 = NTOK;
  const float* src = kvv + (size_t)b*NTOK*1024 + 512 + c;
  float s = 0.f;
  for (int r = r0; r < r1; ++r) s += src[(size_t)r*1024];
  part[(((size_t)z*BATCH + b) << 9) + c] = s;
}

__global__ void colmean_reduce(const float* __restrict__ part, float* __restrict__ mv)
{
  int i = blockIdx.x * 256 + threadIdx.x;
  if (i >= BATCH*DIMM) return;
  int b = i >> 9, c = i & 511;
  float s = 0.f;
  #pragma unroll
  for (int z = 0; z < CM_Z; ++z) s += part[(((size_t)z*BATCH + b) << 9) + c];
  mv[b*DIMM + c] = s * (1.0f/1552.0f);
}

// ---------------- fusion q@k^T ----------------
__global__ void fsim_kernel(const float* __restrict__ kv, const float* __restrict__ qf,
                            float* __restrict__ sim)
{
  int h = blockIdx.x, b = blockIdx.y, z = blockIdx.z;
  __shared__ float qs[16][64];
  for (int i = threadIdx.x; i < 16*64; i += 256){
    int q = i >> 6, d = i & 63;
    qs[q][d] = qf[((size_t)(b*16 + q))*DIMM + h*64 + d];
  }
  __syncthreads();
  int jj = z*256 + threadIdx.x;
  int j = (jj < 768) ? jj : jj + 16;
  const float* kr = kv + ((size_t)(b*NTOK + j))*1024 + h*64;
  float acc[16];
  #pragma unroll
  for (int q = 0; q < 16; ++q) acc[q] = 0.f;
  #pragma unroll
  for (int d4 = 0; d4 < 16; ++d4){
    float4 kd = *(const float4*)(kr + d4*4);
    #pragma unroll
    for (int q = 0; q < 16; ++q)
      acc[q] += qs[q][d4*4+0]*kd.x + qs[q][d4*4+1]*kd.y + qs[q][d4*4+2]*kd.z + qs[q][d4*4+3]*kd.w;
  }
  float* so = sim + ((size_t)(b*8 + h) * 16) * 1536 + jj;
  #pragma unroll
  for (int q = 0; q < 16; ++q) so[(size_t)q*1536] = acc[q] * 0.125f;
}

// ---------------- softmax over 1536 (in place) ----------------
__global__ void softmax_kernel(float* __restrict__ sim)
{
  float* x = sim + (size_t)blockIdx.x * 1536;
  float e[6];
  float m = -3.4e38f;
  #pragma unroll
  for (int i = 0; i < 6; ++i){ e[i] = x[threadIdx.x + i*256]; m = fmaxf(m, e[i]); }
  #pragma unroll
  for (int off = 32; off >= 1; off >>= 1) m = fmaxf(m, __shfl_xor(m, off));
  __shared__ float red[4];
  int w = threadIdx.x >> 6;
  if ((threadIdx.x & 63) == 0) red[w] = m;
  __syncthreads();
  m = fmaxf(fmaxf(red[0], red[1]), fmaxf(red[2], red[3]));
  __syncthreads();
  float s = 0.f;
  #pragma unroll
  for (int i = 0; i < 6; ++i){ e[i] = expf(e[i] - m); s += e[i]; }
  #pragma unroll
  for (int off = 32; off >= 1; off >>= 1) s += __shfl_xor(s, off);
  if ((threadIdx.x & 63) == 0) red[w] = s;
  __syncthreads();
  s = red[0] + red[1] + red[2] + red[3];
  float inv = 1.0f / s;
  #pragma unroll
  for (int i = 0; i < 6; ++i) x[threadIdx.x + i*256] = e[i] * inv;
}

// ---------------- attn @ V for fusion rows ----------------
__global__ void fpv_part(const float* __restrict__ kv, const float* __restrict__ sim,
                         float* __restrict__ part)
{
  int h = blockIdx.x, b = blockIdx.y, z = blockIdx.z;
  int d = threadIdx.x & 63, g = threadIdx.x >> 6;
  float acc[4] = {0.f, 0.f, 0.f, 0.f};
  const float* sb = sim + ((size_t)(b*8 + h) * 16) * 1536;
  int j0 = z * 128;
  for (int jj = j0; jj < j0 + 128; ++jj){
    int j = (jj < 768) ? jj : jj + 16;
    float vd = kv[((size_t)(b*NTOK + j))*1024 + 512 + h*64 + d];
    #pragma unroll
    for (int q = 0; q < 4; ++q) acc[q] += sb[(size_t)(g*4 + q)*1536 + jj] * vd;
  }
  float* po = part + ((((size_t)z*BATCH + b)*8 + h)*16)*64;
  #pragma unroll
  for (int q = 0; q < 4; ++q) po[(size_t)(g*4 + q)*64 + d] = acc[q];
}

__global__ void fpv_reduce(const float* __restrict__ part, float* __restrict__ outf)
{
  int i = blockIdx.x * 256 + threadIdx.x;
  if (i >= BATCH*16*DIMM) return;
  int d = i & 63; int rest = i >> 6;
  int h = rest & 7; rest >>= 3;
  int q = rest & 15; int b = rest >> 4;
  float s = 0.f;
  #pragma unroll
  for (int z = 0; z < FPV_Z; ++z)
    s += part[(((((size_t)z*BATCH + b)*8 + h)*16) + q)*64 + d];
  outf[((size_t)(b*16 + q))*DIMM + h*64 + d] = s;
}

// ---------------- pack [mean ; 16 fusion outs] -> bf16 ----------------
__global__ void packz_kernel(const float* __restrict__ mv, const float* __restrict__ outf,
                             u16* __restrict__ zb)
{
  int i = blockIdx.x * 256 + threadIdx.x;
  if (i >= BATCH*17*DIMM) return;
  int c = i & 511;
  int tt = i >> 9;
  int b = tt / 17, r = tt % 17;
  float v = (r == 0) ? mv[b*DIMM + c] : outf[((size_t)b*16 + (r-1))*DIMM + c];
  zb[i] = f2bf(v);
}

// ---------------- residual scatter-add ----------------
__global__ void resadd_kernel(float* __restrict__ tok, const float* __restrict__ proj)
{
  int n = blockIdx.x, b = blockIdx.y;
  int pr = (n >= 768 && n < 784) ? (1 + n - 768) : 0;
  const float* p = proj + ((size_t)b*17 + pr)*DIMM;
  float* tr = tok + ((size_t)(b*NTOK + n))*DIMM;
  for (int c = threadIdx.x; c < DIMM; c += 256) tr[c] += p[c];
}

// ---------------- GEGLU (writes full padded stride; pad cols = 0) ----------------
__global__ void geglu_kernel(const float* __restrict__ h, u16* __restrict__ g, int n)
{
  int i = blockIdx.x * 256 + threadIdx.x;
  if (i >= n) return;
  int r = i / GSTRIDE, c = i % GSTRIDE;
  float out = 0.f;
  if (c < IFFC){
    float x1 = h[(size_t)r*IFF2 + c];
    float gt = h[(size_t)r*IFF2 + IFFC + c];
    float ge = 0.5f * gt * (1.0f + erff(gt * 0.70710678118654752f));
    out = ge * x1;
  }
  g[i] = f2bf(out);
}

// ---------------- parallel mat-vec: out[c] = scale*sum_k y[k]*w[k*512+c] ----------------
__global__ void matvec512(const float* __restrict__ y, const float* __restrict__ w,
                          float* __restrict__ out, float scale)
{
  __shared__ float ys[512];
  __shared__ float red[4][64];
  int t = threadIdx.x;
  ys[t] = y[t]; ys[t+256] = y[t+256];
  __syncthreads();
  int col = blockIdx.x*64 + (t & 63);
  int kq = t >> 6;
  float s = 0.f;
  #pragma unroll 4
  for (int k = kq*128; k < kq*128+128; ++k) s += ys[k] * w[(size_t)k*512 + col];
  red[kq][t & 63] = s;
  __syncthreads();
  if (t < 64)
    out[blockIdx.x*64 + t] = (red[0][t]+red[1][t]+red[2][t]+red[3][t]) * scale;
}

// ---------------- pooled rows: out[br][c] = sum_k po[k]*wo[k*512+c] + rt[r][c] ----------------
__global__ void pooledmv(const float* __restrict__ mv, const float* __restrict__ out2,
                         const float* __restrict__ wo, const float* __restrict__ rt,
                         float* __restrict__ out)
{
  int br = blockIdx.y; int b = br/3, r = br%3;
  const float* y = (r < 2) ? (mv + (size_t)b*DIMM) : (out2 + (size_t)b*DIMM);
  __shared__ float ys[512];
  __shared__ float red[4][64];
  int t = threadIdx.x;
  ys[t] = y[t]; ys[t+256] = y[t+256];
  __syncthreads();
  int col = blockIdx.x*64 + (t & 63);
  int kq = t >> 6;
  float s = 0.f;
  #pragma unroll 4
  for (int k = kq*128; k < kq*128+128; ++k) s += ys[k] * wo[(size_t)k*512 + col];
  red[kq][t & 63] = s;
  __syncthreads();
  if (t < 64){
    int c = blockIdx.x*64 + t;
    out[(size_t)br*DIMM + c] = red[0][t]+red[1][t]+red[2][t]+red[3][t] + rt[(size_t)r*DIMM + c];
  }
}

// ---------------- pool: attention of return-token 2 over 16 fusion keys ----------------
__global__ void poolattn2_kernel(const float* __restrict__ kv, const float* __restrict__ q2,
                                 float* __restrict__ out2)
{
  int h = blockIdx.x, b = blockIdx.y, d = threadIdx.x;
  __shared__ float sm[16];
  if (d < 16){
    const float* kr = kv + ((size_t)(b*NTOK + 768 + d))*1024 + h*64;
    float a = 0.f;
    for (int k = 0; k < 64; ++k) a += q2[h*64 + k] * kr[k];
    sm[d] = a;
  }
  __syncthreads();
  float m = -3.4e38f;
  #pragma unroll
  for (int j = 0; j < 16; ++j) m = fmaxf(m, sm[j]);
  float wv[16]; float s = 0.f;
  #pragma unroll
  for (int j = 0; j < 16; ++j){ wv[j] = expf(sm[j] - m); s += wv[j]; }
  float inv = 1.0f / s;
  float a = 0.f;
  #pragma unroll
  for (int j = 0; j < 16; ++j)
    a += wv[j] * kv[((size_t)(b*NTOK + 768 + j))*1024 + 512 + h*64 + d];
  out2[(size_t)b*DIMM + h*64 + d] = a * inv;
}

// =================================================================
extern "C" void kernel_launch(void* const* d_in, const int* in_sizes, int n_in,
                              void* d_out, int out_size, void* d_ws, size_t ws_size,
                              hipStream_t stream)
{
  const float* rna        = (const float*)d_in[0];
  const float* atac       = (const float*)d_in[1];
  const float* rna_ln1_g  = (const float*)d_in[2];
  const float* rna_ln1_b  = (const float*)d_in[3];
  const float* rna_w      = (const float*)d_in[4];
  const float* rna_b      = (const float*)d_in[5];
  const float* rna_ln2_g  = (const float*)d_in[6];
  const float* rna_ln2_b  = (const float*)d_in[7];
  const float* atac_ln1_g = (const float*)d_in[8];
  const float* atac_ln1_b = (const float*)d_in[9];
  const float* atac_w     = (const float*)d_in[10];
  const float* atac_b     = (const float*)d_in[11];
  const float* atac_ln2_g = (const float*)d_in[12];
  const float* atac_ln2_b = (const float*)d_in[13];
  const float* fusion_tok = (const float*)d_in[14];
  const float* lay_ag     = (const float*)d_in[15];
  const float* lay_wq     = (const float*)d_in[16];
  const float* lay_wkv    = (const float*)d_in[17];
  const float* lay_wo     = (const float*)d_in[18];
  const float* lay_fg     = (const float*)d_in[19];
  const float* lay_w1     = (const float*)d_in[20];
  const float* lay_w2     = (const float*)d_in[21];
  const float* final_g    = (const float*)d_in[22];
  const float* ret_tok    = (const float*)d_in[23];
  const float* pool_g     = (const float*)d_in[24];
  const float* pool_wq    = (const float*)d_in[25];
  const float* pool_wkv   = (const float*)d_in[26];
  const float* pool_wo    = (const float*)d_in[27];

  // FFN width decision: full rows if ws allows, else halves
  const size_t FIXED = 59000000ULL;   // fixed carve incl. bf16 weights (with slop)
  const size_t VAR_FULL = (size_t)MALL*IFF2*4 + (size_t)MALL*GSTRIDE*2 + (size_t)2*MALL*512*4;
  const int nh = (ws_size >= FIXED + VAR_FULL) ? 1 : 2;
  const int rowsF = MALL / nh;
  const int mgF = (rowsF + 127) / 128;

  uint8_t* ws = (uint8_t*)d_ws;
  size_t off = 0;
  auto carve = [&](size_t bytes) -> uint8_t* {
    uint8_t* p = ws + off;
    off += (bytes + 255) & ~(size_t)255;
    return p;
  };
  // bf16 transposed weights
  u16* rna_wt   = (u16*)carve((size_t)512*1024*2);
  u16* atac_wt  = (u16*)carve((size_t)512*1024*2);
  u16* wkvt     = (u16*)carve((size_t)4*1024*512*2);
  u16* wqt      = (u16*)carve((size_t)4*512*512*2);
  u16* wot      = (u16*)carve((size_t)4*512*512*2);
  u16* w1t      = (u16*)carve((size_t)4*IFF2*512*2);
  u16* w2t      = (u16*)carve((size_t)4*512*GSTRIDE*2);
  u16* pool_wkvt= (u16*)carve((size_t)1024*512*2);
  // activations
  float* tok   = (float*)carve((size_t)MALL * DIMM * 4);
  u16*   xn    = (u16*)  carve((size_t)MALL * DIMM * 2);
  float* kv    = (float*)carve((size_t)MALL * 1024 * 4);
  u16*   lnbuf = (u16*)  carve((size_t)1536 * 1024 * 2);
  float* sim   = (float*)carve((size_t)BATCH*8*16*1536 * 4);
  float* qfus  = (float*)carve((size_t)BATCH*16*DIMM * 4);
  float* outf  = (float*)carve((size_t)BATCH*16*DIMM * 4);
  u16*   zb    = (u16*)  carve((size_t)BATCH*17*DIMM * 2);
  float* proj  = (float*)carve((size_t)BATCH*17*DIMM * 4);
  float* mv    = (float*)carve((size_t)BATCH*DIMM * 4);
  float* q2    = (float*)carve((size_t)DIMM * 4);
  float* yq2   = (float*)carve((size_t)DIMM * 4);
  float* out2  = (float*)carve((size_t)BATCH*DIMM * 4);
  float* fpvp  = (float*)carve((size_t)FPV_Z*BATCH*8*16*64 * 4);
  float* cmp_  = (float*)carve((size_t)CM_Z*BATCH*DIMM * 4);
  float* hbuf  = (float*)carve((size_t)rowsF * IFF2 * 4);
  u16*   gbuf  = (u16*)  carve((size_t)rowsF * GSTRIDE * 2);
  size_t skmax = (size_t)((rowsF > 1536) ? rowsF : 1536) * 512;
  float* skpart = (float*)carve(2 * skmax * 4);
  (void)ws_size;

  // ---- weight conversion (bf16, transposed [N][ldk]) ----
  convT_kernel<<<dim3(32, 16, 1), 256, 0, stream>>>(rna_w, rna_wt, 1024, 512, 1024, 0, 0);
  convT_kernel<<<dim3(32, 16, 1), 256, 0, stream>>>(atac_w, atac_wt, 1024, 512, 1024, 0, 0);
  convT_kernel<<<dim3(16, 32, 4), 256, 0, stream>>>(lay_wkv, wkvt, 512, 1024, 512,
                                                    (size_t)512*1024, (size_t)1024*512);
  convT_kernel<<<dim3(16, 16, 4), 256, 0, stream>>>(lay_wq, wqt, 512, 512, 512,
                                                    (size_t)512*512, (size_t)512*512);
  convT_kernel<<<dim3(16, 16, 4), 256, 0, stream>>>(lay_wo, wot, 512, 512, 512,
                                                    (size_t)512*512, (size_t)512*512);
  convT_kernel<<<dim3(16, 86, 4), 256, 0, stream>>>(lay_w1, w1t, 512, IFF2, 512,
                                                    (size_t)512*IFF2, (size_t)IFF2*512);
  convT_kernel<<<dim3(43, 16, 4), 256, 0, stream>>>(lay_w2, w2t, IFFC, 512, GSTRIDE,
                                                    (size_t)IFFC*512, (size_t)512*GSTRIDE);
  convT_kernel<<<dim3(16, 32, 1), 256, 0, stream>>>(pool_wkv, pool_wkvt, 512, 1024, 512, 0, 0);

  // ---- embeddings (split-K 2 over K=1024) ----
  ln_kernel<<<1536, 256, 0, stream>>>(rna, rna_ln1_g, rna_ln1_b, nullptr, lnbuf, 1024);
  gemm512<<<dim3(12, 4, 2), 512, 0, stream>>>(lnbuf, 1024, rna_wt, 1024, skpart, 512,
                                              (size_t)1536*512, 1536, 512, 1024, 512);
  skreduce<<<(1536*512 + 255)/256, 256, 0, stream>>>(hbuf, skpart, 1536*512, rna_b, 0);
  for (int b = 0; b < BATCH; ++b)
    ln_kernel<<<768, 256, 0, stream>>>(hbuf + (size_t)b*768*DIMM, rna_ln2_g, rna_ln2_b,
                                       tok + (size_t)b*NTOK*DIMM, nullptr, 512);
  ln_kernel<<<1536, 256, 0, stream>>>(atac, atac_ln1_g, atac_ln1_b, nullptr, lnbuf, 1024);
  gemm512<<<dim3(12, 4, 2), 512, 0, stream>>>(lnbuf, 1024, atac_wt, 1024, skpart, 512,
                                              (size_t)1536*512, 1536, 512, 1024, 512);
  skreduce<<<(1536*512 + 255)/256, 256, 0, stream>>>(hbuf, skpart, 1536*512, atac_b, 0);
  for (int b = 0; b < BATCH; ++b)
    ln_kernel<<<768, 256, 0, stream>>>(hbuf + (size_t)b*768*DIMM, atac_ln2_g, atac_ln2_b,
                                       tok + ((size_t)b*NTOK + 784)*DIMM, nullptr, 512);
  fuscopy_kernel<<<(BATCH*16*DIMM + 255)/256, 256, 0, stream>>>(fusion_tok, tok);

  // ---- transformer layers ----
  for (int l = 0; l < 4; ++l){
    const float* ag  = lay_ag  + (size_t)l*DIMM;
    const float* fg  = lay_fg  + (size_t)l*DIMM;
    const u16* wkvt_l = wkvt + (size_t)l*1024*512;
    const u16* wqt_l  = wqt  + (size_t)l*512*512;
    const u16* wot_l  = wot  + (size_t)l*512*512;
    const u16* w1t_l  = w1t  + (size_t)l*IFF2*512;
    const u16* w2t_l  = w2t  + (size_t)l*512*GSTRIDE;

    // attention
    ln_kernel<<<MALL, 256, 0, stream>>>(tok, ag, nullptr, nullptr, xn, 512);
    gemm512<<<dim3(25, 8, 1), 512, 0, stream>>>(xn, 512, wkvt_l, 512, kv, 1024, 0,
                                                MALL, 1024, 512, 512);
    gemm_tiny<<<dim3(1, 4, 2), 256, 0, stream>>>(xn + (size_t)768*DIMM, 512, (size_t)NTOK*DIMM,
                                                 wqt_l, 512, qfus, 512, (size_t)16*DIMM, 16, 512, 512);
    colmean_part<<<dim3(2, BATCH, CM_Z), 256, 0, stream>>>(kv, cmp_);
    colmean_reduce<<<(BATCH*DIMM + 255)/256, 256, 0, stream>>>(cmp_, mv);
    fsim_kernel<<<dim3(8, BATCH, 6), 256, 0, stream>>>(kv, qfus, sim);
    softmax_kernel<<<BATCH*8*16, 256, 0, stream>>>(sim);
    fpv_part<<<dim3(8, BATCH, FPV_Z), 256, 0, stream>>>(kv, sim, fpvp);
    fpv_reduce<<<(BATCH*16*DIMM + 255)/256, 256, 0, stream>>>(fpvp, outf);
    packz_kernel<<<(BATCH*17*DIMM + 255)/256, 256, 0, stream>>>(mv, outf, zb);
    gemm_tiny<<<dim3(1, 4, 2), 256, 0, stream>>>(zb, 512, (size_t)17*DIMM,
                                                 wot_l, 512, proj, 512, (size_t)17*DIMM, 17, 512, 512);
    resadd_kernel<<<dim3(NTOK, BATCH), 256, 0, stream>>>(tok, proj);

    // GEGLU FFN
    ln_kernel<<<MALL, 256, 0, stream>>>(tok, fg, nullptr, nullptr, xn, 512);
    for (int hf = 0; hf < nh; ++hf){
      const u16* xh = xn + (size_t)hf*rowsF*DIMM;
      gemm512<<<dim3(mgF, 22, 1), 512, 0, stream>>>(xh, 512, w1t_l, 512, hbuf, IFF2, 0,
                                                    rowsF, IFF2, 512, 512);
      geglu_kernel<<<(rowsF*GSTRIDE + 255)/256, 256, 0, stream>>>(hbuf, gbuf, rowsF*GSTRIDE);
      gemm512<<<dim3(mgF, 4, 2), 512, 0, stream>>>(gbuf, GSTRIDE, w2t_l, GSTRIDE, skpart, 512,
                                                   (size_t)rowsF*512, rowsF, 512, GSTRIDE, 704);
      skreduce<<<(rowsF*512 + 255)/256, 256, 0, stream>>>(tok + (size_t)hf*rowsF*DIMM,
                                                          skpart, rowsF*512, nullptr, 1);
    }
  }

  // ---- final LN + pooling ----
  ln_kernel<<<MALL, 256, 0, stream>>>(tok, final_g, nullptr, nullptr, xn, 512);
  gemm512<<<dim3(25, 8, 1), 512, 0, stream>>>(xn, 512, pool_wkvt, 512, kv, 1024, 0,
                                              MALL, 1024, 512, 512);
  colmean_part<<<dim3(2, BATCH, CM_Z), 256, 0, stream>>>(kv, cmp_);
  colmean_reduce<<<(BATCH*DIMM + 255)/256, 256, 0, stream>>>(cmp_, mv);
  ln_kernel<<<1, 256, 0, stream>>>(ret_tok + 2*DIMM, pool_g, nullptr, yq2, nullptr, 512);
  matvec512<<<8, 256, 0, stream>>>(yq2, pool_wq, q2, 0.125f);
  poolattn2_kernel<<<dim3(8, BATCH), 64, 0, stream>>>(kv, q2, out2);
  pooledmv<<<dim3(8, 6), 256, 0, stream>>>(mv, out2, pool_wo, ret_tok, (float*)d_out);
}

// Round 5
// 815.034 us; speedup vs baseline: 4.0354x; 1.1808x over previous
//
#include <hip/hip_runtime.h>
#include <stdint.h>
#include <stddef.h>

#define NTOK 1552
#define DIMM 512
#define IFFC 1365
#define IFF2 2730
#define NW1 2816       // padded/permuted w1 output cols (2*1408)
#define GSTRIDE 1408   // geglu output row stride (bf16) = padded K of w2
#define BATCH 2
#define MALL (BATCH*NTOK)   // 3104
#define FPV_Z 12
#define CM_Z 16

typedef unsigned short u16;
typedef __attribute__((ext_vector_type(8))) short bf16x8;
typedef __attribute__((ext_vector_type(4))) float f32x4;

__device__ __forceinline__ u16 f2bf(float f){
  union { float f; uint32_t u; } v; v.f = f;
  uint32_t u = v.u;
  uint32_t r = (u + 0x7FFFu + ((u >> 16) & 1u)) >> 16;
  return (u16)r;
}

// ---------- one-dispatch weight convert/transpose (8 segments) ----------
// seg5 (w1) uses the geglu column permutation; outputs bf16 [N][ldk] zero-padded.
__global__ void convall(const float* s0,const float* s1,const float* s2,const float* s3,
                        const float* s4,const float* s5,const float* s6,const float* s7,
                        u16* d0,u16* d1,u16* d2,u16* d3,u16* d4,u16* d5,u16* d6,u16* d7)
{
  const float* srcs[8] = {s0,s1,s2,s3,s4,s5,s6,s7};
  u16* dsts[8] = {d0,d1,d2,d3,d4,d5,d6,d7};
  const int KT[8]   = {32,32,16,16,16,16,44,16};
  const int NT[8]   = {16,16,32,16,16,88,16,32};
  const int TC[8]   = {512,512,2048,1024,1024,5632,2816,512};
  const int K_[8]   = {1024,1024,512,512,512,512,1365,512};
  const int NSRC[8] = {512,512,1024,512,512,2730,512,1024};
  const int LDK[8]  = {1024,1024,512,512,512,512,1408,512};
  const int NOUT[8] = {512,512,1024,512,512,2816,512,1024};
  const int WS_[8]  = {0,0,512*1024,512*512,512*512,512*2730,1365*512,0};
  const int WT_[8]  = {0,0,1024*512,512*512,512*512,2816*512,512*1408,0};

  int bid = blockIdx.x;
  int seg = 0, base = 0;
  while (seg < 7 && bid >= base + TC[seg]) { base += TC[seg]; ++seg; }
  int loc = bid - base;
  int kt = KT[seg], nt = NT[seg];
  int z = loc / (kt*nt); loc -= z*(kt*nt);
  int kb = (loc % kt) * 32, nb = (loc / kt) * 32;
  const float* w = srcs[seg] + (size_t)z * WS_[seg];
  u16* wt = dsts[seg] + (size_t)z * WT_[seg];
  int K = K_[seg], NS = NSRC[seg], ldk = LDK[seg], NO = NOUT[seg];

  __shared__ float tile[32][33];
  int tx = threadIdx.x & 31, ty = threadIdx.x >> 5;
  for (int r = ty; r < 32; r += 8){
    int k = kb + r, n = nb + tx;
    float v = 0.f;
    if (k < K && n < NO){
      int osrc = n; bool ok = (n < NS);
      if (seg == 5){
        int bb = n >> 7, rr = n & 127, g = rr >> 5, h = rr & 31;
        int j = bb*64 + g*16 + (h & 15);
        ok = (j < 1365);
        osrc = (h < 16) ? j : 1365 + j;
      }
      if (ok) v = w[(size_t)k*NS + osrc];
    }
    tile[r][tx] = v;
  }
  __syncthreads();
  for (int r = ty; r < 32; r += 8){
    int n = nb + r, k = kb + tx;
    if (n < NO && k < ldk) wt[(size_t)n*ldk + k] = f2bf(tile[tx][r]);
  }
}

// ---------------- LayerNorm: one block per row ----------------
__global__ void ln_kernel(const float* __restrict__ in, const float* __restrict__ g,
                          const float* __restrict__ bta, float* __restrict__ of32,
                          u16* __restrict__ obf, int D)
{
  const int r = blockIdx.x;
  const float* x = in + (size_t)r * D;
  float s = 0.f, ss = 0.f;
  for (int c = threadIdx.x; c < D; c += 256){ float v = x[c]; s += v; ss += v*v; }
  #pragma unroll
  for (int off = 32; off >= 1; off >>= 1){ s += __shfl_xor(s, off); ss += __shfl_xor(ss, off); }
  __shared__ float rs_[4], rss_[4];
  int w = threadIdx.x >> 6;
  if ((threadIdx.x & 63) == 0){ rs_[w] = s; rss_[w] = ss; }
  __syncthreads();
  s = rs_[0] + rs_[1] + rs_[2] + rs_[3];
  ss = rss_[0] + rss_[1] + rss_[2] + rss_[3];
  float mu = s / D;
  float rstd = rsqrtf(ss / D - mu*mu + 1e-5f);
  for (int c = threadIdx.x; c < D; c += 256){
    float y = (x[c] - mu) * rstd * g[c] + (bta ? bta[c] : 0.f);
    if (of32) of32[(size_t)r*D + c] = y;
    if (obf)  obf[(size_t)r*D + c] = f2bf(y);
  }
}

// ---- embed: tok_row = LN(part0+part1+bias; g,b) scattered into tok ----
__global__ void embed_addln(const float* __restrict__ part, const float* __restrict__ bias,
                            const float* __restrict__ g, const float* __restrict__ bta,
                            float* __restrict__ tok, int atacflag)
{
  int r = blockIdx.x;          // 0..1535
  int b = r / 768, rr = r % 768;
  const float* p0 = part + (size_t)r*DIMM;
  const float* p1 = p0 + (size_t)1536*DIMM;
  int t = threadIdx.x;
  float v0 = p0[t] + p1[t] + bias[t];
  float v1 = p0[t+256] + p1[t+256] + bias[t+256];
  float s = v0 + v1, ss = v0*v0 + v1*v1;
  #pragma unroll
  for (int off = 32; off >= 1; off >>= 1){ s += __shfl_xor(s, off); ss += __shfl_xor(ss, off); }
  __shared__ float rs_[4], rss_[4];
  int w = t >> 6;
  if ((t & 63) == 0){ rs_[w] = s; rss_[w] = ss; }
  __syncthreads();
  s = rs_[0]+rs_[1]+rs_[2]+rs_[3];
  ss = rss_[0]+rss_[1]+rss_[2]+rss_[3];
  float mu = s / DIMM;
  float rstd = rsqrtf(ss / DIMM - mu*mu + 1e-5f);
  float* tr = tok + ((size_t)(b*NTOK + (atacflag ? 784 : 0) + rr))*DIMM;
  tr[t]     = (v0 - mu)*rstd*g[t]     + bta[t];
  tr[t+256] = (v1 - mu)*rstd*g[t+256] + bta[t+256];
}

// ---- residual-add (attention proj, broadcast row0) + FFN LN -> tok, xn ----
__global__ void resadd_ffnln(float* __restrict__ tok, const float* __restrict__ proj,
                             const float* __restrict__ g, u16* __restrict__ xn)
{
  int n = blockIdx.x, b = blockIdx.y;
  int pr = (n >= 768 && n < 784) ? (1 + n - 768) : 0;
  const float* p = proj + ((size_t)b*17 + pr)*DIMM;
  size_t row = (size_t)(b*NTOK + n)*DIMM;
  int t = threadIdx.x;
  float v0 = tok[row + t]     + p[t];
  float v1 = tok[row + t+256] + p[t+256];
  tok[row + t] = v0; tok[row + t+256] = v1;
  float s = v0 + v1, ss = v0*v0 + v1*v1;
  #pragma unroll
  for (int off = 32; off >= 1; off >>= 1){ s += __shfl_xor(s, off); ss += __shfl_xor(ss, off); }
  __shared__ float rs_[4], rss_[4];
  int w = t >> 6;
  if ((t & 63) == 0){ rs_[w] = s; rss_[w] = ss; }
  __syncthreads();
  s = rs_[0]+rs_[1]+rs_[2]+rs_[3];
  ss = rss_[0]+rss_[1]+rss_[2]+rss_[3];
  float mu = s / DIMM;
  float rstd = rsqrtf(ss / DIMM - mu*mu + 1e-5f);
  xn[row + t]     = f2bf((v0 - mu)*rstd*g[t]);
  xn[row + t+256] = f2bf((v1 - mu)*rstd*g[t+256]);
}

// ---- splitK-add (FFN out) + next LN (attn LN or final LN) -> tok, xn ----
__global__ void skadd_ln(float* __restrict__ tok, const float* __restrict__ part,
                         const float* __restrict__ g, u16* __restrict__ xn)
{
  int r = blockIdx.x;   // 0..MALL-1
  size_t row = (size_t)r*DIMM;
  const float* p0 = part + row;
  const float* p1 = p0 + (size_t)MALL*DIMM;
  int t = threadIdx.x;
  float v0 = tok[row + t]     + p0[t]     + p1[t];
  float v1 = tok[row + t+256] + p0[t+256] + p1[t+256];
  tok[row + t] = v0; tok[row + t+256] = v1;
  float s = v0 + v1, ss = v0*v0 + v1*v1;
  #pragma unroll
  for (int off = 32; off >= 1; off >>= 1){ s += __shfl_xor(s, off); ss += __shfl_xor(ss, off); }
  __shared__ float rs_[4], rss_[4];
  int w = t >> 6;
  if ((t & 63) == 0){ rs_[w] = s; rss_[w] = ss; }
  __syncthreads();
  s = rs_[0]+rs_[1]+rs_[2]+rs_[3];
  ss = rss_[0]+rss_[1]+rss_[2]+rss_[3];
  float mu = s / DIMM;
  float rstd = rsqrtf(ss / DIMM - mu*mu + 1e-5f);
  xn[row + t]     = f2bf((v0 - mu)*rstd*g[t]);
  xn[row + t+256] = f2bf((v1 - mu)*rstd*g[t+256]);
}

// ------- gemm512: 8-wave 128x128 tile, B bf16 [N][ldk]; splitK via grid.z;
//         optional GEGLU epilogue (gout != nullptr) -------
__global__ __launch_bounds__(512) void gemm512(
    const u16* __restrict__ A, int lda,
    const u16* __restrict__ Bt, int ldk,
    float* __restrict__ C, int ldc, size_t Cz,
    u16* __restrict__ gout,
    int M, int Nn, int K, int kchunk)
{
  __shared__ __align__(16) u16 As[128][40];
  __shared__ __align__(16) u16 Bs[128][40];
  const int t = threadIdx.x;
  const int lane = t & 63;
  const int w = t >> 6;          // 0..7
  const int wr = (w >> 2) * 64;
  const int wc = (w & 3) * 32;
  const int row0 = blockIdx.x * 128, col0 = blockIdx.y * 128;
  const int z = blockIdx.z;
  const int kbeg = z * kchunk;
  const int kend = (kbeg + kchunk < K) ? (kbeg + kchunk) : K;
  C += (size_t)z * Cz;
  const int l15 = lane & 15;
  const int l4 = (lane >> 4) * 8;
  f32x4 acc[4][2];
  #pragma unroll
  for (int m = 0; m < 4; ++m)
    #pragma unroll
    for (int n = 0; n < 2; ++n)
      #pragma unroll
      for (int j = 0; j < 4; ++j) acc[m][n][j] = 0.f;

  for (int k0 = kbeg; k0 < kend; k0 += 32) {
    {
      int r = t >> 2, c8 = (t & 3) * 8;
      bf16x8 av;
      #pragma unroll
      for (int j = 0; j < 8; ++j) av[j] = 0;
      int gr = row0 + r;
      if (gr < M) av = *(const bf16x8*)(A + (size_t)gr*lda + k0 + c8);
      *(bf16x8*)(&As[r][c8]) = av;
    }
    {
      int col = t & 127, kb = (t >> 7) * 8;
      bf16x8 bv;
      #pragma unroll
      for (int j = 0; j < 8; ++j) bv[j] = 0;
      int gc = col0 + col;
      if (gc < Nn) bv = *(const bf16x8*)(Bt + (size_t)gc*ldk + k0 + kb);
      *(bf16x8*)(&Bs[col][kb]) = bv;
    }
    __syncthreads();
    bf16x8 af[4], bfr[2];
    #pragma unroll
    for (int m = 0; m < 4; ++m) af[m]  = *(const bf16x8*)(&As[wr + m*16 + l15][l4]);
    #pragma unroll
    for (int n = 0; n < 2; ++n) bfr[n] = *(const bf16x8*)(&Bs[wc + n*16 + l15][l4]);
    #pragma unroll
    for (int m = 0; m < 4; ++m)
      #pragma unroll
      for (int n = 0; n < 2; ++n)
        acc[m][n] = __builtin_amdgcn_mfma_f32_16x16x32_bf16(af[m], bfr[n], acc[m][n], 0, 0, 0);
    __syncthreads();
  }
  const int rb = (lane >> 4) * 4;
  if (gout){
    // GEGLU epilogue: n=0 fragment = x1, n=1 fragment = gate (same lane/row)
    int jcol = (col0 >> 1) + (w & 3)*16 + l15;
    #pragma unroll
    for (int m = 0; m < 4; ++m){
      int gr0 = row0 + wr + m*16 + rb;
      #pragma unroll
      for (int j = 0; j < 4; ++j){
        int gr = gr0 + j;
        if (gr < M){
          float gt = acc[m][1][j];
          float ge = 0.5f * gt * (1.0f + erff(gt * 0.70710678118654752f));
          gout[(size_t)gr*GSTRIDE + jcol] = f2bf(ge * acc[m][0][j]);
        }
      }
    }
  } else {
    #pragma unroll
    for (int m = 0; m < 4; ++m){
      int gr0 = row0 + wr + m*16 + rb;
      #pragma unroll
      for (int n = 0; n < 2; ++n){
        int gc = col0 + wc + n*16 + l15;
        if (gc >= Nn) continue;
        #pragma unroll
        for (int j = 0; j < 4; ++j){
          int gr = gr0 + j;
          if (gr < M) C[(size_t)gr*ldc + gc] = acc[m][n][j];
        }
      }
    }
  }
}

// ------- tiny GEMM (M<=128), B bf16 [N][ldk], batched over grid.z -------
__global__ __launch_bounds__(256) void gemm_tiny(
    const u16* __restrict__ A, int lda, size_t Abat,
    const u16* __restrict__ Bt, int ldk,
    float* __restrict__ C, int ldc, size_t Cbat,
    int M, int Nn, int K)
{
  A += (size_t)blockIdx.z * Abat;
  C += (size_t)blockIdx.z * Cbat;
  __shared__ __align__(16) u16 As[128][40];
  __shared__ __align__(16) u16 Bs[128][40];
  const int t = threadIdx.x;
  const int lane = t & 63;
  const int w = t >> 6;
  const int wr = (w >> 1) * 64, wc = (w & 1) * 64;
  const int col0 = blockIdx.y * 128;
  const int l15 = lane & 15;
  const int l4 = (lane >> 4) * 8;
  f32x4 acc[4][4];
  #pragma unroll
  for (int m = 0; m < 4; ++m)
    #pragma unroll
    for (int n = 0; n < 4; ++n)
      #pragma unroll
      for (int j = 0; j < 4; ++j) acc[m][n][j] = 0.f;

  for (int k0 = 0; k0 < K; k0 += 32) {
    #pragma unroll
    for (int u = 0; u < 2; ++u){
      int id = t + u*256;
      int r = id >> 2, c8 = (id & 3) * 8;
      bf16x8 av;
      #pragma unroll
      for (int j = 0; j < 8; ++j) av[j] = 0;
      if (r < M) av = *(const bf16x8*)(A + (size_t)r*lda + k0 + c8);
      *(bf16x8*)(&As[r][c8]) = av;
    }
    {
      int col = t & 127, kb = (t >> 7) * 16;
      bf16x8 b0, b1;
      #pragma unroll
      for (int j = 0; j < 8; ++j){ b0[j] = 0; b1[j] = 0; }
      int gc = col0 + col;
      if (gc < Nn){
        b0 = *(const bf16x8*)(Bt + (size_t)gc*ldk + k0 + kb);
        b1 = *(const bf16x8*)(Bt + (size_t)gc*ldk + k0 + kb + 8);
      }
      *(bf16x8*)(&Bs[col][kb])     = b0;
      *(bf16x8*)(&Bs[col][kb + 8]) = b1;
    }
    __syncthreads();
    bf16x8 af[4], bfr[4];
    #pragma unroll
    for (int m = 0; m < 4; ++m) af[m]  = *(const bf16x8*)(&As[wr + m*16 + l15][l4]);
    #pragma unroll
    for (int n = 0; n < 4; ++n) bfr[n] = *(const bf16x8*)(&Bs[wc + n*16 + l15][l4]);
    #pragma unroll
    for (int m = 0; m < 4; ++m)
      #pragma unroll
      for (int n = 0; n < 4; ++n)
        acc[m][n] = __builtin_amdgcn_mfma_f32_16x16x32_bf16(af[m], bfr[n], acc[m][n], 0, 0, 0);
    __syncthreads();
  }
  const int rb = (lane >> 4) * 4;
  #pragma unroll
  for (int m = 0; m < 4; ++m){
    int gr0 = wr + m*16 + rb;
    #pragma unroll
    for (int n = 0; n < 4; ++n){
      int gc = col0 + wc + n*16 + l15;
      if (gc >= Nn) continue;
      #pragma unroll
      for (int j = 0; j < 4; ++j){
        int gr = gr0 + j;
        if (gr < M) C[(size_t)gr*ldc + gc] = acc[m][n][j];
      }
    }
  }
}

// ---------------- copy fusion tokens into tok ----------------
__global__ void fuscopy_kernel(const float* __restrict__ ft, float* __restrict__ tok)
{
  int i = blockIdx.x * 256 + threadIdx.x;
  if (i >= BATCH*16*DIMM) return;
  int c = i & 511; int tt = i >> 9; int b = tt >> 4; int r = tt & 15;
  tok[((size_t)(b*NTOK + 768 + r))*DIMM + c] = ft[r*DIMM + c];
}

// ---------------- column mean of V: partials over row-chunks ----------------
__global__ void colmean_part(const float* __restrict__ kvv, float* __restrict__ part)
{
  int c = blockIdx.x * 256 + threadIdx.x;
  int b = blockIdx.y, z = blockIdx.z;
  int r0 = z * 97;
  int r1 = r0 + 97; if (r1 > NTOK) r1 = NTOK;
  const float* src = kvv + (size_t)b*NTOK*1024 + 512 + c;
  float s = 0.f;
  for (int r = r0; r < r1; ++r) s += src[(size_t)r*1024];
  part[(((size_t)z*BATCH + b) << 9) + c] = s;
}

__global__ void colmean_reduce(const float* __restrict__ part, float* __restrict__ mv)
{
  int i = blockIdx.x * 256 + threadIdx.x;
  if (i >= BATCH*DIMM) return;
  int b = i >> 9, c = i & 511;
  float s = 0.f;
  #pragma unroll
  for (int z = 0; z < CM_Z; ++z) s += part[(((size_t)z*BATCH + b) << 9) + c];
  mv[b*DIMM + c] = s * (1.0f/1552.0f);
}

// ---------------- fusion q@k^T ----------------
__global__ void fsim_kernel(const float* __restrict__ kv, const float* __restrict__ qf,
                            float* __restrict__ sim)
{
  int h = blockIdx.x, b = blockIdx.y, z = blockIdx.z;
  __shared__ float qs[16][64];
  for (int i = threadIdx.x; i < 16*64; i += 256){
    int q = i >> 6, d = i & 63;
    qs[q][d] = qf[((size_t)(b*16 + q))*DIMM + h*64 + d];
  }
  __syncthreads();
  int jj = z*256 + threadIdx.x;
  int j = (jj < 768) ? jj : jj + 16;
  const float* kr = kv + ((size_t)(b*NTOK + j))*1024 + h*64;
  float acc[16];
  #pragma unroll
  for (int q = 0; q < 16; ++q) acc[q] = 0.f;
  #pragma unroll
  for (int d4 = 0; d4 < 16; ++d4){
    float4 kd = *(const float4*)(kr + d4*4);
    #pragma unroll
    for (int q = 0; q < 16; ++q)
      acc[q] += qs[q][d4*4+0]*kd.x + qs[q][d4*4+1]*kd.y + qs[q][d4*4+2]*kd.z + qs[q][d4*4+3]*kd.w;
  }
  float* so = sim + ((size_t)(b*8 + h) * 16) * 1536 + jj;
  #pragma unroll
  for (int q = 0; q < 16; ++q) so[(size_t)q*1536] = acc[q] * 0.125f;
}

// ---------------- softmax over 1536 (in place) ----------------
__global__ void softmax_kernel(float* __restrict__ sim)
{
  float* x = sim + (size_t)blockIdx.x * 1536;
  float e[6];
  float m = -3.4e38f;
  #pragma unroll
  for (int i = 0; i < 6; ++i){ e[i] = x[threadIdx.x + i*256]; m = fmaxf(m, e[i]); }
  #pragma unroll
  for (int off = 32; off >= 1; off >>= 1) m = fmaxf(m, __shfl_xor(m, off));
  __shared__ float red[4];
  int w = threadIdx.x >> 6;
  if ((threadIdx.x & 63) == 0) red[w] = m;
  __syncthreads();
  m = fmaxf(fmaxf(red[0], red[1]), fmaxf(red[2], red[3]));
  __syncthreads();
  float s = 0.f;
  #pragma unroll
  for (int i = 0; i < 6; ++i){ e[i] = expf(e[i] - m); s += e[i]; }
  #pragma unroll
  for (int off = 32; off >= 1; off >>= 1) s += __shfl_xor(s, off);
  if ((threadIdx.x & 63) == 0) red[w] = s;
  __syncthreads();
  s = red[0] + red[1] + red[2] + red[3];
  float inv = 1.0f / s;
  #pragma unroll
  for (int i = 0; i < 6; ++i) x[threadIdx.x + i*256] = e[i] * inv;
}

// ---------------- attn @ V for fusion rows (partials) ----------------
__global__ void fpv_part(const float* __restrict__ kv, const float* __restrict__ sim,
                         float* __restrict__ part)
{
  int h = blockIdx.x, b = blockIdx.y, z = blockIdx.z;
  int d = threadIdx.x & 63, g = threadIdx.x >> 6;
  float acc[4] = {0.f, 0.f, 0.f, 0.f};
  const float* sb = sim + ((size_t)(b*8 + h) * 16) * 1536;
  int j0 = z * 128;
  for (int jj = j0; jj < j0 + 128; ++jj){
    int j = (jj < 768) ? jj : jj + 16;
    float vd = kv[((size_t)(b*NTOK + j))*1024 + 512 + h*64 + d];
    #pragma unroll
    for (int q = 0; q < 4; ++q) acc[q] += sb[(size_t)(g*4 + q)*1536 + jj] * vd;
  }
  float* po = part + ((((size_t)z*BATCH + b)*8 + h)*16)*64;
  #pragma unroll
  for (int q = 0; q < 4; ++q) po[(size_t)(g*4 + q)*64 + d] = acc[q];
}

// ---- zbuild: zb[b][0]=colmean, zb[b][1..16]=fpv out (bf16) ----
__global__ void zbuild(const float* __restrict__ cmp_, const float* __restrict__ fpvp,
                       u16* __restrict__ zb)
{
  int i = blockIdx.x * 256 + threadIdx.x;
  if (i >= BATCH*17*DIMM) return;
  int c = i & 511;
  int tt = i >> 9;
  int b = tt / 17, r = tt % 17;
  float s = 0.f;
  if (r == 0){
    #pragma unroll
    for (int z = 0; z < CM_Z; ++z) s += cmp_[(((size_t)z*BATCH + b) << 9) + c];
    s *= (1.0f/1552.0f);
  } else {
    int d = c & 63, h = c >> 6, q = r - 1;
    #pragma unroll
    for (int z = 0; z < FPV_Z; ++z)
      s += fpvp[(((((size_t)z*BATCH + b)*8 + h)*16) + q)*64 + d];
  }
  zb[i] = f2bf(s);
}

// ---------------- parallel mat-vec (pool q2) ----------------
__global__ void matvec512(const float* __restrict__ y, const float* __restrict__ w,
                          float* __restrict__ out, float scale)
{
  __shared__ float ys[512];
  __shared__ float red[4][64];
  int t = threadIdx.x;
  ys[t] = y[t]; ys[t+256] = y[t+256];
  __syncthreads();
  int col = blockIdx.x*64 + (t & 63);
  int kq = t >> 6;
  float s = 0.f;
  #pragma unroll 4
  for (int k = kq*128; k < kq*128+128; ++k) s += ys[k] * w[(size_t)k*512 + col];
  red[kq][t & 63] = s;
  __syncthreads();
  if (t < 64)
    out[blockIdx.x*64 + t] = (red[0][t]+red[1][t]+red[2][t]+red[3][t]) * scale;
}

// ---------------- pooled rows ----------------
__global__ void pooledmv(const float* __restrict__ mv, const float* __restrict__ out2,
                         const float* __restrict__ wo, const float* __restrict__ rt,
                         float* __restrict__ out)
{
  int br = blockIdx.y; int b = br/3, r = br%3;
  const float* y = (r < 2) ? (mv + (size_t)b*DIMM) : (out2 + (size_t)b*DIMM);
  __shared__ float ys[512];
  __shared__ float red[4][64];
  int t = threadIdx.x;
  ys[t] = y[t]; ys[t+256] = y[t+256];
  __syncthreads();
  int col = blockIdx.x*64 + (t & 63);
  int kq = t >> 6;
  float s = 0.f;
  #pragma unroll 4
  for (int k = kq*128; k < kq*128+128; ++k) s += ys[k] * wo[(size_t)k*512 + col];
  red[kq][t & 63] = s;
  __syncthreads();
  if (t < 64){
    int c = blockIdx.x*64 + t;
    out[(size_t)br*DIMM + c] = red[0][t]+red[1][t]+red[2][t]+red[3][t] + rt[(size_t)r*DIMM + c];
  }
}

// ---------------- pool attention of return-token 2 over 16 fusion keys ----------------
__global__ void poolattn2_kernel(const float* __restrict__ kv, const float* __restrict__ q2,
                                 float* __restrict__ out2)
{
  int h = blockIdx.x, b = blockIdx.y, d = threadIdx.x;
  __shared__ float sm[16];
  if (d < 16){
    const float* kr = kv + ((size_t)(b*NTOK + 768 + d))*1024 + h*64;
    float a = 0.f;
    for (int k = 0; k < 64; ++k) a += q2[h*64 + k] * kr[k];
    sm[d] = a;
  }
  __syncthreads();
  float m = -3.4e38f;
  #pragma unroll
  for (int j = 0; j < 16; ++j) m = fmaxf(m, sm[j]);
  float wv[16]; float s = 0.f;
  #pragma unroll
  for (int j = 0; j < 16; ++j){ wv[j] = expf(sm[j] - m); s += wv[j]; }
  float inv = 1.0f / s;
  float a = 0.f;
  #pragma unroll
  for (int j = 0; j < 16; ++j)
    a += wv[j] * kv[((size_t)(b*NTOK + 768 + j))*1024 + 512 + h*64 + d];
  out2[(size_t)b*DIMM + h*64 + d] = a * inv;
}

// =================================================================
extern "C" void kernel_launch(void* const* d_in, const int* in_sizes, int n_in,
                              void* d_out, int out_size, void* d_ws, size_t ws_size,
                              hipStream_t stream)
{
  const float* rna        = (const float*)d_in[0];
  const float* atac       = (const float*)d_in[1];
  const float* rna_ln1_g  = (const float*)d_in[2];
  const float* rna_ln1_b  = (const float*)d_in[3];
  const float* rna_w      = (const float*)d_in[4];
  const float* rna_b      = (const float*)d_in[5];
  const float* rna_ln2_g  = (const float*)d_in[6];
  const float* rna_ln2_b  = (const float*)d_in[7];
  const float* atac_ln1_g = (const float*)d_in[8];
  const float* atac_ln1_b = (const float*)d_in[9];
  const float* atac_w     = (const float*)d_in[10];
  const float* atac_b     = (const float*)d_in[11];
  const float* atac_ln2_g = (const float*)d_in[12];
  const float* atac_ln2_b = (const float*)d_in[13];
  const float* fusion_tok = (const float*)d_in[14];
  const float* lay_ag     = (const float*)d_in[15];
  const float* lay_wq     = (const float*)d_in[16];
  const float* lay_wkv    = (const float*)d_in[17];
  const float* lay_wo     = (const float*)d_in[18];
  const float* lay_fg     = (const float*)d_in[19];
  const float* lay_w1     = (const float*)d_in[20];
  const float* lay_w2     = (const float*)d_in[21];
  const float* final_g    = (const float*)d_in[22];
  const float* ret_tok    = (const float*)d_in[23];
  const float* pool_g     = (const float*)d_in[24];
  const float* pool_wq    = (const float*)d_in[25];
  const float* pool_wkv   = (const float*)d_in[26];
  const float* pool_wo    = (const float*)d_in[27];

  uint8_t* ws = (uint8_t*)d_ws;
  size_t off = 0;
  auto carve = [&](size_t bytes) -> uint8_t* {
    uint8_t* p = ws + off;
    off += (bytes + 255) & ~(size_t)255;
    return p;
  };
  // bf16 weights
  u16* rna_wt   = (u16*)carve((size_t)512*1024*2);
  u16* atac_wt  = (u16*)carve((size_t)512*1024*2);
  u16* wkvt     = (u16*)carve((size_t)4*1024*512*2);
  u16* wqt      = (u16*)carve((size_t)4*512*512*2);
  u16* wot      = (u16*)carve((size_t)4*512*512*2);
  u16* w1t      = (u16*)carve((size_t)4*NW1*512*2);
  u16* w2t      = (u16*)carve((size_t)4*512*GSTRIDE*2);
  u16* pool_wkvt= (u16*)carve((size_t)1024*512*2);
  // activations
  float* tok   = (float*)carve((size_t)MALL * DIMM * 4);
  u16*   xn    = (u16*)  carve((size_t)MALL * DIMM * 2);
  float* kv    = (float*)carve((size_t)MALL * 1024 * 4);
  u16*   lnbuf = (u16*)  carve((size_t)1536 * 1024 * 2);
  float* sim   = (float*)carve((size_t)BATCH*8*16*1536 * 4);
  float* qfus  = (float*)carve((size_t)BATCH*16*DIMM * 4);
  u16*   zb    = (u16*)  carve((size_t)BATCH*17*DIMM * 2);
  float* proj  = (float*)carve((size_t)BATCH*17*DIMM * 4);
  float* mv    = (float*)carve((size_t)BATCH*DIMM * 4);
  float* q2    = (float*)carve((size_t)DIMM * 4);
  float* yq2   = (float*)carve((size_t)DIMM * 4);
  float* out2  = (float*)carve((size_t)BATCH*DIMM * 4);
  float* fpvp  = (float*)carve((size_t)FPV_Z*BATCH*8*16*64 * 4);
  float* cmp_  = (float*)carve((size_t)CM_Z*BATCH*DIMM * 4);
  u16*   gbuf  = (u16*)  carve((size_t)MALL * GSTRIDE * 2);
  float* skpart= (float*)carve((size_t)2 * MALL * 512 * 4);
  (void)ws_size;

  // ---- one-dispatch weight conversion ----
  convall<<<14080, 256, 0, stream>>>(rna_w, atac_w, lay_wkv, lay_wq, lay_wo, lay_w1, lay_w2, pool_wkv,
                                     rna_wt, atac_wt, wkvt, wqt, wot, w1t, w2t, pool_wkvt);

  // ---- embeddings ----
  ln_kernel<<<1536, 256, 0, stream>>>(rna, rna_ln1_g, rna_ln1_b, nullptr, lnbuf, 1024);
  gemm512<<<dim3(12, 4, 2), 512, 0, stream>>>(lnbuf, 1024, rna_wt, 1024, skpart, 512,
                                              (size_t)1536*512, nullptr, 1536, 512, 1024, 512);
  embed_addln<<<1536, 256, 0, stream>>>(skpart, rna_b, rna_ln2_g, rna_ln2_b, tok, 0);
  ln_kernel<<<1536, 256, 0, stream>>>(atac, atac_ln1_g, atac_ln1_b, nullptr, lnbuf, 1024);
  gemm512<<<dim3(12, 4, 2), 512, 0, stream>>>(lnbuf, 1024, atac_wt, 1024, skpart, 512,
                                              (size_t)1536*512, nullptr, 1536, 512, 1024, 512);
  embed_addln<<<1536, 256, 0, stream>>>(skpart, atac_b, atac_ln2_g, atac_ln2_b, tok, 1);
  fuscopy_kernel<<<(BATCH*16*DIMM + 255)/256, 256, 0, stream>>>(fusion_tok, tok);

  // layer-0 attention LN
  ln_kernel<<<MALL, 256, 0, stream>>>(tok, lay_ag, nullptr, nullptr, xn, 512);

  // ---- transformer layers ----
  for (int l = 0; l < 4; ++l){
    const float* fg  = lay_fg + (size_t)l*DIMM;
    const float* gnext = (l < 3) ? (lay_ag + (size_t)(l+1)*DIMM) : final_g;
    const u16* wkvt_l = wkvt + (size_t)l*1024*512;
    const u16* wqt_l  = wqt  + (size_t)l*512*512;
    const u16* wot_l  = wot  + (size_t)l*512*512;
    const u16* w1t_l  = w1t  + (size_t)l*NW1*512;
    const u16* w2t_l  = w2t  + (size_t)l*512*GSTRIDE;

    gemm512<<<dim3(25, 8, 1), 512, 0, stream>>>(xn, 512, wkvt_l, 512, kv, 1024, 0,
                                                nullptr, MALL, 1024, 512, 512);
    gemm_tiny<<<dim3(1, 4, 2), 256, 0, stream>>>(xn + (size_t)768*DIMM, 512, (size_t)NTOK*DIMM,
                                                 wqt_l, 512, qfus, 512, (size_t)16*DIMM, 16, 512, 512);
    colmean_part<<<dim3(2, BATCH, CM_Z), 256, 0, stream>>>(kv, cmp_);
    fsim_kernel<<<dim3(8, BATCH, 6), 256, 0, stream>>>(kv, qfus, sim);
    softmax_kernel<<<BATCH*8*16, 256, 0, stream>>>(sim);
    fpv_part<<<dim3(8, BATCH, FPV_Z), 256, 0, stream>>>(kv, sim, fpvp);
    zbuild<<<(BATCH*17*DIMM + 255)/256, 256, 0, stream>>>(cmp_, fpvp, zb);
    gemm_tiny<<<dim3(1, 4, 2), 256, 0, stream>>>(zb, 512, (size_t)17*DIMM,
                                                 wot_l, 512, proj, 512, (size_t)17*DIMM, 17, 512, 512);
    resadd_ffnln<<<dim3(NTOK, BATCH), 256, 0, stream>>>(tok, proj, fg, xn);
    gemm512<<<dim3(25, 22, 1), 512, 0, stream>>>(xn, 512, w1t_l, 512, nullptr, 0, 0,
                                                 gbuf, MALL, NW1, 512, 512);
    gemm512<<<dim3(25, 4, 2), 512, 0, stream>>>(gbuf, GSTRIDE, w2t_l, GSTRIDE, skpart, 512,
                                                (size_t)MALL*512, nullptr, MALL, 512, GSTRIDE, 704);
    skadd_ln<<<MALL, 256, 0, stream>>>(tok, skpart, gnext, xn);
  }

  // ---- pooling (xn holds final-LN tokens) ----
  gemm512<<<dim3(25, 8, 1), 512, 0, stream>>>(xn, 512, pool_wkvt, 512, kv, 1024, 0,
                                              nullptr, MALL, 1024, 512, 512);
  colmean_part<<<dim3(2, BATCH, CM_Z), 256, 0, stream>>>(kv, cmp_);
  colmean_reduce<<<(BATCH*DIMM + 255)/256, 256, 0, stream>>>(cmp_, mv);
  ln_kernel<<<1, 256, 0, stream>>>(ret_tok + 2*DIMM, pool_g, nullptr, yq2, nullptr, 512);
  matvec512<<<8, 256, 0, stream>>>(yq2, pool_wq, q2, 0.125f);
  poolattn2_kernel<<<dim3(8, BATCH), 64, 0, stream>>>(kv, q2, out2);
  pooledmv<<<dim3(8, 6), 256, 0, stream>>>(mv, out2, pool_wo, ret_tok, (float*)d_out);
}

// Round 6
// 744.507 us; speedup vs baseline: 4.4177x; 1.0947x over previous
//
#include <hip/hip_runtime.h>
#include <stdint.h>
#include <stddef.h>

#define NTOK 1552
#define DIMM 512
#define IFFC 1365
#define IFF2 2730
#define NW1 2816       // padded/permuted w1 output cols (2*1408)
#define GSTRIDE 1408   // geglu output row stride (bf16) = padded K of w2
#define BATCH 2
#define MALL (BATCH*NTOK)   // 3104

typedef unsigned short u16;
typedef __attribute__((ext_vector_type(8))) short bf16x8;
typedef __attribute__((ext_vector_type(4))) float f32x4;

__device__ __forceinline__ u16 f2bf(float f){
  union { float f; uint32_t u; } v; v.f = f;
  uint32_t u = v.u;
  uint32_t r = (u + 0x7FFFu + ((u >> 16) & 1u)) >> 16;
  return (u16)r;
}
__device__ __forceinline__ float bf2f(u16 x){
  union { uint32_t u; float f; } v; v.u = ((uint32_t)x) << 16; return v.f;
}

// ---------- one-dispatch weight convert/transpose (8 segments), vectorized ----------
__global__ void convall(const float* s0,const float* s1,const float* s2,const float* s3,
                        const float* s4,const float* s5,const float* s6,const float* s7,
                        u16* d0,u16* d1,u16* d2,u16* d3,u16* d4,u16* d5,u16* d6,u16* d7)
{
  const float* srcs[8] = {s0,s1,s2,s3,s4,s5,s6,s7};
  u16* dsts[8] = {d0,d1,d2,d3,d4,d5,d6,d7};
  const int KT[8]   = {32,32,16,16,16,16,44,16};
  const int NT[8]   = {16,16,32,16,16,88,16,32};
  const int TC[8]   = {512,512,2048,1024,1024,5632,2816,512};
  const int K_[8]   = {1024,1024,512,512,512,512,1365,512};
  const int NSRC[8] = {512,512,1024,512,512,2730,512,1024};
  const int LDK[8]  = {1024,1024,512,512,512,512,1408,512};
  const int NOUT[8] = {512,512,1024,512,512,2816,512,1024};
  const int WS_[8]  = {0,0,512*1024,512*512,512*512,512*2730,1365*512,0};
  const int WT_[8]  = {0,0,1024*512,512*512,512*512,2816*512,512*1408,0};

  int bid = blockIdx.x;
  int seg = 0, base = 0;
  while (seg < 7 && bid >= base + TC[seg]) { base += TC[seg]; ++seg; }
  int loc = bid - base;
  int kt = KT[seg], nt = NT[seg]; (void)nt;
  int z = loc / (kt*NT[seg]); loc -= z*(kt*NT[seg]);
  int kb = (loc % kt) * 32, nb = (loc / kt) * 32;
  const float* w = srcs[seg] + (size_t)z * WS_[seg];
  u16* wt = dsts[seg] + (size_t)z * WT_[seg];
  int K = K_[seg], NS = NSRC[seg], ldk = LDK[seg], NO = NOUT[seg];

  __shared__ float tile[32][33];
  int t = threadIdx.x;
  {
    int k = t >> 3, n4 = (t & 7) * 4;
    int gk = kb + k;
    float4 v = make_float4(0.f,0.f,0.f,0.f);
    if (gk < K){
      if (seg != 5){
        int gn = nb + n4;
        if (gn + 4 <= NS){
          v = *(const float4*)(w + (size_t)gk*NS + gn);
        } else {
          float* pv = (float*)&v;
          #pragma unroll
          for (int i = 0; i < 4; ++i){ int n = gn + i; if (n < NS) pv[i] = w[(size_t)gk*NS + n]; }
        }
      } else {
        float* pv = (float*)&v;
        #pragma unroll
        for (int i = 0; i < 4; ++i){
          int n = nb + n4 + i;
          if (n < NO){
            int bb = n >> 7, rr = n & 127, g = rr >> 5, hh = rr & 31;
            int j = bb*64 + g*16 + (hh & 15);
            if (j < 1365) pv[i] = w[(size_t)gk*NS + ((hh < 16) ? j : 1365 + j)];
          }
        }
      }
    }
    tile[k][n4] = v.x; tile[k][n4+1] = v.y; tile[k][n4+2] = v.z; tile[k][n4+3] = v.w;
  }
  __syncthreads();
  if (t < 128){
    int n = t >> 2, k8 = (t & 3) * 8;
    int gn = nb + n, gk = kb + k8;
    if (gn < NO && gk < ldk){
      u16 sh[8];
      #pragma unroll
      for (int i = 0; i < 8; ++i) sh[i] = f2bf(tile[k8+i][n]);
      *(bf16x8*)(wt + (size_t)gn*ldk + gk) = *(bf16x8*)sh;
    }
  }
}

// ---------------- LayerNorm: one block per row ----------------
__global__ void ln_kernel(const float* __restrict__ in, const float* __restrict__ g,
                          const float* __restrict__ bta, float* __restrict__ of32,
                          u16* __restrict__ obf, int D)
{
  const int r = blockIdx.x;
  const float* x = in + (size_t)r * D;
  float s = 0.f, ss = 0.f;
  for (int c = threadIdx.x; c < D; c += 256){ float v = x[c]; s += v; ss += v*v; }
  #pragma unroll
  for (int off = 32; off >= 1; off >>= 1){ s += __shfl_xor(s, off); ss += __shfl_xor(ss, off); }
  __shared__ float rs_[4], rss_[4];
  int w = threadIdx.x >> 6;
  if ((threadIdx.x & 63) == 0){ rs_[w] = s; rss_[w] = ss; }
  __syncthreads();
  s = rs_[0] + rs_[1] + rs_[2] + rs_[3];
  ss = rss_[0] + rss_[1] + rss_[2] + rss_[3];
  float mu = s / D;
  float rstd = rsqrtf(ss / D - mu*mu + 1e-5f);
  for (int c = threadIdx.x; c < D; c += 256){
    float y = (x[c] - mu) * rstd * g[c] + (bta ? bta[c] : 0.f);
    if (of32) of32[(size_t)r*D + c] = y;
    if (obf)  obf[(size_t)r*D + c] = f2bf(y);
  }
}

// ---- batched embed LN1 (rna rows 0..1535, atac rows 1536..3071) ----
__global__ void embed_ln1(const float* __restrict__ rna, const float* __restrict__ atac,
                          const float* __restrict__ g0, const float* __restrict__ b0,
                          const float* __restrict__ g1, const float* __restrict__ b1,
                          u16* __restrict__ out)
{
  int r = blockIdx.x;
  const float* x; const float* g; const float* bb;
  if (r < 1536){ x = rna + (size_t)r*1024; g = g0; bb = b0; }
  else { x = atac + (size_t)(r-1536)*1024; g = g1; bb = b1; }
  float s = 0.f, ss = 0.f;
  int t = threadIdx.x;
  float v0 = x[t], v1 = x[t+256], v2 = x[t+512], v3 = x[t+768];
  s = v0+v1+v2+v3; ss = v0*v0+v1*v1+v2*v2+v3*v3;
  #pragma unroll
  for (int off = 32; off >= 1; off >>= 1){ s += __shfl_xor(s, off); ss += __shfl_xor(ss, off); }
  __shared__ float rs_[4], rss_[4];
  int w = t >> 6;
  if ((t & 63) == 0){ rs_[w] = s; rss_[w] = ss; }
  __syncthreads();
  s = rs_[0]+rs_[1]+rs_[2]+rs_[3];
  ss = rss_[0]+rss_[1]+rss_[2]+rss_[3];
  float mu = s / 1024.f;
  float rstd = rsqrtf(ss / 1024.f - mu*mu + 1e-5f);
  u16* o = out + (size_t)r*1024;
  o[t]     = f2bf((v0-mu)*rstd*g[t]     + bb[t]);
  o[t+256] = f2bf((v1-mu)*rstd*g[t+256] + bb[t+256]);
  o[t+512] = f2bf((v2-mu)*rstd*g[t+512] + bb[t+512]);
  o[t+768] = f2bf((v3-mu)*rstd*g[t+768] + bb[t+768]);
}

// ---- batched embed: add splitK parts + bias, LN2, scatter into tok ----
__global__ void embed_addln2(const float* __restrict__ part,
                             const float* __restrict__ rb, const float* __restrict__ ab,
                             const float* __restrict__ g0, const float* __restrict__ bt0,
                             const float* __restrict__ g1, const float* __restrict__ bt1,
                             float* __restrict__ tok)
{
  int r = blockIdx.x;          // 0..3071
  int mod = (r >= 1536);
  int rl = mod ? r - 1536 : r;
  int b = rl / 768, rr = rl % 768;
  const float* bias = mod ? ab : rb;
  const float* g = mod ? g1 : g0;
  const float* bt = mod ? bt1 : bt0;
  const float* p0 = part + (size_t)r*DIMM;
  const float* p1 = p0 + (size_t)3072*DIMM;
  int t = threadIdx.x;
  float v0 = p0[t] + p1[t] + bias[t];
  float v1 = p0[t+256] + p1[t+256] + bias[t+256];
  float s = v0 + v1, ss = v0*v0 + v1*v1;
  #pragma unroll
  for (int off = 32; off >= 1; off >>= 1){ s += __shfl_xor(s, off); ss += __shfl_xor(ss, off); }
  __shared__ float rs_[4], rss_[4];
  int w = t >> 6;
  if ((t & 63) == 0){ rs_[w] = s; rss_[w] = ss; }
  __syncthreads();
  s = rs_[0]+rs_[1]+rs_[2]+rs_[3];
  ss = rss_[0]+rss_[1]+rss_[2]+rss_[3];
  float mu = s / DIMM;
  float rstd = rsqrtf(ss / DIMM - mu*mu + 1e-5f);
  float* tr = tok + ((size_t)(b*NTOK + (mod ? 784 : 0) + rr))*DIMM;
  tr[t]     = (v0 - mu)*rstd*g[t]     + bt[t];
  tr[t+256] = (v1 - mu)*rstd*g[t+256] + bt[t+256];
}

// ---- residual-add (attention proj, broadcast row0) + FFN LN -> tok, xn ----
__global__ void resadd_ffnln(float* __restrict__ tok, const float* __restrict__ proj,
                             const float* __restrict__ g, u16* __restrict__ xn)
{
  int n = blockIdx.x, b = blockIdx.y;
  int pr = (n >= 768 && n < 784) ? (1 + n - 768) : 0;
  const float* p = proj + ((size_t)b*17 + pr)*DIMM;
  size_t row = (size_t)(b*NTOK + n)*DIMM;
  int t = threadIdx.x;
  float v0 = tok[row + t]     + p[t];
  float v1 = tok[row + t+256] + p[t+256];
  tok[row + t] = v0; tok[row + t+256] = v1;
  float s = v0 + v1, ss = v0*v0 + v1*v1;
  #pragma unroll
  for (int off = 32; off >= 1; off >>= 1){ s += __shfl_xor(s, off); ss += __shfl_xor(ss, off); }
  __shared__ float rs_[4], rss_[4];
  int w = t >> 6;
  if ((t & 63) == 0){ rs_[w] = s; rss_[w] = ss; }
  __syncthreads();
  s = rs_[0]+rs_[1]+rs_[2]+rs_[3];
  ss = rss_[0]+rss_[1]+rss_[2]+rss_[3];
  float mu = s / DIMM;
  float rstd = rsqrtf(ss / DIMM - mu*mu + 1e-5f);
  xn[row + t]     = f2bf((v0 - mu)*rstd*g[t]);
  xn[row + t+256] = f2bf((v1 - mu)*rstd*g[t+256]);
}

// ---- splitK-add (FFN out) + next LN -> tok, xn ----
__global__ void skadd_ln(float* __restrict__ tok, const float* __restrict__ part,
                         const float* __restrict__ g, u16* __restrict__ xn)
{
  int r = blockIdx.x;
  size_t row = (size_t)r*DIMM;
  const float* p0 = part + row;
  const float* p1 = p0 + (size_t)MALL*DIMM;
  int t = threadIdx.x;
  float v0 = tok[row + t]     + p0[t]     + p1[t];
  float v1 = tok[row + t+256] + p0[t+256] + p1[t+256];
  tok[row + t] = v0; tok[row + t+256] = v1;
  float s = v0 + v1, ss = v0*v0 + v1*v1;
  #pragma unroll
  for (int off = 32; off >= 1; off >>= 1){ s += __shfl_xor(s, off); ss += __shfl_xor(ss, off); }
  __shared__ float rs_[4], rss_[4];
  int w = t >> 6;
  if ((t & 63) == 0){ rs_[w] = s; rss_[w] = ss; }
  __syncthreads();
  s = rs_[0]+rs_[1]+rs_[2]+rs_[3];
  ss = rss_[0]+rss_[1]+rss_[2]+rss_[3];
  float mu = s / DIMM;
  float rstd = rsqrtf(ss / DIMM - mu*mu + 1e-5f);
  xn[row + t]     = f2bf((v0 - mu)*rstd*g[t]);
  xn[row + t+256] = f2bf((v1 - mu)*rstd*g[t+256]);
}

// ------- gemm512: 8-wave 128x128; B bf16 [N][ldk]; optional B-switch at row mswitch;
//         splitK via grid.z; optional GEGLU epilogue (gout); optional V-colsum (csum) -------
__global__ __launch_bounds__(512) void gemm512(
    const u16* __restrict__ A, int lda,
    const u16* __restrict__ Bt, const u16* __restrict__ BtB, int mswitch, int ldk,
    float* __restrict__ C, int ldc, size_t Cz,
    u16* __restrict__ gout, float* __restrict__ csum,
    int M, int Nn, int K, int kchunk)
{
  __shared__ __align__(16) u16 As[128][40];
  __shared__ __align__(16) u16 Bs[128][40];
  __shared__ float colsum[2][128];
  const int t = threadIdx.x;
  const int lane = t & 63;
  const int w = t >> 6;
  const int wr = (w >> 2) * 64;
  const int wc = (w & 3) * 32;
  const int row0 = blockIdx.x * 128, col0 = blockIdx.y * 128;
  if (BtB && row0 >= mswitch) Bt = BtB;
  const int z = blockIdx.z;
  const int kbeg = z * kchunk;
  const int kend = (kbeg + kchunk < K) ? (kbeg + kchunk) : K;
  C += (size_t)z * Cz;
  const int l15 = lane & 15;
  const int l4 = (lane >> 4) * 8;
  f32x4 acc[4][2];
  #pragma unroll
  for (int m = 0; m < 4; ++m)
    #pragma unroll
    for (int n = 0; n < 2; ++n)
      #pragma unroll
      for (int j = 0; j < 4; ++j) acc[m][n][j] = 0.f;

  for (int k0 = kbeg; k0 < kend; k0 += 32) {
    {
      int r = t >> 2, c8 = (t & 3) * 8;
      bf16x8 av;
      #pragma unroll
      for (int j = 0; j < 8; ++j) av[j] = 0;
      int gr = row0 + r;
      if (gr < M) av = *(const bf16x8*)(A + (size_t)gr*lda + k0 + c8);
      *(bf16x8*)(&As[r][c8]) = av;
    }
    {
      int col = t & 127, kb = (t >> 7) * 8;
      bf16x8 bv;
      #pragma unroll
      for (int j = 0; j < 8; ++j) bv[j] = 0;
      int gc = col0 + col;
      if (gc < Nn) bv = *(const bf16x8*)(Bt + (size_t)gc*ldk + k0 + kb);
      *(bf16x8*)(&Bs[col][kb]) = bv;
    }
    __syncthreads();
    bf16x8 af[4], bfr[2];
    #pragma unroll
    for (int m = 0; m < 4; ++m) af[m]  = *(const bf16x8*)(&As[wr + m*16 + l15][l4]);
    #pragma unroll
    for (int n = 0; n < 2; ++n) bfr[n] = *(const bf16x8*)(&Bs[wc + n*16 + l15][l4]);
    #pragma unroll
    for (int m = 0; m < 4; ++m)
      #pragma unroll
      for (int n = 0; n < 2; ++n)
        acc[m][n] = __builtin_amdgcn_mfma_f32_16x16x32_bf16(af[m], bfr[n], acc[m][n], 0, 0, 0);
    __syncthreads();
  }
  const int rb = (lane >> 4) * 4;
  if (gout){
    int jcol = (col0 >> 1) + (w & 3)*16 + l15;
    #pragma unroll
    for (int m = 0; m < 4; ++m){
      int gr0 = row0 + wr + m*16 + rb;
      #pragma unroll
      for (int j = 0; j < 4; ++j){
        int gr = gr0 + j;
        if (gr < M){
          float gt = acc[m][1][j];
          float ge = 0.5f * gt * (1.0f + erff(gt * 0.70710678118654752f));
          gout[(size_t)gr*GSTRIDE + jcol] = f2bf(ge * acc[m][0][j]);
        }
      }
    }
  } else {
    #pragma unroll
    for (int m = 0; m < 4; ++m){
      int gr0 = row0 + wr + m*16 + rb;
      #pragma unroll
      for (int n = 0; n < 2; ++n){
        int gc = col0 + wc + n*16 + l15;
        if (gc >= Nn) continue;
        #pragma unroll
        for (int j = 0; j < 4; ++j){
          int gr = gr0 + j;
          if (gr < M) C[(size_t)gr*ldc + gc] = acc[m][n][j];
        }
      }
    }
  }
  // V-column partial sums (per batch) for colmean fusion
  if (csum && col0 >= 512){
    if (t < 256) colsum[t>>7][t&127] = 0.f;
    __syncthreads();
    #pragma unroll
    for (int n = 0; n < 2; ++n){
      float lv0 = 0.f, lv1 = 0.f;
      #pragma unroll
      for (int m = 0; m < 4; ++m){
        int gr0 = row0 + wr + m*16 + rb;
        #pragma unroll
        for (int j = 0; j < 4; ++j){
          float v = acc[m][n][j];
          if (gr0 + j < NTOK) lv0 += v; else lv1 += v;
        }
      }
      int lc = wc + n*16 + l15;
      atomicAdd(&colsum[0][lc], lv0);
      atomicAdd(&colsum[1][lc], lv1);
    }
    __syncthreads();
    if (t < 256){
      int bb = t>>7, c = t&127;
      csum[((size_t)(bb*25) + blockIdx.x)*512 + (col0 - 512) + c] = colsum[bb][c];
    }
  }
}

// ------- tiny GEMM (M<=128), B bf16 [N][ldk], batched over grid.z -------
__global__ __launch_bounds__(256) void gemm_tiny(
    const u16* __restrict__ A, int lda, size_t Abat,
    const u16* __restrict__ Bt, int ldk,
    float* __restrict__ C, int ldc, size_t Cbat,
    int M, int Nn, int K)
{
  A += (size_t)blockIdx.z * Abat;
  C += (size_t)blockIdx.z * Cbat;
  __shared__ __align__(16) u16 As[128][40];
  __shared__ __align__(16) u16 Bs[128][40];
  const int t = threadIdx.x;
  const int lane = t & 63;
  const int w = t >> 6;
  const int wr = (w >> 1) * 64, wc = (w & 1) * 64;
  const int col0 = blockIdx.y * 128;
  const int l15 = lane & 15;
  const int l4 = (lane >> 4) * 8;
  f32x4 acc[4][4];
  #pragma unroll
  for (int m = 0; m < 4; ++m)
    #pragma unroll
    for (int n = 0; n < 4; ++n)
      #pragma unroll
      for (int j = 0; j < 4; ++j) acc[m][n][j] = 0.f;

  for (int k0 = 0; k0 < K; k0 += 32) {
    #pragma unroll
    for (int u = 0; u < 2; ++u){
      int id = t + u*256;
      int r = id >> 2, c8 = (id & 3) * 8;
      bf16x8 av;
      #pragma unroll
      for (int j = 0; j < 8; ++j) av[j] = 0;
      if (r < M) av = *(const bf16x8*)(A + (size_t)r*lda + k0 + c8);
      *(bf16x8*)(&As[r][c8]) = av;
    }
    {
      int col = t & 127, kb = (t >> 7) * 16;
      bf16x8 b0, b1;
      #pragma unroll
      for (int j = 0; j < 8; ++j){ b0[j] = 0; b1[j] = 0; }
      int gc = col0 + col;
      if (gc < Nn){
        b0 = *(const bf16x8*)(Bt + (size_t)gc*ldk + k0 + kb);
        b1 = *(const bf16x8*)(Bt + (size_t)gc*ldk + k0 + kb + 8);
      }
      *(bf16x8*)(&Bs[col][kb])     = b0;
      *(bf16x8*)(&Bs[col][kb + 8]) = b1;
    }
    __syncthreads();
    bf16x8 af[4], bfr[4];
    #pragma unroll
    for (int m = 0; m < 4; ++m) af[m]  = *(const bf16x8*)(&As[wr + m*16 + l15][l4]);
    #pragma unroll
    for (int n = 0; n < 4; ++n) bfr[n] = *(const bf16x8*)(&Bs[wc + n*16 + l15][l4]);
    #pragma unroll
    for (int m = 0; m < 4; ++m)
      #pragma unroll
      for (int n = 0; n < 4; ++n)
        acc[m][n] = __builtin_amdgcn_mfma_f32_16x16x32_bf16(af[m], bfr[n], acc[m][n], 0, 0, 0);
    __syncthreads();
  }
  const int rb = (lane >> 4) * 4;
  #pragma unroll
  for (int m = 0; m < 4; ++m){
    int gr0 = wr + m*16 + rb;
    #pragma unroll
    for (int n = 0; n < 4; ++n){
      int gc = col0 + wc + n*16 + l15;
      if (gc >= Nn) continue;
      #pragma unroll
      for (int j = 0; j < 4; ++j){
        int gr = gr0 + j;
        if (gr < M) C[(size_t)gr*ldc + gc] = acc[m][n][j];
      }
    }
  }
}

// ---------------- fused attention: q-proj + QK^T + softmax + PV -> zb rows 1..16 ----------------
__global__ __launch_bounds__(256) void fused_attn(
    const u16* __restrict__ xn, const u16* __restrict__ wqt,
    const float* __restrict__ kv, u16* __restrict__ zb)
{
  int h = blockIdx.x, b = blockIdx.y, qg = blockIdx.z;
  int t = threadIdx.x;
  int lane = t & 63, wid = t >> 6;
  __shared__ float qs[4][64];
  __shared__ float pl[4][1536];
  __shared__ float red[4][4];

  // 1) q projection (4 rows x 64 dims), scaled by 1/8
  {
    int q = t >> 6, d = t & 63;
    int row = b*NTOK + 768 + qg*4 + q;
    const u16* xr = xn + (size_t)row*DIMM;
    const u16* wrr = wqt + (size_t)(h*64 + d)*DIMM;
    float a = 0.f;
    for (int k = 0; k < 512; k += 8){
      bf16x8 xv = *(const bf16x8*)(xr + k);
      bf16x8 wv = *(const bf16x8*)(wrr + k);
      #pragma unroll
      for (int i = 0; i < 8; ++i) a += bf2f((u16)xv[i]) * bf2f((u16)wv[i]);
    }
    qs[q][d] = a * 0.125f;
  }
  __syncthreads();

  // 2) QK^T for 6 j's per thread
  float sj[6][4];
  #pragma unroll
  for (int z = 0; z < 6; ++z){
    int jj = z*256 + t;
    int j = (jj < 768) ? jj : jj + 16;
    const float* kr = kv + ((size_t)(b*NTOK + j))*1024 + h*64;
    float a0=0.f, a1=0.f, a2=0.f, a3=0.f;
    #pragma unroll
    for (int d = 0; d < 64; d += 4){
      float4 kd = *(const float4*)(kr + d);
      a0 += qs[0][d]*kd.x + qs[0][d+1]*kd.y + qs[0][d+2]*kd.z + qs[0][d+3]*kd.w;
      a1 += qs[1][d]*kd.x + qs[1][d+1]*kd.y + qs[1][d+2]*kd.z + qs[1][d+3]*kd.w;
      a2 += qs[2][d]*kd.x + qs[2][d+1]*kd.y + qs[2][d+2]*kd.z + qs[2][d+3]*kd.w;
      a3 += qs[3][d]*kd.x + qs[3][d+1]*kd.y + qs[3][d+2]*kd.z + qs[3][d+3]*kd.w;
    }
    sj[z][0]=a0; sj[z][1]=a1; sj[z][2]=a2; sj[z][3]=a3;
  }

  // 3) softmax across 1536 per q
  float mq[4] = {-3.4e38f,-3.4e38f,-3.4e38f,-3.4e38f};
  #pragma unroll
  for (int z = 0; z < 6; ++z)
    #pragma unroll
    for (int q = 0; q < 4; ++q) mq[q] = fmaxf(mq[q], sj[z][q]);
  #pragma unroll
  for (int off = 32; off >= 1; off >>= 1)
    #pragma unroll
    for (int q = 0; q < 4; ++q) mq[q] = fmaxf(mq[q], __shfl_xor(mq[q], off));
  if (lane == 0){ red[wid][0]=mq[0]; red[wid][1]=mq[1]; red[wid][2]=mq[2]; red[wid][3]=mq[3]; }
  __syncthreads();
  #pragma unroll
  for (int q = 0; q < 4; ++q)
    mq[q] = fmaxf(fmaxf(red[0][q], red[1][q]), fmaxf(red[2][q], red[3][q]));
  __syncthreads();
  float sq[4] = {0.f,0.f,0.f,0.f};
  #pragma unroll
  for (int z = 0; z < 6; ++z)
    #pragma unroll
    for (int q = 0; q < 4; ++q){ sj[z][q] = expf(sj[z][q] - mq[q]); sq[q] += sj[z][q]; }
  #pragma unroll
  for (int off = 32; off >= 1; off >>= 1)
    #pragma unroll
    for (int q = 0; q < 4; ++q) sq[q] += __shfl_xor(sq[q], off);
  if (lane == 0){ red[wid][0]=sq[0]; red[wid][1]=sq[1]; red[wid][2]=sq[2]; red[wid][3]=sq[3]; }
  __syncthreads();
  float inv[4];
  #pragma unroll
  for (int q = 0; q < 4; ++q)
    inv[q] = 1.0f / (red[0][q] + red[1][q] + red[2][q] + red[3][q]);
  #pragma unroll
  for (int z = 0; z < 6; ++z)
    #pragma unroll
    for (int q = 0; q < 4; ++q) pl[q][z*256 + t] = sj[z][q] * inv[q];
  __syncthreads();

  // 4) PV: thread -> (q = t>>6, d = t&63)
  {
    int q = t >> 6, d = t & 63;
    const float* vb = kv + (size_t)b*NTOK*1024 + 512 + h*64 + d;
    float a0=0.f, a1=0.f, a2=0.f, a3=0.f;
    for (int jj = 0; jj < 768; jj += 4){
      a0 += pl[q][jj]   * vb[(size_t)jj*1024];
      a1 += pl[q][jj+1] * vb[(size_t)(jj+1)*1024];
      a2 += pl[q][jj+2] * vb[(size_t)(jj+2)*1024];
      a3 += pl[q][jj+3] * vb[(size_t)(jj+3)*1024];
    }
    for (int jj = 768; jj < 1536; jj += 4){
      a0 += pl[q][jj]   * vb[(size_t)(jj+16)*1024];
      a1 += pl[q][jj+1] * vb[(size_t)(jj+17)*1024];
      a2 += pl[q][jj+2] * vb[(size_t)(jj+18)*1024];
      a3 += pl[q][jj+3] * vb[(size_t)(jj+19)*1024];
    }
    int qi = qg*4 + q;
    zb[((size_t)(b*17 + 1 + qi))*DIMM + h*64 + d] = f2bf(a0+a1+a2+a3);
  }
}

// ---- finish colmean from gemm csum partials: zb row0 (bf16) and/or mv (f32) ----
__global__ void csum_finish(const float* __restrict__ csum, u16* __restrict__ zb,
                            float* __restrict__ mv)
{
  int i = blockIdx.x * 256 + threadIdx.x;   // 0..1023
  if (i >= BATCH*DIMM) return;
  int b = i >> 9, c = i & 511;
  float s = 0.f;
  #pragma unroll
  for (int bx = 0; bx < 25; ++bx) s += csum[((size_t)(b*25) + bx)*512 + c];
  s *= (1.0f/1552.0f);
  if (zb) zb[((size_t)(b*17))*DIMM + c] = f2bf(s);
  if (mv) mv[(size_t)b*DIMM + c] = s;
}

// ---------------- copy fusion tokens into tok ----------------
__global__ void fuscopy_kernel(const float* __restrict__ ft, float* __restrict__ tok)
{
  int i = blockIdx.x * 256 + threadIdx.x;
  if (i >= BATCH*16*DIMM) return;
  int c = i & 511; int tt = i >> 9; int b = tt >> 4; int r = tt & 15;
  tok[((size_t)(b*NTOK + 768 + r))*DIMM + c] = ft[r*DIMM + c];
}

// ---------------- parallel mat-vec (pool q2) ----------------
__global__ void matvec512(const float* __restrict__ y, const float* __restrict__ w,
                          float* __restrict__ out, float scale)
{
  __shared__ float ys[512];
  __shared__ float red[4][64];
  int t = threadIdx.x;
  ys[t] = y[t]; ys[t+256] = y[t+256];
  __syncthreads();
  int col = blockIdx.x*64 + (t & 63);
  int kq = t >> 6;
  float s = 0.f;
  #pragma unroll 4
  for (int k = kq*128; k < kq*128+128; ++k) s += ys[k] * w[(size_t)k*512 + col];
  red[kq][t & 63] = s;
  __syncthreads();
  if (t < 64)
    out[blockIdx.x*64 + t] = (red[0][t]+red[1][t]+red[2][t]+red[3][t]) * scale;
}

// ---------------- pooled rows ----------------
__global__ void pooledmv(const float* __restrict__ mv, const float* __restrict__ out2,
                         const float* __restrict__ wo, const float* __restrict__ rt,
                         float* __restrict__ out)
{
  int br = blockIdx.y; int b = br/3, r = br%3;
  const float* y = (r < 2) ? (mv + (size_t)b*DIMM) : (out2 + (size_t)b*DIMM);
  __shared__ float ys[512];
  __shared__ float red[4][64];
  int t = threadIdx.x;
  ys[t] = y[t]; ys[t+256] = y[t+256];
  __syncthreads();
  int col = blockIdx.x*64 + (t & 63);
  int kq = t >> 6;
  float s = 0.f;
  #pragma unroll 4
  for (int k = kq*128; k < kq*128+128; ++k) s += ys[k] * wo[(size_t)k*512 + col];
  red[kq][t & 63] = s;
  __syncthreads();
  if (t < 64){
    int c = blockIdx.x*64 + t;
    out[(size_t)br*DIMM + c] = red[0][t]+red[1][t]+red[2][t]+red[3][t] + rt[(size_t)r*DIMM + c];
  }
}

// ---------------- pool attention of return-token 2 over 16 fusion keys ----------------
__global__ void poolattn2_kernel(const float* __restrict__ kv, const float* __restrict__ q2,
                                 float* __restrict__ out2)
{
  int h = blockIdx.x, b = blockIdx.y, d = threadIdx.x;
  __shared__ float sm[16];
  if (d < 16){
    const float* kr = kv + ((size_t)(b*NTOK + 768 + d))*1024 + h*64;
    float a = 0.f;
    for (int k = 0; k < 64; ++k) a += q2[h*64 + k] * kr[k];
    sm[d] = a;
  }
  __syncthreads();
  float m = -3.4e38f;
  #pragma unroll
  for (int j = 0; j < 16; ++j) m = fmaxf(m, sm[j]);
  float wv[16]; float s = 0.f;
  #pragma unroll
  for (int j = 0; j < 16; ++j){ wv[j] = expf(sm[j] - m); s += wv[j]; }
  float inv = 1.0f / s;
  float a = 0.f;
  #pragma unroll
  for (int j = 0; j < 16; ++j)
    a += wv[j] * kv[((size_t)(b*NTOK + 768 + j))*1024 + 512 + h*64 + d];
  out2[(size_t)b*DIMM + h*64 + d] = a * inv;
}

// =================================================================
extern "C" void kernel_launch(void* const* d_in, const int* in_sizes, int n_in,
                              void* d_out, int out_size, void* d_ws, size_t ws_size,
                              hipStream_t stream)
{
  const float* rna        = (const float*)d_in[0];
  const float* atac       = (const float*)d_in[1];
  const float* rna_ln1_g  = (const float*)d_in[2];
  const float* rna_ln1_b  = (const float*)d_in[3];
  const float* rna_w      = (const float*)d_in[4];
  const float* rna_b      = (const float*)d_in[5];
  const float* rna_ln2_g  = (const float*)d_in[6];
  const float* rna_ln2_b  = (const float*)d_in[7];
  const float* atac_ln1_g = (const float*)d_in[8];
  const float* atac_ln1_b = (const float*)d_in[9];
  const float* atac_w     = (const float*)d_in[10];
  const float* atac_b     = (const float*)d_in[11];
  const float* atac_ln2_g = (const float*)d_in[12];
  const float* atac_ln2_b = (const float*)d_in[13];
  const float* fusion_tok = (const float*)d_in[14];
  const float* lay_ag     = (const float*)d_in[15];
  const float* lay_wq     = (const float*)d_in[16];
  const float* lay_wkv    = (const float*)d_in[17];
  const float* lay_wo     = (const float*)d_in[18];
  const float* lay_fg     = (const float*)d_in[19];
  const float* lay_w1     = (const float*)d_in[20];
  const float* lay_w2     = (const float*)d_in[21];
  const float* final_g    = (const float*)d_in[22];
  const float* ret_tok    = (const float*)d_in[23];
  const float* pool_g     = (const float*)d_in[24];
  const float* pool_wq    = (const float*)d_in[25];
  const float* pool_wkv   = (const float*)d_in[26];
  const float* pool_wo    = (const float*)d_in[27];

  uint8_t* ws = (uint8_t*)d_ws;
  size_t off = 0;
  auto carve = [&](size_t bytes) -> uint8_t* {
    uint8_t* p = ws + off;
    off += (bytes + 255) & ~(size_t)255;
    return p;
  };
  // bf16 weights
  u16* rna_wt   = (u16*)carve((size_t)512*1024*2);
  u16* atac_wt  = (u16*)carve((size_t)512*1024*2);
  u16* wkvt     = (u16*)carve((size_t)4*1024*512*2);
  u16* wqt      = (u16*)carve((size_t)4*512*512*2);
  u16* wot      = (u16*)carve((size_t)4*512*512*2);
  u16* w1t      = (u16*)carve((size_t)4*NW1*512*2);
  u16* w2t      = (u16*)carve((size_t)4*512*GSTRIDE*2);
  u16* pool_wkvt= (u16*)carve((size_t)1024*512*2);
  // activations
  float* tok   = (float*)carve((size_t)MALL * DIMM * 4);
  u16*   xn    = (u16*)  carve((size_t)MALL * DIMM * 2);
  float* kv    = (float*)carve((size_t)MALL * 1024 * 4);
  u16*   lnbuf = (u16*)  carve((size_t)3072 * 1024 * 2);
  u16*   zb    = (u16*)  carve((size_t)BATCH*17*DIMM * 2);
  float* proj  = (float*)carve((size_t)BATCH*17*DIMM * 4);
  float* mv    = (float*)carve((size_t)BATCH*DIMM * 4);
  float* q2    = (float*)carve((size_t)DIMM * 4);
  float* yq2   = (float*)carve((size_t)DIMM * 4);
  float* out2  = (float*)carve((size_t)BATCH*DIMM * 4);
  float* csum  = (float*)carve((size_t)BATCH*25*512 * 4);
  u16*   gbuf  = (u16*)  carve((size_t)MALL * GSTRIDE * 2);
  float* skpart= (float*)carve((size_t)2 * MALL * 512 * 4);
  (void)ws_size;

  // ---- one-dispatch weight conversion ----
  convall<<<14080, 256, 0, stream>>>(rna_w, atac_w, lay_wkv, lay_wq, lay_wo, lay_w1, lay_w2, pool_wkv,
                                     rna_wt, atac_wt, wkvt, wqt, wot, w1t, w2t, pool_wkvt);

  // ---- embeddings (both modalities batched) ----
  embed_ln1<<<3072, 256, 0, stream>>>(rna, atac, rna_ln1_g, rna_ln1_b, atac_ln1_g, atac_ln1_b, lnbuf);
  gemm512<<<dim3(24, 4, 2), 512, 0, stream>>>(lnbuf, 1024, rna_wt, atac_wt, 1536, 1024,
                                              skpart, 512, (size_t)3072*512, nullptr, nullptr,
                                              3072, 512, 1024, 512);
  embed_addln2<<<3072, 256, 0, stream>>>(skpart, rna_b, atac_b, rna_ln2_g, rna_ln2_b,
                                         atac_ln2_g, atac_ln2_b, tok);
  fuscopy_kernel<<<(BATCH*16*DIMM + 255)/256, 256, 0, stream>>>(fusion_tok, tok);

  // layer-0 attention LN
  ln_kernel<<<MALL, 256, 0, stream>>>(tok, lay_ag, nullptr, nullptr, xn, 512);

  // ---- transformer layers ----
  for (int l = 0; l < 4; ++l){
    const float* fg  = lay_fg + (size_t)l*DIMM;
    const float* gnext = (l < 3) ? (lay_ag + (size_t)(l+1)*DIMM) : final_g;
    const u16* wkvt_l = wkvt + (size_t)l*1024*512;
    const u16* wqt_l  = wqt  + (size_t)l*512*512;
    const u16* wot_l  = wot  + (size_t)l*512*512;
    const u16* w1t_l  = w1t  + (size_t)l*NW1*512;
    const u16* w2t_l  = w2t  + (size_t)l*512*GSTRIDE;

    gemm512<<<dim3(25, 8, 1), 512, 0, stream>>>(xn, 512, wkvt_l, nullptr, 0, 512,
                                                kv, 1024, 0, nullptr, csum, MALL, 1024, 512, 512);
    fused_attn<<<dim3(8, BATCH, 4), 256, 0, stream>>>(xn, wqt_l, kv, zb);
    csum_finish<<<4, 256, 0, stream>>>(csum, zb, nullptr);
    gemm_tiny<<<dim3(1, 4, 2), 256, 0, stream>>>(zb, 512, (size_t)17*DIMM,
                                                 wot_l, 512, proj, 512, (size_t)17*DIMM, 17, 512, 512);
    resadd_ffnln<<<dim3(NTOK, BATCH), 256, 0, stream>>>(tok, proj, fg, xn);
    gemm512<<<dim3(25, 22, 1), 512, 0, stream>>>(xn, 512, w1t_l, nullptr, 0, 512,
                                                 nullptr, 0, 0, gbuf, nullptr, MALL, NW1, 512, 512);
    gemm512<<<dim3(25, 4, 2), 512, 0, stream>>>(gbuf, GSTRIDE, w2t_l, nullptr, 0, GSTRIDE,
                                                skpart, 512, (size_t)MALL*512, nullptr, nullptr,
                                                MALL, 512, GSTRIDE, 704);
    skadd_ln<<<MALL, 256, 0, stream>>>(tok, skpart, gnext, xn);
  }

  // ---- pooling (xn holds final-LN tokens) ----
  gemm512<<<dim3(25, 8, 1), 512, 0, stream>>>(xn, 512, pool_wkvt, nullptr, 0, 512,
                                              kv, 1024, 0, nullptr, csum, MALL, 1024, 512, 512);
  csum_finish<<<4, 256, 0, stream>>>(csum, nullptr, mv);
  ln_kernel<<<1, 256, 0, stream>>>(ret_tok + 2*DIMM, pool_g, nullptr, yq2, nullptr, 512);
  matvec512<<<8, 256, 0, stream>>>(yq2, pool_wq, q2, 0.125f);
  poolattn2_kernel<<<dim3(8, BATCH), 64, 0, stream>>>(kv, q2, out2);
  pooledmv<<<dim3(8, 6), 256, 0, stream>>>(mv, out2, pool_wo, ret_tok, (float*)d_out);
}

// Round 7
// 671.160 us; speedup vs baseline: 4.9005x; 1.1093x over previous
//
#include <hip/hip_runtime.h>
#include <stdint.h>
#include <stddef.h>

#define NTOK 1552
#define DIMM 512
#define IFFC 1365
#define IFF2 2730
#define NW1 2816       // padded/permuted w1 output cols (2*1408)
#define GSTRIDE 1408   // geglu output row stride (bf16) = padded K of w2
#define BATCH 2
#define MALL (BATCH*NTOK)   // 3104

typedef unsigned short u16;
typedef __attribute__((ext_vector_type(8))) short bf16x8;
typedef __attribute__((ext_vector_type(4))) float f32x4;

__device__ __forceinline__ u16 f2bf(float f){
  union { float f; uint32_t u; } v; v.f = f;
  uint32_t u = v.u;
  uint32_t r = (u + 0x7FFFu + ((u >> 16) & 1u)) >> 16;
  return (u16)r;
}
__device__ __forceinline__ float bf2f(u16 x){
  union { uint32_t u; float f; } v; v.u = ((uint32_t)x) << 16; return v.f;
}

// ---------- one-dispatch weight convert/transpose (8 segments), vectorized ----------
__global__ void convall(const float* s0,const float* s1,const float* s2,const float* s3,
                        const float* s4,const float* s5,const float* s6,const float* s7,
                        u16* d0,u16* d1,u16* d2,u16* d3,u16* d4,u16* d5,u16* d6,u16* d7)
{
  const float* srcs[8] = {s0,s1,s2,s3,s4,s5,s6,s7};
  u16* dsts[8] = {d0,d1,d2,d3,d4,d5,d6,d7};
  const int KT[8]   = {32,32,16,16,16,16,44,16};
  const int NT[8]   = {16,16,32,16,16,88,16,32};
  const int TC[8]   = {512,512,2048,1024,1024,5632,2816,512};
  const int K_[8]   = {1024,1024,512,512,512,512,1365,512};
  const int NSRC[8] = {512,512,1024,512,512,2730,512,1024};
  const int LDK[8]  = {1024,1024,512,512,512,512,1408,512};
  const int NOUT[8] = {512,512,1024,512,512,2816,512,1024};
  const int WS_[8]  = {0,0,512*1024,512*512,512*512,512*2730,1365*512,0};
  const int WT_[8]  = {0,0,1024*512,512*512,512*512,2816*512,512*1408,0};

  int bid = blockIdx.x;
  int seg = 0, base = 0;
  while (seg < 7 && bid >= base + TC[seg]) { base += TC[seg]; ++seg; }
  int loc = bid - base;
  int kt = KT[seg];
  int z = loc / (kt*NT[seg]); loc -= z*(kt*NT[seg]);
  int kb = (loc % kt) * 32, nb = (loc / kt) * 32;
  const float* w = srcs[seg] + (size_t)z * WS_[seg];
  u16* wt = dsts[seg] + (size_t)z * WT_[seg];
  int K = K_[seg], NS = NSRC[seg], ldk = LDK[seg], NO = NOUT[seg];

  __shared__ float tile[32][33];
  int t = threadIdx.x;
  {
    int k = t >> 3, n4 = (t & 7) * 4;
    int gk = kb + k;
    float4 v = make_float4(0.f,0.f,0.f,0.f);
    if (gk < K){
      if (seg != 5){
        int gn = nb + n4;
        if (gn + 4 <= NS){
          v = *(const float4*)(w + (size_t)gk*NS + gn);
        } else {
          float* pv = (float*)&v;
          #pragma unroll
          for (int i = 0; i < 4; ++i){ int n = gn + i; if (n < NS) pv[i] = w[(size_t)gk*NS + n]; }
        }
      } else {
        float* pv = (float*)&v;
        #pragma unroll
        for (int i = 0; i < 4; ++i){
          int n = nb + n4 + i;
          if (n < NO){
            int bb = n >> 7, rr = n & 127, g = rr >> 5, hh = rr & 31;
            int j = bb*64 + g*16 + (hh & 15);
            if (j < 1365) pv[i] = w[(size_t)gk*NS + ((hh < 16) ? j : 1365 + j)];
          }
        }
      }
    }
    tile[k][n4] = v.x; tile[k][n4+1] = v.y; tile[k][n4+2] = v.z; tile[k][n4+3] = v.w;
  }
  __syncthreads();
  if (t < 128){
    int n = t >> 2, k8 = (t & 3) * 8;
    int gn = nb + n, gk = kb + k8;
    if (gn < NO && gk < ldk){
      u16 sh[8];
      #pragma unroll
      for (int i = 0; i < 8; ++i) sh[i] = f2bf(tile[k8+i][n]);
      *(bf16x8*)(wt + (size_t)gn*ldk + gk) = *(bf16x8*)sh;
    }
  }
}

// ---------------- LayerNorm: one block per row ----------------
__global__ void ln_kernel(const float* __restrict__ in, const float* __restrict__ g,
                          const float* __restrict__ bta, float* __restrict__ of32,
                          u16* __restrict__ obf, int D)
{
  const int r = blockIdx.x;
  const float* x = in + (size_t)r * D;
  float s = 0.f, ss = 0.f;
  for (int c = threadIdx.x; c < D; c += 256){ float v = x[c]; s += v; ss += v*v; }
  #pragma unroll
  for (int off = 32; off >= 1; off >>= 1){ s += __shfl_xor(s, off); ss += __shfl_xor(ss, off); }
  __shared__ float rs_[4], rss_[4];
  int w = threadIdx.x >> 6;
  if ((threadIdx.x & 63) == 0){ rs_[w] = s; rss_[w] = ss; }
  __syncthreads();
  s = rs_[0] + rs_[1] + rs_[2] + rs_[3];
  ss = rss_[0] + rss_[1] + rss_[2] + rss_[3];
  float mu = s / D;
  float rstd = rsqrtf(ss / D - mu*mu + 1e-5f);
  for (int c = threadIdx.x; c < D; c += 256){
    float y = (x[c] - mu) * rstd * g[c] + (bta ? bta[c] : 0.f);
    if (of32) of32[(size_t)r*D + c] = y;
    if (obf)  obf[(size_t)r*D + c] = f2bf(y);
  }
}

// ---- batched embed LN1 (rna rows 0..1535, atac rows 1536..3071) ----
__global__ void embed_ln1(const float* __restrict__ rna, const float* __restrict__ atac,
                          const float* __restrict__ g0, const float* __restrict__ b0,
                          const float* __restrict__ g1, const float* __restrict__ b1,
                          u16* __restrict__ out)
{
  int r = blockIdx.x;
  const float* x; const float* g; const float* bb;
  if (r < 1536){ x = rna + (size_t)r*1024; g = g0; bb = b0; }
  else { x = atac + (size_t)(r-1536)*1024; g = g1; bb = b1; }
  float s = 0.f, ss = 0.f;
  int t = threadIdx.x;
  float v0 = x[t], v1 = x[t+256], v2 = x[t+512], v3 = x[t+768];
  s = v0+v1+v2+v3; ss = v0*v0+v1*v1+v2*v2+v3*v3;
  #pragma unroll
  for (int off = 32; off >= 1; off >>= 1){ s += __shfl_xor(s, off); ss += __shfl_xor(ss, off); }
  __shared__ float rs_[4], rss_[4];
  int w = t >> 6;
  if ((t & 63) == 0){ rs_[w] = s; rss_[w] = ss; }
  __syncthreads();
  s = rs_[0]+rs_[1]+rs_[2]+rs_[3];
  ss = rss_[0]+rss_[1]+rss_[2]+rss_[3];
  float mu = s / 1024.f;
  float rstd = rsqrtf(ss / 1024.f - mu*mu + 1e-5f);
  u16* o = out + (size_t)r*1024;
  o[t]     = f2bf((v0-mu)*rstd*g[t]     + bb[t]);
  o[t+256] = f2bf((v1-mu)*rstd*g[t+256] + bb[t+256]);
  o[t+512] = f2bf((v2-mu)*rstd*g[t+512] + bb[t+512]);
  o[t+768] = f2bf((v3-mu)*rstd*g[t+768] + bb[t+768]);
}

// ---- batched embed: add splitK parts + bias, LN2, scatter into tok ----
__global__ void embed_addln2(const float* __restrict__ part,
                             const float* __restrict__ rb, const float* __restrict__ ab,
                             const float* __restrict__ g0, const float* __restrict__ bt0,
                             const float* __restrict__ g1, const float* __restrict__ bt1,
                             float* __restrict__ tok)
{
  int r = blockIdx.x;          // 0..3071
  int mod = (r >= 1536);
  int rl = mod ? r - 1536 : r;
  int b = rl / 768, rr = rl % 768;
  const float* bias = mod ? ab : rb;
  const float* g = mod ? g1 : g0;
  const float* bt = mod ? bt1 : bt0;
  const float* p0 = part + (size_t)r*DIMM;
  const float* p1 = p0 + (size_t)3072*DIMM;
  int t = threadIdx.x;
  float v0 = p0[t] + p1[t] + bias[t];
  float v1 = p0[t+256] + p1[t+256] + bias[t+256];
  float s = v0 + v1, ss = v0*v0 + v1*v1;
  #pragma unroll
  for (int off = 32; off >= 1; off >>= 1){ s += __shfl_xor(s, off); ss += __shfl_xor(ss, off); }
  __shared__ float rs_[4], rss_[4];
  int w = t >> 6;
  if ((t & 63) == 0){ rs_[w] = s; rss_[w] = ss; }
  __syncthreads();
  s = rs_[0]+rs_[1]+rs_[2]+rs_[3];
  ss = rss_[0]+rss_[1]+rss_[2]+rss_[3];
  float mu = s / DIMM;
  float rstd = rsqrtf(ss / DIMM - mu*mu + 1e-5f);
  float* tr = tok + ((size_t)(b*NTOK + (mod ? 784 : 0) + rr))*DIMM;
  tr[t]     = (v0 - mu)*rstd*g[t]     + bt[t];
  tr[t+256] = (v1 - mu)*rstd*g[t+256] + bt[t+256];
}

// ---- residual-add (attention proj, broadcast row0) + FFN LN -> tok, xn ----
__global__ void resadd_ffnln(float* __restrict__ tok, const float* __restrict__ proj,
                             const float* __restrict__ g, u16* __restrict__ xn)
{
  int n = blockIdx.x, b = blockIdx.y;
  int pr = (n >= 768 && n < 784) ? (1 + n - 768) : 0;
  const float* p = proj + ((size_t)b*17 + pr)*DIMM;
  size_t row = (size_t)(b*NTOK + n)*DIMM;
  int t = threadIdx.x;
  float v0 = tok[row + t]     + p[t];
  float v1 = tok[row + t+256] + p[t+256];
  tok[row + t] = v0; tok[row + t+256] = v1;
  float s = v0 + v1, ss = v0*v0 + v1*v1;
  #pragma unroll
  for (int off = 32; off >= 1; off >>= 1){ s += __shfl_xor(s, off); ss += __shfl_xor(ss, off); }
  __shared__ float rs_[4], rss_[4];
  int w = t >> 6;
  if ((t & 63) == 0){ rs_[w] = s; rss_[w] = ss; }
  __syncthreads();
  s = rs_[0]+rs_[1]+rs_[2]+rs_[3];
  ss = rss_[0]+rss_[1]+rss_[2]+rss_[3];
  float mu = s / DIMM;
  float rstd = rsqrtf(ss / DIMM - mu*mu + 1e-5f);
  xn[row + t]     = f2bf((v0 - mu)*rstd*g[t]);
  xn[row + t+256] = f2bf((v1 - mu)*rstd*g[t+256]);
}

// ---- splitK-add (FFN out) + next LN -> tok, xn ----
__global__ void skadd_ln(float* __restrict__ tok, const float* __restrict__ part,
                         const float* __restrict__ g, u16* __restrict__ xn)
{
  int r = blockIdx.x;
  size_t row = (size_t)r*DIMM;
  const float* p0 = part + row;
  const float* p1 = p0 + (size_t)MALL*DIMM;
  int t = threadIdx.x;
  float v0 = tok[row + t]     + p0[t]     + p1[t];
  float v1 = tok[row + t+256] + p0[t+256] + p1[t+256];
  tok[row + t] = v0; tok[row + t+256] = v1;
  float s = v0 + v1, ss = v0*v0 + v1*v1;
  #pragma unroll
  for (int off = 32; off >= 1; off >>= 1){ s += __shfl_xor(s, off); ss += __shfl_xor(ss, off); }
  __shared__ float rs_[4], rss_[4];
  int w = t >> 6;
  if ((t & 63) == 0){ rs_[w] = s; rss_[w] = ss; }
  __syncthreads();
  s = rs_[0]+rs_[1]+rs_[2]+rs_[3];
  ss = rss_[0]+rss_[1]+rss_[2]+rss_[3];
  float mu = s / DIMM;
  float rstd = rsqrtf(ss / DIMM - mu*mu + 1e-5f);
  xn[row + t]     = f2bf((v0 - mu)*rstd*g[t]);
  xn[row + t+256] = f2bf((v1 - mu)*rstd*g[t+256]);
}

// ------- gemm512: 8-wave 128x128; B bf16 [N][ldk]; optional B-switch at row mswitch;
//         splitK via grid.z; optional GEGLU epilogue (gout); optional V-colsum (csum) -------
__global__ __launch_bounds__(512) void gemm512(
    const u16* __restrict__ A, int lda,
    const u16* __restrict__ Bt, const u16* __restrict__ BtB, int mswitch, int ldk,
    float* __restrict__ C, int ldc, size_t Cz,
    u16* __restrict__ gout, float* __restrict__ csum,
    int M, int Nn, int K, int kchunk)
{
  __shared__ __align__(16) u16 As[128][40];
  __shared__ __align__(16) u16 Bs[128][40];
  __shared__ float colsum[2][128];
  const int t = threadIdx.x;
  const int lane = t & 63;
  const int w = t >> 6;
  const int wr = (w >> 2) * 64;
  const int wc = (w & 3) * 32;
  const int row0 = blockIdx.x * 128, col0 = blockIdx.y * 128;
  if (BtB && row0 >= mswitch) Bt = BtB;
  const int z = blockIdx.z;
  const int kbeg = z * kchunk;
  const int kend = (kbeg + kchunk < K) ? (kbeg + kchunk) : K;
  C += (size_t)z * Cz;
  const int l15 = lane & 15;
  const int l4 = (lane >> 4) * 8;
  f32x4 acc[4][2];
  #pragma unroll
  for (int m = 0; m < 4; ++m)
    #pragma unroll
    for (int n = 0; n < 2; ++n)
      #pragma unroll
      for (int j = 0; j < 4; ++j) acc[m][n][j] = 0.f;

  for (int k0 = kbeg; k0 < kend; k0 += 32) {
    {
      int r = t >> 2, c8 = (t & 3) * 8;
      bf16x8 av;
      #pragma unroll
      for (int j = 0; j < 8; ++j) av[j] = 0;
      int gr = row0 + r;
      if (gr < M) av = *(const bf16x8*)(A + (size_t)gr*lda + k0 + c8);
      *(bf16x8*)(&As[r][c8]) = av;
    }
    {
      int col = t & 127, kb = (t >> 7) * 8;
      bf16x8 bv;
      #pragma unroll
      for (int j = 0; j < 8; ++j) bv[j] = 0;
      int gc = col0 + col;
      if (gc < Nn) bv = *(const bf16x8*)(Bt + (size_t)gc*ldk + k0 + kb);
      *(bf16x8*)(&Bs[col][kb]) = bv;
    }
    __syncthreads();
    bf16x8 af[4], bfr[2];
    #pragma unroll
    for (int m = 0; m < 4; ++m) af[m]  = *(const bf16x8*)(&As[wr + m*16 + l15][l4]);
    #pragma unroll
    for (int n = 0; n < 2; ++n) bfr[n] = *(const bf16x8*)(&Bs[wc + n*16 + l15][l4]);
    #pragma unroll
    for (int m = 0; m < 4; ++m)
      #pragma unroll
      for (int n = 0; n < 2; ++n)
        acc[m][n] = __builtin_amdgcn_mfma_f32_16x16x32_bf16(af[m], bfr[n], acc[m][n], 0, 0, 0);
    __syncthreads();
  }
  const int rb = (lane >> 4) * 4;
  if (gout){
    int jcol = (col0 >> 1) + (w & 3)*16 + l15;
    #pragma unroll
    for (int m = 0; m < 4; ++m){
      int gr0 = row0 + wr + m*16 + rb;
      #pragma unroll
      for (int j = 0; j < 4; ++j){
        int gr = gr0 + j;
        if (gr < M){
          float gt = acc[m][1][j];
          float ge = 0.5f * gt * (1.0f + erff(gt * 0.70710678118654752f));
          gout[(size_t)gr*GSTRIDE + jcol] = f2bf(ge * acc[m][0][j]);
        }
      }
    }
  } else {
    #pragma unroll
    for (int m = 0; m < 4; ++m){
      int gr0 = row0 + wr + m*16 + rb;
      #pragma unroll
      for (int n = 0; n < 2; ++n){
        int gc = col0 + wc + n*16 + l15;
        if (gc >= Nn) continue;
        #pragma unroll
        for (int j = 0; j < 4; ++j){
          int gr = gr0 + j;
          if (gr < M) C[(size_t)gr*ldc + gc] = acc[m][n][j];
        }
      }
    }
  }
  if (csum && col0 >= 512){
    if (t < 256) colsum[t>>7][t&127] = 0.f;
    __syncthreads();
    #pragma unroll
    for (int n = 0; n < 2; ++n){
      float lv0 = 0.f, lv1 = 0.f;
      #pragma unroll
      for (int m = 0; m < 4; ++m){
        int gr0 = row0 + wr + m*16 + rb;
        #pragma unroll
        for (int j = 0; j < 4; ++j){
          float v = acc[m][n][j];
          if (gr0 + j < NTOK) lv0 += v; else lv1 += v;
        }
      }
      int lc = wc + n*16 + l15;
      atomicAdd(&colsum[0][lc], lv0);
      atomicAdd(&colsum[1][lc], lv1);
    }
    __syncthreads();
    if (t < 256){
      int bb = t>>7, c = t&127;
      csum[((size_t)(bb*25) + blockIdx.x)*512 + (col0 - 512) + c] = colsum[bb][c];
    }
  }
}

// ------- tiny GEMM (M<=128), B bf16 [N][ldk], batched over grid.z -------
__global__ __launch_bounds__(256) void gemm_tiny(
    const u16* __restrict__ A, int lda, size_t Abat,
    const u16* __restrict__ Bt, int ldk,
    float* __restrict__ C, int ldc, size_t Cbat,
    int M, int Nn, int K)
{
  A += (size_t)blockIdx.z * Abat;
  C += (size_t)blockIdx.z * Cbat;
  __shared__ __align__(16) u16 As[128][40];
  __shared__ __align__(16) u16 Bs[128][40];
  const int t = threadIdx.x;
  const int lane = t & 63;
  const int w = t >> 6;
  const int wr = (w >> 1) * 64, wc = (w & 1) * 64;
  const int col0 = blockIdx.y * 128;
  const int l15 = lane & 15;
  const int l4 = (lane >> 4) * 8;
  f32x4 acc[4][4];
  #pragma unroll
  for (int m = 0; m < 4; ++m)
    #pragma unroll
    for (int n = 0; n < 4; ++n)
      #pragma unroll
      for (int j = 0; j < 4; ++j) acc[m][n][j] = 0.f;

  for (int k0 = 0; k0 < K; k0 += 32) {
    #pragma unroll
    for (int u = 0; u < 2; ++u){
      int id = t + u*256;
      int r = id >> 2, c8 = (id & 3) * 8;
      bf16x8 av;
      #pragma unroll
      for (int j = 0; j < 8; ++j) av[j] = 0;
      if (r < M) av = *(const bf16x8*)(A + (size_t)r*lda + k0 + c8);
      *(bf16x8*)(&As[r][c8]) = av;
    }
    {
      int col = t & 127, kb = (t >> 7) * 16;
      bf16x8 b0, b1;
      #pragma unroll
      for (int j = 0; j < 8; ++j){ b0[j] = 0; b1[j] = 0; }
      int gc = col0 + col;
      if (gc < Nn){
        b0 = *(const bf16x8*)(Bt + (size_t)gc*ldk + k0 + kb);
        b1 = *(const bf16x8*)(Bt + (size_t)gc*ldk + k0 + kb + 8);
      }
      *(bf16x8*)(&Bs[col][kb])     = b0;
      *(bf16x8*)(&Bs[col][kb + 8]) = b1;
    }
    __syncthreads();
    bf16x8 af[4], bfr[4];
    #pragma unroll
    for (int m = 0; m < 4; ++m) af[m]  = *(const bf16x8*)(&As[wr + m*16 + l15][l4]);
    #pragma unroll
    for (int n = 0; n < 4; ++n) bfr[n] = *(const bf16x8*)(&Bs[wc + n*16 + l15][l4]);
    #pragma unroll
    for (int m = 0; m < 4; ++m)
      #pragma unroll
      for (int n = 0; n < 4; ++n)
        acc[m][n] = __builtin_amdgcn_mfma_f32_16x16x32_bf16(af[m], bfr[n], acc[m][n], 0, 0, 0);
    __syncthreads();
  }
  const int rb = (lane >> 4) * 4;
  #pragma unroll
  for (int m = 0; m < 4; ++m){
    int gr0 = wr + m*16 + rb;
    #pragma unroll
    for (int n = 0; n < 4; ++n){
      int gc = col0 + wc + n*16 + l15;
      if (gc >= Nn) continue;
      #pragma unroll
      for (int j = 0; j < 4; ++j){
        int gr = gr0 + j;
        if (gr < M) C[(size_t)gr*ldc + gc] = acc[m][n][j];
      }
    }
  }
}

// ---------------- fused attention: one block per (h, b, q-row) ----------------
__global__ __launch_bounds__(256) void fused_attn(
    const u16* __restrict__ xn, const u16* __restrict__ wqt,
    const float* __restrict__ kv, u16* __restrict__ zb)
{
  int h = blockIdx.x, b = blockIdx.y, qi = blockIdx.z;
  int t = threadIdx.x;
  int lane = t & 63, wid = t >> 6;
  __shared__ float xs[512];
  __shared__ float qs[64];
  __shared__ float pl[1536];
  __shared__ float red[4][64];
  __shared__ float redm[4], sinv_s;

  // 0) stage x row (bf16 -> f32)
  {
    int row = b*NTOK + 768 + qi;
    const u16* xr = xn + (size_t)row*DIMM;
    xs[t] = bf2f(xr[t]);
    xs[t+256] = bf2f(xr[t+256]);
  }
  __syncthreads();

  // 1) q projection: thread (d = t&63, kq = t>>6) -> 128-k partial
  {
    int d = lane, kq = wid;
    const u16* wrr = wqt + (size_t)(h*64 + d)*DIMM + kq*128;
    float a = 0.f;
    #pragma unroll
    for (int k = 0; k < 128; k += 8){
      bf16x8 wv = *(const bf16x8*)(wrr + k);
      int kb = kq*128 + k;
      #pragma unroll
      for (int i = 0; i < 8; ++i) a += xs[kb+i] * bf2f((u16)wv[i]);
    }
    red[kq][d] = a;
  }
  __syncthreads();
  if (t < 64) qs[t] = (red[0][t] + red[1][t] + red[2][t] + red[3][t]) * 0.125f;
  __syncthreads();

  // 2) QK^T: 6 j per thread
  float sj[6];
  #pragma unroll
  for (int z = 0; z < 6; ++z){
    int jj = z*256 + t;
    int j = (jj < 768) ? jj : jj + 16;
    const float* kr = kv + ((size_t)(b*NTOK + j))*1024 + h*64;
    float a = 0.f;
    #pragma unroll
    for (int d = 0; d < 64; d += 4){
      float4 kd = *(const float4*)(kr + d);
      a += qs[d]*kd.x + qs[d+1]*kd.y + qs[d+2]*kd.z + qs[d+3]*kd.w;
    }
    sj[z] = a;
  }

  // 3) softmax (unnormalized P to LDS; 1/sum folded into PV write)
  float m = -3.4e38f;
  #pragma unroll
  for (int z = 0; z < 6; ++z) m = fmaxf(m, sj[z]);
  #pragma unroll
  for (int off = 32; off >= 1; off >>= 1) m = fmaxf(m, __shfl_xor(m, off));
  if (lane == 0) redm[wid] = m;
  __syncthreads();
  m = fmaxf(fmaxf(redm[0], redm[1]), fmaxf(redm[2], redm[3]));
  float sq = 0.f;
  #pragma unroll
  for (int z = 0; z < 6; ++z){ sj[z] = __expf(sj[z] - m); sq += sj[z]; }
  #pragma unroll
  for (int z = 0; z < 6; ++z) pl[z*256 + t] = sj[z];
  #pragma unroll
  for (int off = 32; off >= 1; off >>= 1) sq += __shfl_xor(sq, off);
  if (lane == 0) redm[wid] = sq;
  __syncthreads();
  if (t == 0) sinv_s = 1.0f / (redm[0] + redm[1] + redm[2] + redm[3]);
  __syncthreads();

  // 4) PV: thread (d = t&63, jq = t>>6); 384 j per thread
  {
    int d = lane, jq = wid;
    int j0 = jq * 384;
    int joff = (jq >= 2) ? 16 : 0;
    const float* vb = kv + (size_t)b*NTOK*1024 + 512 + h*64 + d + (size_t)joff*1024;
    float a0=0.f, a1=0.f, a2=0.f, a3=0.f;
    #pragma unroll 2
    for (int jj = j0; jj < j0 + 384; jj += 4){
      const float* vp = vb + (size_t)jj*1024;
      a0 += pl[jj]   * vp[0];
      a1 += pl[jj+1] * vp[1024];
      a2 += pl[jj+2] * vp[2048];
      a3 += pl[jj+3] * vp[3072];
    }
    red[jq][d] = a0+a1+a2+a3;
  }
  __syncthreads();
  if (t < 64){
    float o = (red[0][t] + red[1][t] + red[2][t] + red[3][t]) * sinv_s;
    zb[((size_t)(b*17 + 1 + qi))*DIMM + h*64 + t] = f2bf(o);
  }
}

// ---- finish colmean from gemm csum partials: zb row0 (bf16) and/or mv (f32) ----
__global__ void csum_finish(const float* __restrict__ csum, u16* __restrict__ zb,
                            float* __restrict__ mv)
{
  int i = blockIdx.x * 256 + threadIdx.x;   // 0..1023
  if (i >= BATCH*DIMM) return;
  int b = i >> 9, c = i & 511;
  float s = 0.f;
  #pragma unroll
  for (int bx = 0; bx < 25; ++bx) s += csum[((size_t)(b*25) + bx)*512 + c];
  s *= (1.0f/1552.0f);
  if (zb) zb[((size_t)(b*17))*DIMM + c] = f2bf(s);
  if (mv) mv[(size_t)b*DIMM + c] = s;
}

// ---------------- copy fusion tokens into tok ----------------
__global__ void fuscopy_kernel(const float* __restrict__ ft, float* __restrict__ tok)
{
  int i = blockIdx.x * 256 + threadIdx.x;
  if (i >= BATCH*16*DIMM) return;
  int c = i & 511; int tt = i >> 9; int b = tt >> 4; int r = tt & 15;
  tok[((size_t)(b*NTOK + 768 + r))*DIMM + c] = ft[r*DIMM + c];
}

// ---------------- parallel mat-vec (pool q2) ----------------
__global__ void matvec512(const float* __restrict__ y, const float* __restrict__ w,
                          float* __restrict__ out, float scale)
{
  __shared__ float ys[512];
  __shared__ float red[4][64];
  int t = threadIdx.x;
  ys[t] = y[t]; ys[t+256] = y[t+256];
  __syncthreads();
  int col = blockIdx.x*64 + (t & 63);
  int kq = t >> 6;
  float s = 0.f;
  #pragma unroll 4
  for (int k = kq*128; k < kq*128+128; ++k) s += ys[k] * w[(size_t)k*512 + col];
  red[kq][t & 63] = s;
  __syncthreads();
  if (t < 64)
    out[blockIdx.x*64 + t] = (red[0][t]+red[1][t]+red[2][t]+red[3][t]) * scale;
}

// ---------------- pooled rows ----------------
__global__ void pooledmv(const float* __restrict__ mv, const float* __restrict__ out2,
                         const float* __restrict__ wo, const float* __restrict__ rt,
                         float* __restrict__ out)
{
  int br = blockIdx.y; int b = br/3, r = br%3;
  const float* y = (r < 2) ? (mv + (size_t)b*DIMM) : (out2 + (size_t)b*DIMM);
  __shared__ float ys[512];
  __shared__ float red[4][64];
  int t = threadIdx.x;
  ys[t] = y[t]; ys[t+256] = y[t+256];
  __syncthreads();
  int col = blockIdx.x*64 + (t & 63);
  int kq = t >> 6;
  float s = 0.f;
  #pragma unroll 4
  for (int k = kq*128; k < kq*128+128; ++k) s += ys[k] * wo[(size_t)k*512 + col];
  red[kq][t & 63] = s;
  __syncthreads();
  if (t < 64){
    int c = blockIdx.x*64 + t;
    out[(size_t)br*DIMM + c] = red[0][t]+red[1][t]+red[2][t]+red[3][t] + rt[(size_t)r*DIMM + c];
  }
}

// ---------------- pool attention of return-token 2 over 16 fusion keys ----------------
__global__ void poolattn2_kernel(const float* __restrict__ kv, const float* __restrict__ q2,
                                 float* __restrict__ out2)
{
  int h = blockIdx.x, b = blockIdx.y, d = threadIdx.x;
  __shared__ float sm[16];
  if (d < 16){
    const float* kr = kv + ((size_t)(b*NTOK + 768 + d))*1024 + h*64;
    float a = 0.f;
    for (int k = 0; k < 64; ++k) a += q2[h*64 + k] * kr[k];
    sm[d] = a;
  }
  __syncthreads();
  float m = -3.4e38f;
  #pragma unroll
  for (int j = 0; j < 16; ++j) m = fmaxf(m, sm[j]);
  float wv[16]; float s = 0.f;
  #pragma unroll
  for (int j = 0; j < 16; ++j){ wv[j] = expf(sm[j] - m); s += wv[j]; }
  float inv = 1.0f / s;
  float a = 0.f;
  #pragma unroll
  for (int j = 0; j < 16; ++j)
    a += wv[j] * kv[((size_t)(b*NTOK + 768 + j))*1024 + 512 + h*64 + d];
  out2[(size_t)b*DIMM + h*64 + d] = a * inv;
}

// =================================================================
extern "C" void kernel_launch(void* const* d_in, const int* in_sizes, int n_in,
                              void* d_out, int out_size, void* d_ws, size_t ws_size,
                              hipStream_t stream)
{
  const float* rna        = (const float*)d_in[0];
  const float* atac       = (const float*)d_in[1];
  const float* rna_ln1_g  = (const float*)d_in[2];
  const float* rna_ln1_b  = (const float*)d_in[3];
  const float* rna_w      = (const float*)d_in[4];
  const float* rna_b      = (const float*)d_in[5];
  const float* rna_ln2_g  = (const float*)d_in[6];
  const float* rna_ln2_b  = (const float*)d_in[7];
  const float* atac_ln1_g = (const float*)d_in[8];
  const float* atac_ln1_b = (const float*)d_in[9];
  const float* atac_w     = (const float*)d_in[10];
  const float* atac_b     = (const float*)d_in[11];
  const float* atac_ln2_g = (const float*)d_in[12];
  const float* atac_ln2_b = (const float*)d_in[13];
  const float* fusion_tok = (const float*)d_in[14];
  const float* lay_ag     = (const float*)d_in[15];
  const float* lay_wq     = (const float*)d_in[16];
  const float* lay_wkv    = (const float*)d_in[17];
  const float* lay_wo     = (const float*)d_in[18];
  const float* lay_fg     = (const float*)d_in[19];
  const float* lay_w1     = (const float*)d_in[20];
  const float* lay_w2     = (const float*)d_in[21];
  const float* final_g    = (const float*)d_in[22];
  const float* ret_tok    = (const float*)d_in[23];
  const float* pool_g     = (const float*)d_in[24];
  const float* pool_wq    = (const float*)d_in[25];
  const float* pool_wkv   = (const float*)d_in[26];
  const float* pool_wo    = (const float*)d_in[27];

  uint8_t* ws = (uint8_t*)d_ws;
  size_t off = 0;
  auto carve = [&](size_t bytes) -> uint8_t* {
    uint8_t* p = ws + off;
    off += (bytes + 255) & ~(size_t)255;
    return p;
  };
  // bf16 weights
  u16* rna_wt   = (u16*)carve((size_t)512*1024*2);
  u16* atac_wt  = (u16*)carve((size_t)512*1024*2);
  u16* wkvt     = (u16*)carve((size_t)4*1024*512*2);
  u16* wqt      = (u16*)carve((size_t)4*512*512*2);
  u16* wot      = (u16*)carve((size_t)4*512*512*2);
  u16* w1t      = (u16*)carve((size_t)4*NW1*512*2);
  u16* w2t      = (u16*)carve((size_t)4*512*GSTRIDE*2);
  u16* pool_wkvt= (u16*)carve((size_t)1024*512*2);
  // activations
  float* tok   = (float*)carve((size_t)MALL * DIMM * 4);
  u16*   xn    = (u16*)  carve((size_t)MALL * DIMM * 2);
  float* kv    = (float*)carve((size_t)MALL * 1024 * 4);
  u16*   lnbuf = (u16*)  carve((size_t)3072 * 1024 * 2);
  u16*   zb    = (u16*)  carve((size_t)BATCH*17*DIMM * 2);
  float* proj  = (float*)carve((size_t)BATCH*17*DIMM * 4);
  float* mv    = (float*)carve((size_t)BATCH*DIMM * 4);
  float* q2    = (float*)carve((size_t)DIMM * 4);
  float* yq2   = (float*)carve((size_t)DIMM * 4);
  float* out2  = (float*)carve((size_t)BATCH*DIMM * 4);
  float* csum  = (float*)carve((size_t)BATCH*25*512 * 4);
  u16*   gbuf  = (u16*)  carve((size_t)MALL * GSTRIDE * 2);
  float* skpart= (float*)carve((size_t)2 * MALL * 512 * 4);
  (void)ws_size;

  // ---- one-dispatch weight conversion ----
  convall<<<14080, 256, 0, stream>>>(rna_w, atac_w, lay_wkv, lay_wq, lay_wo, lay_w1, lay_w2, pool_wkv,
                                     rna_wt, atac_wt, wkvt, wqt, wot, w1t, w2t, pool_wkvt);

  // ---- embeddings (both modalities batched) ----
  embed_ln1<<<3072, 256, 0, stream>>>(rna, atac, rna_ln1_g, rna_ln1_b, atac_ln1_g, atac_ln1_b, lnbuf);
  gemm512<<<dim3(24, 4, 2), 512, 0, stream>>>(lnbuf, 1024, rna_wt, atac_wt, 1536, 1024,
                                              skpart, 512, (size_t)3072*512, nullptr, nullptr,
                                              3072, 512, 1024, 512);
  embed_addln2<<<3072, 256, 0, stream>>>(skpart, rna_b, atac_b, rna_ln2_g, rna_ln2_b,
                                         atac_ln2_g, atac_ln2_b, tok);
  fuscopy_kernel<<<(BATCH*16*DIMM + 255)/256, 256, 0, stream>>>(fusion_tok, tok);

  // layer-0 attention LN
  ln_kernel<<<MALL, 256, 0, stream>>>(tok, lay_ag, nullptr, nullptr, xn, 512);

  // ---- transformer layers ----
  for (int l = 0; l < 4; ++l){
    const float* fg  = lay_fg + (size_t)l*DIMM;
    const float* gnext = (l < 3) ? (lay_ag + (size_t)(l+1)*DIMM) : final_g;
    const u16* wkvt_l = wkvt + (size_t)l*1024*512;
    const u16* wqt_l  = wqt  + (size_t)l*512*512;
    const u16* wot_l  = wot  + (size_t)l*512*512;
    const u16* w1t_l  = w1t  + (size_t)l*NW1*512;
    const u16* w2t_l  = w2t  + (size_t)l*512*GSTRIDE;

    gemm512<<<dim3(25, 8, 1), 512, 0, stream>>>(xn, 512, wkvt_l, nullptr, 0, 512,
                                                kv, 1024, 0, nullptr, csum, MALL, 1024, 512, 512);
    fused_attn<<<dim3(8, BATCH, 16), 256, 0, stream>>>(xn, wqt_l, kv, zb);
    csum_finish<<<4, 256, 0, stream>>>(csum, zb, nullptr);
    gemm_tiny<<<dim3(1, 4, 2), 256, 0, stream>>>(zb, 512, (size_t)17*DIMM,
                                                 wot_l, 512, proj, 512, (size_t)17*DIMM, 17, 512, 512);
    resadd_ffnln<<<dim3(NTOK, BATCH), 256, 0, stream>>>(tok, proj, fg, xn);
    gemm512<<<dim3(25, 22, 1), 512, 0, stream>>>(xn, 512, w1t_l, nullptr, 0, 512,
                                                 nullptr, 0, 0, gbuf, nullptr, MALL, NW1, 512, 512);
    gemm512<<<dim3(25, 4, 2), 512, 0, stream>>>(gbuf, GSTRIDE, w2t_l, nullptr, 0, GSTRIDE,
                                                skpart, 512, (size_t)MALL*512, nullptr, nullptr,
                                                MALL, 512, GSTRIDE, 704);
    skadd_ln<<<MALL, 256, 0, stream>>>(tok, skpart, gnext, xn);
  }

  // ---- pooling (xn holds final-LN tokens) ----
  gemm512<<<dim3(25, 8, 1), 512, 0, stream>>>(xn, 512, pool_wkvt, nullptr, 0, 512,
                                              kv, 1024, 0, nullptr, csum, MALL, 1024, 512, 512);
  csum_finish<<<4, 256, 0, stream>>>(csum, nullptr, mv);
  ln_kernel<<<1, 256, 0, stream>>>(ret_tok + 2*DIMM, pool_g, nullptr, yq2, nullptr, 512);
  matvec512<<<8, 256, 0, stream>>>(yq2, pool_wq, q2, 0.125f);
  poolattn2_kernel<<<dim3(8, BATCH), 64, 0, stream>>>(kv, q2, out2);
  pooledmv<<<dim3(8, 6), 256, 0, stream>>>(mv, out2, pool_wo, ret_tok, (float*)d_out);
}

// Round 8
// 631.542 us; speedup vs baseline: 5.2079x; 1.0627x over previous
//
#include <hip/hip_runtime.h>
#include <stdint.h>
#include <stddef.h>

#define NTOK 1552
#define DIMM 512
#define IFFC 1365
#define IFF2 2730
#define NW1 2816       // padded/permuted w1 output cols (2*1408)
#define GSTRIDE 1408   // geglu output row stride (bf16) = padded K of w2
#define BATCH 2
#define MALL (BATCH*NTOK)   // 3104
#define AZ 6           // attention j-chunks (256 keys each)

typedef unsigned short u16;
typedef __attribute__((ext_vector_type(8))) short bf16x8;
typedef __attribute__((ext_vector_type(4))) float f32x4;

__device__ __forceinline__ u16 f2bf(float f){
  union { float f; uint32_t u; } v; v.f = f;
  uint32_t u = v.u;
  uint32_t r = (u + 0x7FFFu + ((u >> 16) & 1u)) >> 16;
  return (u16)r;
}
__device__ __forceinline__ float bf2f(u16 x){
  union { uint32_t u; float f; } v; v.u = ((uint32_t)x) << 16; return v.f;
}

// ---------- one-dispatch weight convert/transpose (8 segments), vectorized ----------
__global__ void convall(const float* s0,const float* s1,const float* s2,const float* s3,
                        const float* s4,const float* s5,const float* s6,const float* s7,
                        u16* d0,u16* d1,u16* d2,u16* d3,u16* d4,u16* d5,u16* d6,u16* d7)
{
  const float* srcs[8] = {s0,s1,s2,s3,s4,s5,s6,s7};
  u16* dsts[8] = {d0,d1,d2,d3,d4,d5,d6,d7};
  const int KT[8]   = {32,32,16,16,16,16,44,16};
  const int NT[8]   = {16,16,32,16,16,88,16,32};
  const int TC[8]   = {512,512,2048,1024,1024,5632,2816,512};
  const int K_[8]   = {1024,1024,512,512,512,512,1365,512};
  const int NSRC[8] = {512,512,1024,512,512,2730,512,1024};
  const int LDK[8]  = {1024,1024,512,512,512,512,1408,512};
  const int NOUT[8] = {512,512,1024,512,512,2816,512,1024};
  const int WS_[8]  = {0,0,512*1024,512*512,512*512,512*2730,1365*512,0};
  const int WT_[8]  = {0,0,1024*512,512*512,512*512,2816*512,512*1408,0};

  int bid = blockIdx.x;
  int seg = 0, base = 0;
  while (seg < 7 && bid >= base + TC[seg]) { base += TC[seg]; ++seg; }
  int loc = bid - base;
  int kt = KT[seg];
  int z = loc / (kt*NT[seg]); loc -= z*(kt*NT[seg]);
  int kb = (loc % kt) * 32, nb = (loc / kt) * 32;
  const float* w = srcs[seg] + (size_t)z * WS_[seg];
  u16* wt = dsts[seg] + (size_t)z * WT_[seg];
  int K = K_[seg], NS = NSRC[seg], ldk = LDK[seg], NO = NOUT[seg];

  __shared__ float tile[32][33];
  int t = threadIdx.x;
  {
    int k = t >> 3, n4 = (t & 7) * 4;
    int gk = kb + k;
    float4 v = make_float4(0.f,0.f,0.f,0.f);
    if (gk < K){
      if (seg != 5){
        int gn = nb + n4;
        if (gn + 4 <= NS){
          v = *(const float4*)(w + (size_t)gk*NS + gn);
        } else {
          float* pv = (float*)&v;
          #pragma unroll
          for (int i = 0; i < 4; ++i){ int n = gn + i; if (n < NS) pv[i] = w[(size_t)gk*NS + n]; }
        }
      } else {
        float* pv = (float*)&v;
        #pragma unroll
        for (int i = 0; i < 4; ++i){
          int n = nb + n4 + i;
          if (n < NO){
            int bb = n >> 7, rr = n & 127, g = rr >> 5, hh = rr & 31;
            int j = bb*64 + g*16 + (hh & 15);
            if (j < 1365) pv[i] = w[(size_t)gk*NS + ((hh < 16) ? j : 1365 + j)];
          }
        }
      }
    }
    tile[k][n4] = v.x; tile[k][n4+1] = v.y; tile[k][n4+2] = v.z; tile[k][n4+3] = v.w;
  }
  __syncthreads();
  if (t < 128){
    int n = t >> 2, k8 = (t & 3) * 8;
    int gn = nb + n, gk = kb + k8;
    if (gn < NO && gk < ldk){
      u16 sh[8];
      #pragma unroll
      for (int i = 0; i < 8; ++i) sh[i] = f2bf(tile[k8+i][n]);
      *(bf16x8*)(wt + (size_t)gn*ldk + gk) = *(bf16x8*)sh;
    }
  }
}

// ---------------- LayerNorm: one block per row ----------------
__global__ void ln_kernel(const float* __restrict__ in, const float* __restrict__ g,
                          const float* __restrict__ bta, float* __restrict__ of32,
                          u16* __restrict__ obf, int D)
{
  const int r = blockIdx.x;
  const float* x = in + (size_t)r * D;
  float s = 0.f, ss = 0.f;
  for (int c = threadIdx.x; c < D; c += 256){ float v = x[c]; s += v; ss += v*v; }
  #pragma unroll
  for (int off = 32; off >= 1; off >>= 1){ s += __shfl_xor(s, off); ss += __shfl_xor(ss, off); }
  __shared__ float rs_[4], rss_[4];
  int w = threadIdx.x >> 6;
  if ((threadIdx.x & 63) == 0){ rs_[w] = s; rss_[w] = ss; }
  __syncthreads();
  s = rs_[0] + rs_[1] + rs_[2] + rs_[3];
  ss = rss_[0] + rss_[1] + rss_[2] + rss_[3];
  float mu = s / D;
  float rstd = rsqrtf(ss / D - mu*mu + 1e-5f);
  for (int c = threadIdx.x; c < D; c += 256){
    float y = (x[c] - mu) * rstd * g[c] + (bta ? bta[c] : 0.f);
    if (of32) of32[(size_t)r*D + c] = y;
    if (obf)  obf[(size_t)r*D + c] = f2bf(y);
  }
}

// ---- batched embed LN1 (rna rows 0..1535, atac rows 1536..3071) ----
__global__ void embed_ln1(const float* __restrict__ rna, const float* __restrict__ atac,
                          const float* __restrict__ g0, const float* __restrict__ b0,
                          const float* __restrict__ g1, const float* __restrict__ b1,
                          u16* __restrict__ out)
{
  int r = blockIdx.x;
  const float* x; const float* g; const float* bb;
  if (r < 1536){ x = rna + (size_t)r*1024; g = g0; bb = b0; }
  else { x = atac + (size_t)(r-1536)*1024; g = g1; bb = b1; }
  float s = 0.f, ss = 0.f;
  int t = threadIdx.x;
  float v0 = x[t], v1 = x[t+256], v2 = x[t+512], v3 = x[t+768];
  s = v0+v1+v2+v3; ss = v0*v0+v1*v1+v2*v2+v3*v3;
  #pragma unroll
  for (int off = 32; off >= 1; off >>= 1){ s += __shfl_xor(s, off); ss += __shfl_xor(ss, off); }
  __shared__ float rs_[4], rss_[4];
  int w = t >> 6;
  if ((t & 63) == 0){ rs_[w] = s; rss_[w] = ss; }
  __syncthreads();
  s = rs_[0]+rs_[1]+rs_[2]+rs_[3];
  ss = rss_[0]+rss_[1]+rss_[2]+rss_[3];
  float mu = s / 1024.f;
  float rstd = rsqrtf(ss / 1024.f - mu*mu + 1e-5f);
  u16* o = out + (size_t)r*1024;
  o[t]     = f2bf((v0-mu)*rstd*g[t]     + bb[t]);
  o[t+256] = f2bf((v1-mu)*rstd*g[t+256] + bb[t+256]);
  o[t+512] = f2bf((v2-mu)*rstd*g[t+512] + bb[t+512]);
  o[t+768] = f2bf((v3-mu)*rstd*g[t+768] + bb[t+768]);
}

// ---- batched embed: add splitK parts + bias, LN2, scatter into tok ----
__global__ void embed_addln2(const float* __restrict__ part,
                             const float* __restrict__ rb, const float* __restrict__ ab,
                             const float* __restrict__ g0, const float* __restrict__ bt0,
                             const float* __restrict__ g1, const float* __restrict__ bt1,
                             float* __restrict__ tok)
{
  int r = blockIdx.x;          // 0..3071
  int mod = (r >= 1536);
  int rl = mod ? r - 1536 : r;
  int b = rl / 768, rr = rl % 768;
  const float* bias = mod ? ab : rb;
  const float* g = mod ? g1 : g0;
  const float* bt = mod ? bt1 : bt0;
  const float* p0 = part + (size_t)r*DIMM;
  const float* p1 = p0 + (size_t)3072*DIMM;
  int t = threadIdx.x;
  float v0 = p0[t] + p1[t] + bias[t];
  float v1 = p0[t+256] + p1[t+256] + bias[t+256];
  float s = v0 + v1, ss = v0*v0 + v1*v1;
  #pragma unroll
  for (int off = 32; off >= 1; off >>= 1){ s += __shfl_xor(s, off); ss += __shfl_xor(ss, off); }
  __shared__ float rs_[4], rss_[4];
  int w = t >> 6;
  if ((t & 63) == 0){ rs_[w] = s; rss_[w] = ss; }
  __syncthreads();
  s = rs_[0]+rs_[1]+rs_[2]+rs_[3];
  ss = rss_[0]+rss_[1]+rss_[2]+rss_[3];
  float mu = s / DIMM;
  float rstd = rsqrtf(ss / DIMM - mu*mu + 1e-5f);
  float* tr = tok + ((size_t)(b*NTOK + (mod ? 784 : 0) + rr))*DIMM;
  tr[t]     = (v0 - mu)*rstd*g[t]     + bt[t];
  tr[t+256] = (v1 - mu)*rstd*g[t+256] + bt[t+256];
}

// ---- residual-add (attention proj, broadcast row0) + FFN LN -> tok, xn ----
__global__ void resadd_ffnln(float* __restrict__ tok, const float* __restrict__ proj,
                             const float* __restrict__ g, u16* __restrict__ xn)
{
  int n = blockIdx.x, b = blockIdx.y;
  int pr = (n >= 768 && n < 784) ? (1 + n - 768) : 0;
  const float* p = proj + ((size_t)b*17 + pr)*DIMM;
  size_t row = (size_t)(b*NTOK + n)*DIMM;
  int t = threadIdx.x;
  float v0 = tok[row + t]     + p[t];
  float v1 = tok[row + t+256] + p[t+256];
  tok[row + t] = v0; tok[row + t+256] = v1;
  float s = v0 + v1, ss = v0*v0 + v1*v1;
  #pragma unroll
  for (int off = 32; off >= 1; off >>= 1){ s += __shfl_xor(s, off); ss += __shfl_xor(ss, off); }
  __shared__ float rs_[4], rss_[4];
  int w = t >> 6;
  if ((t & 63) == 0){ rs_[w] = s; rss_[w] = ss; }
  __syncthreads();
  s = rs_[0]+rs_[1]+rs_[2]+rs_[3];
  ss = rss_[0]+rss_[1]+rss_[2]+rss_[3];
  float mu = s / DIMM;
  float rstd = rsqrtf(ss / DIMM - mu*mu + 1e-5f);
  xn[row + t]     = f2bf((v0 - mu)*rstd*g[t]);
  xn[row + t+256] = f2bf((v1 - mu)*rstd*g[t+256]);
}

// ---- splitK-add (FFN out) + next LN -> tok, xn ----
__global__ void skadd_ln(float* __restrict__ tok, const float* __restrict__ part,
                         const float* __restrict__ g, u16* __restrict__ xn)
{
  int r = blockIdx.x;
  size_t row = (size_t)r*DIMM;
  const float* p0 = part + row;
  const float* p1 = p0 + (size_t)MALL*DIMM;
  int t = threadIdx.x;
  float v0 = tok[row + t]     + p0[t]     + p1[t];
  float v1 = tok[row + t+256] + p0[t+256] + p1[t+256];
  tok[row + t] = v0; tok[row + t+256] = v1;
  float s = v0 + v1, ss = v0*v0 + v1*v1;
  #pragma unroll
  for (int off = 32; off >= 1; off >>= 1){ s += __shfl_xor(s, off); ss += __shfl_xor(ss, off); }
  __shared__ float rs_[4], rss_[4];
  int w = t >> 6;
  if ((t & 63) == 0){ rs_[w] = s; rss_[w] = ss; }
  __syncthreads();
  s = rs_[0]+rs_[1]+rs_[2]+rs_[3];
  ss = rss_[0]+rss_[1]+rss_[2]+rss_[3];
  float mu = s / DIMM;
  float rstd = rsqrtf(ss / DIMM - mu*mu + 1e-5f);
  xn[row + t]     = f2bf((v0 - mu)*rstd*g[t]);
  xn[row + t+256] = f2bf((v1 - mu)*rstd*g[t+256]);
}

// ------- gemm512: 8-wave 128x128; B bf16 [N][ldk]; optional B-switch at row mswitch;
//         splitK via grid.z; optional GEGLU epilogue (gout); optional V-colsum (csum) -------
__global__ __launch_bounds__(512) void gemm512(
    const u16* __restrict__ A, int lda,
    const u16* __restrict__ Bt, const u16* __restrict__ BtB, int mswitch, int ldk,
    float* __restrict__ C, int ldc, size_t Cz,
    u16* __restrict__ gout, float* __restrict__ csum,
    int M, int Nn, int K, int kchunk)
{
  __shared__ __align__(16) u16 As[128][40];
  __shared__ __align__(16) u16 Bs[128][40];
  __shared__ float colsum[2][128];
  const int t = threadIdx.x;
  const int lane = t & 63;
  const int w = t >> 6;
  const int wr = (w >> 2) * 64;
  const int wc = (w & 3) * 32;
  const int row0 = blockIdx.x * 128, col0 = blockIdx.y * 128;
  if (BtB && row0 >= mswitch) Bt = BtB;
  const int z = blockIdx.z;
  const int kbeg = z * kchunk;
  const int kend = (kbeg + kchunk < K) ? (kbeg + kchunk) : K;
  C += (size_t)z * Cz;
  const int l15 = lane & 15;
  const int l4 = (lane >> 4) * 8;
  f32x4 acc[4][2];
  #pragma unroll
  for (int m = 0; m < 4; ++m)
    #pragma unroll
    for (int n = 0; n < 2; ++n)
      #pragma unroll
      for (int j = 0; j < 4; ++j) acc[m][n][j] = 0.f;

  for (int k0 = kbeg; k0 < kend; k0 += 32) {
    {
      int r = t >> 2, c8 = (t & 3) * 8;
      bf16x8 av;
      #pragma unroll
      for (int j = 0; j < 8; ++j) av[j] = 0;
      int gr = row0 + r;
      if (gr < M) av = *(const bf16x8*)(A + (size_t)gr*lda + k0 + c8);
      *(bf16x8*)(&As[r][c8]) = av;
    }
    {
      int col = t & 127, kb = (t >> 7) * 8;
      bf16x8 bv;
      #pragma unroll
      for (int j = 0; j < 8; ++j) bv[j] = 0;
      int gc = col0 + col;
      if (gc < Nn) bv = *(const bf16x8*)(Bt + (size_t)gc*ldk + k0 + kb);
      *(bf16x8*)(&Bs[col][kb]) = bv;
    }
    __syncthreads();
    bf16x8 af[4], bfr[2];
    #pragma unroll
    for (int m = 0; m < 4; ++m) af[m]  = *(const bf16x8*)(&As[wr + m*16 + l15][l4]);
    #pragma unroll
    for (int n = 0; n < 2; ++n) bfr[n] = *(const bf16x8*)(&Bs[wc + n*16 + l15][l4]);
    #pragma unroll
    for (int m = 0; m < 4; ++m)
      #pragma unroll
      for (int n = 0; n < 2; ++n)
        acc[m][n] = __builtin_amdgcn_mfma_f32_16x16x32_bf16(af[m], bfr[n], acc[m][n], 0, 0, 0);
    __syncthreads();
  }
  const int rb = (lane >> 4) * 4;
  if (gout){
    int jcol = (col0 >> 1) + (w & 3)*16 + l15;
    #pragma unroll
    for (int m = 0; m < 4; ++m){
      int gr0 = row0 + wr + m*16 + rb;
      #pragma unroll
      for (int j = 0; j < 4; ++j){
        int gr = gr0 + j;
        if (gr < M){
          float gt = acc[m][1][j];
          float ge = 0.5f * gt * (1.0f + erff(gt * 0.70710678118654752f));
          gout[(size_t)gr*GSTRIDE + jcol] = f2bf(ge * acc[m][0][j]);
        }
      }
    }
  } else {
    #pragma unroll
    for (int m = 0; m < 4; ++m){
      int gr0 = row0 + wr + m*16 + rb;
      #pragma unroll
      for (int n = 0; n < 2; ++n){
        int gc = col0 + wc + n*16 + l15;
        if (gc >= Nn) continue;
        #pragma unroll
        for (int j = 0; j < 4; ++j){
          int gr = gr0 + j;
          if (gr < M) C[(size_t)gr*ldc + gc] = acc[m][n][j];
        }
      }
    }
  }
  if (csum && col0 >= 512){
    if (t < 256) colsum[t>>7][t&127] = 0.f;
    __syncthreads();
    #pragma unroll
    for (int n = 0; n < 2; ++n){
      float lv0 = 0.f, lv1 = 0.f;
      #pragma unroll
      for (int m = 0; m < 4; ++m){
        int gr0 = row0 + wr + m*16 + rb;
        #pragma unroll
        for (int j = 0; j < 4; ++j){
          float v = acc[m][n][j];
          if (gr0 + j < NTOK) lv0 += v; else lv1 += v;
        }
      }
      int lc = wc + n*16 + l15;
      atomicAdd(&colsum[0][lc], lv0);
      atomicAdd(&colsum[1][lc], lv1);
    }
    __syncthreads();
    if (t < 256){
      int bb = t>>7, c = t&127;
      csum[((size_t)(bb*25) + blockIdx.x)*512 + (col0 - 512) + c] = colsum[bb][c];
    }
  }
}

// ------- tiny GEMM (M<=128), B bf16 [N][ldk], batched over grid.z -------
__global__ __launch_bounds__(256) void gemm_tiny(
    const u16* __restrict__ A, int lda, size_t Abat,
    const u16* __restrict__ Bt, int ldk,
    float* __restrict__ C, int ldc, size_t Cbat,
    int M, int Nn, int K)
{
  A += (size_t)blockIdx.z * Abat;
  C += (size_t)blockIdx.z * Cbat;
  __shared__ __align__(16) u16 As[128][40];
  __shared__ __align__(16) u16 Bs[128][40];
  const int t = threadIdx.x;
  const int lane = t & 63;
  const int w = t >> 6;
  const int wr = (w >> 1) * 64, wc = (w & 1) * 64;
  const int col0 = blockIdx.y * 128;
  const int l15 = lane & 15;
  const int l4 = (lane >> 4) * 8;
  f32x4 acc[4][4];
  #pragma unroll
  for (int m = 0; m < 4; ++m)
    #pragma unroll
    for (int n = 0; n < 4; ++n)
      #pragma unroll
      for (int j = 0; j < 4; ++j) acc[m][n][j] = 0.f;

  for (int k0 = 0; k0 < K; k0 += 32) {
    #pragma unroll
    for (int u = 0; u < 2; ++u){
      int id = t + u*256;
      int r = id >> 2, c8 = (id & 3) * 8;
      bf16x8 av;
      #pragma unroll
      for (int j = 0; j < 8; ++j) av[j] = 0;
      if (r < M) av = *(const bf16x8*)(A + (size_t)r*lda + k0 + c8);
      *(bf16x8*)(&As[r][c8]) = av;
    }
    {
      int col = t & 127, kb = (t >> 7) * 16;
      bf16x8 b0, b1;
      #pragma unroll
      for (int j = 0; j < 8; ++j){ b0[j] = 0; b1[j] = 0; }
      int gc = col0 + col;
      if (gc < Nn){
        b0 = *(const bf16x8*)(Bt + (size_t)gc*ldk + k0 + kb);
        b1 = *(const bf16x8*)(Bt + (size_t)gc*ldk + k0 + kb + 8);
      }
      *(bf16x8*)(&Bs[col][kb])     = b0;
      *(bf16x8*)(&Bs[col][kb + 8]) = b1;
    }
    __syncthreads();
    bf16x8 af[4], bfr[4];
    #pragma unroll
    for (int m = 0; m < 4; ++m) af[m]  = *(const bf16x8*)(&As[wr + m*16 + l15][l4]);
    #pragma unroll
    for (int n = 0; n < 4; ++n) bfr[n] = *(const bf16x8*)(&Bs[wc + n*16 + l15][l4]);
    #pragma unroll
    for (int m = 0; m < 4; ++m)
      #pragma unroll
      for (int n = 0; n < 4; ++n)
        acc[m][n] = __builtin_amdgcn_mfma_f32_16x16x32_bf16(af[m], bfr[n], acc[m][n], 0, 0, 0);
    __syncthreads();
  }
  const int rb = (lane >> 4) * 4;
  #pragma unroll
  for (int m = 0; m < 4; ++m){
    int gr0 = wr + m*16 + rb;
    #pragma unroll
    for (int n = 0; n < 4; ++n){
      int gc = col0 + wc + n*16 + l15;
      if (gc >= Nn) continue;
      #pragma unroll
      for (int j = 0; j < 4; ++j){
        int gr = gr0 + j;
        if (gr < M) C[(size_t)gr*ldc + gc] = acc[m][n][j];
      }
    }
  }
}

// ------- fused attention, flash-split: one block per (h, b, qi, jz); 256 keys/block -------
// apart layout: [(jz*BATCH+b)*8+h)*16+qi] * 68 floats: [0..63]=O_part, [64]=m, [65]=s
__global__ __launch_bounds__(256) void fused_attn(
    const u16* __restrict__ xn, const u16* __restrict__ wqt,
    const float* __restrict__ kv, float* __restrict__ apart)
{
  int h = blockIdx.x, b = blockIdx.y;
  int qi = blockIdx.z / AZ, jz = blockIdx.z % AZ;
  int t = threadIdx.x;
  int lane = t & 63, wid = t >> 6;
  __shared__ float xs[512];
  __shared__ float qs[64];
  __shared__ float pl[256];
  __shared__ float red[4][64];
  __shared__ float redm[4];

  // 0) stage x row
  {
    int row = b*NTOK + 768 + qi;
    const u16* xr = xn + (size_t)row*DIMM;
    xs[t] = bf2f(xr[t]);
    xs[t+256] = bf2f(xr[t+256]);
  }
  __syncthreads();

  // 1) q projection (redundant across jz; cheap)
  {
    const u16* wrr = wqt + (size_t)(h*64 + lane)*DIMM + wid*128;
    float a = 0.f;
    #pragma unroll
    for (int k = 0; k < 128; k += 8){
      bf16x8 wv = *(const bf16x8*)(wrr + k);
      int kb = wid*128 + k;
      #pragma unroll
      for (int i = 0; i < 8; ++i) a += xs[kb+i] * bf2f((u16)wv[i]);
    }
    red[wid][lane] = a;
  }
  __syncthreads();
  if (t < 64) qs[t] = (red[0][t] + red[1][t] + red[2][t] + red[3][t]) * 0.125f;
  __syncthreads();

  // 2) QK^T for this chunk's 256 keys (1 per thread)
  int jj = jz*256 + t;
  int j = (jj < 768) ? jj : jj + 16;
  float a = 0.f;
  {
    const float* kr = kv + ((size_t)(b*NTOK + j))*1024 + h*64;
    #pragma unroll
    for (int d = 0; d < 64; d += 4){
      float4 kd = *(const float4*)(kr + d);
      a += qs[d]*kd.x + qs[d+1]*kd.y + qs[d+2]*kd.z + qs[d+3]*kd.w;
    }
  }

  // 3) chunk-local softmax (unnormalized)
  float m = a;
  #pragma unroll
  for (int off = 32; off >= 1; off >>= 1) m = fmaxf(m, __shfl_xor(m, off));
  if (lane == 0) redm[wid] = m;
  __syncthreads();
  m = fmaxf(fmaxf(redm[0], redm[1]), fmaxf(redm[2], redm[3]));
  float p = __expf(a - m);
  pl[t] = p;
  float sq = p;
  #pragma unroll
  for (int off = 32; off >= 1; off >>= 1) sq += __shfl_xor(sq, off);
  if (lane == 0) redm[wid] = sq;
  __syncthreads();

  // 4) partial PV: d = lane, 64 j per wave
  {
    int j0 = wid * 64;
    const float* vb = kv + ((size_t)(b*NTOK + jz*256 + j0 + ((jz*256 + j0 >= 768) ? 16 : 0)))*1024
                      + 512 + h*64 + lane;
    float a0=0.f, a1=0.f, a2=0.f, a3=0.f;
    #pragma unroll 4
    for (int i = 0; i < 64; i += 4){
      const float* vp = vb + (size_t)i*1024;
      a0 += pl[j0+i]   * vp[0];
      a1 += pl[j0+i+1] * vp[1024];
      a2 += pl[j0+i+2] * vp[2048];
      a3 += pl[j0+i+3] * vp[3072];
    }
    red[wid][lane] = a0+a1+a2+a3;
  }
  __syncthreads();
  float* po = apart + ((((size_t)jz*BATCH + b)*8 + h)*16 + qi) * 68;
  if (t < 64) po[t] = red[0][t] + red[1][t] + red[2][t] + red[3][t];
  else if (t == 64) po[64] = m;
  else if (t == 65) po[65] = redm[0] + redm[1] + redm[2] + redm[3];
}

// ---- merge attention partials (blocks 0..63) + csum row0 finish (blocks 64..67) ----
__global__ void attn_merge(const float* __restrict__ apart, const float* __restrict__ csum,
                           u16* __restrict__ zb)
{
  int bid = blockIdx.x, t = threadIdx.x;
  if (bid < 64){
    int i = bid*256 + t;                 // (b,h,qi,d)
    int d = i & 63; int rest = i >> 6;
    int qi = rest & 15; int h = (rest >> 4) & 7; int b = rest >> 7;
    size_t base = ((size_t)b*8 + h)*16 + qi;
    float mz[AZ], sz[AZ];
    float M = -3.4e38f;
    #pragma unroll
    for (int z = 0; z < AZ; ++z){
      const float* po = apart + ((size_t)z*BATCH*8*16 + base) * 68;
      mz[z] = po[64]; sz[z] = po[65];
      M = fmaxf(M, mz[z]);
    }
    float S = 0.f, O = 0.f;
    #pragma unroll
    for (int z = 0; z < AZ; ++z){
      const float* po = apart + ((size_t)z*BATCH*8*16 + base) * 68;
      float w = __expf(mz[z] - M);
      S += sz[z] * w;
      O += po[d] * w;
    }
    zb[((size_t)(b*17 + 1 + qi))*DIMM + h*64 + d] = f2bf(O / S);
  } else {
    int i = (bid - 64)*256 + t;          // 0..1023
    if (i >= BATCH*DIMM) return;
    int b = i >> 9, c = i & 511;
    float s = 0.f;
    #pragma unroll
    for (int bx = 0; bx < 25; ++bx) s += csum[((size_t)(b*25) + bx)*512 + c];
    zb[((size_t)(b*17))*DIMM + c] = f2bf(s * (1.0f/1552.0f));
  }
}

// ---- finish colmean from gemm csum partials (pool path, f32 mv) ----
__global__ void csum_finish(const float* __restrict__ csum, float* __restrict__ mv)
{
  int i = blockIdx.x * 256 + threadIdx.x;
  if (i >= BATCH*DIMM) return;
  int b = i >> 9, c = i & 511;
  float s = 0.f;
  #pragma unroll
  for (int bx = 0; bx < 25; ++bx) s += csum[((size_t)(b*25) + bx)*512 + c];
  mv[(size_t)b*DIMM + c] = s * (1.0f/1552.0f);
}

// ---------------- copy fusion tokens into tok ----------------
__global__ void fuscopy_kernel(const float* __restrict__ ft, float* __restrict__ tok)
{
  int i = blockIdx.x * 256 + threadIdx.x;
  if (i >= BATCH*16*DIMM) return;
  int c = i & 511; int tt = i >> 9; int b = tt >> 4; int r = tt & 15;
  tok[((size_t)(b*NTOK + 768 + r))*DIMM + c] = ft[r*DIMM + c];
}

// ---------------- parallel mat-vec (pool q2) ----------------
__global__ void matvec512(const float* __restrict__ y, const float* __restrict__ w,
                          float* __restrict__ out, float scale)
{
  __shared__ float ys[512];
  __shared__ float red[4][64];
  int t = threadIdx.x;
  ys[t] = y[t]; ys[t+256] = y[t+256];
  __syncthreads();
  int col = blockIdx.x*64 + (t & 63);
  int kq = t >> 6;
  float s = 0.f;
  #pragma unroll 4
  for (int k = kq*128; k < kq*128+128; ++k) s += ys[k] * w[(size_t)k*512 + col];
  red[kq][t & 63] = s;
  __syncthreads();
  if (t < 64)
    out[blockIdx.x*64 + t] = (red[0][t]+red[1][t]+red[2][t]+red[3][t]) * scale;
}

// ---------------- pooled rows ----------------
__global__ void pooledmv(const float* __restrict__ mv, const float* __restrict__ out2,
                         const float* __restrict__ wo, const float* __restrict__ rt,
                         float* __restrict__ out)
{
  int br = blockIdx.y; int b = br/3, r = br%3;
  const float* y = (r < 2) ? (mv + (size_t)b*DIMM) : (out2 + (size_t)b*DIMM);
  __shared__ float ys[512];
  __shared__ float red[4][64];
  int t = threadIdx.x;
  ys[t] = y[t]; ys[t+256] = y[t+256];
  __syncthreads();
  int col = blockIdx.x*64 + (t & 63);
  int kq = t >> 6;
  float s = 0.f;
  #pragma unroll 4
  for (int k = kq*128; k < kq*128+128; ++k) s += ys[k] * wo[(size_t)k*512 + col];
  red[kq][t & 63] = s;
  __syncthreads();
  if (t < 64){
    int c = blockIdx.x*64 + t;
    out[(size_t)br*DIMM + c] = red[0][t]+red[1][t]+red[2][t]+red[3][t] + rt[(size_t)r*DIMM + c];
  }
}

// ---------------- pool attention of return-token 2 over 16 fusion keys ----------------
__global__ void poolattn2_kernel(const float* __restrict__ kv, const float* __restrict__ q2,
                                 float* __restrict__ out2)
{
  int h = blockIdx.x, b = blockIdx.y, d = threadIdx.x;
  __shared__ float sm[16];
  if (d < 16){
    const float* kr = kv + ((size_t)(b*NTOK + 768 + d))*1024 + h*64;
    float a = 0.f;
    for (int k = 0; k < 64; ++k) a += q2[h*64 + k] * kr[k];
    sm[d] = a;
  }
  __syncthreads();
  float m = -3.4e38f;
  #pragma unroll
  for (int j = 0; j < 16; ++j) m = fmaxf(m, sm[j]);
  float wv[16]; float s = 0.f;
  #pragma unroll
  for (int j = 0; j < 16; ++j){ wv[j] = expf(sm[j] - m); s += wv[j]; }
  float inv = 1.0f / s;
  float a = 0.f;
  #pragma unroll
  for (int j = 0; j < 16; ++j)
    a += wv[j] * kv[((size_t)(b*NTOK + 768 + j))*1024 + 512 + h*64 + d];
  out2[(size_t)b*DIMM + h*64 + d] = a * inv;
}

// =================================================================
extern "C" void kernel_launch(void* const* d_in, const int* in_sizes, int n_in,
                              void* d_out, int out_size, void* d_ws, size_t ws_size,
                              hipStream_t stream)
{
  const float* rna        = (const float*)d_in[0];
  const float* atac       = (const float*)d_in[1];
  const float* rna_ln1_g  = (const float*)d_in[2];
  const float* rna_ln1_b  = (const float*)d_in[3];
  const float* rna_w      = (const float*)d_in[4];
  const float* rna_b      = (const float*)d_in[5];
  const float* rna_ln2_g  = (const float*)d_in[6];
  const float* rna_ln2_b  = (const float*)d_in[7];
  const float* atac_ln1_g = (const float*)d_in[8];
  const float* atac_ln1_b = (const float*)d_in[9];
  const float* atac_w     = (const float*)d_in[10];
  const float* atac_b     = (const float*)d_in[11];
  const float* atac_ln2_g = (const float*)d_in[12];
  const float* atac_ln2_b = (const float*)d_in[13];
  const float* fusion_tok = (const float*)d_in[14];
  const float* lay_ag     = (const float*)d_in[15];
  const float* lay_wq     = (const float*)d_in[16];
  const float* lay_wkv    = (const float*)d_in[17];
  const float* lay_wo     = (const float*)d_in[18];
  const float* lay_fg     = (const float*)d_in[19];
  const float* lay_w1     = (const float*)d_in[20];
  const float* lay_w2     = (const float*)d_in[21];
  const float* final_g    = (const float*)d_in[22];
  const float* ret_tok    = (const float*)d_in[23];
  const float* pool_g     = (const float*)d_in[24];
  const float* pool_wq    = (const float*)d_in[25];
  const float* pool_wkv   = (const float*)d_in[26];
  const float* pool_wo    = (const float*)d_in[27];

  uint8_t* ws = (uint8_t*)d_ws;
  size_t off = 0;
  auto carve = [&](size_t bytes) -> uint8_t* {
    uint8_t* p = ws + off;
    off += (bytes + 255) & ~(size_t)255;
    return p;
  };
  // bf16 weights
  u16* rna_wt   = (u16*)carve((size_t)512*1024*2);
  u16* atac_wt  = (u16*)carve((size_t)512*1024*2);
  u16* wkvt     = (u16*)carve((size_t)4*1024*512*2);
  u16* wqt      = (u16*)carve((size_t)4*512*512*2);
  u16* wot      = (u16*)carve((size_t)4*512*512*2);
  u16* w1t      = (u16*)carve((size_t)4*NW1*512*2);
  u16* w2t      = (u16*)carve((size_t)4*512*GSTRIDE*2);
  u16* pool_wkvt= (u16*)carve((size_t)1024*512*2);
  // activations
  float* tok   = (float*)carve((size_t)MALL * DIMM * 4);
  u16*   xn    = (u16*)  carve((size_t)MALL * DIMM * 2);
  float* kv    = (float*)carve((size_t)MALL * 1024 * 4);
  u16*   lnbuf = (u16*)  carve((size_t)3072 * 1024 * 2);
  u16*   zb    = (u16*)  carve((size_t)BATCH*17*DIMM * 2);
  float* proj  = (float*)carve((size_t)BATCH*17*DIMM * 4);
  float* mv    = (float*)carve((size_t)BATCH*DIMM * 4);
  float* q2    = (float*)carve((size_t)DIMM * 4);
  float* yq2   = (float*)carve((size_t)DIMM * 4);
  float* out2  = (float*)carve((size_t)BATCH*DIMM * 4);
  float* csum  = (float*)carve((size_t)BATCH*25*512 * 4);
  float* apart = (float*)carve((size_t)AZ*BATCH*8*16*68 * 4);
  u16*   gbuf  = (u16*)  carve((size_t)MALL * GSTRIDE * 2);
  float* skpart= (float*)carve((size_t)2 * MALL * 512 * 4);
  (void)ws_size;

  // ---- one-dispatch weight conversion ----
  convall<<<14080, 256, 0, stream>>>(rna_w, atac_w, lay_wkv, lay_wq, lay_wo, lay_w1, lay_w2, pool_wkv,
                                     rna_wt, atac_wt, wkvt, wqt, wot, w1t, w2t, pool_wkvt);

  // ---- embeddings (both modalities batched) ----
  embed_ln1<<<3072, 256, 0, stream>>>(rna, atac, rna_ln1_g, rna_ln1_b, atac_ln1_g, atac_ln1_b, lnbuf);
  gemm512<<<dim3(24, 4, 2), 512, 0, stream>>>(lnbuf, 1024, rna_wt, atac_wt, 1536, 1024,
                                              skpart, 512, (size_t)3072*512, nullptr, nullptr,
                                              3072, 512, 1024, 512);
  embed_addln2<<<3072, 256, 0, stream>>>(skpart, rna_b, atac_b, rna_ln2_g, rna_ln2_b,
                                         atac_ln2_g, atac_ln2_b, tok);
  fuscopy_kernel<<<(BATCH*16*DIMM + 255)/256, 256, 0, stream>>>(fusion_tok, tok);

  // layer-0 attention LN
  ln_kernel<<<MALL, 256, 0, stream>>>(tok, lay_ag, nullptr, nullptr, xn, 512);

  // ---- transformer layers ----
  for (int l = 0; l < 4; ++l){
    const float* fg  = lay_fg + (size_t)l*DIMM;
    const float* gnext = (l < 3) ? (lay_ag + (size_t)(l+1)*DIMM) : final_g;
    const u16* wkvt_l = wkvt + (size_t)l*1024*512;
    const u16* wqt_l  = wqt  + (size_t)l*512*512;
    const u16* wot_l  = wot  + (size_t)l*512*512;
    const u16* w1t_l  = w1t  + (size_t)l*NW1*512;
    const u16* w2t_l  = w2t  + (size_t)l*512*GSTRIDE;

    gemm512<<<dim3(25, 8, 1), 512, 0, stream>>>(xn, 512, wkvt_l, nullptr, 0, 512,
                                                kv, 1024, 0, nullptr, csum, MALL, 1024, 512, 512);
    fused_attn<<<dim3(8, BATCH, 16*AZ), 256, 0, stream>>>(xn, wqt_l, kv, apart);
    attn_merge<<<68, 256, 0, stream>>>(apart, csum, zb);
    gemm_tiny<<<dim3(1, 4, 2), 256, 0, stream>>>(zb, 512, (size_t)17*DIMM,
                                                 wot_l, 512, proj, 512, (size_t)17*DIMM, 17, 512, 512);
    resadd_ffnln<<<dim3(NTOK, BATCH), 256, 0, stream>>>(tok, proj, fg, xn);
    gemm512<<<dim3(25, 22, 1), 512, 0, stream>>>(xn, 512, w1t_l, nullptr, 0, 512,
                                                 nullptr, 0, 0, gbuf, nullptr, MALL, NW1, 512, 512);
    gemm512<<<dim3(25, 4, 2), 512, 0, stream>>>(gbuf, GSTRIDE, w2t_l, nullptr, 0, GSTRIDE,
                                                skpart, 512, (size_t)MALL*512, nullptr, nullptr,
                                                MALL, 512, GSTRIDE, 704);
    skadd_ln<<<MALL, 256, 0, stream>>>(tok, skpart, gnext, xn);
  }

  // ---- pooling (xn holds final-LN tokens) ----
  gemm512<<<dim3(25, 8, 1), 512, 0, stream>>>(xn, 512, pool_wkvt, nullptr, 0, 512,
                                              kv, 1024, 0, nullptr, csum, MALL, 1024, 512, 512);
  csum_finish<<<4, 256, 0, stream>>>(csum, mv);
  ln_kernel<<<1, 256, 0, stream>>>(ret_tok + 2*DIMM, pool_g, nullptr, yq2, nullptr, 512);
  matvec512<<<8, 256, 0, stream>>>(yq2, pool_wq, q2, 0.125f);
  poolattn2_kernel<<<dim3(8, BATCH), 64, 0, stream>>>(kv, q2, out2);
  pooledmv<<<dim3(8, 6), 256, 0, stream>>>(mv, out2, pool_wo, ret_tok, (float*)d_out);
}

// Round 9
// 563.277 us; speedup vs baseline: 5.8390x; 1.1212x over previous
//
#include <hip/hip_runtime.h>
#include <stdint.h>
#include <stddef.h>

#define NTOK 1552
#define DIMM 512
#define IFFC 1365
#define IFF2 2730
#define NW1 2816       // padded/permuted w1 output cols (2*1408)
#define GSTRIDE 1408   // geglu output row stride (bf16) = padded K of w2
#define BATCH 2
#define MALL (BATCH*NTOK)   // 3104
#define AZ 6           // attention j-chunks (256 keys each)

typedef unsigned short u16;
typedef __attribute__((ext_vector_type(8))) short bf16x8;
typedef __attribute__((ext_vector_type(4))) float f32x4;

__device__ __forceinline__ u16 f2bf(float f){
  union { float f; uint32_t u; } v; v.f = f;
  uint32_t u = v.u;
  uint32_t r = (u + 0x7FFFu + ((u >> 16) & 1u)) >> 16;
  return (u16)r;
}
__device__ __forceinline__ float bf2f(u16 x){
  union { uint32_t u; float f; } v; v.u = ((uint32_t)x) << 16; return v.f;
}

// async global->LDS, 16B per lane; LDS dest must be wave-uniform base (lane*16 implicit)
__device__ __forceinline__ void gload_lds16(const u16* g, u16* l){
  __builtin_amdgcn_global_load_lds((const __attribute__((address_space(1))) void*)g,
                                   (__attribute__((address_space(3))) void*)l, 16, 0, 0);
}

// ---------- one-dispatch weight convert/transpose (8 segments), vectorized ----------
__global__ void convall(const float* s0,const float* s1,const float* s2,const float* s3,
                        const float* s4,const float* s5,const float* s6,const float* s7,
                        u16* d0,u16* d1,u16* d2,u16* d3,u16* d4,u16* d5,u16* d6,u16* d7)
{
  const float* srcs[8] = {s0,s1,s2,s3,s4,s5,s6,s7};
  u16* dsts[8] = {d0,d1,d2,d3,d4,d5,d6,d7};
  const int KT[8]   = {32,32,16,16,16,16,44,16};
  const int NT[8]   = {16,16,32,16,16,88,16,32};
  const int TC[8]   = {512,512,2048,1024,1024,5632,2816,512};
  const int K_[8]   = {1024,1024,512,512,512,512,1365,512};
  const int NSRC[8] = {512,512,1024,512,512,2730,512,1024};
  const int LDK[8]  = {1024,1024,512,512,512,512,1408,512};
  const int NOUT[8] = {512,512,1024,512,512,2816,512,1024};
  const int WS_[8]  = {0,0,512*1024,512*512,512*512,512*2730,1365*512,0};
  const int WT_[8]  = {0,0,1024*512,512*512,512*512,2816*512,512*1408,0};

  int bid = blockIdx.x;
  int seg = 0, base = 0;
  while (seg < 7 && bid >= base + TC[seg]) { base += TC[seg]; ++seg; }
  int loc = bid - base;
  int kt = KT[seg];
  int z = loc / (kt*NT[seg]); loc -= z*(kt*NT[seg]);
  int kb = (loc % kt) * 32, nb = (loc / kt) * 32;
  const float* w = srcs[seg] + (size_t)z * WS_[seg];
  u16* wt = dsts[seg] + (size_t)z * WT_[seg];
  int K = K_[seg], NS = NSRC[seg], ldk = LDK[seg], NO = NOUT[seg];

  __shared__ float tile[32][33];
  int t = threadIdx.x;
  {
    int k = t >> 3, n4 = (t & 7) * 4;
    int gk = kb + k;
    float4 v = make_float4(0.f,0.f,0.f,0.f);
    if (gk < K){
      if (seg != 5){
        int gn = nb + n4;
        if (gn + 4 <= NS){
          v = *(const float4*)(w + (size_t)gk*NS + gn);
        } else {
          float* pv = (float*)&v;
          #pragma unroll
          for (int i = 0; i < 4; ++i){ int n = gn + i; if (n < NS) pv[i] = w[(size_t)gk*NS + n]; }
        }
      } else {
        float* pv = (float*)&v;
        #pragma unroll
        for (int i = 0; i < 4; ++i){
          int n = nb + n4 + i;
          if (n < NO){
            int bb = n >> 7, rr = n & 127, g = rr >> 5, hh = rr & 31;
            int j = bb*64 + g*16 + (hh & 15);
            if (j < 1365) pv[i] = w[(size_t)gk*NS + ((hh < 16) ? j : 1365 + j)];
          }
        }
      }
    }
    tile[k][n4] = v.x; tile[k][n4+1] = v.y; tile[k][n4+2] = v.z; tile[k][n4+3] = v.w;
  }
  __syncthreads();
  if (t < 128){
    int n = t >> 2, k8 = (t & 3) * 8;
    int gn = nb + n, gk = kb + k8;
    if (gn < NO && gk < ldk){
      u16 sh[8];
      #pragma unroll
      for (int i = 0; i < 8; ++i) sh[i] = f2bf(tile[k8+i][n]);
      *(bf16x8*)(wt + (size_t)gn*ldk + gk) = *(bf16x8*)sh;
    }
  }
}

// ---------------- LayerNorm: one block per row ----------------
__global__ void ln_kernel(const float* __restrict__ in, const float* __restrict__ g,
                          const float* __restrict__ bta, float* __restrict__ of32,
                          u16* __restrict__ obf, int D)
{
  const int r = blockIdx.x;
  const float* x = in + (size_t)r * D;
  float s = 0.f, ss = 0.f;
  for (int c = threadIdx.x; c < D; c += 256){ float v = x[c]; s += v; ss += v*v; }
  #pragma unroll
  for (int off = 32; off >= 1; off >>= 1){ s += __shfl_xor(s, off); ss += __shfl_xor(ss, off); }
  __shared__ float rs_[4], rss_[4];
  int w = threadIdx.x >> 6;
  if ((threadIdx.x & 63) == 0){ rs_[w] = s; rss_[w] = ss; }
  __syncthreads();
  s = rs_[0] + rs_[1] + rs_[2] + rs_[3];
  ss = rss_[0] + rss_[1] + rss_[2] + rss_[3];
  float mu = s / D;
  float rstd = rsqrtf(ss / D - mu*mu + 1e-5f);
  for (int c = threadIdx.x; c < D; c += 256){
    float y = (x[c] - mu) * rstd * g[c] + (bta ? bta[c] : 0.f);
    if (of32) of32[(size_t)r*D + c] = y;
    if (obf)  obf[(size_t)r*D + c] = f2bf(y);
  }
}

// ---- batched embed LN1 (rna rows 0..1535, atac rows 1536..3071) ----
__global__ void embed_ln1(const float* __restrict__ rna, const float* __restrict__ atac,
                          const float* __restrict__ g0, const float* __restrict__ b0,
                          const float* __restrict__ g1, const float* __restrict__ b1,
                          u16* __restrict__ out)
{
  int r = blockIdx.x;
  const float* x; const float* g; const float* bb;
  if (r < 1536){ x = rna + (size_t)r*1024; g = g0; bb = b0; }
  else { x = atac + (size_t)(r-1536)*1024; g = g1; bb = b1; }
  float s = 0.f, ss = 0.f;
  int t = threadIdx.x;
  float v0 = x[t], v1 = x[t+256], v2 = x[t+512], v3 = x[t+768];
  s = v0+v1+v2+v3; ss = v0*v0+v1*v1+v2*v2+v3*v3;
  #pragma unroll
  for (int off = 32; off >= 1; off >>= 1){ s += __shfl_xor(s, off); ss += __shfl_xor(ss, off); }
  __shared__ float rs_[4], rss_[4];
  int w = t >> 6;
  if ((t & 63) == 0){ rs_[w] = s; rss_[w] = ss; }
  __syncthreads();
  s = rs_[0]+rs_[1]+rs_[2]+rs_[3];
  ss = rss_[0]+rss_[1]+rss_[2]+rss_[3];
  float mu = s / 1024.f;
  float rstd = rsqrtf(ss / 1024.f - mu*mu + 1e-5f);
  u16* o = out + (size_t)r*1024;
  o[t]     = f2bf((v0-mu)*rstd*g[t]     + bb[t]);
  o[t+256] = f2bf((v1-mu)*rstd*g[t+256] + bb[t+256]);
  o[t+512] = f2bf((v2-mu)*rstd*g[t+512] + bb[t+512]);
  o[t+768] = f2bf((v3-mu)*rstd*g[t+768] + bb[t+768]);
}

// ---- batched embed: add splitK parts + bias, LN2, scatter into tok ----
__global__ void embed_addln2(const float* __restrict__ part,
                             const float* __restrict__ rb, const float* __restrict__ ab,
                             const float* __restrict__ g0, const float* __restrict__ bt0,
                             const float* __restrict__ g1, const float* __restrict__ bt1,
                             float* __restrict__ tok)
{
  int r = blockIdx.x;          // 0..3071
  int mod = (r >= 1536);
  int rl = mod ? r - 1536 : r;
  int b = rl / 768, rr = rl % 768;
  const float* bias = mod ? ab : rb;
  const float* g = mod ? g1 : g0;
  const float* bt = mod ? bt1 : bt0;
  const float* p0 = part + (size_t)r*DIMM;
  const float* p1 = p0 + (size_t)3072*DIMM;
  int t = threadIdx.x;
  float v0 = p0[t] + p1[t] + bias[t];
  float v1 = p0[t+256] + p1[t+256] + bias[t+256];
  float s = v0 + v1, ss = v0*v0 + v1*v1;
  #pragma unroll
  for (int off = 32; off >= 1; off >>= 1){ s += __shfl_xor(s, off); ss += __shfl_xor(ss, off); }
  __shared__ float rs_[4], rss_[4];
  int w = t >> 6;
  if ((t & 63) == 0){ rs_[w] = s; rss_[w] = ss; }
  __syncthreads();
  s = rs_[0]+rs_[1]+rs_[2]+rs_[3];
  ss = rss_[0]+rss_[1]+rss_[2]+rss_[3];
  float mu = s / DIMM;
  float rstd = rsqrtf(ss / DIMM - mu*mu + 1e-5f);
  float* tr = tok + ((size_t)(b*NTOK + (mod ? 784 : 0) + rr))*DIMM;
  tr[t]     = (v0 - mu)*rstd*g[t]     + bt[t];
  tr[t+256] = (v1 - mu)*rstd*g[t+256] + bt[t+256];
}

// ---- residual-add (attention proj, broadcast row0) + FFN LN -> tok, xn ----
__global__ void resadd_ffnln(float* __restrict__ tok, const float* __restrict__ proj,
                             const float* __restrict__ g, u16* __restrict__ xn)
{
  int n = blockIdx.x, b = blockIdx.y;
  int pr = (n >= 768 && n < 784) ? (1 + n - 768) : 0;
  const float* p = proj + ((size_t)b*17 + pr)*DIMM;
  size_t row = (size_t)(b*NTOK + n)*DIMM;
  int t = threadIdx.x;
  float v0 = tok[row + t]     + p[t];
  float v1 = tok[row + t+256] + p[t+256];
  tok[row + t] = v0; tok[row + t+256] = v1;
  float s = v0 + v1, ss = v0*v0 + v1*v1;
  #pragma unroll
  for (int off = 32; off >= 1; off >>= 1){ s += __shfl_xor(s, off); ss += __shfl_xor(ss, off); }
  __shared__ float rs_[4], rss_[4];
  int w = t >> 6;
  if ((t & 63) == 0){ rs_[w] = s; rss_[w] = ss; }
  __syncthreads();
  s = rs_[0]+rs_[1]+rs_[2]+rs_[3];
  ss = rss_[0]+rss_[1]+rss_[2]+rss_[3];
  float mu = s / DIMM;
  float rstd = rsqrtf(ss / DIMM - mu*mu + 1e-5f);
  xn[row + t]     = f2bf((v0 - mu)*rstd*g[t]);
  xn[row + t+256] = f2bf((v1 - mu)*rstd*g[t+256]);
}

// ---- splitK-add (FFN out) + next LN -> tok, xn ----
__global__ void skadd_ln(float* __restrict__ tok, const float* __restrict__ part,
                         const float* __restrict__ g, u16* __restrict__ xn)
{
  int r = blockIdx.x;
  size_t row = (size_t)r*DIMM;
  const float* p0 = part + row;
  const float* p1 = p0 + (size_t)MALL*DIMM;
  int t = threadIdx.x;
  float v0 = tok[row + t]     + p0[t]     + p1[t];
  float v1 = tok[row + t+256] + p0[t+256] + p1[t+256];
  tok[row + t] = v0; tok[row + t+256] = v1;
  float s = v0 + v1, ss = v0*v0 + v1*v1;
  #pragma unroll
  for (int off = 32; off >= 1; off >>= 1){ s += __shfl_xor(s, off); ss += __shfl_xor(ss, off); }
  __shared__ float rs_[4], rss_[4];
  int w = t >> 6;
  if ((t & 63) == 0){ rs_[w] = s; rss_[w] = ss; }
  __syncthreads();
  s = rs_[0]+rs_[1]+rs_[2]+rs_[3];
  ss = rss_[0]+rss_[1]+rss_[2]+rss_[3];
  float mu = s / DIMM;
  float rstd = rsqrtf(ss / DIMM - mu*mu + 1e-5f);
  xn[row + t]     = f2bf((v0 - mu)*rstd*g[t]);
  xn[row + t+256] = f2bf((v1 - mu)*rstd*g[t+256]);
}

// ------- gemm512: 8-wave 128x128; B bf16 [N][ldk]; global_load_lds staging (linear LDS);
//         optional B-switch at row mswitch; splitK via grid.z; optional GEGLU epilogue;
//         optional V-colsum (csum). OOB rows/cols are CLAMPED (outputs masked on write). -------
__global__ __launch_bounds__(512) void gemm512(
    const u16* __restrict__ A, int lda,
    const u16* __restrict__ Bt, const u16* __restrict__ BtB, int mswitch, int ldk,
    float* __restrict__ C, int ldc, size_t Cz,
    u16* __restrict__ gout, float* __restrict__ csum,
    int M, int Nn, int K, int kchunk)
{
  __shared__ __align__(16) u16 As_lin[128*32];
  __shared__ __align__(16) u16 Bs_lin[128*32];
  __shared__ float colsum[2][128];
  const int t = threadIdx.x;
  const int lane = t & 63;
  const int w = t >> 6;
  const int wr = (w >> 2) * 64;
  const int wc = (w & 3) * 32;
  const int row0 = blockIdx.x * 128, col0 = blockIdx.y * 128;
  if (BtB && row0 >= mswitch) Bt = BtB;
  const int z = blockIdx.z;
  const int kbeg = z * kchunk;
  const int kend = (kbeg + kchunk < K) ? (kbeg + kchunk) : K;
  C += (size_t)z * Cz;
  const int l15 = lane & 15;
  const int l4 = (lane >> 4) * 8;
  // staging addresses (fixed per thread): row/col = t>>2, k-offset = (t&3)*8
  const int sr = t >> 2, sc8 = (t & 3) * 8;
  int gr_s = row0 + sr; if (gr_s >= M) gr_s = M - 1;
  int gc_s = col0 + sr; if (gc_s >= Nn) gc_s = Nn - 1;
  const u16* Ag = A + (size_t)gr_s*lda + sc8;
  const u16* Bg = Bt + (size_t)gc_s*ldk + sc8;
  u16* Al = &As_lin[(size_t)w * 512];   // wave-uniform LDS base; HW adds lane*16B
  u16* Bl = &Bs_lin[(size_t)w * 512];

  f32x4 acc[4][2];
  #pragma unroll
  for (int m = 0; m < 4; ++m)
    #pragma unroll
    for (int n = 0; n < 2; ++n)
      #pragma unroll
      for (int j = 0; j < 4; ++j) acc[m][n][j] = 0.f;

  for (int k0 = kbeg; k0 < kend; k0 += 32) {
    gload_lds16(Ag + k0, Al);
    gload_lds16(Bg + k0, Bl);
    __syncthreads();
    bf16x8 af[4], bfr[2];
    #pragma unroll
    for (int m = 0; m < 4; ++m) af[m]  = *(const bf16x8*)(&As_lin[(wr + m*16 + l15)*32 + l4]);
    #pragma unroll
    for (int n = 0; n < 2; ++n) bfr[n] = *(const bf16x8*)(&Bs_lin[(wc + n*16 + l15)*32 + l4]);
    #pragma unroll
    for (int m = 0; m < 4; ++m)
      #pragma unroll
      for (int n = 0; n < 2; ++n)
        acc[m][n] = __builtin_amdgcn_mfma_f32_16x16x32_bf16(af[m], bfr[n], acc[m][n], 0, 0, 0);
    __syncthreads();
  }
  const int rb = (lane >> 4) * 4;
  if (gout){
    int jcol = (col0 >> 1) + (w & 3)*16 + l15;
    #pragma unroll
    for (int m = 0; m < 4; ++m){
      int gr0 = row0 + wr + m*16 + rb;
      #pragma unroll
      for (int j = 0; j < 4; ++j){
        int gr = gr0 + j;
        if (gr < M){
          float gt = acc[m][1][j];
          float ge = 0.5f * gt * (1.0f + erff(gt * 0.70710678118654752f));
          gout[(size_t)gr*GSTRIDE + jcol] = f2bf(ge * acc[m][0][j]);
        }
      }
    }
  } else {
    #pragma unroll
    for (int m = 0; m < 4; ++m){
      int gr0 = row0 + wr + m*16 + rb;
      #pragma unroll
      for (int n = 0; n < 2; ++n){
        int gc = col0 + wc + n*16 + l15;
        if (gc >= Nn) continue;
        #pragma unroll
        for (int j = 0; j < 4; ++j){
          int gr = gr0 + j;
          if (gr < M) C[(size_t)gr*ldc + gc] = acc[m][n][j];
        }
      }
    }
  }
  if (csum && col0 >= 512){
    if (t < 256) colsum[t>>7][t&127] = 0.f;
    __syncthreads();
    #pragma unroll
    for (int n = 0; n < 2; ++n){
      float lv0 = 0.f, lv1 = 0.f;
      #pragma unroll
      for (int m = 0; m < 4; ++m){
        int gr0 = row0 + wr + m*16 + rb;
        #pragma unroll
        for (int j = 0; j < 4; ++j){
          float v = acc[m][n][j];
          if (gr0 + j < NTOK) lv0 += v; else lv1 += v;
        }
      }
      int lc = wc + n*16 + l15;
      atomicAdd(&colsum[0][lc], lv0);
      atomicAdd(&colsum[1][lc], lv1);
    }
    __syncthreads();
    if (t < 256){
      int bb = t>>7, c = t&127;
      csum[((size_t)(bb*25) + blockIdx.x)*512 + (col0 - 512) + c] = colsum[bb][c];
    }
  }
}

// ------- tiny GEMM (M<=128), B bf16 [N][ldk], batched over grid.z -------
__global__ __launch_bounds__(256) void gemm_tiny(
    const u16* __restrict__ A, int lda, size_t Abat,
    const u16* __restrict__ Bt, int ldk,
    float* __restrict__ C, int ldc, size_t Cbat,
    int M, int Nn, int K)
{
  A += (size_t)blockIdx.z * Abat;
  C += (size_t)blockIdx.z * Cbat;
  __shared__ __align__(16) u16 As[128][40];
  __shared__ __align__(16) u16 Bs[128][40];
  const int t = threadIdx.x;
  const int lane = t & 63;
  const int w = t >> 6;
  const int wr = (w >> 1) * 64, wc = (w & 1) * 64;
  const int col0 = blockIdx.y * 128;
  const int l15 = lane & 15;
  const int l4 = (lane >> 4) * 8;
  f32x4 acc[4][4];
  #pragma unroll
  for (int m = 0; m < 4; ++m)
    #pragma unroll
    for (int n = 0; n < 4; ++n)
      #pragma unroll
      for (int j = 0; j < 4; ++j) acc[m][n][j] = 0.f;

  for (int k0 = 0; k0 < K; k0 += 32) {
    #pragma unroll
    for (int u = 0; u < 2; ++u){
      int id = t + u*256;
      int r = id >> 2, c8 = (id & 3) * 8;
      bf16x8 av;
      #pragma unroll
      for (int j = 0; j < 8; ++j) av[j] = 0;
      if (r < M) av = *(const bf16x8*)(A + (size_t)r*lda + k0 + c8);
      *(bf16x8*)(&As[r][c8]) = av;
    }
    {
      int col = t & 127, kb = (t >> 7) * 16;
      bf16x8 b0, b1;
      #pragma unroll
      for (int j = 0; j < 8; ++j){ b0[j] = 0; b1[j] = 0; }
      int gc = col0 + col;
      if (gc < Nn){
        b0 = *(const bf16x8*)(Bt + (size_t)gc*ldk + k0 + kb);
        b1 = *(const bf16x8*)(Bt + (size_t)gc*ldk + k0 + kb + 8);
      }
      *(bf16x8*)(&Bs[col][kb])     = b0;
      *(bf16x8*)(&Bs[col][kb + 8]) = b1;
    }
    __syncthreads();
    bf16x8 af[4], bfr[4];
    #pragma unroll
    for (int m = 0; m < 4; ++m) af[m]  = *(const bf16x8*)(&As[wr + m*16 + l15][l4]);
    #pragma unroll
    for (int n = 0; n < 4; ++n) bfr[n] = *(const bf16x8*)(&Bs[wc + n*16 + l15][l4]);
    #pragma unroll
    for (int m = 0; m < 4; ++m)
      #pragma unroll
      for (int n = 0; n < 4; ++n)
        acc[m][n] = __builtin_amdgcn_mfma_f32_16x16x32_bf16(af[m], bfr[n], acc[m][n], 0, 0, 0);
    __syncthreads();
  }
  const int rb = (lane >> 4) * 4;
  #pragma unroll
  for (int m = 0; m < 4; ++m){
    int gr0 = wr + m*16 + rb;
    #pragma unroll
    for (int n = 0; n < 4; ++n){
      int gc = col0 + wc + n*16 + l15;
      if (gc >= Nn) continue;
      #pragma unroll
      for (int j = 0; j < 4; ++j){
        int gr = gr0 + j;
        if (gr < M) C[(size_t)gr*ldc + gc] = acc[m][n][j];
      }
    }
  }
}

// ------- fused attention, flash-split: one block per (h, b, qi, jz); 256 keys/block -------
// apart layout: [(jz*BATCH+b)*8+h)*16+qi] * 68 floats: [0..63]=O_part, [64]=m, [65]=s
__global__ __launch_bounds__(256) void fused_attn(
    const u16* __restrict__ xn, const u16* __restrict__ wqt,
    const float* __restrict__ kv, float* __restrict__ apart)
{
  int h = blockIdx.x, b = blockIdx.y;
  int qi = blockIdx.z / AZ, jz = blockIdx.z % AZ;
  int t = threadIdx.x;
  int lane = t & 63, wid = t >> 6;
  __shared__ float xs[512];
  __shared__ float qs[64];
  __shared__ float pl[256];
  __shared__ float red[4][64];
  __shared__ float redm[4];

  // 0) stage x row
  {
    int row = b*NTOK + 768 + qi;
    const u16* xr = xn + (size_t)row*DIMM;
    xs[t] = bf2f(xr[t]);
    xs[t+256] = bf2f(xr[t+256]);
  }
  __syncthreads();

  // 1) q projection (redundant across jz; cheap)
  {
    const u16* wrr = wqt + (size_t)(h*64 + lane)*DIMM + wid*128;
    float a = 0.f;
    #pragma unroll
    for (int k = 0; k < 128; k += 8){
      bf16x8 wv = *(const bf16x8*)(wrr + k);
      int kb = wid*128 + k;
      #pragma unroll
      for (int i = 0; i < 8; ++i) a += xs[kb+i] * bf2f((u16)wv[i]);
    }
    red[wid][lane] = a;
  }
  __syncthreads();
  if (t < 64) qs[t] = (red[0][t] + red[1][t] + red[2][t] + red[3][t]) * 0.125f;
  __syncthreads();

  // 2) QK^T for this chunk's 256 keys (1 per thread)
  int jj = jz*256 + t;
  int j = (jj < 768) ? jj : jj + 16;
  float a = 0.f;
  {
    const float* kr = kv + ((size_t)(b*NTOK + j))*1024 + h*64;
    #pragma unroll
    for (int d = 0; d < 64; d += 4){
      float4 kd = *(const float4*)(kr + d);
      a += qs[d]*kd.x + qs[d+1]*kd.y + qs[d+2]*kd.z + qs[d+3]*kd.w;
    }
  }

  // 3) chunk-local softmax (unnormalized)
  float m = a;
  #pragma unroll
  for (int off = 32; off >= 1; off >>= 1) m = fmaxf(m, __shfl_xor(m, off));
  if (lane == 0) redm[wid] = m;
  __syncthreads();
  m = fmaxf(fmaxf(redm[0], redm[1]), fmaxf(redm[2], redm[3]));
  float p = __expf(a - m);
  pl[t] = p;
  float sq = p;
  #pragma unroll
  for (int off = 32; off >= 1; off >>= 1) sq += __shfl_xor(sq, off);
  if (lane == 0) redm[wid] = sq;
  __syncthreads();

  // 4) partial PV: d = lane, 64 j per wave
  {
    int j0 = wid * 64;
    const float* vb = kv + ((size_t)(b*NTOK + jz*256 + j0 + ((jz*256 + j0 >= 768) ? 16 : 0)))*1024
                      + 512 + h*64 + lane;
    float a0=0.f, a1=0.f, a2=0.f, a3=0.f;
    #pragma unroll 4
    for (int i = 0; i < 64; i += 4){
      const float* vp = vb + (size_t)i*1024;
      a0 += pl[j0+i]   * vp[0];
      a1 += pl[j0+i+1] * vp[1024];
      a2 += pl[j0+i+2] * vp[2048];
      a3 += pl[j0+i+3] * vp[3072];
    }
    red[wid][lane] = a0+a1+a2+a3;
  }
  __syncthreads();
  float* po = apart + ((((size_t)jz*BATCH + b)*8 + h)*16 + qi) * 68;
  if (t < 64) po[t] = red[0][t] + red[1][t] + red[2][t] + red[3][t];
  else if (t == 64) po[64] = m;
  else if (t == 65) po[65] = redm[0] + redm[1] + redm[2] + redm[3];
}

// ---- merge attention partials (blocks 0..63) + csum row0 finish (blocks 64..67) ----
__global__ void attn_merge(const float* __restrict__ apart, const float* __restrict__ csum,
                           u16* __restrict__ zb)
{
  int bid = blockIdx.x, t = threadIdx.x;
  if (bid < 64){
    int i = bid*256 + t;                 // (b,h,qi,d)
    int d = i & 63; int rest = i >> 6;
    int qi = rest & 15; int h = (rest >> 4) & 7; int b = rest >> 7;
    size_t base = ((size_t)b*8 + h)*16 + qi;
    float mz[AZ], sz[AZ];
    float M = -3.4e38f;
    #pragma unroll
    for (int z = 0; z < AZ; ++z){
      const float* po = apart + ((size_t)z*BATCH*8*16 + base) * 68;
      mz[z] = po[64]; sz[z] = po[65];
      M = fmaxf(M, mz[z]);
    }
    float S = 0.f, O = 0.f;
    #pragma unroll
    for (int z = 0; z < AZ; ++z){
      const float* po = apart + ((size_t)z*BATCH*8*16 + base) * 68;
      float w = __expf(mz[z] - M);
      S += sz[z] * w;
      O += po[d] * w;
    }
    zb[((size_t)(b*17 + 1 + qi))*DIMM + h*64 + d] = f2bf(O / S);
  } else {
    int i = (bid - 64)*256 + t;          // 0..1023
    if (i >= BATCH*DIMM) return;
    int b = i >> 9, c = i & 511;
    float s = 0.f;
    #pragma unroll
    for (int bx = 0; bx < 25; ++bx) s += csum[((size_t)(b*25) + bx)*512 + c];
    zb[((size_t)(b*17))*DIMM + c] = f2bf(s * (1.0f/1552.0f));
  }
}

// ---- finish colmean from gemm csum partials (pool path, f32 mv) ----
__global__ void csum_finish(const float* __restrict__ csum, float* __restrict__ mv)
{
  int i = blockIdx.x * 256 + threadIdx.x;
  if (i >= BATCH*DIMM) return;
  int b = i >> 9, c = i & 511;
  float s = 0.f;
  #pragma unroll
  for (int bx = 0; bx < 25; ++bx) s += csum[((size_t)(b*25) + bx)*512 + c];
  mv[(size_t)b*DIMM + c] = s * (1.0f/1552.0f);
}

// ---------------- copy fusion tokens into tok ----------------
__global__ void fuscopy_kernel(const float* __restrict__ ft, float* __restrict__ tok)
{
  int i = blockIdx.x * 256 + threadIdx.x;
  if (i >= BATCH*16*DIMM) return;
  int c = i & 511; int tt = i >> 9; int b = tt >> 4; int r = tt & 15;
  tok[((size_t)(b*NTOK + 768 + r))*DIMM + c] = ft[r*DIMM + c];
}

// ---------------- parallel mat-vec (pool q2) ----------------
__global__ void matvec512(const float* __restrict__ y, const float* __restrict__ w,
                          float* __restrict__ out, float scale)
{
  __shared__ float ys[512];
  __shared__ float red[4][64];
  int t = threadIdx.x;
  ys[t] = y[t]; ys[t+256] = y[t+256];
  __syncthreads();
  int col = blockIdx.x*64 + (t & 63);
  int kq = t >> 6;
  float s = 0.f;
  #pragma unroll 4
  for (int k = kq*128; k < kq*128+128; ++k) s += ys[k] * w[(size_t)k*512 + col];
  red[kq][t & 63] = s;
  __syncthreads();
  if (t < 64)
    out[blockIdx.x*64 + t] = (red[0][t]+red[1][t]+red[2][t]+red[3][t]) * scale;
}

// ---------------- pooled rows ----------------
__global__ void pooledmv(const float* __restrict__ mv, const float* __restrict__ out2,
                         const float* __restrict__ wo, const float* __restrict__ rt,
                         float* __restrict__ out)
{
  int br = blockIdx.y; int b = br/3, r = br%3;
  const float* y = (r < 2) ? (mv + (size_t)b*DIMM) : (out2 + (size_t)b*DIMM);
  __shared__ float ys[512];
  __shared__ float red[4][64];
  int t = threadIdx.x;
  ys[t] = y[t]; ys[t+256] = y[t+256];
  __syncthreads();
  int col = blockIdx.x*64 + (t & 63);
  int kq = t >> 6;
  float s = 0.f;
  #pragma unroll 4
  for (int k = kq*128; k < kq*128+128; ++k) s += ys[k] * wo[(size_t)k*512 + col];
  red[kq][t & 63] = s;
  __syncthreads();
  if (t < 64){
    int c = blockIdx.x*64 + t;
    out[(size_t)br*DIMM + c] = red[0][t]+red[1][t]+red[2][t]+red[3][t] + rt[(size_t)r*DIMM + c];
  }
}

// ---------------- pool attention of return-token 2 over 16 fusion keys ----------------
__global__ void poolattn2_kernel(const float* __restrict__ kv, const float* __restrict__ q2,
                                 float* __restrict__ out2)
{
  int h = blockIdx.x, b = blockIdx.y, d = threadIdx.x;
  __shared__ float sm[16];
  if (d < 16){
    const float* kr = kv + ((size_t)(b*NTOK + 768 + d))*1024 + h*64;
    float a = 0.f;
    for (int k = 0; k < 64; ++k) a += q2[h*64 + k] * kr[k];
    sm[d] = a;
  }
  __syncthreads();
  float m = -3.4e38f;
  #pragma unroll
  for (int j = 0; j < 16; ++j) m = fmaxf(m, sm[j]);
  float wv[16]; float s = 0.f;
  #pragma unroll
  for (int j = 0; j < 16; ++j){ wv[j] = expf(sm[j] - m); s += wv[j]; }
  float inv = 1.0f / s;
  float a = 0.f;
  #pragma unroll
  for (int j = 0; j < 16; ++j)
    a += wv[j] * kv[((size_t)(b*NTOK + 768 + j))*1024 + 512 + h*64 + d];
  out2[(size_t)b*DIMM + h*64 + d] = a * inv;
}

// =================================================================
extern "C" void kernel_launch(void* const* d_in, const int* in_sizes, int n_in,
                              void* d_out, int out_size, void* d_ws, size_t ws_size,
                              hipStream_t stream)
{
  const float* rna        = (const float*)d_in[0];
  const float* atac       = (const float*)d_in[1];
  const float* rna_ln1_g  = (const float*)d_in[2];
  const float* rna_ln1_b  = (const float*)d_in[3];
  const float* rna_w      = (const float*)d_in[4];
  const float* rna_b      = (const float*)d_in[5];
  const float* rna_ln2_g  = (const float*)d_in[6];
  const float* rna_ln2_b  = (const float*)d_in[7];
  const float* atac_ln1_g = (const float*)d_in[8];
  const float* atac_ln1_b = (const float*)d_in[9];
  const float* atac_w     = (const float*)d_in[10];
  const float* atac_b     = (const float*)d_in[11];
  const float* atac_ln2_g = (const float*)d_in[12];
  const float* atac_ln2_b = (const float*)d_in[13];
  const float* fusion_tok = (const float*)d_in[14];
  const float* lay_ag     = (const float*)d_in[15];
  const float* lay_wq     = (const float*)d_in[16];
  const float* lay_wkv    = (const float*)d_in[17];
  const float* lay_wo     = (const float*)d_in[18];
  const float* lay_fg     = (const float*)d_in[19];
  const float* lay_w1     = (const float*)d_in[20];
  const float* lay_w2     = (const float*)d_in[21];
  const float* final_g    = (const float*)d_in[22];
  const float* ret_tok    = (const float*)d_in[23];
  const float* pool_g     = (const float*)d_in[24];
  const float* pool_wq    = (const float*)d_in[25];
  const float* pool_wkv   = (const float*)d_in[26];
  const float* pool_wo    = (const float*)d_in[27];

  uint8_t* ws = (uint8_t*)d_ws;
  size_t off = 0;
  auto carve = [&](size_t bytes) -> uint8_t* {
    uint8_t* p = ws + off;
    off += (bytes + 255) & ~(size_t)255;
    return p;
  };
  // bf16 weights
  u16* rna_wt   = (u16*)carve((size_t)512*1024*2);
  u16* atac_wt  = (u16*)carve((size_t)512*1024*2);
  u16* wkvt     = (u16*)carve((size_t)4*1024*512*2);
  u16* wqt      = (u16*)carve((size_t)4*512*512*2);
  u16* wot      = (u16*)carve((size_t)4*512*512*2);
  u16* w1t      = (u16*)carve((size_t)4*NW1*512*2);
  u16* w2t      = (u16*)carve((size_t)4*512*GSTRIDE*2);
  u16* pool_wkvt= (u16*)carve((size_t)1024*512*2);
  // activations
  float* tok   = (float*)carve((size_t)MALL * DIMM * 4);
  u16*   xn    = (u16*)  carve((size_t)MALL * DIMM * 2);
  float* kv    = (float*)carve((size_t)MALL * 1024 * 4);
  u16*   lnbuf = (u16*)  carve((size_t)3072 * 1024 * 2);
  u16*   zb    = (u16*)  carve((size_t)BATCH*17*DIMM * 2);
  float* proj  = (float*)carve((size_t)BATCH*17*DIMM * 4);
  float* mv    = (float*)carve((size_t)BATCH*DIMM * 4);
  float* q2    = (float*)carve((size_t)DIMM * 4);
  float* yq2   = (float*)carve((size_t)DIMM * 4);
  float* out2  = (float*)carve((size_t)BATCH*DIMM * 4);
  float* csum  = (float*)carve((size_t)BATCH*25*512 * 4);
  float* apart = (float*)carve((size_t)AZ*BATCH*8*16*68 * 4);
  u16*   gbuf  = (u16*)  carve((size_t)MALL * GSTRIDE * 2);
  float* skpart= (float*)carve((size_t)2 * MALL * 512 * 4);
  (void)ws_size;

  // ---- one-dispatch weight conversion ----
  convall<<<14080, 256, 0, stream>>>(rna_w, atac_w, lay_wkv, lay_wq, lay_wo, lay_w1, lay_w2, pool_wkv,
                                     rna_wt, atac_wt, wkvt, wqt, wot, w1t, w2t, pool_wkvt);

  // ---- embeddings (both modalities batched) ----
  embed_ln1<<<3072, 256, 0, stream>>>(rna, atac, rna_ln1_g, rna_ln1_b, atac_ln1_g, atac_ln1_b, lnbuf);
  gemm512<<<dim3(24, 4, 2), 512, 0, stream>>>(lnbuf, 1024, rna_wt, atac_wt, 1536, 1024,
                                              skpart, 512, (size_t)3072*512, nullptr, nullptr,
                                              3072, 512, 1024, 512);
  embed_addln2<<<3072, 256, 0, stream>>>(skpart, rna_b, atac_b, rna_ln2_g, rna_ln2_b,
                                         atac_ln2_g, atac_ln2_b, tok);
  fuscopy_kernel<<<(BATCH*16*DIMM + 255)/256, 256, 0, stream>>>(fusion_tok, tok);

  // layer-0 attention LN
  ln_kernel<<<MALL, 256, 0, stream>>>(tok, lay_ag, nullptr, nullptr, xn, 512);

  // ---- transformer layers ----
  for (int l = 0; l < 4; ++l){
    const float* fg  = lay_fg + (size_t)l*DIMM;
    const float* gnext = (l < 3) ? (lay_ag + (size_t)(l+1)*DIMM) : final_g;
    const u16* wkvt_l = wkvt + (size_t)l*1024*512;
    const u16* wqt_l  = wqt  + (size_t)l*512*512;
    const u16* wot_l  = wot  + (size_t)l*512*512;
    const u16* w1t_l  = w1t  + (size_t)l*NW1*512;
    const u16* w2t_l  = w2t  + (size_t)l*512*GSTRIDE;

    gemm512<<<dim3(25, 8, 1), 512, 0, stream>>>(xn, 512, wkvt_l, nullptr, 0, 512,
                                                kv, 1024, 0, nullptr, csum, MALL, 1024, 512, 512);
    fused_attn<<<dim3(8, BATCH, 16*AZ), 256, 0, stream>>>(xn, wqt_l, kv, apart);
    attn_merge<<<68, 256, 0, stream>>>(apart, csum, zb);
    gemm_tiny<<<dim3(1, 4, 2), 256, 0, stream>>>(zb, 512, (size_t)17*DIMM,
                                                 wot_l, 512, proj, 512, (size_t)17*DIMM, 17, 512, 512);
    resadd_ffnln<<<dim3(NTOK, BATCH), 256, 0, stream>>>(tok, proj, fg, xn);
    gemm512<<<dim3(25, 22, 1), 512, 0, stream>>>(xn, 512, w1t_l, nullptr, 0, 512,
                                                 nullptr, 0, 0, gbuf, nullptr, MALL, NW1, 512, 512);
    gemm512<<<dim3(25, 4, 2), 512, 0, stream>>>(gbuf, GSTRIDE, w2t_l, nullptr, 0, GSTRIDE,
                                                skpart, 512, (size_t)MALL*512, nullptr, nullptr,
                                                MALL, 512, GSTRIDE, 704);
    skadd_ln<<<MALL, 256, 0, stream>>>(tok, skpart, gnext, xn);
  }

  // ---- pooling (xn holds final-LN tokens) ----
  gemm512<<<dim3(25, 8, 1), 512, 0, stream>>>(xn, 512, pool_wkvt, nullptr, 0, 512,
                                              kv, 1024, 0, nullptr, csum, MALL, 1024, 512, 512);
  csum_finish<<<4, 256, 0, stream>>>(csum, mv);
  ln_kernel<<<1, 256, 0, stream>>>(ret_tok + 2*DIMM, pool_g, nullptr, yq2, nullptr, 512);
  matvec512<<<8, 256, 0, stream>>>(yq2, pool_wq, q2, 0.125f);
  poolattn2_kernel<<<dim3(8, BATCH), 64, 0, stream>>>(kv, q2, out2);
  pooledmv<<<dim3(8, 6), 256, 0, stream>>>(mv, out2, pool_wo, ret_tok, (float*)d_out);
}

// Round 10
// 561.903 us; speedup vs baseline: 5.8533x; 1.0024x over previous
//
#include <hip/hip_runtime.h>
#include <stdint.h>
#include <stddef.h>

#define NTOK 1552
#define DIMM 512
#define IFFC 1365
#define IFF2 2730
#define NW1 2816       // padded/permuted w1 output cols (2*1408)
#define GSTRIDE 1408   // geglu output row stride (bf16) = padded K of w2
#define BATCH 2
#define MALL (BATCH*NTOK)   // 3104
#define AZ 6           // attention j-chunks (256 keys each)

typedef unsigned short u16;
typedef __attribute__((ext_vector_type(8))) short bf16x8;
typedef __attribute__((ext_vector_type(4))) float f32x4;

__device__ __forceinline__ u16 f2bf(float f){
  union { float f; uint32_t u; } v; v.f = f;
  uint32_t u = v.u;
  uint32_t r = (u + 0x7FFFu + ((u >> 16) & 1u)) >> 16;
  return (u16)r;
}
__device__ __forceinline__ float bf2f(u16 x){
  union { uint32_t u; float f; } v; v.u = ((uint32_t)x) << 16; return v.f;
}

// async global->LDS, 16B per lane; LDS dest is wave-uniform base (lane*16 implicit)
__device__ __forceinline__ void gload_lds16(const u16* g, u16* l){
  __builtin_amdgcn_global_load_lds((const __attribute__((address_space(1))) void*)g,
                                   (__attribute__((address_space(3))) void*)l, 16, 0, 0);
}

// ---------- one-dispatch weight convert/transpose (8 segments), vectorized ----------
__global__ void convall(const float* s0,const float* s1,const float* s2,const float* s3,
                        const float* s4,const float* s5,const float* s6,const float* s7,
                        u16* d0,u16* d1,u16* d2,u16* d3,u16* d4,u16* d5,u16* d6,u16* d7)
{
  const float* srcs[8] = {s0,s1,s2,s3,s4,s5,s6,s7};
  u16* dsts[8] = {d0,d1,d2,d3,d4,d5,d6,d7};
  const int KT[8]   = {32,32,16,16,16,16,44,16};
  const int NT[8]   = {16,16,32,16,16,88,16,32};
  const int TC[8]   = {512,512,2048,1024,1024,5632,2816,512};
  const int K_[8]   = {1024,1024,512,512,512,512,1365,512};
  const int NSRC[8] = {512,512,1024,512,512,2730,512,1024};
  const int LDK[8]  = {1024,1024,512,512,512,512,1408,512};
  const int NOUT[8] = {512,512,1024,512,512,2816,512,1024};
  const int WS_[8]  = {0,0,512*1024,512*512,512*512,512*2730,1365*512,0};
  const int WT_[8]  = {0,0,1024*512,512*512,512*512,2816*512,512*1408,0};

  int bid = blockIdx.x;
  int seg = 0, base = 0;
  while (seg < 7 && bid >= base + TC[seg]) { base += TC[seg]; ++seg; }
  int loc = bid - base;
  int kt = KT[seg];
  int z = loc / (kt*NT[seg]); loc -= z*(kt*NT[seg]);
  int kb = (loc % kt) * 32, nb = (loc / kt) * 32;
  const float* w = srcs[seg] + (size_t)z * WS_[seg];
  u16* wt = dsts[seg] + (size_t)z * WT_[seg];
  int K = K_[seg], NS = NSRC[seg], ldk = LDK[seg], NO = NOUT[seg];

  __shared__ float tile[32][33];
  int t = threadIdx.x;
  {
    int k = t >> 3, n4 = (t & 7) * 4;
    int gk = kb + k;
    float4 v = make_float4(0.f,0.f,0.f,0.f);
    if (gk < K){
      if (seg != 5){
        int gn = nb + n4;
        if (gn + 4 <= NS){
          v = *(const float4*)(w + (size_t)gk*NS + gn);
        } else {
          float* pv = (float*)&v;
          #pragma unroll
          for (int i = 0; i < 4; ++i){ int n = gn + i; if (n < NS) pv[i] = w[(size_t)gk*NS + n]; }
        }
      } else {
        float* pv = (float*)&v;
        #pragma unroll
        for (int i = 0; i < 4; ++i){
          int n = nb + n4 + i;
          if (n < NO){
            int bb = n >> 7, rr = n & 127, g = rr >> 5, hh = rr & 31;
            int j = bb*64 + g*16 + (hh & 15);
            if (j < 1365) pv[i] = w[(size_t)gk*NS + ((hh < 16) ? j : 1365 + j)];
          }
        }
      }
    }
    tile[k][n4] = v.x; tile[k][n4+1] = v.y; tile[k][n4+2] = v.z; tile[k][n4+3] = v.w;
  }
  __syncthreads();
  if (t < 128){
    int n = t >> 2, k8 = (t & 3) * 8;
    int gn = nb + n, gk = kb + k8;
    if (gn < NO && gk < ldk){
      u16 sh[8];
      #pragma unroll
      for (int i = 0; i < 8; ++i) sh[i] = f2bf(tile[k8+i][n]);
      *(bf16x8*)(wt + (size_t)gn*ldk + gk) = *(bf16x8*)sh;
    }
  }
}

// ---- batched embed LN1 (rna rows 0..1535, atac rows 1536..3071) ----
__global__ void embed_ln1(const float* __restrict__ rna, const float* __restrict__ atac,
                          const float* __restrict__ g0, const float* __restrict__ b0,
                          const float* __restrict__ g1, const float* __restrict__ b1,
                          u16* __restrict__ out)
{
  int r = blockIdx.x;
  const float* x; const float* g; const float* bb;
  if (r < 1536){ x = rna + (size_t)r*1024; g = g0; bb = b0; }
  else { x = atac + (size_t)(r-1536)*1024; g = g1; bb = b1; }
  float s = 0.f, ss = 0.f;
  int t = threadIdx.x;
  float v0 = x[t], v1 = x[t+256], v2 = x[t+512], v3 = x[t+768];
  s = v0+v1+v2+v3; ss = v0*v0+v1*v1+v2*v2+v3*v3;
  #pragma unroll
  for (int off = 32; off >= 1; off >>= 1){ s += __shfl_xor(s, off); ss += __shfl_xor(ss, off); }
  __shared__ float rs_[4], rss_[4];
  int w = t >> 6;
  if ((t & 63) == 0){ rs_[w] = s; rss_[w] = ss; }
  __syncthreads();
  s = rs_[0]+rs_[1]+rs_[2]+rs_[3];
  ss = rss_[0]+rss_[1]+rss_[2]+rss_[3];
  float mu = s / 1024.f;
  float rstd = rsqrtf(ss / 1024.f - mu*mu + 1e-5f);
  u16* o = out + (size_t)r*1024;
  o[t]     = f2bf((v0-mu)*rstd*g[t]     + bb[t]);
  o[t+256] = f2bf((v1-mu)*rstd*g[t+256] + bb[t+256]);
  o[t+512] = f2bf((v2-mu)*rstd*g[t+512] + bb[t+512]);
  o[t+768] = f2bf((v3-mu)*rstd*g[t+768] + bb[t+768]);
}

// ---- batched embed: splitK add + bias + LN2 -> tok, then layer-0 attn-LN -> xn ----
__global__ void embed_addln2(const float* __restrict__ part,
                             const float* __restrict__ rb, const float* __restrict__ ab,
                             const float* __restrict__ g0, const float* __restrict__ bt0,
                             const float* __restrict__ g1, const float* __restrict__ bt1,
                             const float* __restrict__ ag0,
                             float* __restrict__ tok, u16* __restrict__ xn)
{
  int r = blockIdx.x;          // 0..3071
  int mod = (r >= 1536);
  int rl = mod ? r - 1536 : r;
  int b = rl / 768, rr = rl % 768;
  const float* bias = mod ? ab : rb;
  const float* g = mod ? g1 : g0;
  const float* bt = mod ? bt1 : bt0;
  const float* p0 = part + (size_t)r*DIMM;
  const float* p1 = p0 + (size_t)3072*DIMM;
  int t = threadIdx.x;
  float v0 = p0[t] + p1[t] + bias[t];
  float v1 = p0[t+256] + p1[t+256] + bias[t+256];
  float s = v0 + v1, ss = v0*v0 + v1*v1;
  #pragma unroll
  for (int off = 32; off >= 1; off >>= 1){ s += __shfl_xor(s, off); ss += __shfl_xor(ss, off); }
  __shared__ float rs_[4], rss_[4];
  int w = t >> 6;
  if ((t & 63) == 0){ rs_[w] = s; rss_[w] = ss; }
  __syncthreads();
  s = rs_[0]+rs_[1]+rs_[2]+rs_[3];
  ss = rss_[0]+rss_[1]+rss_[2]+rss_[3];
  float mu = s / DIMM;
  float rstd = rsqrtf(ss / DIMM - mu*mu + 1e-5f);
  size_t row = (size_t)(b*NTOK + (mod ? 784 : 0) + rr)*DIMM;
  float t0 = (v0 - mu)*rstd*g[t]     + bt[t];
  float t1 = (v1 - mu)*rstd*g[t+256] + bt[t+256];
  tok[row + t] = t0; tok[row + t+256] = t1;
  // second LN (layer-0 attention LN) -> xn
  float s2 = t0 + t1, ss2 = t0*t0 + t1*t1;
  #pragma unroll
  for (int off = 32; off >= 1; off >>= 1){ s2 += __shfl_xor(s2, off); ss2 += __shfl_xor(ss2, off); }
  __syncthreads();
  if ((t & 63) == 0){ rs_[w] = s2; rss_[w] = ss2; }
  __syncthreads();
  s2 = rs_[0]+rs_[1]+rs_[2]+rs_[3];
  ss2 = rss_[0]+rss_[1]+rss_[2]+rss_[3];
  float mu2 = s2 / DIMM;
  float rstd2 = rsqrtf(ss2 / DIMM - mu2*mu2 + 1e-5f);
  xn[row + t]     = f2bf((t0 - mu2)*rstd2*ag0[t]);
  xn[row + t+256] = f2bf((t1 - mu2)*rstd2*ag0[t+256]);
}

// ---- fusion tokens -> tok rows + layer-0 attn-LN -> xn ----
__global__ void fuscopy_ln(const float* __restrict__ ft, const float* __restrict__ ag0,
                           float* __restrict__ tok, u16* __restrict__ xn)
{
  int bid = blockIdx.x;       // 0..31
  int b = bid >> 4, rr = bid & 15;
  int t = threadIdx.x;
  const float* x = ft + (size_t)rr*DIMM;
  float v0 = x[t], v1 = x[t+256];
  size_t row = (size_t)(b*NTOK + 768 + rr)*DIMM;
  tok[row + t] = v0; tok[row + t+256] = v1;
  float s = v0 + v1, ss = v0*v0 + v1*v1;
  #pragma unroll
  for (int off = 32; off >= 1; off >>= 1){ s += __shfl_xor(s, off); ss += __shfl_xor(ss, off); }
  __shared__ float rs_[4], rss_[4];
  int w = t >> 6;
  if ((t & 63) == 0){ rs_[w] = s; rss_[w] = ss; }
  __syncthreads();
  s = rs_[0]+rs_[1]+rs_[2]+rs_[3];
  ss = rss_[0]+rss_[1]+rss_[2]+rss_[3];
  float mu = s / DIMM;
  float rstd = rsqrtf(ss / DIMM - mu*mu + 1e-5f);
  xn[row + t]     = f2bf((v0 - mu)*rstd*ag0[t]);
  xn[row + t+256] = f2bf((v1 - mu)*rstd*ag0[t+256]);
}

// ---- residual-add (attention proj, broadcast row0) + FFN LN -> tok, xn ----
__global__ void resadd_ffnln(float* __restrict__ tok, const float* __restrict__ proj,
                             const float* __restrict__ g, u16* __restrict__ xn)
{
  int n = blockIdx.x, b = blockIdx.y;
  int pr = (n >= 768 && n < 784) ? (1 + n - 768) : 0;
  const float* p = proj + ((size_t)b*17 + pr)*DIMM;
  size_t row = (size_t)(b*NTOK + n)*DIMM;
  int t = threadIdx.x;
  float v0 = tok[row + t]     + p[t];
  float v1 = tok[row + t+256] + p[t+256];
  tok[row + t] = v0; tok[row + t+256] = v1;
  float s = v0 + v1, ss = v0*v0 + v1*v1;
  #pragma unroll
  for (int off = 32; off >= 1; off >>= 1){ s += __shfl_xor(s, off); ss += __shfl_xor(ss, off); }
  __shared__ float rs_[4], rss_[4];
  int w = t >> 6;
  if ((t & 63) == 0){ rs_[w] = s; rss_[w] = ss; }
  __syncthreads();
  s = rs_[0]+rs_[1]+rs_[2]+rs_[3];
  ss = rss_[0]+rss_[1]+rss_[2]+rss_[3];
  float mu = s / DIMM;
  float rstd = rsqrtf(ss / DIMM - mu*mu + 1e-5f);
  xn[row + t]     = f2bf((v0 - mu)*rstd*g[t]);
  xn[row + t+256] = f2bf((v1 - mu)*rstd*g[t+256]);
}

// ---- splitK-add (FFN out) + next LN -> tok, xn ----
__global__ void skadd_ln(float* __restrict__ tok, const float* __restrict__ part,
                         const float* __restrict__ g, u16* __restrict__ xn)
{
  int r = blockIdx.x;
  size_t row = (size_t)r*DIMM;
  const float* p0 = part + row;
  const float* p1 = p0 + (size_t)MALL*DIMM;
  int t = threadIdx.x;
  float v0 = tok[row + t]     + p0[t]     + p1[t];
  float v1 = tok[row + t+256] + p0[t+256] + p1[t+256];
  tok[row + t] = v0; tok[row + t+256] = v1;
  float s = v0 + v1, ss = v0*v0 + v1*v1;
  #pragma unroll
  for (int off = 32; off >= 1; off >>= 1){ s += __shfl_xor(s, off); ss += __shfl_xor(ss, off); }
  __shared__ float rs_[4], rss_[4];
  int w = t >> 6;
  if ((t & 63) == 0){ rs_[w] = s; rss_[w] = ss; }
  __syncthreads();
  s = rs_[0]+rs_[1]+rs_[2]+rs_[3];
  ss = rss_[0]+rss_[1]+rss_[2]+rss_[3];
  float mu = s / DIMM;
  float rstd = rsqrtf(ss / DIMM - mu*mu + 1e-5f);
  xn[row + t]     = f2bf((v0 - mu)*rstd*g[t]);
  xn[row + t+256] = f2bf((v1 - mu)*rstd*g[t+256]);
}

// ------- gemm512: 8-wave 128x128; B bf16 [N][ldk]; global_load_lds staging (linear LDS);
//         optional B-switch at row mswitch; splitK via grid.z; optional GEGLU epilogue;
//         optional V-colsum (csum). OOB rows/cols are CLAMPED (outputs masked on write). -------
__global__ __launch_bounds__(512) void gemm512(
    const u16* __restrict__ A, int lda,
    const u16* __restrict__ Bt, const u16* __restrict__ BtB, int mswitch, int ldk,
    float* __restrict__ C, int ldc, size_t Cz,
    u16* __restrict__ gout, float* __restrict__ csum,
    int M, int Nn, int K, int kchunk)
{
  __shared__ __align__(16) u16 As_lin[128*32];
  __shared__ __align__(16) u16 Bs_lin[128*32];
  __shared__ float colsum[2][128];
  const int t = threadIdx.x;
  const int lane = t & 63;
  const int w = t >> 6;
  const int wr = (w >> 2) * 64;
  const int wc = (w & 3) * 32;
  const int row0 = blockIdx.x * 128, col0 = blockIdx.y * 128;
  if (BtB && row0 >= mswitch) Bt = BtB;
  const int z = blockIdx.z;
  const int kbeg = z * kchunk;
  const int kend = (kbeg + kchunk < K) ? (kbeg + kchunk) : K;
  C += (size_t)z * Cz;
  const int l15 = lane & 15;
  const int l4 = (lane >> 4) * 8;
  const int sr = t >> 2, sc8 = (t & 3) * 8;
  int gr_s = row0 + sr; if (gr_s >= M) gr_s = M - 1;
  int gc_s = col0 + sr; if (gc_s >= Nn) gc_s = Nn - 1;
  const u16* Ag = A + (size_t)gr_s*lda + sc8;
  const u16* Bg = Bt + (size_t)gc_s*ldk + sc8;
  u16* Al = &As_lin[(size_t)w * 512];
  u16* Bl = &Bs_lin[(size_t)w * 512];

  f32x4 acc[4][2];
  #pragma unroll
  for (int m = 0; m < 4; ++m)
    #pragma unroll
    for (int n = 0; n < 2; ++n)
      #pragma unroll
      for (int j = 0; j < 4; ++j) acc[m][n][j] = 0.f;

  for (int k0 = kbeg; k0 < kend; k0 += 32) {
    gload_lds16(Ag + k0, Al);
    gload_lds16(Bg + k0, Bl);
    __syncthreads();
    bf16x8 af[4], bfr[2];
    #pragma unroll
    for (int m = 0; m < 4; ++m) af[m]  = *(const bf16x8*)(&As_lin[(wr + m*16 + l15)*32 + l4]);
    #pragma unroll
    for (int n = 0; n < 2; ++n) bfr[n] = *(const bf16x8*)(&Bs_lin[(wc + n*16 + l15)*32 + l4]);
    #pragma unroll
    for (int m = 0; m < 4; ++m)
      #pragma unroll
      for (int n = 0; n < 2; ++n)
        acc[m][n] = __builtin_amdgcn_mfma_f32_16x16x32_bf16(af[m], bfr[n], acc[m][n], 0, 0, 0);
    __syncthreads();
  }
  const int rb = (lane >> 4) * 4;
  if (gout){
    int jcol = (col0 >> 1) + (w & 3)*16 + l15;
    #pragma unroll
    for (int m = 0; m < 4; ++m){
      int gr0 = row0 + wr + m*16 + rb;
      #pragma unroll
      for (int j = 0; j < 4; ++j){
        int gr = gr0 + j;
        if (gr < M){
          float gt = acc[m][1][j];
          float ge = 0.5f * gt * (1.0f + erff(gt * 0.70710678118654752f));
          gout[(size_t)gr*GSTRIDE + jcol] = f2bf(ge * acc[m][0][j]);
        }
      }
    }
  } else {
    #pragma unroll
    for (int m = 0; m < 4; ++m){
      int gr0 = row0 + wr + m*16 + rb;
      #pragma unroll
      for (int n = 0; n < 2; ++n){
        int gc = col0 + wc + n*16 + l15;
        if (gc >= Nn) continue;
        #pragma unroll
        for (int j = 0; j < 4; ++j){
          int gr = gr0 + j;
          if (gr < M) C[(size_t)gr*ldc + gc] = acc[m][n][j];
        }
      }
    }
  }
  if (csum && col0 >= 512){
    if (t < 256) colsum[t>>7][t&127] = 0.f;
    __syncthreads();
    #pragma unroll
    for (int n = 0; n < 2; ++n){
      float lv0 = 0.f, lv1 = 0.f;
      #pragma unroll
      for (int m = 0; m < 4; ++m){
        int gr0 = row0 + wr + m*16 + rb;
        #pragma unroll
        for (int j = 0; j < 4; ++j){
          float v = acc[m][n][j];
          if (gr0 + j < NTOK) lv0 += v; else lv1 += v;
        }
      }
      int lc = wc + n*16 + l15;
      atomicAdd(&colsum[0][lc], lv0);
      atomicAdd(&colsum[1][lc], lv1);
    }
    __syncthreads();
    if (t < 256){
      int bb = t>>7, c = t&127;
      csum[((size_t)(bb*25) + blockIdx.x)*512 + (col0 - 512) + c] = colsum[bb][c];
    }
  }
}

// ------- fused attention, flash-split: one block per (h, b, qi, jz); 256 keys/block -------
// apart layout: [((jz*BATCH+b)*8+h)*16+qi] * 68 floats: [0..63]=O_part, [64]=m, [65]=s
__global__ __launch_bounds__(256) void fused_attn(
    const u16* __restrict__ xn, const u16* __restrict__ wqt,
    const float* __restrict__ kv, float* __restrict__ apart)
{
  int h = blockIdx.x, b = blockIdx.y;
  int qi = blockIdx.z / AZ, jz = blockIdx.z % AZ;
  int t = threadIdx.x;
  int lane = t & 63, wid = t >> 6;
  __shared__ float xs[512];
  __shared__ float qs[64];
  __shared__ float pl[256];
  __shared__ float red[4][64];
  __shared__ float redm[4];

  {
    int row = b*NTOK + 768 + qi;
    const u16* xr = xn + (size_t)row*DIMM;
    xs[t] = bf2f(xr[t]);
    xs[t+256] = bf2f(xr[t+256]);
  }
  __syncthreads();

  {
    const u16* wrr = wqt + (size_t)(h*64 + lane)*DIMM + wid*128;
    float a = 0.f;
    #pragma unroll
    for (int k = 0; k < 128; k += 8){
      bf16x8 wv = *(const bf16x8*)(wrr + k);
      int kb = wid*128 + k;
      #pragma unroll
      for (int i = 0; i < 8; ++i) a += xs[kb+i] * bf2f((u16)wv[i]);
    }
    red[wid][lane] = a;
  }
  __syncthreads();
  if (t < 64) qs[t] = (red[0][t] + red[1][t] + red[2][t] + red[3][t]) * 0.125f;
  __syncthreads();

  int jj = jz*256 + t;
  int j = (jj < 768) ? jj : jj + 16;
  float a = 0.f;
  {
    const float* kr = kv + ((size_t)(b*NTOK + j))*1024 + h*64;
    #pragma unroll
    for (int d = 0; d < 64; d += 4){
      float4 kd = *(const float4*)(kr + d);
      a += qs[d]*kd.x + qs[d+1]*kd.y + qs[d+2]*kd.z + qs[d+3]*kd.w;
    }
  }

  float m = a;
  #pragma unroll
  for (int off = 32; off >= 1; off >>= 1) m = fmaxf(m, __shfl_xor(m, off));
  if (lane == 0) redm[wid] = m;
  __syncthreads();
  m = fmaxf(fmaxf(redm[0], redm[1]), fmaxf(redm[2], redm[3]));
  float p = __expf(a - m);
  pl[t] = p;
  float sq = p;
  #pragma unroll
  for (int off = 32; off >= 1; off >>= 1) sq += __shfl_xor(sq, off);
  if (lane == 0) redm[wid] = sq;
  __syncthreads();

  {
    int j0 = wid * 64;
    const float* vb = kv + ((size_t)(b*NTOK + jz*256 + j0 + ((jz*256 + j0 >= 768) ? 16 : 0)))*1024
                      + 512 + h*64 + lane;
    float a0=0.f, a1=0.f, a2=0.f, a3=0.f;
    #pragma unroll 4
    for (int i = 0; i < 64; i += 4){
      const float* vp = vb + (size_t)i*1024;
      a0 += pl[j0+i]   * vp[0];
      a1 += pl[j0+i+1] * vp[1024];
      a2 += pl[j0+i+2] * vp[2048];
      a3 += pl[j0+i+3] * vp[3072];
    }
    red[wid][lane] = a0+a1+a2+a3;
  }
  __syncthreads();
  float* po = apart + ((((size_t)jz*BATCH + b)*8 + h)*16 + qi) * 68;
  if (t < 64) po[t] = red[0][t] + red[1][t] + red[2][t] + red[3][t];
  else if (t == 64) po[64] = m;
  else if (t == 65) po[65] = redm[0] + redm[1] + redm[2] + redm[3];
}

// ------- attn_out: merge flash partials + colmean row + wo-projection, fused -------
// grid (8 colchunks, BATCH, 4 row-groups); rows: g0={0..4}, g1={5..8}, g2={9..12}, g3={13..16}
__global__ __launch_bounds__(256) void attn_out(
    const float* __restrict__ apart, const float* __restrict__ csum,
    const u16* __restrict__ wot, float* __restrict__ proj)
{
  int colchunk = blockIdx.x;
  int b = blockIdx.y;
  int rg = blockIdx.z;
  int r0 = (rg == 0) ? 0 : (1 + 4*rg);
  int nr = (rg == 0) ? 5 : 4;
  __shared__ float zbl[5][512];
  __shared__ float red[4][64];
  int t = threadIdx.x;

  for (int rr = 0; rr < nr; ++rr){
    int r = r0 + rr;
    if (r == 0){
      for (int c = t; c < 512; c += 256){
        float s = 0.f;
        #pragma unroll
        for (int bx = 0; bx < 25; ++bx) s += csum[((size_t)(b*25)+bx)*512 + c];
        zbl[rr][c] = s * (1.0f/1552.0f);
      }
    } else {
      int qi = r - 1;
      for (int c = t; c < 512; c += 256){
        int h = c >> 6, d = c & 63;
        size_t base = ((size_t)b*8 + h)*16 + qi;
        float mz[AZ], sz[AZ];
        float M = -3.4e38f;
        #pragma unroll
        for (int z = 0; z < AZ; ++z){
          const float* po = apart + ((size_t)z*BATCH*8*16 + base)*68;
          mz[z] = po[64]; sz[z] = po[65];
          M = fmaxf(M, mz[z]);
        }
        float S = 0.f, O = 0.f;
        #pragma unroll
        for (int z = 0; z < AZ; ++z){
          const float* po = apart + ((size_t)z*BATCH*8*16 + base)*68;
          float wz = __expf(mz[z] - M);
          S += sz[z]*wz; O += po[d]*wz;
        }
        zbl[rr][c] = O / S;
      }
    }
  }
  __syncthreads();

  int col = colchunk*64 + (t & 63);
  int kq = t >> 6;
  const u16* wrow = wot + (size_t)col*512 + kq*128;
  for (int rr = 0; rr < nr; ++rr){
    float a = 0.f;
    #pragma unroll
    for (int k = 0; k < 128; k += 8){
      bf16x8 wv = *(const bf16x8*)(wrow + k);
      #pragma unroll
      for (int i = 0; i < 8; ++i) a += zbl[rr][kq*128 + k + i] * bf2f((u16)wv[i]);
    }
    red[kq][t & 63] = a;
    __syncthreads();
    if (t < 64)
      proj[((size_t)(b*17) + r0 + rr)*DIMM + colchunk*64 + t] =
        red[0][t] + red[1][t] + red[2][t] + red[3][t];
    __syncthreads();
  }
}

// ------- pool_final: csum->mv, LN+q2, 16-key attention, wo-matvec + residual, fused -------
// grid (8 colchunks, 6 br)
__global__ __launch_bounds__(256) void pool_final(
    const float* __restrict__ csum, const float* __restrict__ rt,
    const float* __restrict__ pg, const float* __restrict__ wq,
    const float* __restrict__ kv, const float* __restrict__ wo,
    float* __restrict__ out)
{
  int colchunk = blockIdx.x;
  int br = blockIdx.y; int b = br/3, r = br%3;
  __shared__ float ys[512];
  __shared__ float q2l[512];
  __shared__ float sm[8][16];
  __shared__ float pn[8][16];
  __shared__ float red[4][64];
  __shared__ float rs_[4], rss_[4];
  int t = threadIdx.x;

  if (r < 2){
    float a0 = 0.f, a1 = 0.f;
    #pragma unroll
    for (int bx = 0; bx < 25; ++bx){
      a0 += csum[((size_t)(b*25)+bx)*512 + t];
      a1 += csum[((size_t)(b*25)+bx)*512 + t + 256];
    }
    ys[t] = a0 * (1.0f/1552.0f);
    ys[t+256] = a1 * (1.0f/1552.0f);
    __syncthreads();
  } else {
    // LN of return-token 2
    const float* x = rt + 2*DIMM;
    float v0 = x[t], v1 = x[t+256];
    float s = v0 + v1, ss = v0*v0 + v1*v1;
    #pragma unroll
    for (int off = 32; off >= 1; off >>= 1){ s += __shfl_xor(s, off); ss += __shfl_xor(ss, off); }
    int w = t >> 6;
    if ((t & 63) == 0){ rs_[w] = s; rss_[w] = ss; }
    __syncthreads();
    s = rs_[0]+rs_[1]+rs_[2]+rs_[3];
    ss = rss_[0]+rss_[1]+rss_[2]+rss_[3];
    float mu = s / DIMM;
    float rstd = rsqrtf(ss / DIMM - mu*mu + 1e-5f);
    ys[t]     = (v0 - mu)*rstd*pg[t];
    ys[t+256] = (v1 - mu)*rstd*pg[t+256];
    __syncthreads();
    // q2 = 0.125 * ys @ wq  (full 512 outputs)
    {
      float a0 = 0.f, a1 = 0.f;
      for (int k = 0; k < 512; ++k){
        float yv = ys[k];
        a0 += yv * wq[(size_t)k*512 + t];
        a1 += yv * wq[(size_t)k*512 + t + 256];
      }
      q2l[t] = a0 * 0.125f;
      q2l[t+256] = a1 * 0.125f;
    }
    __syncthreads();
    // sims over 16 fusion keys
    if (t < 128){
      int h = t >> 4, j = t & 15;
      const float* kr = kv + ((size_t)(b*NTOK + 768 + j))*1024 + h*64;
      float a = 0.f;
      #pragma unroll
      for (int d = 0; d < 64; ++d) a += q2l[h*64 + d] * kr[d];
      sm[h][j] = a;
    }
    __syncthreads();
    if (t < 8){
      float m = -3.4e38f;
      #pragma unroll
      for (int j = 0; j < 16; ++j) m = fmaxf(m, sm[t][j]);
      float e[16]; float s2 = 0.f;
      #pragma unroll
      for (int j = 0; j < 16; ++j){ e[j] = __expf(sm[t][j] - m); s2 += e[j]; }
      float inv = 1.0f / s2;
      #pragma unroll
      for (int j = 0; j < 16; ++j) pn[t][j] = e[j] * inv;
    }
    __syncthreads();
    // out2 -> ys
    {
      int c0 = t, c1 = t + 256;
      int h0 = c0 >> 6, h1 = c1 >> 6;
      float a0 = 0.f, a1 = 0.f;
      #pragma unroll
      for (int j = 0; j < 16; ++j){
        const float* vr = kv + ((size_t)(b*NTOK + 768 + j))*1024 + 512;
        a0 += pn[h0][j] * vr[c0];
        a1 += pn[h1][j] * vr[c1];
      }
      ys[c0] = a0; ys[c1] = a1;
    }
    __syncthreads();
  }

  // final: out[br][col] = ys @ wo + rt[r]
  int col = colchunk*64 + (t & 63);
  int kq = t >> 6;
  float a = 0.f;
  #pragma unroll 4
  for (int k = kq*128; k < kq*128 + 128; ++k) a += ys[k] * wo[(size_t)k*512 + col];
  red[kq][t & 63] = a;
  __syncthreads();
  if (t < 64){
    int c = colchunk*64 + t;
    out[(size_t)br*DIMM + c] = red[0][t]+red[1][t]+red[2][t]+red[3][t] + rt[(size_t)r*DIMM + c];
  }
}

// =================================================================
extern "C" void kernel_launch(void* const* d_in, const int* in_sizes, int n_in,
                              void* d_out, int out_size, void* d_ws, size_t ws_size,
                              hipStream_t stream)
{
  const float* rna        = (const float*)d_in[0];
  const float* atac       = (const float*)d_in[1];
  const float* rna_ln1_g  = (const float*)d_in[2];
  const float* rna_ln1_b  = (const float*)d_in[3];
  const float* rna_w      = (const float*)d_in[4];
  const float* rna_b      = (const float*)d_in[5];
  const float* rna_ln2_g  = (const float*)d_in[6];
  const float* rna_ln2_b  = (const float*)d_in[7];
  const float* atac_ln1_g = (const float*)d_in[8];
  const float* atac_ln1_b = (const float*)d_in[9];
  const float* atac_w     = (const float*)d_in[10];
  const float* atac_b     = (const float*)d_in[11];
  const float* atac_ln2_g = (const float*)d_in[12];
  const float* atac_ln2_b = (const float*)d_in[13];
  const float* fusion_tok = (const float*)d_in[14];
  const float* lay_ag     = (const float*)d_in[15];
  const float* lay_wq     = (const float*)d_in[16];
  const float* lay_wkv    = (const float*)d_in[17];
  const float* lay_wo     = (const float*)d_in[18];
  const float* lay_fg     = (const float*)d_in[19];
  const float* lay_w1     = (const float*)d_in[20];
  const float* lay_w2     = (const float*)d_in[21];
  const float* final_g    = (const float*)d_in[22];
  const float* ret_tok    = (const float*)d_in[23];
  const float* pool_g     = (const float*)d_in[24];
  const float* pool_wq    = (const float*)d_in[25];
  const float* pool_wkv   = (const float*)d_in[26];
  const float* pool_wo    = (const float*)d_in[27];

  uint8_t* ws = (uint8_t*)d_ws;
  size_t off = 0;
  auto carve = [&](size_t bytes) -> uint8_t* {
    uint8_t* p = ws + off;
    off += (bytes + 255) & ~(size_t)255;
    return p;
  };
  // bf16 weights
  u16* rna_wt   = (u16*)carve((size_t)512*1024*2);
  u16* atac_wt  = (u16*)carve((size_t)512*1024*2);
  u16* wkvt     = (u16*)carve((size_t)4*1024*512*2);
  u16* wqt      = (u16*)carve((size_t)4*512*512*2);
  u16* wot      = (u16*)carve((size_t)4*512*512*2);
  u16* w1t      = (u16*)carve((size_t)4*NW1*512*2);
  u16* w2t      = (u16*)carve((size_t)4*512*GSTRIDE*2);
  u16* pool_wkvt= (u16*)carve((size_t)1024*512*2);
  // activations
  float* tok   = (float*)carve((size_t)MALL * DIMM * 4);
  u16*   xn    = (u16*)  carve((size_t)MALL * DIMM * 2);
  float* kv    = (float*)carve((size_t)MALL * 1024 * 4);
  u16*   lnbuf = (u16*)  carve((size_t)3072 * 1024 * 2);
  float* proj  = (float*)carve((size_t)BATCH*17*DIMM * 4);
  float* csum  = (float*)carve((size_t)BATCH*25*512 * 4);
  float* apart = (float*)carve((size_t)AZ*BATCH*8*16*68 * 4);
  u16*   gbuf  = (u16*)  carve((size_t)MALL * GSTRIDE * 2);
  float* skpart= (float*)carve((size_t)2 * MALL * 512 * 4);
  (void)ws_size;

  // ---- one-dispatch weight conversion ----
  convall<<<14080, 256, 0, stream>>>(rna_w, atac_w, lay_wkv, lay_wq, lay_wo, lay_w1, lay_w2, pool_wkv,
                                     rna_wt, atac_wt, wkvt, wqt, wot, w1t, w2t, pool_wkvt);

  // ---- embeddings (both modalities batched; layer-0 LN fused into tails) ----
  embed_ln1<<<3072, 256, 0, stream>>>(rna, atac, rna_ln1_g, rna_ln1_b, atac_ln1_g, atac_ln1_b, lnbuf);
  gemm512<<<dim3(24, 4, 2), 512, 0, stream>>>(lnbuf, 1024, rna_wt, atac_wt, 1536, 1024,
                                              skpart, 512, (size_t)3072*512, nullptr, nullptr,
                                              3072, 512, 1024, 512);
  embed_addln2<<<3072, 256, 0, stream>>>(skpart, rna_b, atac_b, rna_ln2_g, rna_ln2_b,
                                         atac_ln2_g, atac_ln2_b, lay_ag, tok, xn);
  fuscopy_ln<<<32, 256, 0, stream>>>(fusion_tok, lay_ag, tok, xn);

  // ---- transformer layers ----
  for (int l = 0; l < 4; ++l){
    const float* fg  = lay_fg + (size_t)l*DIMM;
    const float* gnext = (l < 3) ? (lay_ag + (size_t)(l+1)*DIMM) : final_g;
    const u16* wkvt_l = wkvt + (size_t)l*1024*512;
    const u16* wqt_l  = wqt  + (size_t)l*512*512;
    const u16* wot_l  = wot  + (size_t)l*512*512;
    const u16* w1t_l  = w1t  + (size_t)l*NW1*512;
    const u16* w2t_l  = w2t  + (size_t)l*512*GSTRIDE;

    gemm512<<<dim3(25, 8, 1), 512, 0, stream>>>(xn, 512, wkvt_l, nullptr, 0, 512,
                                                kv, 1024, 0, nullptr, csum, MALL, 1024, 512, 512);
    fused_attn<<<dim3(8, BATCH, 16*AZ), 256, 0, stream>>>(xn, wqt_l, kv, apart);
    attn_out<<<dim3(8, BATCH, 4), 256, 0, stream>>>(apart, csum, wot_l, proj);
    resadd_ffnln<<<dim3(NTOK, BATCH), 256, 0, stream>>>(tok, proj, fg, xn);
    gemm512<<<dim3(25, 22, 1), 512, 0, stream>>>(xn, 512, w1t_l, nullptr, 0, 512,
                                                 nullptr, 0, 0, gbuf, nullptr, MALL, NW1, 512, 512);
    gemm512<<<dim3(25, 4, 2), 512, 0, stream>>>(gbuf, GSTRIDE, w2t_l, nullptr, 0, GSTRIDE,
                                                skpart, 512, (size_t)MALL*512, nullptr, nullptr,
                                                MALL, 512, GSTRIDE, 704);
    skadd_ln<<<MALL, 256, 0, stream>>>(tok, skpart, gnext, xn);
  }

  // ---- pooling (xn holds final-LN tokens) ----
  gemm512<<<dim3(25, 8, 1), 512, 0, stream>>>(xn, 512, pool_wkvt, nullptr, 0, 512,
                                              kv, 1024, 0, nullptr, csum, MALL, 1024, 512, 512);
  pool_final<<<dim3(8, 6), 256, 0, stream>>>(csum, ret_tok, pool_g, pool_wq, kv, pool_wo,
                                             (float*)d_out);
}

// Round 11
// 548.955 us; speedup vs baseline: 5.9914x; 1.0236x over previous
//
#include <hip/hip_runtime.h>
#include <stdint.h>
#include <stddef.h>

#define NTOK 1552
#define DIMM 512
#define IFFC 1365
#define IFF2 2730
#define NW1 2816       // padded/permuted w1 output cols (2*1408)
#define GSTRIDE 1408   // geglu output row stride (bf16) = padded K of w2
#define BATCH 2
#define MALL (BATCH*NTOK)   // 3104
#define AZ 6           // attention j-chunks (256 keys each)

typedef unsigned short u16;
typedef __attribute__((ext_vector_type(8))) short bf16x8;
typedef __attribute__((ext_vector_type(4))) float f32x4;

__device__ __forceinline__ u16 f2bf(float f){
  union { float f; uint32_t u; } v; v.f = f;
  uint32_t u = v.u;
  uint32_t r = (u + 0x7FFFu + ((u >> 16) & 1u)) >> 16;
  return (u16)r;
}
__device__ __forceinline__ float bf2f(u16 x){
  union { uint32_t u; float f; } v; v.u = ((uint32_t)x) << 16; return v.f;
}

// async global->LDS, 16B per lane; LDS dest is wave-uniform base (lane*16 implicit)
__device__ __forceinline__ void gload_lds16(const u16* g, u16* l){
  __builtin_amdgcn_global_load_lds((const __attribute__((address_space(1))) void*)g,
                                   (__attribute__((address_space(3))) void*)l, 16, 0, 0);
}

// ---------- one-dispatch weight convert/transpose (8 segments), vectorized ----------
__global__ void convall(const float* s0,const float* s1,const float* s2,const float* s3,
                        const float* s4,const float* s5,const float* s6,const float* s7,
                        u16* d0,u16* d1,u16* d2,u16* d3,u16* d4,u16* d5,u16* d6,u16* d7)
{
  const float* srcs[8] = {s0,s1,s2,s3,s4,s5,s6,s7};
  u16* dsts[8] = {d0,d1,d2,d3,d4,d5,d6,d7};
  const int KT[8]   = {32,32,16,16,16,16,44,16};
  const int NT[8]   = {16,16,32,16,16,88,16,32};
  const int TC[8]   = {512,512,2048,1024,1024,5632,2816,512};
  const int K_[8]   = {1024,1024,512,512,512,512,1365,512};
  const int NSRC[8] = {512,512,1024,512,512,2730,512,1024};
  const int LDK[8]  = {1024,1024,512,512,512,512,1408,512};
  const int NOUT[8] = {512,512,1024,512,512,2816,512,1024};
  const int WS_[8]  = {0,0,512*1024,512*512,512*512,512*2730,1365*512,0};
  const int WT_[8]  = {0,0,1024*512,512*512,512*512,2816*512,512*1408,0};

  int bid = blockIdx.x;
  int seg = 0, base = 0;
  while (seg < 7 && bid >= base + TC[seg]) { base += TC[seg]; ++seg; }
  int loc = bid - base;
  int kt = KT[seg];
  int z = loc / (kt*NT[seg]); loc -= z*(kt*NT[seg]);
  int kb = (loc % kt) * 32, nb = (loc / kt) * 32;
  const float* w = srcs[seg] + (size_t)z * WS_[seg];
  u16* wt = dsts[seg] + (size_t)z * WT_[seg];
  int K = K_[seg], NS = NSRC[seg], ldk = LDK[seg], NO = NOUT[seg];

  __shared__ float tile[32][33];
  int t = threadIdx.x;
  {
    int k = t >> 3, n4 = (t & 7) * 4;
    int gk = kb + k;
    float4 v = make_float4(0.f,0.f,0.f,0.f);
    if (gk < K){
      if (seg != 5){
        int gn = nb + n4;
        if (gn + 4 <= NS){
          v = *(const float4*)(w + (size_t)gk*NS + gn);
        } else {
          float* pv = (float*)&v;
          #pragma unroll
          for (int i = 0; i < 4; ++i){ int n = gn + i; if (n < NS) pv[i] = w[(size_t)gk*NS + n]; }
        }
      } else {
        float* pv = (float*)&v;
        #pragma unroll
        for (int i = 0; i < 4; ++i){
          int n = nb + n4 + i;
          if (n < NO){
            int bb = n >> 7, rr = n & 127, g = rr >> 5, hh = rr & 31;
            int j = bb*64 + g*16 + (hh & 15);
            if (j < 1365) pv[i] = w[(size_t)gk*NS + ((hh < 16) ? j : 1365 + j)];
          }
        }
      }
    }
    tile[k][n4] = v.x; tile[k][n4+1] = v.y; tile[k][n4+2] = v.z; tile[k][n4+3] = v.w;
  }
  __syncthreads();
  if (t < 128){
    int n = t >> 2, k8 = (t & 3) * 8;
    int gn = nb + n, gk = kb + k8;
    if (gn < NO && gk < ldk){
      u16 sh[8];
      #pragma unroll
      for (int i = 0; i < 8; ++i) sh[i] = f2bf(tile[k8+i][n]);
      *(bf16x8*)(wt + (size_t)gn*ldk + gk) = *(bf16x8*)sh;
    }
  }
}

// ---- batched embed LN1 (rna rows 0..1535, atac rows 1536..3071) ----
__global__ void embed_ln1(const float* __restrict__ rna, const float* __restrict__ atac,
                          const float* __restrict__ g0, const float* __restrict__ b0,
                          const float* __restrict__ g1, const float* __restrict__ b1,
                          u16* __restrict__ out)
{
  int r = blockIdx.x;
  const float* x; const float* g; const float* bb;
  if (r < 1536){ x = rna + (size_t)r*1024; g = g0; bb = b0; }
  else { x = atac + (size_t)(r-1536)*1024; g = g1; bb = b1; }
  float s = 0.f, ss = 0.f;
  int t = threadIdx.x;
  float v0 = x[t], v1 = x[t+256], v2 = x[t+512], v3 = x[t+768];
  s = v0+v1+v2+v3; ss = v0*v0+v1*v1+v2*v2+v3*v3;
  #pragma unroll
  for (int off = 32; off >= 1; off >>= 1){ s += __shfl_xor(s, off); ss += __shfl_xor(ss, off); }
  __shared__ float rs_[4], rss_[4];
  int w = t >> 6;
  if ((t & 63) == 0){ rs_[w] = s; rss_[w] = ss; }
  __syncthreads();
  s = rs_[0]+rs_[1]+rs_[2]+rs_[3];
  ss = rss_[0]+rss_[1]+rss_[2]+rss_[3];
  float mu = s / 1024.f;
  float rstd = rsqrtf(ss / 1024.f - mu*mu + 1e-5f);
  u16* o = out + (size_t)r*1024;
  o[t]     = f2bf((v0-mu)*rstd*g[t]     + bb[t]);
  o[t+256] = f2bf((v1-mu)*rstd*g[t+256] + bb[t+256]);
  o[t+512] = f2bf((v2-mu)*rstd*g[t+512] + bb[t+512]);
  o[t+768] = f2bf((v3-mu)*rstd*g[t+768] + bb[t+768]);
}

// ---- batched embed: splitK add + bias + LN2 -> tok, then layer-0 attn-LN -> xn ----
__global__ void embed_addln2(const float* __restrict__ part,
                             const float* __restrict__ rb, const float* __restrict__ ab,
                             const float* __restrict__ g0, const float* __restrict__ bt0,
                             const float* __restrict__ g1, const float* __restrict__ bt1,
                             const float* __restrict__ ag0,
                             float* __restrict__ tok, u16* __restrict__ xn)
{
  int r = blockIdx.x;          // 0..3071
  int mod = (r >= 1536);
  int rl = mod ? r - 1536 : r;
  int b = rl / 768, rr = rl % 768;
  const float* bias = mod ? ab : rb;
  const float* g = mod ? g1 : g0;
  const float* bt = mod ? bt1 : bt0;
  const float* p0 = part + (size_t)r*DIMM;
  const float* p1 = p0 + (size_t)3072*DIMM;
  int t = threadIdx.x;
  float v0 = p0[t] + p1[t] + bias[t];
  float v1 = p0[t+256] + p1[t+256] + bias[t+256];
  float s = v0 + v1, ss = v0*v0 + v1*v1;
  #pragma unroll
  for (int off = 32; off >= 1; off >>= 1){ s += __shfl_xor(s, off); ss += __shfl_xor(ss, off); }
  __shared__ float rs_[4], rss_[4];
  int w = t >> 6;
  if ((t & 63) == 0){ rs_[w] = s; rss_[w] = ss; }
  __syncthreads();
  s = rs_[0]+rs_[1]+rs_[2]+rs_[3];
  ss = rss_[0]+rss_[1]+rss_[2]+rss_[3];
  float mu = s / DIMM;
  float rstd = rsqrtf(ss / DIMM - mu*mu + 1e-5f);
  size_t row = (size_t)(b*NTOK + (mod ? 784 : 0) + rr)*DIMM;
  float t0 = (v0 - mu)*rstd*g[t]     + bt[t];
  float t1 = (v1 - mu)*rstd*g[t+256] + bt[t+256];
  tok[row + t] = t0; tok[row + t+256] = t1;
  float s2 = t0 + t1, ss2 = t0*t0 + t1*t1;
  #pragma unroll
  for (int off = 32; off >= 1; off >>= 1){ s2 += __shfl_xor(s2, off); ss2 += __shfl_xor(ss2, off); }
  __syncthreads();
  if ((t & 63) == 0){ rs_[w] = s2; rss_[w] = ss2; }
  __syncthreads();
  s2 = rs_[0]+rs_[1]+rs_[2]+rs_[3];
  ss2 = rss_[0]+rss_[1]+rss_[2]+rss_[3];
  float mu2 = s2 / DIMM;
  float rstd2 = rsqrtf(ss2 / DIMM - mu2*mu2 + 1e-5f);
  xn[row + t]     = f2bf((t0 - mu2)*rstd2*ag0[t]);
  xn[row + t+256] = f2bf((t1 - mu2)*rstd2*ag0[t+256]);
}

// ---- fusion tokens -> tok rows + layer-0 attn-LN -> xn ----
__global__ void fuscopy_ln(const float* __restrict__ ft, const float* __restrict__ ag0,
                           float* __restrict__ tok, u16* __restrict__ xn)
{
  int bid = blockIdx.x;       // 0..31
  int b = bid >> 4, rr = bid & 15;
  int t = threadIdx.x;
  const float* x = ft + (size_t)rr*DIMM;
  float v0 = x[t], v1 = x[t+256];
  size_t row = (size_t)(b*NTOK + 768 + rr)*DIMM;
  tok[row + t] = v0; tok[row + t+256] = v1;
  float s = v0 + v1, ss = v0*v0 + v1*v1;
  #pragma unroll
  for (int off = 32; off >= 1; off >>= 1){ s += __shfl_xor(s, off); ss += __shfl_xor(ss, off); }
  __shared__ float rs_[4], rss_[4];
  int w = t >> 6;
  if ((t & 63) == 0){ rs_[w] = s; rss_[w] = ss; }
  __syncthreads();
  s = rs_[0]+rs_[1]+rs_[2]+rs_[3];
  ss = rss_[0]+rss_[1]+rss_[2]+rss_[3];
  float mu = s / DIMM;
  float rstd = rsqrtf(ss / DIMM - mu*mu + 1e-5f);
  xn[row + t]     = f2bf((v0 - mu)*rstd*ag0[t]);
  xn[row + t+256] = f2bf((v1 - mu)*rstd*ag0[t+256]);
}

// ---- residual-add (attention proj, broadcast row0) + FFN LN -> tok, xn ----
__global__ void resadd_ffnln(float* __restrict__ tok, const float* __restrict__ proj,
                             const float* __restrict__ g, u16* __restrict__ xn)
{
  int n = blockIdx.x, b = blockIdx.y;
  int pr = (n >= 768 && n < 784) ? (1 + n - 768) : 0;
  const float* p = proj + ((size_t)b*17 + pr)*DIMM;
  size_t row = (size_t)(b*NTOK + n)*DIMM;
  int t = threadIdx.x;
  float v0 = tok[row + t]     + p[t];
  float v1 = tok[row + t+256] + p[t+256];
  tok[row + t] = v0; tok[row + t+256] = v1;
  float s = v0 + v1, ss = v0*v0 + v1*v1;
  #pragma unroll
  for (int off = 32; off >= 1; off >>= 1){ s += __shfl_xor(s, off); ss += __shfl_xor(ss, off); }
  __shared__ float rs_[4], rss_[4];
  int w = t >> 6;
  if ((t & 63) == 0){ rs_[w] = s; rss_[w] = ss; }
  __syncthreads();
  s = rs_[0]+rs_[1]+rs_[2]+rs_[3];
  ss = rss_[0]+rss_[1]+rss_[2]+rss_[3];
  float mu = s / DIMM;
  float rstd = rsqrtf(ss / DIMM - mu*mu + 1e-5f);
  xn[row + t]     = f2bf((v0 - mu)*rstd*g[t]);
  xn[row + t+256] = f2bf((v1 - mu)*rstd*g[t+256]);
}

// ---- splitK-add (FFN out) + next LN -> tok, xn ----
__global__ void skadd_ln(float* __restrict__ tok, const float* __restrict__ part,
                         const float* __restrict__ g, u16* __restrict__ xn)
{
  int r = blockIdx.x;
  size_t row = (size_t)r*DIMM;
  const float* p0 = part + row;
  const float* p1 = p0 + (size_t)MALL*DIMM;
  int t = threadIdx.x;
  float v0 = tok[row + t]     + p0[t]     + p1[t];
  float v1 = tok[row + t+256] + p0[t+256] + p1[t+256];
  tok[row + t] = v0; tok[row + t+256] = v1;
  float s = v0 + v1, ss = v0*v0 + v1*v1;
  #pragma unroll
  for (int off = 32; off >= 1; off >>= 1){ s += __shfl_xor(s, off); ss += __shfl_xor(ss, off); }
  __shared__ float rs_[4], rss_[4];
  int w = t >> 6;
  if ((t & 63) == 0){ rs_[w] = s; rss_[w] = ss; }
  __syncthreads();
  s = rs_[0]+rs_[1]+rs_[2]+rs_[3];
  ss = rss_[0]+rss_[1]+rss_[2]+rss_[3];
  float mu = s / DIMM;
  float rstd = rsqrtf(ss / DIMM - mu*mu + 1e-5f);
  xn[row + t]     = f2bf((v0 - mu)*rstd*g[t]);
  xn[row + t+256] = f2bf((v1 - mu)*rstd*g[t+256]);
}

// ------- gemm512: 8-wave 128x128; B bf16 [N][ldk]; global_load_lds staging (linear LDS);
//         optional B-switch at row mswitch; splitK via grid.z; optional GEGLU epilogue;
//         optional V-colsum (csum). OOB rows/cols are CLAMPED (outputs masked on write). -------
__global__ __launch_bounds__(512) void gemm512(
    const u16* __restrict__ A, int lda,
    const u16* __restrict__ Bt, const u16* __restrict__ BtB, int mswitch, int ldk,
    float* __restrict__ C, int ldc, size_t Cz,
    u16* __restrict__ gout, float* __restrict__ csum,
    int M, int Nn, int K, int kchunk)
{
  __shared__ __align__(16) u16 As_lin[128*32];
  __shared__ __align__(16) u16 Bs_lin[128*32];
  __shared__ float colsum[2][128];
  const int t = threadIdx.x;
  const int lane = t & 63;
  const int w = t >> 6;
  const int wr = (w >> 2) * 64;
  const int wc = (w & 3) * 32;
  const int row0 = blockIdx.x * 128, col0 = blockIdx.y * 128;
  if (BtB && row0 >= mswitch) Bt = BtB;
  const int z = blockIdx.z;
  const int kbeg = z * kchunk;
  const int kend = (kbeg + kchunk < K) ? (kbeg + kchunk) : K;
  C += (size_t)z * Cz;
  const int l15 = lane & 15;
  const int l4 = (lane >> 4) * 8;
  const int sr = t >> 2, sc8 = (t & 3) * 8;
  int gr_s = row0 + sr; if (gr_s >= M) gr_s = M - 1;
  int gc_s = col0 + sr; if (gc_s >= Nn) gc_s = Nn - 1;
  const u16* Ag = A + (size_t)gr_s*lda + sc8;
  const u16* Bg = Bt + (size_t)gc_s*ldk + sc8;
  u16* Al = &As_lin[(size_t)w * 512];
  u16* Bl = &Bs_lin[(size_t)w * 512];

  f32x4 acc[4][2];
  #pragma unroll
  for (int m = 0; m < 4; ++m)
    #pragma unroll
    for (int n = 0; n < 2; ++n)
      #pragma unroll
      for (int j = 0; j < 4; ++j) acc[m][n][j] = 0.f;

  for (int k0 = kbeg; k0 < kend; k0 += 32) {
    gload_lds16(Ag + k0, Al);
    gload_lds16(Bg + k0, Bl);
    __syncthreads();
    bf16x8 af[4], bfr[2];
    #pragma unroll
    for (int m = 0; m < 4; ++m) af[m]  = *(const bf16x8*)(&As_lin[(wr + m*16 + l15)*32 + l4]);
    #pragma unroll
    for (int n = 0; n < 2; ++n) bfr[n] = *(const bf16x8*)(&Bs_lin[(wc + n*16 + l15)*32 + l4]);
    #pragma unroll
    for (int m = 0; m < 4; ++m)
      #pragma unroll
      for (int n = 0; n < 2; ++n)
        acc[m][n] = __builtin_amdgcn_mfma_f32_16x16x32_bf16(af[m], bfr[n], acc[m][n], 0, 0, 0);
    __syncthreads();
  }
  const int rb = (lane >> 4) * 4;
  if (gout){
    int jcol = (col0 >> 1) + (w & 3)*16 + l15;
    #pragma unroll
    for (int m = 0; m < 4; ++m){
      int gr0 = row0 + wr + m*16 + rb;
      #pragma unroll
      for (int j = 0; j < 4; ++j){
        int gr = gr0 + j;
        if (gr < M){
          float gt = acc[m][1][j];
          float ge = 0.5f * gt * (1.0f + erff(gt * 0.70710678118654752f));
          gout[(size_t)gr*GSTRIDE + jcol] = f2bf(ge * acc[m][0][j]);
        }
      }
    }
  } else {
    #pragma unroll
    for (int m = 0; m < 4; ++m){
      int gr0 = row0 + wr + m*16 + rb;
      #pragma unroll
      for (int n = 0; n < 2; ++n){
        int gc = col0 + wc + n*16 + l15;
        if (gc >= Nn) continue;
        #pragma unroll
        for (int j = 0; j < 4; ++j){
          int gr = gr0 + j;
          if (gr < M) C[(size_t)gr*ldc + gc] = acc[m][n][j];
        }
      }
    }
  }
  if (csum && col0 >= 512){
    if (t < 256) colsum[t>>7][t&127] = 0.f;
    __syncthreads();
    #pragma unroll
    for (int n = 0; n < 2; ++n){
      float lv0 = 0.f, lv1 = 0.f;
      #pragma unroll
      for (int m = 0; m < 4; ++m){
        int gr0 = row0 + wr + m*16 + rb;
        #pragma unroll
        for (int j = 0; j < 4; ++j){
          float v = acc[m][n][j];
          if (gr0 + j < NTOK) lv0 += v; else lv1 += v;
        }
      }
      int lc = wc + n*16 + l15;
      atomicAdd(&colsum[0][lc], lv0);
      atomicAdd(&colsum[1][lc], lv1);
    }
    __syncthreads();
    if (t < 256){
      int bb = t>>7, c = t&127;
      csum[((size_t)(bb*25) + blockIdx.x)*512 + (col0 - 512) + c] = colsum[bb][c];
    }
  }
}

// ------- fused attention, flash-split: one block per (h, b, qi, jz); 256 keys/block -------
// apart layout: [((jz*BATCH+b)*8+h)*16+qi] * 68 floats: [0..63]=O_part, [64]=m, [65]=s
__global__ __launch_bounds__(256) void fused_attn(
    const u16* __restrict__ xn, const u16* __restrict__ wqt,
    const float* __restrict__ kv, float* __restrict__ apart)
{
  int h = blockIdx.x, b = blockIdx.y;
  int qi = blockIdx.z / AZ, jz = blockIdx.z % AZ;
  int t = threadIdx.x;
  int lane = t & 63, wid = t >> 6;
  __shared__ float xs[512];
  __shared__ float qs[64];
  __shared__ float pl[256];
  __shared__ float red[4][64];
  __shared__ float redm[4];

  {
    int row = b*NTOK + 768 + qi;
    const u16* xr = xn + (size_t)row*DIMM;
    xs[t] = bf2f(xr[t]);
    xs[t+256] = bf2f(xr[t+256]);
  }
  __syncthreads();

  {
    const u16* wrr = wqt + (size_t)(h*64 + lane)*DIMM + wid*128;
    float a = 0.f;
    #pragma unroll
    for (int k = 0; k < 128; k += 8){
      bf16x8 wv = *(const bf16x8*)(wrr + k);
      int kb = wid*128 + k;
      #pragma unroll
      for (int i = 0; i < 8; ++i) a += xs[kb+i] * bf2f((u16)wv[i]);
    }
    red[wid][lane] = a;
  }
  __syncthreads();
  if (t < 64) qs[t] = (red[0][t] + red[1][t] + red[2][t] + red[3][t]) * 0.125f;
  __syncthreads();

  int jj = jz*256 + t;
  int j = (jj < 768) ? jj : jj + 16;
  float a = 0.f;
  {
    const float* kr = kv + ((size_t)(b*NTOK + j))*1024 + h*64;
    #pragma unroll
    for (int d = 0; d < 64; d += 4){
      float4 kd = *(const float4*)(kr + d);
      a += qs[d]*kd.x + qs[d+1]*kd.y + qs[d+2]*kd.z + qs[d+3]*kd.w;
    }
  }

  float m = a;
  #pragma unroll
  for (int off = 32; off >= 1; off >>= 1) m = fmaxf(m, __shfl_xor(m, off));
  if (lane == 0) redm[wid] = m;
  __syncthreads();
  m = fmaxf(fmaxf(redm[0], redm[1]), fmaxf(redm[2], redm[3]));
  float p = __expf(a - m);
  pl[t] = p;
  float sq = p;
  #pragma unroll
  for (int off = 32; off >= 1; off >>= 1) sq += __shfl_xor(sq, off);
  if (lane == 0) redm[wid] = sq;
  __syncthreads();

  {
    int j0 = wid * 64;
    const float* vb = kv + ((size_t)(b*NTOK + jz*256 + j0 + ((jz*256 + j0 >= 768) ? 16 : 0)))*1024
                      + 512 + h*64 + lane;
    float a0=0.f, a1=0.f, a2=0.f, a3=0.f;
    #pragma unroll 4
    for (int i = 0; i < 64; i += 4){
      const float* vp = vb + (size_t)i*1024;
      a0 += pl[j0+i]   * vp[0];
      a1 += pl[j0+i+1] * vp[1024];
      a2 += pl[j0+i+2] * vp[2048];
      a3 += pl[j0+i+3] * vp[3072];
    }
    red[wid][lane] = a0+a1+a2+a3;
  }
  __syncthreads();
  float* po = apart + ((((size_t)jz*BATCH + b)*8 + h)*16 + qi) * 68;
  if (t < 64) po[t] = red[0][t] + red[1][t] + red[2][t] + red[3][t];
  else if (t == 64) po[64] = m;
  else if (t == 65) po[65] = redm[0] + redm[1] + redm[2] + redm[3];
}

// ------- attn_out: merge flash partials + colmean row + wo-projection, fused -------
// grid (8 colchunks, BATCH, 4 row-groups); rows: g0={0..4}, g1={5..8}, g2={9..12}, g3={13..16}
__global__ __launch_bounds__(256) void attn_out(
    const float* __restrict__ apart, const float* __restrict__ csum,
    const u16* __restrict__ wot, float* __restrict__ proj)
{
  int colchunk = blockIdx.x;
  int b = blockIdx.y;
  int rg = blockIdx.z;
  int r0 = (rg == 0) ? 0 : (1 + 4*rg);
  int nr = (rg == 0) ? 5 : 4;
  __shared__ float zbl[5][512];
  __shared__ float red[4][64];
  int t = threadIdx.x;

  for (int rr = 0; rr < nr; ++rr){
    int r = r0 + rr;
    if (r == 0){
      for (int c = t; c < 512; c += 256){
        float s = 0.f;
        #pragma unroll
        for (int bx = 0; bx < 25; ++bx) s += csum[((size_t)(b*25)+bx)*512 + c];
        zbl[rr][c] = s * (1.0f/1552.0f);
      }
    } else {
      int qi = r - 1;
      for (int c = t; c < 512; c += 256){
        int h = c >> 6, d = c & 63;
        size_t base = ((size_t)b*8 + h)*16 + qi;
        float mz[AZ], sz[AZ];
        float M = -3.4e38f;
        #pragma unroll
        for (int z = 0; z < AZ; ++z){
          const float* po = apart + ((size_t)z*BATCH*8*16 + base)*68;
          mz[z] = po[64]; sz[z] = po[65];
          M = fmaxf(M, mz[z]);
        }
        float S = 0.f, O = 0.f;
        #pragma unroll
        for (int z = 0; z < AZ; ++z){
          const float* po = apart + ((size_t)z*BATCH*8*16 + base)*68;
          float wz = __expf(mz[z] - M);
          S += sz[z]*wz; O += po[d]*wz;
        }
        zbl[rr][c] = O / S;
      }
    }
  }
  __syncthreads();

  int col = colchunk*64 + (t & 63);
  int kq = t >> 6;
  const u16* wrow = wot + (size_t)col*512 + kq*128;
  for (int rr = 0; rr < nr; ++rr){
    float a = 0.f;
    #pragma unroll
    for (int k = 0; k < 128; k += 8){
      bf16x8 wv = *(const bf16x8*)(wrow + k);
      #pragma unroll
      for (int i = 0; i < 8; ++i) a += zbl[rr][kq*128 + k + i] * bf2f((u16)wv[i]);
    }
    red[kq][t & 63] = a;
    __syncthreads();
    if (t < 64)
      proj[((size_t)(b*17) + r0 + rr)*DIMM + colchunk*64 + t] =
        red[0][t] + red[1][t] + red[2][t] + red[3][t];
    __syncthreads();
  }
}

// ------- pool_final: csum->mv, LN+q2, 16-key attention, wo-matvec + residual, fused -------
// grid (8 colchunks, 6 br). ILP-optimized mat-vecs (float4 weights, k-split + LDS reduce).
__global__ __launch_bounds__(256) void pool_final(
    const float* __restrict__ csum, const float* __restrict__ rt,
    const float* __restrict__ pg, const float* __restrict__ wq,
    const float* __restrict__ kv, const float* __restrict__ wo,
    float* __restrict__ out)
{
  int colchunk = blockIdx.x;
  int br = blockIdx.y; int b = br/3, r = br%3;
  __shared__ float ys[512];
  __shared__ float q2l[512];
  __shared__ float qred[2][512];
  __shared__ float fred[16][64];
  __shared__ float sm[8][16];
  __shared__ float pn[8][16];
  __shared__ float rs_[4], rss_[4];
  int t = threadIdx.x;

  if (r < 2){
    float a0 = 0.f, a1 = 0.f;
    #pragma unroll
    for (int bx = 0; bx < 25; ++bx){
      a0 += csum[((size_t)(b*25)+bx)*512 + t];
      a1 += csum[((size_t)(b*25)+bx)*512 + t + 256];
    }
    ys[t] = a0 * (1.0f/1552.0f);
    ys[t+256] = a1 * (1.0f/1552.0f);
    __syncthreads();
  } else {
    // LN of return-token 2
    const float* x = rt + 2*DIMM;
    float v0 = x[t], v1 = x[t+256];
    float s = v0 + v1, ss = v0*v0 + v1*v1;
    #pragma unroll
    for (int off = 32; off >= 1; off >>= 1){ s += __shfl_xor(s, off); ss += __shfl_xor(ss, off); }
    int w = t >> 6;
    if ((t & 63) == 0){ rs_[w] = s; rss_[w] = ss; }
    __syncthreads();
    s = rs_[0]+rs_[1]+rs_[2]+rs_[3];
    ss = rss_[0]+rss_[1]+rss_[2]+rss_[3];
    float mu = s / DIMM;
    float rstd = rsqrtf(ss / DIMM - mu*mu + 1e-5f);
    ys[t]     = (v0 - mu)*rstd*pg[t];
    ys[t+256] = (v1 - mu)*rstd*pg[t+256];
    __syncthreads();
    // q2 = 0.125 * ys @ wq : float4 cols (4/thread), 2-way k-split, LDS reduce
    {
      int c4 = (t & 127) * 4;
      int kq = t >> 7;           // 0..1
      float ax=0.f, ay=0.f, az=0.f, aw=0.f;
      #pragma unroll 8
      for (int k = kq*256; k < kq*256 + 256; ++k){
        float yv = ys[k];
        float4 w4 = *(const float4*)(wq + (size_t)k*512 + c4);
        ax += yv*w4.x; ay += yv*w4.y; az += yv*w4.z; aw += yv*w4.w;
      }
      qred[kq][c4] = ax; qred[kq][c4+1] = ay; qred[kq][c4+2] = az; qred[kq][c4+3] = aw;
    }
    __syncthreads();
    q2l[t]     = (qred[0][t]     + qred[1][t])     * 0.125f;
    q2l[t+256] = (qred[0][t+256] + qred[1][t+256]) * 0.125f;
    __syncthreads();
    // sims over 16 fusion keys
    if (t < 128){
      int h = t >> 4, j = t & 15;
      const float* kr = kv + ((size_t)(b*NTOK + 768 + j))*1024 + h*64;
      float a = 0.f;
      #pragma unroll
      for (int d = 0; d < 64; ++d) a += q2l[h*64 + d] * kr[d];
      sm[h][j] = a;
    }
    __syncthreads();
    if (t < 8){
      float m = -3.4e38f;
      #pragma unroll
      for (int j = 0; j < 16; ++j) m = fmaxf(m, sm[t][j]);
      float e[16]; float s2 = 0.f;
      #pragma unroll
      for (int j = 0; j < 16; ++j){ e[j] = __expf(sm[t][j] - m); s2 += e[j]; }
      float inv = 1.0f / s2;
      #pragma unroll
      for (int j = 0; j < 16; ++j) pn[t][j] = e[j] * inv;
    }
    __syncthreads();
    // out2 -> ys
    {
      int c0 = t, c1 = t + 256;
      int h0 = c0 >> 6, h1 = c1 >> 6;
      float a0 = 0.f, a1 = 0.f;
      #pragma unroll
      for (int j = 0; j < 16; ++j){
        const float* vr = kv + ((size_t)(b*NTOK + 768 + j))*1024 + 512;
        a0 += pn[h0][j] * vr[c0];
        a1 += pn[h1][j] * vr[c1];
      }
      ys[c0] = a0; ys[c1] = a1;
    }
    __syncthreads();
  }

  // final: out[br][col] = ys @ wo + rt[r]
  // float4 cols (4/thread over the 64-col chunk), 16-way k-split (32 k each), LDS reduce
  {
    int c4l = (t & 15) * 4;                   // local col group 0..60
    int c4 = colchunk*64 + c4l;
    int kq = t >> 4;                          // 0..15
    float ax=0.f, ay=0.f, az=0.f, aw=0.f;
    #pragma unroll 8
    for (int k = kq*32; k < kq*32 + 32; ++k){
      float yv = ys[k];
      float4 w4 = *(const float4*)(wo + (size_t)k*512 + c4);
      ax += yv*w4.x; ay += yv*w4.y; az += yv*w4.z; aw += yv*w4.w;
    }
    fred[kq][c4l] = ax; fred[kq][c4l+1] = ay; fred[kq][c4l+2] = az; fred[kq][c4l+3] = aw;
  }
  __syncthreads();
  if (t < 64){
    float a = 0.f;
    #pragma unroll
    for (int kq = 0; kq < 16; ++kq) a += fred[kq][t];
    int c = colchunk*64 + t;
    out[(size_t)br*DIMM + c] = a + rt[(size_t)r*DIMM + c];
  }
}

// =================================================================
extern "C" void kernel_launch(void* const* d_in, const int* in_sizes, int n_in,
                              void* d_out, int out_size, void* d_ws, size_t ws_size,
                              hipStream_t stream)
{
  const float* rna        = (const float*)d_in[0];
  const float* atac       = (const float*)d_in[1];
  const float* rna_ln1_g  = (const float*)d_in[2];
  const float* rna_ln1_b  = (const float*)d_in[3];
  const float* rna_w      = (const float*)d_in[4];
  const float* rna_b      = (const float*)d_in[5];
  const float* rna_ln2_g  = (const float*)d_in[6];
  const float* rna_ln2_b  = (const float*)d_in[7];
  const float* atac_ln1_g = (const float*)d_in[8];
  const float* atac_ln1_b = (const float*)d_in[9];
  const float* atac_w     = (const float*)d_in[10];
  const float* atac_b     = (const float*)d_in[11];
  const float* atac_ln2_g = (const float*)d_in[12];
  const float* atac_ln2_b = (const float*)d_in[13];
  const float* fusion_tok = (const float*)d_in[14];
  const float* lay_ag     = (const float*)d_in[15];
  const float* lay_wq     = (const float*)d_in[16];
  const float* lay_wkv    = (const float*)d_in[17];
  const float* lay_wo     = (const float*)d_in[18];
  const float* lay_fg     = (const float*)d_in[19];
  const float* lay_w1     = (const float*)d_in[20];
  const float* lay_w2     = (const float*)d_in[21];
  const float* final_g    = (const float*)d_in[22];
  const float* ret_tok    = (const float*)d_in[23];
  const float* pool_g     = (const float*)d_in[24];
  const float* pool_wq    = (const float*)d_in[25];
  const float* pool_wkv   = (const float*)d_in[26];
  const float* pool_wo    = (const float*)d_in[27];

  uint8_t* ws = (uint8_t*)d_ws;
  size_t off = 0;
  auto carve = [&](size_t bytes) -> uint8_t* {
    uint8_t* p = ws + off;
    off += (bytes + 255) & ~(size_t)255;
    return p;
  };
  // bf16 weights
  u16* rna_wt   = (u16*)carve((size_t)512*1024*2);
  u16* atac_wt  = (u16*)carve((size_t)512*1024*2);
  u16* wkvt     = (u16*)carve((size_t)4*1024*512*2);
  u16* wqt      = (u16*)carve((size_t)4*512*512*2);
  u16* wot      = (u16*)carve((size_t)4*512*512*2);
  u16* w1t      = (u16*)carve((size_t)4*NW1*512*2);
  u16* w2t      = (u16*)carve((size_t)4*512*GSTRIDE*2);
  u16* pool_wkvt= (u16*)carve((size_t)1024*512*2);
  // activations
  float* tok   = (float*)carve((size_t)MALL * DIMM * 4);
  u16*   xn    = (u16*)  carve((size_t)MALL * DIMM * 2);
  float* kv    = (float*)carve((size_t)MALL * 1024 * 4);
  u16*   lnbuf = (u16*)  carve((size_t)3072 * 1024 * 2);
  float* proj  = (float*)carve((size_t)BATCH*17*DIMM * 4);
  float* csum  = (float*)carve((size_t)BATCH*25*512 * 4);
  float* apart = (float*)carve((size_t)AZ*BATCH*8*16*68 * 4);
  u16*   gbuf  = (u16*)  carve((size_t)MALL * GSTRIDE * 2);
  float* skpart= (float*)carve((size_t)2 * MALL * 512 * 4);
  (void)ws_size;

  // ---- one-dispatch weight conversion ----
  convall<<<14080, 256, 0, stream>>>(rna_w, atac_w, lay_wkv, lay_wq, lay_wo, lay_w1, lay_w2, pool_wkv,
                                     rna_wt, atac_wt, wkvt, wqt, wot, w1t, w2t, pool_wkvt);

  // ---- embeddings (both modalities batched; layer-0 LN fused into tails) ----
  embed_ln1<<<3072, 256, 0, stream>>>(rna, atac, rna_ln1_g, rna_ln1_b, atac_ln1_g, atac_ln1_b, lnbuf);
  gemm512<<<dim3(24, 4, 2), 512, 0, stream>>>(lnbuf, 1024, rna_wt, atac_wt, 1536, 1024,
                                              skpart, 512, (size_t)3072*512, nullptr, nullptr,
                                              3072, 512, 1024, 512);
  embed_addln2<<<3072, 256, 0, stream>>>(skpart, rna_b, atac_b, rna_ln2_g, rna_ln2_b,
                                         atac_ln2_g, atac_ln2_b, lay_ag, tok, xn);
  fuscopy_ln<<<32, 256, 0, stream>>>(fusion_tok, lay_ag, tok, xn);

  // ---- transformer layers ----
  for (int l = 0; l < 4; ++l){
    const float* fg  = lay_fg + (size_t)l*DIMM;
    const float* gnext = (l < 3) ? (lay_ag + (size_t)(l+1)*DIMM) : final_g;
    const u16* wkvt_l = wkvt + (size_t)l*1024*512;
    const u16* wqt_l  = wqt  + (size_t)l*512*512;
    const u16* wot_l  = wot  + (size_t)l*512*512;
    const u16* w1t_l  = w1t  + (size_t)l*NW1*512;
    const u16* w2t_l  = w2t  + (size_t)l*512*GSTRIDE;

    gemm512<<<dim3(25, 8, 1), 512, 0, stream>>>(xn, 512, wkvt_l, nullptr, 0, 512,
                                                kv, 1024, 0, nullptr, csum, MALL, 1024, 512, 512);
    fused_attn<<<dim3(8, BATCH, 16*AZ), 256, 0, stream>>>(xn, wqt_l, kv, apart);
    attn_out<<<dim3(8, BATCH, 4), 256, 0, stream>>>(apart, csum, wot_l, proj);
    resadd_ffnln<<<dim3(NTOK, BATCH), 256, 0, stream>>>(tok, proj, fg, xn);
    gemm512<<<dim3(25, 22, 1), 512, 0, stream>>>(xn, 512, w1t_l, nullptr, 0, 512,
                                                 nullptr, 0, 0, gbuf, nullptr, MALL, NW1, 512, 512);
    gemm512<<<dim3(25, 4, 2), 512, 0, stream>>>(gbuf, GSTRIDE, w2t_l, nullptr, 0, GSTRIDE,
                                                skpart, 512, (size_t)MALL*512, nullptr, nullptr,
                                                MALL, 512, GSTRIDE, 704);
    skadd_ln<<<MALL, 256, 0, stream>>>(tok, skpart, gnext, xn);
  }

  // ---- pooling (xn holds final-LN tokens) ----
  gemm512<<<dim3(25, 8, 1), 512, 0, stream>>>(xn, 512, pool_wkvt, nullptr, 0, 512,
                                              kv, 1024, 0, nullptr, csum, MALL, 1024, 512, 512);
  pool_final<<<dim3(8, 6), 256, 0, stream>>>(csum, ret_tok, pool_g, pool_wq, kv, pool_wo,
                                             (float*)d_out);
}

// Round 12
// 540.628 us; speedup vs baseline: 6.0837x; 1.0154x over previous
//
#include <hip/hip_runtime.h>
#include <stdint.h>
#include <stddef.h>

#define NTOK 1552
#define DIMM 512
#define IFFC 1365
#define IFF2 2730
#define NW1 2816       // padded/permuted w1 output cols (2*1408)
#define GSTRIDE 1408   // geglu output row stride (bf16) = padded K of w2
#define BATCH 2
#define MALL (BATCH*NTOK)   // 3104
#define AZ 6           // attention j-chunks (256 keys each)

typedef unsigned short u16;
typedef __attribute__((ext_vector_type(8))) short bf16x8;
typedef __attribute__((ext_vector_type(4))) float f32x4;

__device__ __forceinline__ u16 f2bf(float f){
  union { float f; uint32_t u; } v; v.f = f;
  uint32_t u = v.u;
  uint32_t r = (u + 0x7FFFu + ((u >> 16) & 1u)) >> 16;
  return (u16)r;
}
__device__ __forceinline__ float bf2f(u16 x){
  union { uint32_t u; float f; } v; v.u = ((uint32_t)x) << 16; return v.f;
}

// async global->LDS, 16B per lane; LDS dest is wave-uniform base (lane*16 implicit)
__device__ __forceinline__ void gload_lds16(const u16* g, u16* l){
  __builtin_amdgcn_global_load_lds((const __attribute__((address_space(1))) void*)g,
                                   (__attribute__((address_space(3))) void*)l, 16, 0, 0);
}

// ---------- one-dispatch weight convert/transpose (8 segments), vectorized ----------
__global__ void convall(const float* s0,const float* s1,const float* s2,const float* s3,
                        const float* s4,const float* s5,const float* s6,const float* s7,
                        u16* d0,u16* d1,u16* d2,u16* d3,u16* d4,u16* d5,u16* d6,u16* d7)
{
  const float* srcs[8] = {s0,s1,s2,s3,s4,s5,s6,s7};
  u16* dsts[8] = {d0,d1,d2,d3,d4,d5,d6,d7};
  const int KT[8]   = {32,32,16,16,16,16,44,16};
  const int NT[8]   = {16,16,32,16,16,88,16,32};
  const int TC[8]   = {512,512,2048,1024,1024,5632,2816,512};
  const int K_[8]   = {1024,1024,512,512,512,512,1365,512};
  const int NSRC[8] = {512,512,1024,512,512,2730,512,1024};
  const int LDK[8]  = {1024,1024,512,512,512,512,1408,512};
  const int NOUT[8] = {512,512,1024,512,512,2816,512,1024};
  const int WS_[8]  = {0,0,512*1024,512*512,512*512,512*2730,1365*512,0};
  const int WT_[8]  = {0,0,1024*512,512*512,512*512,2816*512,512*1408,0};

  int bid = blockIdx.x;
  int seg = 0, base = 0;
  while (seg < 7 && bid >= base + TC[seg]) { base += TC[seg]; ++seg; }
  int loc = bid - base;
  int kt = KT[seg];
  int z = loc / (kt*NT[seg]); loc -= z*(kt*NT[seg]);
  int kb = (loc % kt) * 32, nb = (loc / kt) * 32;
  const float* w = srcs[seg] + (size_t)z * WS_[seg];
  u16* wt = dsts[seg] + (size_t)z * WT_[seg];
  int K = K_[seg], NS = NSRC[seg], ldk = LDK[seg], NO = NOUT[seg];

  __shared__ float tile[32][33];
  int t = threadIdx.x;
  {
    int k = t >> 3, n4 = (t & 7) * 4;
    int gk = kb + k;
    float4 v = make_float4(0.f,0.f,0.f,0.f);
    if (gk < K){
      if (seg != 5){
        int gn = nb + n4;
        if (gn + 4 <= NS){
          v = *(const float4*)(w + (size_t)gk*NS + gn);
        } else {
          float* pv = (float*)&v;
          #pragma unroll
          for (int i = 0; i < 4; ++i){ int n = gn + i; if (n < NS) pv[i] = w[(size_t)gk*NS + n]; }
        }
      } else {
        float* pv = (float*)&v;
        #pragma unroll
        for (int i = 0; i < 4; ++i){
          int n = nb + n4 + i;
          if (n < NO){
            int bb = n >> 7, rr = n & 127, g = rr >> 5, hh = rr & 31;
            int j = bb*64 + g*16 + (hh & 15);
            if (j < 1365) pv[i] = w[(size_t)gk*NS + ((hh < 16) ? j : 1365 + j)];
          }
        }
      }
    }
    tile[k][n4] = v.x; tile[k][n4+1] = v.y; tile[k][n4+2] = v.z; tile[k][n4+3] = v.w;
  }
  __syncthreads();
  if (t < 128){
    int n = t >> 2, k8 = (t & 3) * 8;
    int gn = nb + n, gk = kb + k8;
    if (gn < NO && gk < ldk){
      u16 sh[8];
      #pragma unroll
      for (int i = 0; i < 8; ++i) sh[i] = f2bf(tile[k8+i][n]);
      *(bf16x8*)(wt + (size_t)gn*ldk + gk) = *(bf16x8*)sh;
    }
  }
}

// ---- batched embed LN1 (rna rows 0..1535, atac rows 1536..3071) ----
__global__ void embed_ln1(const float* __restrict__ rna, const float* __restrict__ atac,
                          const float* __restrict__ g0, const float* __restrict__ b0,
                          const float* __restrict__ g1, const float* __restrict__ b1,
                          u16* __restrict__ out)
{
  int r = blockIdx.x;
  const float* x; const float* g; const float* bb;
  if (r < 1536){ x = rna + (size_t)r*1024; g = g0; bb = b0; }
  else { x = atac + (size_t)(r-1536)*1024; g = g1; bb = b1; }
  float s = 0.f, ss = 0.f;
  int t = threadIdx.x;
  float v0 = x[t], v1 = x[t+256], v2 = x[t+512], v3 = x[t+768];
  s = v0+v1+v2+v3; ss = v0*v0+v1*v1+v2*v2+v3*v3;
  #pragma unroll
  for (int off = 32; off >= 1; off >>= 1){ s += __shfl_xor(s, off); ss += __shfl_xor(ss, off); }
  __shared__ float rs_[4], rss_[4];
  int w = t >> 6;
  if ((t & 63) == 0){ rs_[w] = s; rss_[w] = ss; }
  __syncthreads();
  s = rs_[0]+rs_[1]+rs_[2]+rs_[3];
  ss = rss_[0]+rss_[1]+rss_[2]+rss_[3];
  float mu = s / 1024.f;
  float rstd = rsqrtf(ss / 1024.f - mu*mu + 1e-5f);
  u16* o = out + (size_t)r*1024;
  o[t]     = f2bf((v0-mu)*rstd*g[t]     + bb[t]);
  o[t+256] = f2bf((v1-mu)*rstd*g[t+256] + bb[t+256]);
  o[t+512] = f2bf((v2-mu)*rstd*g[t+512] + bb[t+512]);
  o[t+768] = f2bf((v3-mu)*rstd*g[t+768] + bb[t+768]);
}

// ---- batched embed: splitK add + bias + LN2 -> tok, then layer-0 attn-LN -> xn ----
__global__ void embed_addln2(const float* __restrict__ part,
                             const float* __restrict__ rb, const float* __restrict__ ab,
                             const float* __restrict__ g0, const float* __restrict__ bt0,
                             const float* __restrict__ g1, const float* __restrict__ bt1,
                             const float* __restrict__ ag0,
                             float* __restrict__ tok, u16* __restrict__ xn)
{
  int r = blockIdx.x;          // 0..3071
  int mod = (r >= 1536);
  int rl = mod ? r - 1536 : r;
  int b = rl / 768, rr = rl % 768;
  const float* bias = mod ? ab : rb;
  const float* g = mod ? g1 : g0;
  const float* bt = mod ? bt1 : bt0;
  const float* p0 = part + (size_t)r*DIMM;
  const float* p1 = p0 + (size_t)3072*DIMM;
  int t = threadIdx.x;
  float v0 = p0[t] + p1[t] + bias[t];
  float v1 = p0[t+256] + p1[t+256] + bias[t+256];
  float s = v0 + v1, ss = v0*v0 + v1*v1;
  #pragma unroll
  for (int off = 32; off >= 1; off >>= 1){ s += __shfl_xor(s, off); ss += __shfl_xor(ss, off); }
  __shared__ float rs_[4], rss_[4];
  int w = t >> 6;
  if ((t & 63) == 0){ rs_[w] = s; rss_[w] = ss; }
  __syncthreads();
  s = rs_[0]+rs_[1]+rs_[2]+rs_[3];
  ss = rss_[0]+rss_[1]+rss_[2]+rss_[3];
  float mu = s / DIMM;
  float rstd = rsqrtf(ss / DIMM - mu*mu + 1e-5f);
  size_t row = (size_t)(b*NTOK + (mod ? 784 : 0) + rr)*DIMM;
  float t0 = (v0 - mu)*rstd*g[t]     + bt[t];
  float t1 = (v1 - mu)*rstd*g[t+256] + bt[t+256];
  tok[row + t] = t0; tok[row + t+256] = t1;
  float s2 = t0 + t1, ss2 = t0*t0 + t1*t1;
  #pragma unroll
  for (int off = 32; off >= 1; off >>= 1){ s2 += __shfl_xor(s2, off); ss2 += __shfl_xor(ss2, off); }
  __syncthreads();
  if ((t & 63) == 0){ rs_[w] = s2; rss_[w] = ss2; }
  __syncthreads();
  s2 = rs_[0]+rs_[1]+rs_[2]+rs_[3];
  ss2 = rss_[0]+rss_[1]+rss_[2]+rss_[3];
  float mu2 = s2 / DIMM;
  float rstd2 = rsqrtf(ss2 / DIMM - mu2*mu2 + 1e-5f);
  xn[row + t]     = f2bf((t0 - mu2)*rstd2*ag0[t]);
  xn[row + t+256] = f2bf((t1 - mu2)*rstd2*ag0[t+256]);
}

// ---- fusion tokens -> tok rows + layer-0 attn-LN -> xn ----
__global__ void fuscopy_ln(const float* __restrict__ ft, const float* __restrict__ ag0,
                           float* __restrict__ tok, u16* __restrict__ xn)
{
  int bid = blockIdx.x;       // 0..31
  int b = bid >> 4, rr = bid & 15;
  int t = threadIdx.x;
  const float* x = ft + (size_t)rr*DIMM;
  float v0 = x[t], v1 = x[t+256];
  size_t row = (size_t)(b*NTOK + 768 + rr)*DIMM;
  tok[row + t] = v0; tok[row + t+256] = v1;
  float s = v0 + v1, ss = v0*v0 + v1*v1;
  #pragma unroll
  for (int off = 32; off >= 1; off >>= 1){ s += __shfl_xor(s, off); ss += __shfl_xor(ss, off); }
  __shared__ float rs_[4], rss_[4];
  int w = t >> 6;
  if ((t & 63) == 0){ rs_[w] = s; rss_[w] = ss; }
  __syncthreads();
  s = rs_[0]+rs_[1]+rs_[2]+rs_[3];
  ss = rss_[0]+rss_[1]+rss_[2]+rss_[3];
  float mu = s / DIMM;
  float rstd = rsqrtf(ss / DIMM - mu*mu + 1e-5f);
  xn[row + t]     = f2bf((v0 - mu)*rstd*ag0[t]);
  xn[row + t+256] = f2bf((v1 - mu)*rstd*ag0[t+256]);
}

// ---- residual-add (attention proj, broadcast row0) + FFN LN -> tok, xn ----
__global__ void resadd_ffnln(float* __restrict__ tok, const float* __restrict__ proj,
                             const float* __restrict__ g, u16* __restrict__ xn)
{
  int n = blockIdx.x, b = blockIdx.y;
  int pr = (n >= 768 && n < 784) ? (1 + n - 768) : 0;
  const float* p = proj + ((size_t)b*17 + pr)*DIMM;
  size_t row = (size_t)(b*NTOK + n)*DIMM;
  int t = threadIdx.x;
  float v0 = tok[row + t]     + p[t];
  float v1 = tok[row + t+256] + p[t+256];
  tok[row + t] = v0; tok[row + t+256] = v1;
  float s = v0 + v1, ss = v0*v0 + v1*v1;
  #pragma unroll
  for (int off = 32; off >= 1; off >>= 1){ s += __shfl_xor(s, off); ss += __shfl_xor(ss, off); }
  __shared__ float rs_[4], rss_[4];
  int w = t >> 6;
  if ((t & 63) == 0){ rs_[w] = s; rss_[w] = ss; }
  __syncthreads();
  s = rs_[0]+rs_[1]+rs_[2]+rs_[3];
  ss = rss_[0]+rss_[1]+rss_[2]+rss_[3];
  float mu = s / DIMM;
  float rstd = rsqrtf(ss / DIMM - mu*mu + 1e-5f);
  xn[row + t]     = f2bf((v0 - mu)*rstd*g[t]);
  xn[row + t+256] = f2bf((v1 - mu)*rstd*g[t+256]);
}

// ---- splitK-add (FFN out) + next LN -> tok, xn ----
__global__ void skadd_ln(float* __restrict__ tok, const float* __restrict__ part,
                         const float* __restrict__ g, u16* __restrict__ xn)
{
  int r = blockIdx.x;
  size_t row = (size_t)r*DIMM;
  const float* p0 = part + row;
  const float* p1 = p0 + (size_t)MALL*DIMM;
  int t = threadIdx.x;
  float v0 = tok[row + t]     + p0[t]     + p1[t];
  float v1 = tok[row + t+256] + p0[t+256] + p1[t+256];
  tok[row + t] = v0; tok[row + t+256] = v1;
  float s = v0 + v1, ss = v0*v0 + v1*v1;
  #pragma unroll
  for (int off = 32; off >= 1; off >>= 1){ s += __shfl_xor(s, off); ss += __shfl_xor(ss, off); }
  __shared__ float rs_[4], rss_[4];
  int w = t >> 6;
  if ((t & 63) == 0){ rs_[w] = s; rss_[w] = ss; }
  __syncthreads();
  s = rs_[0]+rs_[1]+rs_[2]+rs_[3];
  ss = rss_[0]+rss_[1]+rss_[2]+rss_[3];
  float mu = s / DIMM;
  float rstd = rsqrtf(ss / DIMM - mu*mu + 1e-5f);
  xn[row + t]     = f2bf((v0 - mu)*rstd*g[t]);
  xn[row + t+256] = f2bf((v1 - mu)*rstd*g[t+256]);
}

// ------- gemm512: 8-wave 128x128; 2-phase double-buffered global_load_lds staging.
//         B bf16 [N][ldk]; optional B-switch at row mswitch; splitK via grid.z;
//         optional GEGLU epilogue; optional V-colsum. OOB clamped (outputs masked). -------
__global__ __launch_bounds__(512) void gemm512(
    const u16* __restrict__ A, int lda,
    const u16* __restrict__ Bt, const u16* __restrict__ BtB, int mswitch, int ldk,
    float* __restrict__ C, int ldc, size_t Cz,
    u16* __restrict__ gout, float* __restrict__ csum,
    int M, int Nn, int K, int kchunk)
{
  __shared__ __align__(16) u16 As_lin[2][128*32];
  __shared__ __align__(16) u16 Bs_lin[2][128*32];
  __shared__ float colsum[2][128];
  const int t = threadIdx.x;
  const int lane = t & 63;
  const int w = t >> 6;
  const int wr = (w >> 2) * 64;
  const int wc = (w & 3) * 32;
  const int row0 = blockIdx.x * 128, col0 = blockIdx.y * 128;
  if (BtB && row0 >= mswitch) Bt = BtB;
  const int z = blockIdx.z;
  const int kbeg = z * kchunk;
  const int kend = (kbeg + kchunk < K) ? (kbeg + kchunk) : K;
  C += (size_t)z * Cz;
  const int l15 = lane & 15;
  const int l4 = (lane >> 4) * 8;
  const int sr = t >> 2, sc8 = (t & 3) * 8;
  int gr_s = row0 + sr; if (gr_s >= M) gr_s = M - 1;
  int gc_s = col0 + sr; if (gc_s >= Nn) gc_s = Nn - 1;
  const u16* Ag = A + (size_t)gr_s*lda + sc8;
  const u16* Bg = Bt + (size_t)gc_s*ldk + sc8;
  const int wb = w * 512;   // wave-uniform LDS word base

  f32x4 acc[4][2];
  #pragma unroll
  for (int m = 0; m < 4; ++m)
    #pragma unroll
    for (int n = 0; n < 2; ++n)
      #pragma unroll
      for (int j = 0; j < 4; ++j) acc[m][n][j] = 0.f;

  // prologue: stage first tile into buffer 0
  gload_lds16(Ag + kbeg, &As_lin[0][wb]);
  gload_lds16(Bg + kbeg, &Bs_lin[0][wb]);
  __syncthreads();

  int cur = 0;
  for (int k0 = kbeg; k0 < kend; k0 += 32) {
    // issue next tile's staging BEFORE computing current (latency hides under MFMA)
    int k1 = k0 + 32;
    if (k1 < kend){
      gload_lds16(Ag + k1, &As_lin[cur^1][wb]);
      gload_lds16(Bg + k1, &Bs_lin[cur^1][wb]);
    }
    const u16* Ar = &As_lin[cur][0];
    const u16* Br = &Bs_lin[cur][0];
    bf16x8 af[4], bfr[2];
    #pragma unroll
    for (int m = 0; m < 4; ++m) af[m]  = *(const bf16x8*)(&Ar[(wr + m*16 + l15)*32 + l4]);
    #pragma unroll
    for (int n = 0; n < 2; ++n) bfr[n] = *(const bf16x8*)(&Br[(wc + n*16 + l15)*32 + l4]);
    #pragma unroll
    for (int m = 0; m < 4; ++m)
      #pragma unroll
      for (int n = 0; n < 2; ++n)
        acc[m][n] = __builtin_amdgcn_mfma_f32_16x16x32_bf16(af[m], bfr[n], acc[m][n], 0, 0, 0);
    // one barrier per tile: drains vmcnt (next tile landed) + lgkmcnt (our reads done)
    __syncthreads();
    cur ^= 1;
  }
  const int rb = (lane >> 4) * 4;
  if (gout){
    int jcol = (col0 >> 1) + (w & 3)*16 + l15;
    #pragma unroll
    for (int m = 0; m < 4; ++m){
      int gr0 = row0 + wr + m*16 + rb;
      #pragma unroll
      for (int j = 0; j < 4; ++j){
        int gr = gr0 + j;
        if (gr < M){
          float gt = acc[m][1][j];
          float ge = 0.5f * gt * (1.0f + erff(gt * 0.70710678118654752f));
          gout[(size_t)gr*GSTRIDE + jcol] = f2bf(ge * acc[m][0][j]);
        }
      }
    }
  } else {
    #pragma unroll
    for (int m = 0; m < 4; ++m){
      int gr0 = row0 + wr + m*16 + rb;
      #pragma unroll
      for (int n = 0; n < 2; ++n){
        int gc = col0 + wc + n*16 + l15;
        if (gc >= Nn) continue;
        #pragma unroll
        for (int j = 0; j < 4; ++j){
          int gr = gr0 + j;
          if (gr < M) C[(size_t)gr*ldc + gc] = acc[m][n][j];
        }
      }
    }
  }
  if (csum && col0 >= 512){
    if (t < 256) colsum[t>>7][t&127] = 0.f;
    __syncthreads();
    #pragma unroll
    for (int n = 0; n < 2; ++n){
      float lv0 = 0.f, lv1 = 0.f;
      #pragma unroll
      for (int m = 0; m < 4; ++m){
        int gr0 = row0 + wr + m*16 + rb;
        #pragma unroll
        for (int j = 0; j < 4; ++j){
          float v = acc[m][n][j];
          if (gr0 + j < NTOK) lv0 += v; else lv1 += v;
        }
      }
      int lc = wc + n*16 + l15;
      atomicAdd(&colsum[0][lc], lv0);
      atomicAdd(&colsum[1][lc], lv1);
    }
    __syncthreads();
    if (t < 256){
      int bb = t>>7, c = t&127;
      csum[((size_t)(bb*25) + blockIdx.x)*512 + (col0 - 512) + c] = colsum[bb][c];
    }
  }
}

// ------- fused attention, flash-split: one block per (h, b, qi, jz); 256 keys/block -------
// apart layout: [((jz*BATCH+b)*8+h)*16+qi] * 68 floats: [0..63]=O_part, [64]=m, [65]=s
__global__ __launch_bounds__(256) void fused_attn(
    const u16* __restrict__ xn, const u16* __restrict__ wqt,
    const float* __restrict__ kv, float* __restrict__ apart)
{
  int h = blockIdx.x, b = blockIdx.y;
  int qi = blockIdx.z / AZ, jz = blockIdx.z % AZ;
  int t = threadIdx.x;
  int lane = t & 63, wid = t >> 6;
  __shared__ float xs[512];
  __shared__ float qs[64];
  __shared__ float pl[256];
  __shared__ float red[4][64];
  __shared__ float redm[4];

  {
    int row = b*NTOK + 768 + qi;
    const u16* xr = xn + (size_t)row*DIMM;
    xs[t] = bf2f(xr[t]);
    xs[t+256] = bf2f(xr[t+256]);
  }
  __syncthreads();

  {
    const u16* wrr = wqt + (size_t)(h*64 + lane)*DIMM + wid*128;
    float a = 0.f;
    #pragma unroll
    for (int k = 0; k < 128; k += 8){
      bf16x8 wv = *(const bf16x8*)(wrr + k);
      int kb = wid*128 + k;
      #pragma unroll
      for (int i = 0; i < 8; ++i) a += xs[kb+i] * bf2f((u16)wv[i]);
    }
    red[wid][lane] = a;
  }
  __syncthreads();
  if (t < 64) qs[t] = (red[0][t] + red[1][t] + red[2][t] + red[3][t]) * 0.125f;
  __syncthreads();

  int jj = jz*256 + t;
  int j = (jj < 768) ? jj : jj + 16;
  float a = 0.f;
  {
    const float* kr = kv + ((size_t)(b*NTOK + j))*1024 + h*64;
    #pragma unroll
    for (int d = 0; d < 64; d += 4){
      float4 kd = *(const float4*)(kr + d);
      a += qs[d]*kd.x + qs[d+1]*kd.y + qs[d+2]*kd.z + qs[d+3]*kd.w;
    }
  }

  float m = a;
  #pragma unroll
  for (int off = 32; off >= 1; off >>= 1) m = fmaxf(m, __shfl_xor(m, off));
  if (lane == 0) redm[wid] = m;
  __syncthreads();
  m = fmaxf(fmaxf(redm[0], redm[1]), fmaxf(redm[2], redm[3]));
  float p = __expf(a - m);
  pl[t] = p;
  float sq = p;
  #pragma unroll
  for (int off = 32; off >= 1; off >>= 1) sq += __shfl_xor(sq, off);
  if (lane == 0) redm[wid] = sq;
  __syncthreads();

  {
    int j0 = wid * 64;
    const float* vb = kv + ((size_t)(b*NTOK + jz*256 + j0 + ((jz*256 + j0 >= 768) ? 16 : 0)))*1024
                      + 512 + h*64 + lane;
    float a0=0.f, a1=0.f, a2=0.f, a3=0.f;
    #pragma unroll 4
    for (int i = 0; i < 64; i += 4){
      const float* vp = vb + (size_t)i*1024;
      a0 += pl[j0+i]   * vp[0];
      a1 += pl[j0+i+1] * vp[1024];
      a2 += pl[j0+i+2] * vp[2048];
      a3 += pl[j0+i+3] * vp[3072];
    }
    red[wid][lane] = a0+a1+a2+a3;
  }
  __syncthreads();
  float* po = apart + ((((size_t)jz*BATCH + b)*8 + h)*16 + qi) * 68;
  if (t < 64) po[t] = red[0][t] + red[1][t] + red[2][t] + red[3][t];
  else if (t == 64) po[64] = m;
  else if (t == 65) po[65] = redm[0] + redm[1] + redm[2] + redm[3];
}

// ------- attn_out: merge flash partials + colmean row + wo-projection, fused -------
// grid (8 colchunks, BATCH, 4 row-groups); rows: g0={0..4}, g1={5..8}, g2={9..12}, g3={13..16}
__global__ __launch_bounds__(256) void attn_out(
    const float* __restrict__ apart, const float* __restrict__ csum,
    const u16* __restrict__ wot, float* __restrict__ proj)
{
  int colchunk = blockIdx.x;
  int b = blockIdx.y;
  int rg = blockIdx.z;
  int r0 = (rg == 0) ? 0 : (1 + 4*rg);
  int nr = (rg == 0) ? 5 : 4;
  __shared__ float zbl[5][512];
  __shared__ float red[4][64];
  int t = threadIdx.x;

  for (int rr = 0; rr < nr; ++rr){
    int r = r0 + rr;
    if (r == 0){
      for (int c = t; c < 512; c += 256){
        float s = 0.f;
        #pragma unroll
        for (int bx = 0; bx < 25; ++bx) s += csum[((size_t)(b*25)+bx)*512 + c];
        zbl[rr][c] = s * (1.0f/1552.0f);
      }
    } else {
      int qi = r - 1;
      for (int c = t; c < 512; c += 256){
        int h = c >> 6, d = c & 63;
        size_t base = ((size_t)b*8 + h)*16 + qi;
        float mz[AZ], sz[AZ];
        float M = -3.4e38f;
        #pragma unroll
        for (int z = 0; z < AZ; ++z){
          const float* po = apart + ((size_t)z*BATCH*8*16 + base)*68;
          mz[z] = po[64]; sz[z] = po[65];
          M = fmaxf(M, mz[z]);
        }
        float S = 0.f, O = 0.f;
        #pragma unroll
        for (int z = 0; z < AZ; ++z){
          const float* po = apart + ((size_t)z*BATCH*8*16 + base)*68;
          float wz = __expf(mz[z] - M);
          S += sz[z]*wz; O += po[d]*wz;
        }
        zbl[rr][c] = O / S;
      }
    }
  }
  __syncthreads();

  int col = colchunk*64 + (t & 63);
  int kq = t >> 6;
  const u16* wrow = wot + (size_t)col*512 + kq*128;
  for (int rr = 0; rr < nr; ++rr){
    float a = 0.f;
    #pragma unroll
    for (int k = 0; k < 128; k += 8){
      bf16x8 wv = *(const bf16x8*)(wrow + k);
      #pragma unroll
      for (int i = 0; i < 8; ++i) a += zbl[rr][kq*128 + k + i] * bf2f((u16)wv[i]);
    }
    red[kq][t & 63] = a;
    __syncthreads();
    if (t < 64)
      proj[((size_t)(b*17) + r0 + rr)*DIMM + colchunk*64 + t] =
        red[0][t] + red[1][t] + red[2][t] + red[3][t];
    __syncthreads();
  }
}

// ------- pool_final: csum->mv, LN+q2, 16-key attention, wo-matvec + residual, fused -------
// grid (8 colchunks, 6 br). ILP-optimized mat-vecs (float4 weights, k-split + LDS reduce).
__global__ __launch_bounds__(256) void pool_final(
    const float* __restrict__ csum, const float* __restrict__ rt,
    const float* __restrict__ pg, const float* __restrict__ wq,
    const float* __restrict__ kv, const float* __restrict__ wo,
    float* __restrict__ out)
{
  int colchunk = blockIdx.x;
  int br = blockIdx.y; int b = br/3, r = br%3;
  __shared__ float ys[512];
  __shared__ float q2l[512];
  __shared__ float qred[2][512];
  __shared__ float fred[16][64];
  __shared__ float sm[8][16];
  __shared__ float pn[8][16];
  __shared__ float rs_[4], rss_[4];
  int t = threadIdx.x;

  if (r < 2){
    float a0 = 0.f, a1 = 0.f;
    #pragma unroll
    for (int bx = 0; bx < 25; ++bx){
      a0 += csum[((size_t)(b*25)+bx)*512 + t];
      a1 += csum[((size_t)(b*25)+bx)*512 + t + 256];
    }
    ys[t] = a0 * (1.0f/1552.0f);
    ys[t+256] = a1 * (1.0f/1552.0f);
    __syncthreads();
  } else {
    const float* x = rt + 2*DIMM;
    float v0 = x[t], v1 = x[t+256];
    float s = v0 + v1, ss = v0*v0 + v1*v1;
    #pragma unroll
    for (int off = 32; off >= 1; off >>= 1){ s += __shfl_xor(s, off); ss += __shfl_xor(ss, off); }
    int w = t >> 6;
    if ((t & 63) == 0){ rs_[w] = s; rss_[w] = ss; }
    __syncthreads();
    s = rs_[0]+rs_[1]+rs_[2]+rs_[3];
    ss = rss_[0]+rss_[1]+rss_[2]+rss_[3];
    float mu = s / DIMM;
    float rstd = rsqrtf(ss / DIMM - mu*mu + 1e-5f);
    ys[t]     = (v0 - mu)*rstd*pg[t];
    ys[t+256] = (v1 - mu)*rstd*pg[t+256];
    __syncthreads();
    {
      int c4 = (t & 127) * 4;
      int kq = t >> 7;
      float ax=0.f, ay=0.f, az=0.f, aw=0.f;
      #pragma unroll 8
      for (int k = kq*256; k < kq*256 + 256; ++k){
        float yv = ys[k];
        float4 w4 = *(const float4*)(wq + (size_t)k*512 + c4);
        ax += yv*w4.x; ay += yv*w4.y; az += yv*w4.z; aw += yv*w4.w;
      }
      qred[kq][c4] = ax; qred[kq][c4+1] = ay; qred[kq][c4+2] = az; qred[kq][c4+3] = aw;
    }
    __syncthreads();
    q2l[t]     = (qred[0][t]     + qred[1][t])     * 0.125f;
    q2l[t+256] = (qred[0][t+256] + qred[1][t+256]) * 0.125f;
    __syncthreads();
    if (t < 128){
      int h = t >> 4, j = t & 15;
      const float* kr = kv + ((size_t)(b*NTOK + 768 + j))*1024 + h*64;
      float a = 0.f;
      #pragma unroll
      for (int d = 0; d < 64; ++d) a += q2l[h*64 + d] * kr[d];
      sm[h][j] = a;
    }
    __syncthreads();
    if (t < 8){
      float m = -3.4e38f;
      #pragma unroll
      for (int j = 0; j < 16; ++j) m = fmaxf(m, sm[t][j]);
      float e[16]; float s2 = 0.f;
      #pragma unroll
      for (int j = 0; j < 16; ++j){ e[j] = __expf(sm[t][j] - m); s2 += e[j]; }
      float inv = 1.0f / s2;
      #pragma unroll
      for (int j = 0; j < 16; ++j) pn[t][j] = e[j] * inv;
    }
    __syncthreads();
    {
      int c0 = t, c1 = t + 256;
      int h0 = c0 >> 6, h1 = c1 >> 6;
      float a0 = 0.f, a1 = 0.f;
      #pragma unroll
      for (int j = 0; j < 16; ++j){
        const float* vr = kv + ((size_t)(b*NTOK + 768 + j))*1024 + 512;
        a0 += pn[h0][j] * vr[c0];
        a1 += pn[h1][j] * vr[c1];
      }
      ys[c0] = a0; ys[c1] = a1;
    }
    __syncthreads();
  }

  {
    int c4l = (t & 15) * 4;
    int c4 = colchunk*64 + c4l;
    int kq = t >> 4;
    float ax=0.f, ay=0.f, az=0.f, aw=0.f;
    #pragma unroll 8
    for (int k = kq*32; k < kq*32 + 32; ++k){
      float yv = ys[k];
      float4 w4 = *(const float4*)(wo + (size_t)k*512 + c4);
      ax += yv*w4.x; ay += yv*w4.y; az += yv*w4.z; aw += yv*w4.w;
    }
    fred[kq][c4l] = ax; fred[kq][c4l+1] = ay; fred[kq][c4l+2] = az; fred[kq][c4l+3] = aw;
  }
  __syncthreads();
  if (t < 64){
    float a = 0.f;
    #pragma unroll
    for (int kq = 0; kq < 16; ++kq) a += fred[kq][t];
    int c = colchunk*64 + t;
    out[(size_t)br*DIMM + c] = a + rt[(size_t)r*DIMM + c];
  }
}

// =================================================================
extern "C" void kernel_launch(void* const* d_in, const int* in_sizes, int n_in,
                              void* d_out, int out_size, void* d_ws, size_t ws_size,
                              hipStream_t stream)
{
  const float* rna        = (const float*)d_in[0];
  const float* atac       = (const float*)d_in[1];
  const float* rna_ln1_g  = (const float*)d_in[2];
  const float* rna_ln1_b  = (const float*)d_in[3];
  const float* rna_w      = (const float*)d_in[4];
  const float* rna_b      = (const float*)d_in[5];
  const float* rna_ln2_g  = (const float*)d_in[6];
  const float* rna_ln2_b  = (const float*)d_in[7];
  const float* atac_ln1_g = (const float*)d_in[8];
  const float* atac_ln1_b = (const float*)d_in[9];
  const float* atac_w     = (const float*)d_in[10];
  const float* atac_b     = (const float*)d_in[11];
  const float* atac_ln2_g = (const float*)d_in[12];
  const float* atac_ln2_b = (const float*)d_in[13];
  const float* fusion_tok = (const float*)d_in[14];
  const float* lay_ag     = (const float*)d_in[15];
  const float* lay_wq     = (const float*)d_in[16];
  const float* lay_wkv    = (const float*)d_in[17];
  const float* lay_wo     = (const float*)d_in[18];
  const float* lay_fg     = (const float*)d_in[19];
  const float* lay_w1     = (const float*)d_in[20];
  const float* lay_w2     = (const float*)d_in[21];
  const float* final_g    = (const float*)d_in[22];
  const float* ret_tok    = (const float*)d_in[23];
  const float* pool_g     = (const float*)d_in[24];
  const float* pool_wq    = (const float*)d_in[25];
  const float* pool_wkv   = (const float*)d_in[26];
  const float* pool_wo    = (const float*)d_in[27];

  uint8_t* ws = (uint8_t*)d_ws;
  size_t off = 0;
  auto carve = [&](size_t bytes) -> uint8_t* {
    uint8_t* p = ws + off;
    off += (bytes + 255) & ~(size_t)255;
    return p;
  };
  // bf16 weights
  u16* rna_wt   = (u16*)carve((size_t)512*1024*2);
  u16* atac_wt  = (u16*)carve((size_t)512*1024*2);
  u16* wkvt     = (u16*)carve((size_t)4*1024*512*2);
  u16* wqt      = (u16*)carve((size_t)4*512*512*2);
  u16* wot      = (u16*)carve((size_t)4*512*512*2);
  u16* w1t      = (u16*)carve((size_t)4*NW1*512*2);
  u16* w2t      = (u16*)carve((size_t)4*512*GSTRIDE*2);
  u16* pool_wkvt= (u16*)carve((size_t)1024*512*2);
  // activations
  float* tok   = (float*)carve((size_t)MALL * DIMM * 4);
  u16*   xn    = (u16*)  carve((size_t)MALL * DIMM * 2);
  float* kv    = (float*)carve((size_t)MALL * 1024 * 4);
  u16*   lnbuf = (u16*)  carve((size_t)3072 * 1024 * 2);
  float* proj  = (float*)carve((size_t)BATCH*17*DIMM * 4);
  float* csum  = (float*)carve((size_t)BATCH*25*512 * 4);
  float* apart = (float*)carve((size_t)AZ*BATCH*8*16*68 * 4);
  u16*   gbuf  = (u16*)  carve((size_t)MALL * GSTRIDE * 2);
  float* skpart= (float*)carve((size_t)2 * MALL * 512 * 4);
  (void)ws_size;

  // ---- one-dispatch weight conversion ----
  convall<<<14080, 256, 0, stream>>>(rna_w, atac_w, lay_wkv, lay_wq, lay_wo, lay_w1, lay_w2, pool_wkv,
                                     rna_wt, atac_wt, wkvt, wqt, wot, w1t, w2t, pool_wkvt);

  // ---- embeddings (both modalities batched; layer-0 LN fused into tails) ----
  embed_ln1<<<3072, 256, 0, stream>>>(rna, atac, rna_ln1_g, rna_ln1_b, atac_ln1_g, atac_ln1_b, lnbuf);
  gemm512<<<dim3(24, 4, 2), 512, 0, stream>>>(lnbuf, 1024, rna_wt, atac_wt, 1536, 1024,
                                              skpart, 512, (size_t)3072*512, nullptr, nullptr,
                                              3072, 512, 1024, 512);
  embed_addln2<<<3072, 256, 0, stream>>>(skpart, rna_b, atac_b, rna_ln2_g, rna_ln2_b,
                                         atac_ln2_g, atac_ln2_b, lay_ag, tok, xn);
  fuscopy_ln<<<32, 256, 0, stream>>>(fusion_tok, lay_ag, tok, xn);

  // ---- transformer layers ----
  for (int l = 0; l < 4; ++l){
    const float* fg  = lay_fg + (size_t)l*DIMM;
    const float* gnext = (l < 3) ? (lay_ag + (size_t)(l+1)*DIMM) : final_g;
    const u16* wkvt_l = wkvt + (size_t)l*1024*512;
    const u16* wqt_l  = wqt  + (size_t)l*512*512;
    const u16* wot_l  = wot  + (size_t)l*512*512;
    const u16* w1t_l  = w1t  + (size_t)l*NW1*512;
    const u16* w2t_l  = w2t  + (size_t)l*512*GSTRIDE;

    gemm512<<<dim3(25, 8, 1), 512, 0, stream>>>(xn, 512, wkvt_l, nullptr, 0, 512,
                                                kv, 1024, 0, nullptr, csum, MALL, 1024, 512, 512);
    fused_attn<<<dim3(8, BATCH, 16*AZ), 256, 0, stream>>>(xn, wqt_l, kv, apart);
    attn_out<<<dim3(8, BATCH, 4), 256, 0, stream>>>(apart, csum, wot_l, proj);
    resadd_ffnln<<<dim3(NTOK, BATCH), 256, 0, stream>>>(tok, proj, fg, xn);
    gemm512<<<dim3(25, 22, 1), 512, 0, stream>>>(xn, 512, w1t_l, nullptr, 0, 512,
                                                 nullptr, 0, 0, gbuf, nullptr, MALL, NW1, 512, 512);
    gemm512<<<dim3(25, 4, 2), 512, 0, stream>>>(gbuf, GSTRIDE, w2t_l, nullptr, 0, GSTRIDE,
                                                skpart, 512, (size_t)MALL*512, nullptr, nullptr,
                                                MALL, 512, GSTRIDE, 704);
    skadd_ln<<<MALL, 256, 0, stream>>>(tok, skpart, gnext, xn);
  }

  // ---- pooling (xn holds final-LN tokens) ----
  gemm512<<<dim3(25, 8, 1), 512, 0, stream>>>(xn, 512, pool_wkvt, nullptr, 0, 512,
                                              kv, 1024, 0, nullptr, csum, MALL, 1024, 512, 512);
  pool_final<<<dim3(8, 6), 256, 0, stream>>>(csum, ret_tok, pool_g, pool_wq, kv, pool_wo,
                                             (float*)d_out);
}

// Round 13
// 525.528 us; speedup vs baseline: 6.2584x; 1.0287x over previous
//
#include <hip/hip_runtime.h>
#include <stdint.h>
#include <stddef.h>

#define NTOK 1552
#define DIMM 512
#define IFFC 1365
#define IFF2 2730
#define NW1 2816       // padded/permuted w1 output cols (2*1408)
#define GSTRIDE 1408   // geglu output row stride (bf16) = padded K of w2
#define BATCH 2
#define MALL (BATCH*NTOK)   // 3104
#define AZ 6           // attention j-chunks (256 keys each)
#define W2SK 3         // w2 splitK
#define EMSK 4         // embed splitK

typedef unsigned short u16;
typedef __attribute__((ext_vector_type(8))) short bf16x8;
typedef __attribute__((ext_vector_type(4))) float f32x4;

__device__ __forceinline__ u16 f2bf(float f){
  union { float f; uint32_t u; } v; v.f = f;
  uint32_t u = v.u;
  uint32_t r = (u + 0x7FFFu + ((u >> 16) & 1u)) >> 16;
  return (u16)r;
}
__device__ __forceinline__ float bf2f(u16 x){
  union { uint32_t u; float f; } v; v.u = ((uint32_t)x) << 16; return v.f;
}

// async global->LDS, 16B per lane; LDS dest is wave-uniform base (lane*16 implicit)
__device__ __forceinline__ void gload_lds16(const u16* g, u16* l){
  __builtin_amdgcn_global_load_lds((const __attribute__((address_space(1))) void*)g,
                                   (__attribute__((address_space(3))) void*)l, 16, 0, 0);
}

// ---------- prep: weight convert/transpose (blocks 0..14079) + embed LN1 (blocks 14080..17151) ----------
__global__ void prep_kernel(const float* s0,const float* s1,const float* s2,const float* s3,
                            const float* s4,const float* s5,const float* s6,const float* s7,
                            u16* d0,u16* d1,u16* d2,u16* d3,u16* d4,u16* d5,u16* d6,u16* d7,
                            const float* rna, const float* atac,
                            const float* g0e, const float* b0e,
                            const float* g1e, const float* b1e, u16* lnout)
{
  __shared__ float tile[32][33];
  __shared__ float rs_[4], rss_[4];
  int t = threadIdx.x;
  if (blockIdx.x >= 14080){
    // ---- embed LN1 path ----
    int r = blockIdx.x - 14080;
    const float* x; const float* g; const float* bb;
    if (r < 1536){ x = rna + (size_t)r*1024; g = g0e; bb = b0e; }
    else { x = atac + (size_t)(r-1536)*1024; g = g1e; bb = b1e; }
    float v0 = x[t], v1 = x[t+256], v2 = x[t+512], v3 = x[t+768];
    float s = v0+v1+v2+v3, ss = v0*v0+v1*v1+v2*v2+v3*v3;
    #pragma unroll
    for (int off = 32; off >= 1; off >>= 1){ s += __shfl_xor(s, off); ss += __shfl_xor(ss, off); }
    int w = t >> 6;
    if ((t & 63) == 0){ rs_[w] = s; rss_[w] = ss; }
    __syncthreads();
    s = rs_[0]+rs_[1]+rs_[2]+rs_[3];
    ss = rss_[0]+rss_[1]+rss_[2]+rss_[3];
    float mu = s / 1024.f;
    float rstd = rsqrtf(ss / 1024.f - mu*mu + 1e-5f);
    u16* o = lnout + (size_t)r*1024;
    o[t]     = f2bf((v0-mu)*rstd*g[t]     + bb[t]);
    o[t+256] = f2bf((v1-mu)*rstd*g[t+256] + bb[t+256]);
    o[t+512] = f2bf((v2-mu)*rstd*g[t+512] + bb[t+512]);
    o[t+768] = f2bf((v3-mu)*rstd*g[t+768] + bb[t+768]);
    return;
  }
  // ---- weight convert path ----
  const float* srcs[8] = {s0,s1,s2,s3,s4,s5,s6,s7};
  u16* dsts[8] = {d0,d1,d2,d3,d4,d5,d6,d7};
  const int KT[8]   = {32,32,16,16,16,16,44,16};
  const int NT[8]   = {16,16,32,16,16,88,16,32};
  const int TC[8]   = {512,512,2048,1024,1024,5632,2816,512};
  const int K_[8]   = {1024,1024,512,512,512,512,1365,512};
  const int NSRC[8] = {512,512,1024,512,512,2730,512,1024};
  const int LDK[8]  = {1024,1024,512,512,512,512,1408,512};
  const int NOUT[8] = {512,512,1024,512,512,2816,512,1024};
  const int WS_[8]  = {0,0,512*1024,512*512,512*512,512*2730,1365*512,0};
  const int WT_[8]  = {0,0,1024*512,512*512,512*512,2816*512,512*1408,0};

  int bid = blockIdx.x;
  int seg = 0, base = 0;
  while (seg < 7 && bid >= base + TC[seg]) { base += TC[seg]; ++seg; }
  int loc = bid - base;
  int kt = KT[seg];
  int z = loc / (kt*NT[seg]); loc -= z*(kt*NT[seg]);
  int kb = (loc % kt) * 32, nb = (loc / kt) * 32;
  const float* w = srcs[seg] + (size_t)z * WS_[seg];
  u16* wt = dsts[seg] + (size_t)z * WT_[seg];
  int K = K_[seg], NS = NSRC[seg], ldk = LDK[seg], NO = NOUT[seg];

  {
    int k = t >> 3, n4 = (t & 7) * 4;
    int gk = kb + k;
    float4 v = make_float4(0.f,0.f,0.f,0.f);
    if (gk < K){
      if (seg != 5){
        int gn = nb + n4;
        if (gn + 4 <= NS){
          v = *(const float4*)(w + (size_t)gk*NS + gn);
        } else {
          float* pv = (float*)&v;
          #pragma unroll
          for (int i = 0; i < 4; ++i){ int n = gn + i; if (n < NS) pv[i] = w[(size_t)gk*NS + n]; }
        }
      } else {
        float* pv = (float*)&v;
        #pragma unroll
        for (int i = 0; i < 4; ++i){
          int n = nb + n4 + i;
          if (n < NO){
            int bb = n >> 7, rr = n & 127, g = rr >> 5, hh = rr & 31;
            int j = bb*64 + g*16 + (hh & 15);
            if (j < 1365) pv[i] = w[(size_t)gk*NS + ((hh < 16) ? j : 1365 + j)];
          }
        }
      }
    }
    tile[k][n4] = v.x; tile[k][n4+1] = v.y; tile[k][n4+2] = v.z; tile[k][n4+3] = v.w;
  }
  __syncthreads();
  if (t < 128){
    int n = t >> 2, k8 = (t & 3) * 8;
    int gn = nb + n, gk = kb + k8;
    if (gn < NO && gk < ldk){
      u16 sh[8];
      #pragma unroll
      for (int i = 0; i < 8; ++i) sh[i] = f2bf(tile[k8+i][n]);
      *(bf16x8*)(wt + (size_t)gn*ldk + gk) = *(bf16x8*)sh;
    }
  }
}

// ---- batched embed: splitK(4) add + bias + LN2 -> tok + layer-0 attn-LN -> xn;
//      blocks 3072..3103 copy fusion tokens + their layer-0 LN ----
__global__ void embed_addln2(const float* __restrict__ part,
                             const float* __restrict__ rb, const float* __restrict__ ab,
                             const float* __restrict__ g0, const float* __restrict__ bt0,
                             const float* __restrict__ g1, const float* __restrict__ bt1,
                             const float* __restrict__ ag0, const float* __restrict__ ft,
                             float* __restrict__ tok, u16* __restrict__ xn)
{
  __shared__ float rs_[4], rss_[4];
  int t = threadIdx.x;
  int bid = blockIdx.x;
  if (bid >= 3072){
    // fusion-token path
    int idx = bid - 3072;
    int b = idx >> 4, rr = idx & 15;
    const float* x = ft + (size_t)rr*DIMM;
    float v0 = x[t], v1 = x[t+256];
    size_t row = (size_t)(b*NTOK + 768 + rr)*DIMM;
    tok[row + t] = v0; tok[row + t+256] = v1;
    float s = v0 + v1, ss = v0*v0 + v1*v1;
    #pragma unroll
    for (int off = 32; off >= 1; off >>= 1){ s += __shfl_xor(s, off); ss += __shfl_xor(ss, off); }
    int w = t >> 6;
    if ((t & 63) == 0){ rs_[w] = s; rss_[w] = ss; }
    __syncthreads();
    s = rs_[0]+rs_[1]+rs_[2]+rs_[3];
    ss = rss_[0]+rss_[1]+rss_[2]+rss_[3];
    float mu = s / DIMM;
    float rstd = rsqrtf(ss / DIMM - mu*mu + 1e-5f);
    xn[row + t]     = f2bf((v0 - mu)*rstd*ag0[t]);
    xn[row + t+256] = f2bf((v1 - mu)*rstd*ag0[t+256]);
    return;
  }
  int r = bid;                  // 0..3071
  int mod = (r >= 1536);
  int rl = mod ? r - 1536 : r;
  int b = rl / 768, rr = rl % 768;
  const float* bias = mod ? ab : rb;
  const float* g = mod ? g1 : g0;
  const float* bt = mod ? bt1 : bt0;
  const float* p0 = part + (size_t)r*DIMM;
  float v0 = bias[t], v1 = bias[t+256];
  #pragma unroll
  for (int z = 0; z < EMSK; ++z){
    const float* pz = p0 + (size_t)z*3072*DIMM;
    v0 += pz[t]; v1 += pz[t+256];
  }
  float s = v0 + v1, ss = v0*v0 + v1*v1;
  #pragma unroll
  for (int off = 32; off >= 1; off >>= 1){ s += __shfl_xor(s, off); ss += __shfl_xor(ss, off); }
  int w = t >> 6;
  if ((t & 63) == 0){ rs_[w] = s; rss_[w] = ss; }
  __syncthreads();
  s = rs_[0]+rs_[1]+rs_[2]+rs_[3];
  ss = rss_[0]+rss_[1]+rss_[2]+rss_[3];
  float mu = s / DIMM;
  float rstd = rsqrtf(ss / DIMM - mu*mu + 1e-5f);
  size_t row = (size_t)(b*NTOK + (mod ? 784 : 0) + rr)*DIMM;
  float t0 = (v0 - mu)*rstd*g[t]     + bt[t];
  float t1 = (v1 - mu)*rstd*g[t+256] + bt[t+256];
  tok[row + t] = t0; tok[row + t+256] = t1;
  float s2 = t0 + t1, ss2 = t0*t0 + t1*t1;
  #pragma unroll
  for (int off = 32; off >= 1; off >>= 1){ s2 += __shfl_xor(s2, off); ss2 += __shfl_xor(ss2, off); }
  __syncthreads();
  if ((t & 63) == 0){ rs_[w] = s2; rss_[w] = ss2; }
  __syncthreads();
  s2 = rs_[0]+rs_[1]+rs_[2]+rs_[3];
  ss2 = rss_[0]+rss_[1]+rss_[2]+rss_[3];
  float mu2 = s2 / DIMM;
  float rstd2 = rsqrtf(ss2 / DIMM - mu2*mu2 + 1e-5f);
  xn[row + t]     = f2bf((t0 - mu2)*rstd2*ag0[t]);
  xn[row + t+256] = f2bf((t1 - mu2)*rstd2*ag0[t+256]);
}

// ---- residual-add (attention proj, broadcast row0) + FFN LN -> tok, xn ----
__global__ void resadd_ffnln(float* __restrict__ tok, const float* __restrict__ proj,
                             const float* __restrict__ g, u16* __restrict__ xn)
{
  int n = blockIdx.x, b = blockIdx.y;
  int pr = (n >= 768 && n < 784) ? (1 + n - 768) : 0;
  const float* p = proj + ((size_t)b*17 + pr)*DIMM;
  size_t row = (size_t)(b*NTOK + n)*DIMM;
  int t = threadIdx.x;
  float v0 = tok[row + t]     + p[t];
  float v1 = tok[row + t+256] + p[t+256];
  tok[row + t] = v0; tok[row + t+256] = v1;
  float s = v0 + v1, ss = v0*v0 + v1*v1;
  #pragma unroll
  for (int off = 32; off >= 1; off >>= 1){ s += __shfl_xor(s, off); ss += __shfl_xor(ss, off); }
  __shared__ float rs_[4], rss_[4];
  int w = t >> 6;
  if ((t & 63) == 0){ rs_[w] = s; rss_[w] = ss; }
  __syncthreads();
  s = rs_[0]+rs_[1]+rs_[2]+rs_[3];
  ss = rss_[0]+rss_[1]+rss_[2]+rss_[3];
  float mu = s / DIMM;
  float rstd = rsqrtf(ss / DIMM - mu*mu + 1e-5f);
  xn[row + t]     = f2bf((v0 - mu)*rstd*g[t]);
  xn[row + t+256] = f2bf((v1 - mu)*rstd*g[t+256]);
}

// ---- splitK(3)-add (FFN out) + next LN -> tok, xn ----
__global__ void skadd_ln(float* __restrict__ tok, const float* __restrict__ part,
                         const float* __restrict__ g, u16* __restrict__ xn)
{
  int r = blockIdx.x;
  size_t row = (size_t)r*DIMM;
  int t = threadIdx.x;
  float v0 = tok[row + t], v1 = tok[row + t+256];
  #pragma unroll
  for (int z = 0; z < W2SK; ++z){
    const float* pz = part + (size_t)z*MALL*DIMM + row;
    v0 += pz[t]; v1 += pz[t+256];
  }
  tok[row + t] = v0; tok[row + t+256] = v1;
  float s = v0 + v1, ss = v0*v0 + v1*v1;
  #pragma unroll
  for (int off = 32; off >= 1; off >>= 1){ s += __shfl_xor(s, off); ss += __shfl_xor(ss, off); }
  __shared__ float rs_[4], rss_[4];
  int w = t >> 6;
  if ((t & 63) == 0){ rs_[w] = s; rss_[w] = ss; }
  __syncthreads();
  s = rs_[0]+rs_[1]+rs_[2]+rs_[3];
  ss = rss_[0]+rss_[1]+rss_[2]+rss_[3];
  float mu = s / DIMM;
  float rstd = rsqrtf(ss / DIMM - mu*mu + 1e-5f);
  xn[row + t]     = f2bf((v0 - mu)*rstd*g[t]);
  xn[row + t+256] = f2bf((v1 - mu)*rstd*g[t+256]);
}

// ------- gemm512: 8-wave 128x128; 2-phase double-buffered global_load_lds staging.
//         B bf16 [N][ldk]; optional B-switch at row mswitch; splitK via grid.z;
//         optional GEGLU epilogue; optional V-colsum. OOB clamped (outputs masked). -------
__global__ __launch_bounds__(512) void gemm512(
    const u16* __restrict__ A, int lda,
    const u16* __restrict__ Bt, const u16* __restrict__ BtB, int mswitch, int ldk,
    float* __restrict__ C, int ldc, size_t Cz,
    u16* __restrict__ gout, float* __restrict__ csum,
    int M, int Nn, int K, int kchunk)
{
  __shared__ __align__(16) u16 As_lin[2][128*32];
  __shared__ __align__(16) u16 Bs_lin[2][128*32];
  __shared__ float colsum[2][128];
  const int t = threadIdx.x;
  const int lane = t & 63;
  const int w = t >> 6;
  const int wr = (w >> 2) * 64;
  const int wc = (w & 3) * 32;
  const int row0 = blockIdx.x * 128, col0 = blockIdx.y * 128;
  if (BtB && row0 >= mswitch) Bt = BtB;
  const int z = blockIdx.z;
  const int kbeg = z * kchunk;
  const int kend = (kbeg + kchunk < K) ? (kbeg + kchunk) : K;
  C += (size_t)z * Cz;
  const int l15 = lane & 15;
  const int l4 = (lane >> 4) * 8;
  const int sr = t >> 2, sc8 = (t & 3) * 8;
  int gr_s = row0 + sr; if (gr_s >= M) gr_s = M - 1;
  int gc_s = col0 + sr; if (gc_s >= Nn) gc_s = Nn - 1;
  const u16* Ag = A + (size_t)gr_s*lda + sc8;
  const u16* Bg = Bt + (size_t)gc_s*ldk + sc8;
  const int wb = w * 512;

  f32x4 acc[4][2];
  #pragma unroll
  for (int m = 0; m < 4; ++m)
    #pragma unroll
    for (int n = 0; n < 2; ++n)
      #pragma unroll
      for (int j = 0; j < 4; ++j) acc[m][n][j] = 0.f;

  gload_lds16(Ag + kbeg, &As_lin[0][wb]);
  gload_lds16(Bg + kbeg, &Bs_lin[0][wb]);
  __syncthreads();

  int cur = 0;
  for (int k0 = kbeg; k0 < kend; k0 += 32) {
    int k1 = k0 + 32;
    if (k1 < kend){
      gload_lds16(Ag + k1, &As_lin[cur^1][wb]);
      gload_lds16(Bg + k1, &Bs_lin[cur^1][wb]);
    }
    const u16* Ar = &As_lin[cur][0];
    const u16* Br = &Bs_lin[cur][0];
    bf16x8 af[4], bfr[2];
    #pragma unroll
    for (int m = 0; m < 4; ++m) af[m]  = *(const bf16x8*)(&Ar[(wr + m*16 + l15)*32 + l4]);
    #pragma unroll
    for (int n = 0; n < 2; ++n) bfr[n] = *(const bf16x8*)(&Br[(wc + n*16 + l15)*32 + l4]);
    #pragma unroll
    for (int m = 0; m < 4; ++m)
      #pragma unroll
      for (int n = 0; n < 2; ++n)
        acc[m][n] = __builtin_amdgcn_mfma_f32_16x16x32_bf16(af[m], bfr[n], acc[m][n], 0, 0, 0);
    __syncthreads();
    cur ^= 1;
  }
  const int rb = (lane >> 4) * 4;
  if (gout){
    int jcol = (col0 >> 1) + (w & 3)*16 + l15;
    #pragma unroll
    for (int m = 0; m < 4; ++m){
      int gr0 = row0 + wr + m*16 + rb;
      #pragma unroll
      for (int j = 0; j < 4; ++j){
        int gr = gr0 + j;
        if (gr < M){
          float gt = acc[m][1][j];
          float ge = 0.5f * gt * (1.0f + erff(gt * 0.70710678118654752f));
          gout[(size_t)gr*GSTRIDE + jcol] = f2bf(ge * acc[m][0][j]);
        }
      }
    }
  } else {
    #pragma unroll
    for (int m = 0; m < 4; ++m){
      int gr0 = row0 + wr + m*16 + rb;
      #pragma unroll
      for (int n = 0; n < 2; ++n){
        int gc = col0 + wc + n*16 + l15;
        if (gc >= Nn) continue;
        #pragma unroll
        for (int j = 0; j < 4; ++j){
          int gr = gr0 + j;
          if (gr < M) C[(size_t)gr*ldc + gc] = acc[m][n][j];
        }
      }
    }
  }
  if (csum && col0 >= 512){
    if (t < 256) colsum[t>>7][t&127] = 0.f;
    __syncthreads();
    #pragma unroll
    for (int n = 0; n < 2; ++n){
      float lv0 = 0.f, lv1 = 0.f;
      #pragma unroll
      for (int m = 0; m < 4; ++m){
        int gr0 = row0 + wr + m*16 + rb;
        #pragma unroll
        for (int j = 0; j < 4; ++j){
          float v = acc[m][n][j];
          if (gr0 + j < NTOK) lv0 += v; else lv1 += v;
        }
      }
      int lc = wc + n*16 + l15;
      atomicAdd(&colsum[0][lc], lv0);
      atomicAdd(&colsum[1][lc], lv1);
    }
    __syncthreads();
    if (t < 256){
      int bb = t>>7, c = t&127;
      csum[((size_t)(bb*25) + blockIdx.x)*512 + (col0 - 512) + c] = colsum[bb][c];
    }
  }
}

// ------- fused attention, flash-split: one block per (h, b, qi, jz); 256 keys/block -------
__global__ __launch_bounds__(256) void fused_attn(
    const u16* __restrict__ xn, const u16* __restrict__ wqt,
    const float* __restrict__ kv, float* __restrict__ apart)
{
  int h = blockIdx.x, b = blockIdx.y;
  int qi = blockIdx.z / AZ, jz = blockIdx.z % AZ;
  int t = threadIdx.x;
  int lane = t & 63, wid = t >> 6;
  __shared__ float xs[512];
  __shared__ float qs[64];
  __shared__ float pl[256];
  __shared__ float red[4][64];
  __shared__ float redm[4];

  {
    int row = b*NTOK + 768 + qi;
    const u16* xr = xn + (size_t)row*DIMM;
    xs[t] = bf2f(xr[t]);
    xs[t+256] = bf2f(xr[t+256]);
  }
  __syncthreads();

  {
    const u16* wrr = wqt + (size_t)(h*64 + lane)*DIMM + wid*128;
    float a = 0.f;
    #pragma unroll
    for (int k = 0; k < 128; k += 8){
      bf16x8 wv = *(const bf16x8*)(wrr + k);
      int kb = wid*128 + k;
      #pragma unroll
      for (int i = 0; i < 8; ++i) a += xs[kb+i] * bf2f((u16)wv[i]);
    }
    red[wid][lane] = a;
  }
  __syncthreads();
  if (t < 64) qs[t] = (red[0][t] + red[1][t] + red[2][t] + red[3][t]) * 0.125f;
  __syncthreads();

  int jj = jz*256 + t;
  int j = (jj < 768) ? jj : jj + 16;
  float a = 0.f;
  {
    const float* kr = kv + ((size_t)(b*NTOK + j))*1024 + h*64;
    #pragma unroll
    for (int d = 0; d < 64; d += 4){
      float4 kd = *(const float4*)(kr + d);
      a += qs[d]*kd.x + qs[d+1]*kd.y + qs[d+2]*kd.z + qs[d+3]*kd.w;
    }
  }

  float m = a;
  #pragma unroll
  for (int off = 32; off >= 1; off >>= 1) m = fmaxf(m, __shfl_xor(m, off));
  if (lane == 0) redm[wid] = m;
  __syncthreads();
  m = fmaxf(fmaxf(redm[0], redm[1]), fmaxf(redm[2], redm[3]));
  float p = __expf(a - m);
  pl[t] = p;
  float sq = p;
  #pragma unroll
  for (int off = 32; off >= 1; off >>= 1) sq += __shfl_xor(sq, off);
  if (lane == 0) redm[wid] = sq;
  __syncthreads();

  {
    int j0 = wid * 64;
    const float* vb = kv + ((size_t)(b*NTOK + jz*256 + j0 + ((jz*256 + j0 >= 768) ? 16 : 0)))*1024
                      + 512 + h*64 + lane;
    float a0=0.f, a1=0.f, a2=0.f, a3=0.f;
    #pragma unroll 4
    for (int i = 0; i < 64; i += 4){
      const float* vp = vb + (size_t)i*1024;
      a0 += pl[j0+i]   * vp[0];
      a1 += pl[j0+i+1] * vp[1024];
      a2 += pl[j0+i+2] * vp[2048];
      a3 += pl[j0+i+3] * vp[3072];
    }
    red[wid][lane] = a0+a1+a2+a3;
  }
  __syncthreads();
  float* po = apart + ((((size_t)jz*BATCH + b)*8 + h)*16 + qi) * 68;
  if (t < 64) po[t] = red[0][t] + red[1][t] + red[2][t] + red[3][t];
  else if (t == 64) po[64] = m;
  else if (t == 65) po[65] = redm[0] + redm[1] + redm[2] + redm[3];
}

// ------- attn_out: merge flash partials + colmean row + wo-projection, fused -------
__global__ __launch_bounds__(256) void attn_out(
    const float* __restrict__ apart, const float* __restrict__ csum,
    const u16* __restrict__ wot, float* __restrict__ proj)
{
  int colchunk = blockIdx.x;
  int b = blockIdx.y;
  int rg = blockIdx.z;
  int r0 = (rg == 0) ? 0 : (1 + 4*rg);
  int nr = (rg == 0) ? 5 : 4;
  __shared__ float zbl[5][512];
  __shared__ float red[4][64];
  int t = threadIdx.x;

  for (int rr = 0; rr < nr; ++rr){
    int r = r0 + rr;
    if (r == 0){
      for (int c = t; c < 512; c += 256){
        float s = 0.f;
        #pragma unroll
        for (int bx = 0; bx < 25; ++bx) s += csum[((size_t)(b*25)+bx)*512 + c];
        zbl[rr][c] = s * (1.0f/1552.0f);
      }
    } else {
      int qi = r - 1;
      for (int c = t; c < 512; c += 256){
        int h = c >> 6, d = c & 63;
        size_t base = ((size_t)b*8 + h)*16 + qi;
        float mz[AZ], sz[AZ];
        float M = -3.4e38f;
        #pragma unroll
        for (int z = 0; z < AZ; ++z){
          const float* po = apart + ((size_t)z*BATCH*8*16 + base)*68;
          mz[z] = po[64]; sz[z] = po[65];
          M = fmaxf(M, mz[z]);
        }
        float S = 0.f, O = 0.f;
        #pragma unroll
        for (int z = 0; z < AZ; ++z){
          const float* po = apart + ((size_t)z*BATCH*8*16 + base)*68;
          float wz = __expf(mz[z] - M);
          S += sz[z]*wz; O += po[d]*wz;
        }
        zbl[rr][c] = O / S;
      }
    }
  }
  __syncthreads();

  int col = colchunk*64 + (t & 63);
  int kq = t >> 6;
  const u16* wrow = wot + (size_t)col*512 + kq*128;
  for (int rr = 0; rr < nr; ++rr){
    float a = 0.f;
    #pragma unroll
    for (int k = 0; k < 128; k += 8){
      bf16x8 wv = *(const bf16x8*)(wrow + k);
      #pragma unroll
      for (int i = 0; i < 8; ++i) a += zbl[rr][kq*128 + k + i] * bf2f((u16)wv[i]);
    }
    red[kq][t & 63] = a;
    __syncthreads();
    if (t < 64)
      proj[((size_t)(b*17) + r0 + rr)*DIMM + colchunk*64 + t] =
        red[0][t] + red[1][t] + red[2][t] + red[3][t];
    __syncthreads();
  }
}

// ------- pool_final: csum->mv, LN+q2, 16-key attention, wo-matvec + residual, fused -------
__global__ __launch_bounds__(256) void pool_final(
    const float* __restrict__ csum, const float* __restrict__ rt,
    const float* __restrict__ pg, const float* __restrict__ wq,
    const float* __restrict__ kv, const float* __restrict__ wo,
    float* __restrict__ out)
{
  int colchunk = blockIdx.x;
  int br = blockIdx.y; int b = br/3, r = br%3;
  __shared__ float ys[512];
  __shared__ float q2l[512];
  __shared__ float qred[2][512];
  __shared__ float fred[16][64];
  __shared__ float sm[8][16];
  __shared__ float pn[8][16];
  __shared__ float rs_[4], rss_[4];
  int t = threadIdx.x;

  if (r < 2){
    float a0 = 0.f, a1 = 0.f;
    #pragma unroll
    for (int bx = 0; bx < 25; ++bx){
      a0 += csum[((size_t)(b*25)+bx)*512 + t];
      a1 += csum[((size_t)(b*25)+bx)*512 + t + 256];
    }
    ys[t] = a0 * (1.0f/1552.0f);
    ys[t+256] = a1 * (1.0f/1552.0f);
    __syncthreads();
  } else {
    const float* x = rt + 2*DIMM;
    float v0 = x[t], v1 = x[t+256];
    float s = v0 + v1, ss = v0*v0 + v1*v1;
    #pragma unroll
    for (int off = 32; off >= 1; off >>= 1){ s += __shfl_xor(s, off); ss += __shfl_xor(ss, off); }
    int w = t >> 6;
    if ((t & 63) == 0){ rs_[w] = s; rss_[w] = ss; }
    __syncthreads();
    s = rs_[0]+rs_[1]+rs_[2]+rs_[3];
    ss = rss_[0]+rss_[1]+rss_[2]+rss_[3];
    float mu = s / DIMM;
    float rstd = rsqrtf(ss / DIMM - mu*mu + 1e-5f);
    ys[t]     = (v0 - mu)*rstd*pg[t];
    ys[t+256] = (v1 - mu)*rstd*pg[t+256];
    __syncthreads();
    {
      int c4 = (t & 127) * 4;
      int kq = t >> 7;
      float ax=0.f, ay=0.f, az=0.f, aw=0.f;
      #pragma unroll 8
      for (int k = kq*256; k < kq*256 + 256; ++k){
        float yv = ys[k];
        float4 w4 = *(const float4*)(wq + (size_t)k*512 + c4);
        ax += yv*w4.x; ay += yv*w4.y; az += yv*w4.z; aw += yv*w4.w;
      }
      qred[kq][c4] = ax; qred[kq][c4+1] = ay; qred[kq][c4+2] = az; qred[kq][c4+3] = aw;
    }
    __syncthreads();
    q2l[t]     = (qred[0][t]     + qred[1][t])     * 0.125f;
    q2l[t+256] = (qred[0][t+256] + qred[1][t+256]) * 0.125f;
    __syncthreads();
    if (t < 128){
      int h = t >> 4, j = t & 15;
      const float* kr = kv + ((size_t)(b*NTOK + 768 + j))*1024 + h*64;
      float a = 0.f;
      #pragma unroll
      for (int d = 0; d < 64; ++d) a += q2l[h*64 + d] * kr[d];
      sm[h][j] = a;
    }
    __syncthreads();
    if (t < 8){
      float m = -3.4e38f;
      #pragma unroll
      for (int j = 0; j < 16; ++j) m = fmaxf(m, sm[t][j]);
      float e[16]; float s2 = 0.f;
      #pragma unroll
      for (int j = 0; j < 16; ++j){ e[j] = __expf(sm[t][j] - m); s2 += e[j]; }
      float inv = 1.0f / s2;
      #pragma unroll
      for (int j = 0; j < 16; ++j) pn[t][j] = e[j] * inv;
    }
    __syncthreads();
    {
      int c0 = t, c1 = t + 256;
      int h0 = c0 >> 6, h1 = c1 >> 6;
      float a0 = 0.f, a1 = 0.f;
      #pragma unroll
      for (int j = 0; j < 16; ++j){
        const float* vr = kv + ((size_t)(b*NTOK + 768 + j))*1024 + 512;
        a0 += pn[h0][j] * vr[c0];
        a1 += pn[h1][j] * vr[c1];
      }
      ys[c0] = a0; ys[c1] = a1;
    }
    __syncthreads();
  }

  {
    int c4l = (t & 15) * 4;
    int c4 = colchunk*64 + c4l;
    int kq = t >> 4;
    float ax=0.f, ay=0.f, az=0.f, aw=0.f;
    #pragma unroll 8
    for (int k = kq*32; k < kq*32 + 32; ++k){
      float yv = ys[k];
      float4 w4 = *(const float4*)(wo + (size_t)k*512 + c4);
      ax += yv*w4.x; ay += yv*w4.y; az += yv*w4.z; aw += yv*w4.w;
    }
    fred[kq][c4l] = ax; fred[kq][c4l+1] = ay; fred[kq][c4l+2] = az; fred[kq][c4l+3] = aw;
  }
  __syncthreads();
  if (t < 64){
    float a = 0.f;
    #pragma unroll
    for (int kq = 0; kq < 16; ++kq) a += fred[kq][t];
    int c = colchunk*64 + t;
    out[(size_t)br*DIMM + c] = a + rt[(size_t)r*DIMM + c];
  }
}

// =================================================================
extern "C" void kernel_launch(void* const* d_in, const int* in_sizes, int n_in,
                              void* d_out, int out_size, void* d_ws, size_t ws_size,
                              hipStream_t stream)
{
  const float* rna        = (const float*)d_in[0];
  const float* atac       = (const float*)d_in[1];
  const float* rna_ln1_g  = (const float*)d_in[2];
  const float* rna_ln1_b  = (const float*)d_in[3];
  const float* rna_w      = (const float*)d_in[4];
  const float* rna_b      = (const float*)d_in[5];
  const float* rna_ln2_g  = (const float*)d_in[6];
  const float* rna_ln2_b  = (const float*)d_in[7];
  const float* atac_ln1_g = (const float*)d_in[8];
  const float* atac_ln1_b = (const float*)d_in[9];
  const float* atac_w     = (const float*)d_in[10];
  const float* atac_b     = (const float*)d_in[11];
  const float* atac_ln2_g = (const float*)d_in[12];
  const float* atac_ln2_b = (const float*)d_in[13];
  const float* fusion_tok = (const float*)d_in[14];
  const float* lay_ag     = (const float*)d_in[15];
  const float* lay_wq     = (const float*)d_in[16];
  const float* lay_wkv    = (const float*)d_in[17];
  const float* lay_wo     = (const float*)d_in[18];
  const float* lay_fg     = (const float*)d_in[19];
  const float* lay_w1     = (const float*)d_in[20];
  const float* lay_w2     = (const float*)d_in[21];
  const float* final_g    = (const float*)d_in[22];
  const float* ret_tok    = (const float*)d_in[23];
  const float* pool_g     = (const float*)d_in[24];
  const float* pool_wq    = (const float*)d_in[25];
  const float* pool_wkv   = (const float*)d_in[26];
  const float* pool_wo    = (const float*)d_in[27];

  uint8_t* ws = (uint8_t*)d_ws;
  size_t off = 0;
  auto carve = [&](size_t bytes) -> uint8_t* {
    uint8_t* p = ws + off;
    off += (bytes + 255) & ~(size_t)255;
    return p;
  };
  // bf16 weights
  u16* rna_wt   = (u16*)carve((size_t)512*1024*2);
  u16* atac_wt  = (u16*)carve((size_t)512*1024*2);
  u16* wkvt     = (u16*)carve((size_t)4*1024*512*2);
  u16* wqt      = (u16*)carve((size_t)4*512*512*2);
  u16* wot      = (u16*)carve((size_t)4*512*512*2);
  u16* w1t      = (u16*)carve((size_t)4*NW1*512*2);
  u16* w2t      = (u16*)carve((size_t)4*512*GSTRIDE*2);
  u16* pool_wkvt= (u16*)carve((size_t)1024*512*2);
  // activations
  float* tok   = (float*)carve((size_t)MALL * DIMM * 4);
  u16*   xn    = (u16*)  carve((size_t)MALL * DIMM * 2);
  float* kv    = (float*)carve((size_t)MALL * 1024 * 4);
  u16*   lnbuf = (u16*)  carve((size_t)3072 * 1024 * 2);
  float* proj  = (float*)carve((size_t)BATCH*17*DIMM * 4);
  float* csum  = (float*)carve((size_t)BATCH*25*512 * 4);
  float* apart = (float*)carve((size_t)AZ*BATCH*8*16*68 * 4);
  u16*   gbuf  = (u16*)  carve((size_t)MALL * GSTRIDE * 2);
  size_t skelems = (size_t)EMSK*3072*512;          // >= W2SK*MALL*512
  float* skpart= (float*)carve(skelems * 4);
  (void)ws_size;

  // ---- prep: weight conversion + embed LN1 (one dispatch) ----
  prep_kernel<<<14080 + 3072, 256, 0, stream>>>(
      rna_w, atac_w, lay_wkv, lay_wq, lay_wo, lay_w1, lay_w2, pool_wkv,
      rna_wt, atac_wt, wkvt, wqt, wot, w1t, w2t, pool_wkvt,
      rna, atac, rna_ln1_g, rna_ln1_b, atac_ln1_g, atac_ln1_b, lnbuf);

  // ---- embed GEMM (splitK 4) + addln2 (incl. fusion tokens + layer-0 LN) ----
  gemm512<<<dim3(24, 4, EMSK), 512, 0, stream>>>(lnbuf, 1024, rna_wt, atac_wt, 1536, 1024,
                                                 skpart, 512, (size_t)3072*512, nullptr, nullptr,
                                                 3072, 512, 1024, 1024/EMSK);
  embed_addln2<<<3104, 256, 0, stream>>>(skpart, rna_b, atac_b, rna_ln2_g, rna_ln2_b,
                                         atac_ln2_g, atac_ln2_b, lay_ag, fusion_tok, tok, xn);

  // ---- transformer layers ----
  for (int l = 0; l < 4; ++l){
    const float* fg  = lay_fg + (size_t)l*DIMM;
    const float* gnext = (l < 3) ? (lay_ag + (size_t)(l+1)*DIMM) : final_g;
    const u16* wkvt_l = wkvt + (size_t)l*1024*512;
    const u16* wqt_l  = wqt  + (size_t)l*512*512;
    const u16* wot_l  = wot  + (size_t)l*512*512;
    const u16* w1t_l  = w1t  + (size_t)l*NW1*512;
    const u16* w2t_l  = w2t  + (size_t)l*512*GSTRIDE;

    gemm512<<<dim3(25, 8, 1), 512, 0, stream>>>(xn, 512, wkvt_l, nullptr, 0, 512,
                                                kv, 1024, 0, nullptr, csum, MALL, 1024, 512, 512);
    fused_attn<<<dim3(8, BATCH, 16*AZ), 256, 0, stream>>>(xn, wqt_l, kv, apart);
    attn_out<<<dim3(8, BATCH, 4), 256, 0, stream>>>(apart, csum, wot_l, proj);
    resadd_ffnln<<<dim3(NTOK, BATCH), 256, 0, stream>>>(tok, proj, fg, xn);
    gemm512<<<dim3(25, 22, 1), 512, 0, stream>>>(xn, 512, w1t_l, nullptr, 0, 512,
                                                 nullptr, 0, 0, gbuf, nullptr, MALL, NW1, 512, 512);
    gemm512<<<dim3(25, 4, W2SK), 512, 0, stream>>>(gbuf, GSTRIDE, w2t_l, nullptr, 0, GSTRIDE,
                                                   skpart, 512, (size_t)MALL*512, nullptr, nullptr,
                                                   MALL, 512, GSTRIDE, 480);
    skadd_ln<<<MALL, 256, 0, stream>>>(tok, skpart, gnext, xn);
  }

  // ---- pooling (xn holds final-LN tokens) ----
  gemm512<<<dim3(25, 8, 1), 512, 0, stream>>>(xn, 512, pool_wkvt, nullptr, 0, 512,
                                              kv, 1024, 0, nullptr, csum, MALL, 1024, 512, 512);
  pool_final<<<dim3(8, 6), 256, 0, stream>>>(csum, ret_tok, pool_g, pool_wq, kv, pool_wo,
                                             (float*)d_out);
}